// Round 1
// baseline (4420.086 us; speedup 1.0000x reference)
//
#include <hip/hip_runtime.h>
#include <hip/hip_bf16.h>
#include <float.h>
#include <math.h>

typedef __hip_bfloat16 bf16;

#define BATCH 32
#define NPTS  1024
#define KNN   20
#define NB    (BATCH*NPTS)      // 32768 nodes
#define NEDGE (NB*KNN)          // 655360 edges

// ---- workspace layout (float units), ws_size-adaptive ----
#define OFF_FLAG 512u
#define OFF_INB  1024u
#define OFF_IDX  988928u          // 655360 ints (idx1 early, idx2 late)
#define OFF_X1   1644288u         // NB*64
#define OFF_X2   3741440u         // NB*128 ; a1 @ OFF_X2, c1 @ OFF_C1 (early)
#define OFF_C1   5838592u
#define OFF_POOL 7935744u         // pool4: 4 x 32*1024
#define SLOW_END 8066816u         // 32.3 MB
#define OFF_B2H  8066816u         // NB*64 (fast path only)
#define FAST_END 10163968u        // 40.7 MB
// ---- layout inside inb (canonical fp32 inputs) ----
#define IN_POSF 0u
#define IN_B1   98304u
#define IN_G1   98368u
#define IN_BE1  98432u
#define IN_B2   98496u
#define IN_G2   98560u
#define IN_BE2  98624u
#define IN_B3   98688u
#define IN_BC2  98752u
#define IN_BL   98880u
#define IN_BM1  99904u
#define IN_BM2  100416u
#define IN_BM3  100672u
#define IN_W1   100736u
#define IN_WBUF 101120u
#define WB_W2   0u
#define WB_W3   4096u
#define WB_WD   8192u            // Wc2 top-bot diff [64x128]
#define WB_WBOT 16384u           // Wc2 bottom      [64x128]
#define WB_WL   24576u
#define WB_WM1  221184u
#define WB_WM2  745472u
#define WB_WM3  876544u
#define IN_TOTAL 987904u

__device__ __forceinline__ float bf2f(bf16 v){ return __bfloat162float(v); }

// ---------------- branchless register top-k insert (static indices only) ----------------
// Exactly equivalent to: if (d < rd[19]) { p=19; while(p>0 && rd[p-1] > d) shift; place }
// (strict >, so ties keep the earlier-seen / lower-index candidate -> matches top_k)
__device__ __forceinline__ void ins_plain(float d, int ci, float* rd, int* ri){
  bool gt[KNN];
  #pragma unroll
  for (int p = 0; p < KNN; p++) gt[p] = rd[p] > d;
  #pragma unroll
  for (int p = KNN-1; p > 0; p--){
    rd[p] = gt[p] ? (gt[p-1] ? rd[p-1] : d)  : rd[p];
    ri[p] = gt[p] ? (gt[p-1] ? ri[p-1] : ci) : ri[p];
  }
  rd[0] = gt[0] ? d  : rd[0];
  ri[0] = gt[0] ? ci : ri[0];
}

// Lexicographic (d, idx) comparator for cross-slot merge (matches original merge).
__device__ __forceinline__ void ins_lex(float d, int ci, float* rd, int* ri){
  bool gt[KNN];
  #pragma unroll
  for (int p = 0; p < KNN; p++)
    gt[p] = (rd[p] > d) || ((rd[p] == d) && (ri[p] > ci));
  #pragma unroll
  for (int p = KNN-1; p > 0; p--){
    rd[p] = gt[p] ? (gt[p-1] ? rd[p-1] : d)  : rd[p];
    ri[p] = gt[p] ? (gt[p-1] ? ri[p-1] : ci) : ri[p];
  }
  rd[0] = gt[0] ? d  : rd[0];
  ri[0] = gt[0] ? ci : ri[0];
}

// ---------------- dtype sniff (fp32 vs bf16 inputs) ----------------
__global__ void k_sniff(const void* pos_raw, int* flag){
  if (blockIdx.x == 0 && threadIdx.x == 0){
    const unsigned short* h = (const unsigned short*)pos_raw;
    int wild = 0;
    for (int k = 0; k < 16; k++){
      unsigned int bits = ((unsigned int)h[2*k]) << 16;
      float v = __uint_as_float(bits);
      float a = fabsf(v);
      if (a != 0.0f && (v != v || a > 1e10f || a < 1e-10f)) wild++;
    }
    *flag = (wild >= 4) ? 1 : 0;
  }
}

__device__ __forceinline__ float rdv(const void* p, int i, int f){
  return f ? ((const float*)p)[i] : bf2f(((const bf16*)p)[i]);
}

// ---------------- normalize ALL inputs to canonical fp32 buffer ----------------
__global__ __launch_bounds__(256) void k_cvt(
    const void* pos, const void* W1, const void* b1, const void* g1, const void* be1,
    const void* W2, const void* b2, const void* g2, const void* be2,
    const void* W3, const void* b3, const void* Wc2, const void* bc2,
    const void* Wl, const void* bl, const void* Wm1, const void* bm1,
    const void* Wm2, const void* bm2, const void* Wm3, const void* bm3,
    const int* flag, float* inb){
  int id = blockIdx.x*256 + threadIdx.x;
  if (id >= (int)IN_TOTAL) return;
  int f = *flag;
  float v;
  if      (id < 98304)  v = rdv(pos, id, f);
  else if (id < 98368)  v = rdv(b1,  id-98304, f);
  else if (id < 98432)  v = rdv(g1,  id-98368, f);
  else if (id < 98496)  v = rdv(be1, id-98432, f);
  else if (id < 98560)  v = rdv(b2,  id-98496, f);
  else if (id < 98624)  v = rdv(g2,  id-98560, f);
  else if (id < 98688)  v = rdv(be2, id-98624, f);
  else if (id < 98752)  v = rdv(b3,  id-98688, f);
  else if (id < 98880)  v = rdv(bc2, id-98752, f);
  else if (id < 99904)  v = rdv(bl,  id-98880, f);
  else if (id < 100416) v = rdv(bm1, id-99904, f);
  else if (id < 100672) v = rdv(bm2, id-100416, f);
  else if (id < 100712) v = rdv(bm3, id-100672, f);
  else if (id < 100736) v = 0.0f;
  else if (id < 101120) v = rdv(W1,  id-100736, f);
  else {
    int t = id - 101120;
    if      (t < 4096)   v = rdv(W2, t, f);
    else if (t < 8192)   v = rdv(W3, t-4096, f);
    else if (t < 16384){ int u = t-8192;  v = rdv(Wc2, u, f) - rdv(Wc2, 8192+u, f); }
    else if (t < 24576){ int u = t-16384; v = rdv(Wc2, 8192+u, f); }
    else if (t < 221184) v = rdv(Wl,  t-24576, f);
    else if (t < 745472) v = rdv(Wm1, t-221184, f);
    else if (t < 876544) v = rdv(Wm2, t-745472, f);
    else                 v = rdv(Wm3, t-876544, f);
  }
  inb[id] = v;
}

// ---------------- a1/c1: affine decomposition of EdgeConv1 layer1 ----------------
__global__ __launch_bounds__(256) void k_prep1(const float* inb, float* a1, float* c1){
  const float* posf = inb + IN_POSF;
  const float* W1f  = inb + IN_W1;
  const float* b1f  = inb + IN_B1;
  int id = blockIdx.x*256 + threadIdx.x;
  int bn = id >> 6, c = id & 63;
  float p0 = posf[bn*3], p1 = posf[bn*3+1], p2 = posf[bn*3+2];
  float wt0 = W1f[c],     wt1 = W1f[64+c],  wt2 = W1f[128+c];
  float wb0 = W1f[192+c], wb1 = W1f[256+c], wb2 = W1f[320+c];
  float cv = p0*wb0 + p1*wb1 + p2*wb2;
  float av = p0*(wt0-wb0) + p1*(wt1-wb1) + p2*(wt2-wb2) + b1f[c];
  a1[id] = av;  c1[id] = cv;
}

// ---------------- kNN in coordinate space (register top-k, branchless insert) ----------------
__global__ __launch_bounds__(256, 3) void k_knn1(const float* inb, int* idx1){
  const float* posf = inb + IN_POSF;
  __shared__ float psx[1024], psy[1024], psz[1024], sqs[1024];
  __shared__ float dls[256*21];
  __shared__ unsigned short ils[256*21];
  int bb = blockIdx.x >> 4;
  int qg = blockIdx.x & 15;
  int tid = threadIdx.x;
  int q_l = tid & 63;
  int slot = tid >> 6;
  for (int t = tid; t < 1024; t += 256){
    float x = posf[(bb*1024+t)*3], y = posf[(bb*1024+t)*3+1], z = posf[(bb*1024+t)*3+2];
    psx[t] = x; psy[t] = y; psz[t] = z; sqs[t] = x*x + y*y + z*z;
  }
  __syncthreads();
  int i_l = qg*64 + q_l;
  float xi0 = psx[i_l], xi1 = psy[i_l], xi2 = psz[i_l];
  float sqi = sqs[i_l];
  float rd[KNN]; int ri[KNN];
  #pragma unroll
  for (int p = 0; p < KNN; p++){ rd[p] = FLT_MAX; ri[p] = 65535; }
  // ascending jj per slot -> ties keep lower idx (matches top_k)
  for (int u = 0; u < 256; u++){
    int jj = 4*u + slot;
    float dot = xi0*psx[jj] + xi1*psy[jj] + xi2*psz[jj];
    float d = sqi + sqs[jj] - 2.0f*dot;
    ins_plain(d, jj, rd, ri);
  }
  // slots 1..3 publish their lists; slot 0 merges in registers
  int base = tid*21;
  if (slot != 0){
    #pragma unroll
    for (int p = 0; p < KNN; p++){ dls[base+p] = rd[p]; ils[base+p] = (unsigned short)ri[p]; }
  }
  __syncthreads();
  if (slot == 0){
    for (int s = 1; s < 4; s++){
      int sb = (s*64 + q_l)*21;
      float cd[KNN]; int cii[KNN];
      #pragma unroll
      for (int p = 0; p < KNN; p++){ cd[p] = dls[sb+p]; cii[p] = (int)ils[sb+p]; }
      #pragma unroll
      for (int p = 0; p < KNN; p++) ins_lex(cd[p], cii[p], rd, ri);
    }
    int gi = bb*1024 + i_l;
    #pragma unroll
    for (int p = 0; p < KNN; p++) idx1[gi*KNN+p] = ri[p];
  }
}

// ---------------- BN1 stats ----------------
__global__ __launch_bounds__(256) void k_stats1(const float* a1, const float* c1,
                                                const int* idx1, double* stats){
  __shared__ float rs[256], rs2[256];
  int tid = threadIdx.x, c = tid & 63, slot = tid >> 6;
  int base = blockIdx.x * 1024;
  float s = 0.f, s2 = 0.f;
  for (int t = 0; t < 256; t++){
    unsigned e = (unsigned)(base + t*4 + slot);
    int i = (int)(e / 20u);
    int b = i >> 10;
    int j = idx1[e];
    float h = a1[i*64+c] + c1[((b<<10)+j)*64 + c];
    s += h; s2 += h*h;
  }
  rs[tid] = s; rs2[tid] = s2;
  __syncthreads();
  if (slot == 0){
    double ts  = (double)rs[c]  + (double)rs[64+c]  + (double)rs[128+c]  + (double)rs[192+c];
    double ts2 = (double)rs2[c] + (double)rs2[64+c] + (double)rs2[128+c] + (double)rs2[192+c];
    atomicAdd(&stats[c], ts);
    atomicAdd(&stats[64+c], ts2);
  }
}

// ---------------- BN2 stats (slot-stride 68: bank-conflict-free) ----------------
__global__ __launch_bounds__(256) void k_stats2(const float* a1, const float* c1,
    const int* idx1, const float* inb, double* stats){
  __shared__ __align__(16) float W2s[4096];
  __shared__ __align__(16) float buf[16*68];
  __shared__ float rs[64], rs2[64];
  int tid = threadIdx.x;
  const float* wbuf = inb + IN_WBUF;
  for (int t = tid; t < 4096; t += 256) W2s[t] = wbuf[WB_W2 + t];
  if (tid < 64){ rs[tid] = 0.f; rs2[tid] = 0.f; }
  int slot = tid >> 4;
  int cg = tid & 15;
  const double M = (double)NEDGE;
  float sc1[4], sh1[4], bb2[4];
  #pragma unroll
  for (int u = 0; u < 4; u++){
    int c = cg*4 + u;
    double mean = stats[c] / M;
    double var  = stats[64+c] / M - mean*mean;
    double rstd = 1.0 / sqrt(var + 1e-5);
    double g = (double)inb[IN_G1 + c];
    sc1[u] = (float)(g*rstd);
    sh1[u] = (float)((double)inb[IN_BE1 + c] - mean*g*rstd);
    bb2[u] = inb[IN_B2 + c];
  }
  float s[4] = {0,0,0,0}, s2[4] = {0,0,0,0};
  int base = blockIdx.x * 256;
  for (int it = 0; it < 16; it++){
    unsigned e = (unsigned)(base + it*16 + slot);
    int i = (int)(e / 20u);
    int b = i >> 10;
    int j = idx1[e];
    int gj = (b<<10) + j;
    float4 av = *(const float4*)(a1 + i*64 + cg*4);
    float4 cv = *(const float4*)(c1 + gj*64 + cg*4);
    float4 h;
    h.x = fmaxf(0.f, (av.x+cv.x)*sc1[0] + sh1[0]);
    h.y = fmaxf(0.f, (av.y+cv.y)*sc1[1] + sh1[1]);
    h.z = fmaxf(0.f, (av.z+cv.z)*sc1[2] + sh1[2]);
    h.w = fmaxf(0.f, (av.w+cv.w)*sc1[3] + sh1[3]);
    *(float4*)(buf + slot*68 + cg*4) = h;
    __syncthreads();
    float acc0 = bb2[0], acc1 = bb2[1], acc2 = bb2[2], acc3 = bb2[3];
    const float* bs = buf + slot*68;
    #pragma unroll
    for (int d4 = 0; d4 < 16; d4++){
      float4 hv = *(const float4*)(bs + d4*4);
      float4 w0 = *(const float4*)(W2s + (d4*4+0)*64 + cg*4);
      float4 w1 = *(const float4*)(W2s + (d4*4+1)*64 + cg*4);
      float4 w2 = *(const float4*)(W2s + (d4*4+2)*64 + cg*4);
      float4 w3 = *(const float4*)(W2s + (d4*4+3)*64 + cg*4);
      acc0 += hv.x*w0.x + hv.y*w1.x + hv.z*w2.x + hv.w*w3.x;
      acc1 += hv.x*w0.y + hv.y*w1.y + hv.z*w2.y + hv.w*w3.y;
      acc2 += hv.x*w0.z + hv.y*w1.z + hv.z*w2.z + hv.w*w3.z;
      acc3 += hv.x*w0.w + hv.y*w1.w + hv.z*w2.w + hv.w*w3.w;
    }
    s[0] += acc0; s2[0] += acc0*acc0;
    s[1] += acc1; s2[1] += acc1*acc1;
    s[2] += acc2; s2[2] += acc2*acc2;
    s[3] += acc3; s2[3] += acc3*acc3;
    __syncthreads();
  }
  #pragma unroll
  for (int u = 0; u < 4; u++){
    atomicAdd(&rs[cg*4+u], s[u]);
    atomicAdd(&rs2[cg*4+u], s2[u]);
  }
  __syncthreads();
  if (tid < 64){
    atomicAdd(&stats[128+tid], (double)rs[tid]);
    atomicAdd(&stats[192+tid], (double)rs2[tid]);
  }
}

// ---------------- full MLP1 + max over k -> x1 (slot-stride 68) ----------------
__global__ __launch_bounds__(256) void k_x1(const float* a1, const float* c1,
    const int* idx1, const float* inb, const double* stats, float* x1){
  __shared__ __align__(16) float W2s[4096], W3s[4096];
  __shared__ __align__(16) float buf1[16*68], buf2[16*68];
  __shared__ __align__(16) float red[16*64];
  int tid = threadIdx.x;
  const float* wbuf = inb + IN_WBUF;
  for (int t = tid; t < 4096; t += 256){ W2s[t] = wbuf[WB_W2+t]; W3s[t] = wbuf[WB_W3+t]; }
  int slotid = tid >> 4;
  int n_l = slotid >> 2, eslot = slotid & 3;
  int cg = tid & 15;
  const double M = (double)NEDGE;
  float sc1[4], sh1[4], bb2[4], sc2[4], sh2[4], bb3[4];
  #pragma unroll
  for (int u = 0; u < 4; u++){
    int c = cg*4 + u;
    double m1 = stats[c] / M;
    double v1 = stats[64+c] / M - m1*m1;
    double r1 = 1.0 / sqrt(v1 + 1e-5);
    double gg1 = (double)inb[IN_G1 + c];
    sc1[u] = (float)(gg1*r1);
    sh1[u] = (float)((double)inb[IN_BE1 + c] - m1*gg1*r1);
    bb2[u] = inb[IN_B2 + c];
    double m2 = stats[128+c] / M;
    double v2 = stats[192+c] / M - m2*m2;
    double r2 = 1.0 / sqrt(v2 + 1e-5);
    double gg2 = (double)inb[IN_G2 + c];
    sc2[u] = (float)(gg2*r2);
    sh2[u] = (float)((double)inb[IN_BE2 + c] - m2*gg2*r2);
    bb3[u] = inb[IN_B3 + c];
  }
  __syncthreads();
  int i = blockIdx.x*4 + n_l;
  int b = i >> 10;
  float mx[4] = {-FLT_MAX, -FLT_MAX, -FLT_MAX, -FLT_MAX};
  for (int it = 0; it < 5; it++){
    int kk = it*4 + eslot;
    int j = idx1[i*KNN + kk];
    int gj = (b<<10) + j;
    float4 av = *(const float4*)(a1 + i*64 + cg*4);
    float4 cv = *(const float4*)(c1 + gj*64 + cg*4);
    float4 h;
    h.x = fmaxf(0.f, (av.x+cv.x)*sc1[0] + sh1[0]);
    h.y = fmaxf(0.f, (av.y+cv.y)*sc1[1] + sh1[1]);
    h.z = fmaxf(0.f, (av.z+cv.z)*sc1[2] + sh1[2]);
    h.w = fmaxf(0.f, (av.w+cv.w)*sc1[3] + sh1[3]);
    *(float4*)(buf1 + slotid*68 + cg*4) = h;
    __syncthreads();
    float a0 = bb2[0], a1v = bb2[1], a2v = bb2[2], a3v = bb2[3];
    const float* bs = buf1 + slotid*68;
    #pragma unroll
    for (int d4 = 0; d4 < 16; d4++){
      float4 hv = *(const float4*)(bs + d4*4);
      float4 w0 = *(const float4*)(W2s + (d4*4+0)*64 + cg*4);
      float4 w1 = *(const float4*)(W2s + (d4*4+1)*64 + cg*4);
      float4 w2 = *(const float4*)(W2s + (d4*4+2)*64 + cg*4);
      float4 w3 = *(const float4*)(W2s + (d4*4+3)*64 + cg*4);
      a0  += hv.x*w0.x + hv.y*w1.x + hv.z*w2.x + hv.w*w3.x;
      a1v += hv.x*w0.y + hv.y*w1.y + hv.z*w2.y + hv.w*w3.y;
      a2v += hv.x*w0.z + hv.y*w1.z + hv.z*w2.z + hv.w*w3.z;
      a3v += hv.x*w0.w + hv.y*w1.w + hv.z*w2.w + hv.w*w3.w;
    }
    float4 h2;
    h2.x = fmaxf(0.f, a0*sc2[0] + sh2[0]);
    h2.y = fmaxf(0.f, a1v*sc2[1] + sh2[1]);
    h2.z = fmaxf(0.f, a2v*sc2[2] + sh2[2]);
    h2.w = fmaxf(0.f, a3v*sc2[3] + sh2[3]);
    *(float4*)(buf2 + slotid*68 + cg*4) = h2;
    __syncthreads();
    float c0 = bb3[0], c1v = bb3[1], c2v = bb3[2], c3v = bb3[3];
    const float* bs2 = buf2 + slotid*68;
    #pragma unroll
    for (int d4 = 0; d4 < 16; d4++){
      float4 hv = *(const float4*)(bs2 + d4*4);
      float4 w0 = *(const float4*)(W3s + (d4*4+0)*64 + cg*4);
      float4 w1 = *(const float4*)(W3s + (d4*4+1)*64 + cg*4);
      float4 w2 = *(const float4*)(W3s + (d4*4+2)*64 + cg*4);
      float4 w3 = *(const float4*)(W3s + (d4*4+3)*64 + cg*4);
      c0  += hv.x*w0.x + hv.y*w1.x + hv.z*w2.x + hv.w*w3.x;
      c1v += hv.x*w0.y + hv.y*w1.y + hv.z*w2.y + hv.w*w3.y;
      c2v += hv.x*w0.z + hv.y*w1.z + hv.z*w2.z + hv.w*w3.z;
      c3v += hv.x*w0.w + hv.y*w1.w + hv.z*w2.w + hv.w*w3.w;
    }
    mx[0] = fmaxf(mx[0], c0);  mx[1] = fmaxf(mx[1], c1v);
    mx[2] = fmaxf(mx[2], c2v); mx[3] = fmaxf(mx[3], c3v);
  }
  *(float4*)(red + slotid*64 + cg*4) = make_float4(mx[0], mx[1], mx[2], mx[3]);
  __syncthreads();
  if (eslot == 0){
    #pragma unroll
    for (int u = 0; u < 4; u++){
      int c = cg*4 + u;
      float m = fmaxf(fmaxf(red[(n_l*4+0)*64+c], red[(n_l*4+1)*64+c]),
                      fmaxf(red[(n_l*4+2)*64+c], red[(n_l*4+3)*64+c]));
      x1[i*64 + c] = m;
    }
  }
}

// ---------------- kNN in 64-d feature space (register top-k, branchless insert) ----------------
// Same scan geometry as before (64 queries x 4 slots, broadcast xs reads, 2-candidate
// ILP, ascending jj order). Top-20 list lives in 40 VGPRs; insert is a fully-unrolled
// branchless compare-and-shift (no LDS latency chain, no divergent walk).
__global__ __launch_bounds__(256, 2) void k_knn2(const float* x1, int* idx2){
  __shared__ __align__(16) float xs[64*68];          // 17408 B
  __shared__ float sqc[64];
  __shared__ float dls[256*21];                      // 21504 B
  __shared__ unsigned short ils[256*21];             // 10752 B
  int bb = blockIdx.x >> 4;          // batch
  int qg = blockIdx.x & 15;          // query group of 64
  int tid = threadIdx.x;
  int q_l = tid & 63;
  int slot = tid >> 6;               // wave index == slot
  int gi = bb*1024 + qg*64 + q_l;
  float4 xiv[16];
  #pragma unroll
  for (int d4 = 0; d4 < 16; d4++)
    xiv[d4] = *(const float4*)(x1 + gi*64 + d4*4);
  float sqi = 0.f;
  #pragma unroll
  for (int d4 = 0; d4 < 16; d4++)
    sqi += xiv[d4].x*xiv[d4].x + xiv[d4].y*xiv[d4].y
         + xiv[d4].z*xiv[d4].z + xiv[d4].w*xiv[d4].w;
  float rd[KNN]; int ri[KNN];
  #pragma unroll
  for (int p = 0; p < KNN; p++){ rd[p] = FLT_MAX; ri[p] = 65535; }
  for (int c0 = 0; c0 < 1024; c0 += 64){
    __syncthreads();
    for (int t = tid; t < 4096; t += 256){
      int r = t >> 6, d = t & 63;
      xs[r*68 + d] = x1[(bb*1024 + c0 + r)*64 + d];
    }
    __syncthreads();
    if (tid < 64){
      float s = 0.f;
      #pragma unroll 16
      for (int d = 0; d < 64; d++) s += xs[tid*68+d]*xs[tid*68+d];
      sqc[tid] = s;
    }
    __syncthreads();
    for (int u = 0; u < 16; u += 2){
      int jj0 = 4*u + slot;
      int jj1 = 4*(u+1) + slot;
      const float* xr0 = xs + jj0*68;
      const float* xr1 = xs + jj1*68;
      float dot0 = 0.f, dot1 = 0.f;
      #pragma unroll
      for (int d4 = 0; d4 < 16; d4++){
        float4 v0 = *(const float4*)(xr0 + d4*4);
        float4 v1 = *(const float4*)(xr1 + d4*4);
        dot0 += xiv[d4].x*v0.x + xiv[d4].y*v0.y + xiv[d4].z*v0.z + xiv[d4].w*v0.w;
        dot1 += xiv[d4].x*v1.x + xiv[d4].y*v1.y + xiv[d4].z*v1.z + xiv[d4].w*v1.w;
      }
      float d0 = sqi + sqc[jj0] - 2.0f*dot0;
      float d1 = sqi + sqc[jj1] - 2.0f*dot1;
      // ascending per-slot candidate order -> ties keep lower idx (= top_k)
      ins_plain(d0, c0 + jj0, rd, ri);
      ins_plain(d1, c0 + jj1, rd, ri);
    }
  }
  // slots 1..3 publish; slot 0 merges in registers with lexicographic comparator
  int base = tid*21;
  if (slot != 0){
    #pragma unroll
    for (int p = 0; p < KNN; p++){ dls[base+p] = rd[p]; ils[base+p] = (unsigned short)ri[p]; }
  }
  __syncthreads();
  if (slot == 0){
    for (int s = 1; s < 4; s++){
      int sb = (s*64 + q_l)*21;
      float cd[KNN]; int cii[KNN];
      #pragma unroll
      for (int p = 0; p < KNN; p++){ cd[p] = dls[sb+p]; cii[p] = (int)ils[sb+p]; }
      #pragma unroll
      for (int p = 0; p < KNN; p++) ins_lex(cd[p], cii[p], rd, ri);
    }
    #pragma unroll
    for (int p = 0; p < KNN; p++) idx2[gi*KNN+p] = ri[p];
  }
}

// ---------------- fast path: B2H = x1 @ Wbot[:, q-half] ----------------
__global__ __launch_bounds__(256) void k_B2h(const float* x1, const float* inb,
                                             int q, float* B2H){
  __shared__ __align__(16) float Wbh[4096];
  __shared__ __align__(16) float xsh[1024];
  int tid = threadIdx.x;
  const float* Wb = inb + IN_WBUF + WB_WBOT;
  for (int t = tid; t < 4096; t += 256){
    int r = t >> 6, cl = t & 63;
    Wbh[t] = Wb[r*128 + q*64 + cl];
  }
  int node0 = blockIdx.x * 16;
  for (int t = tid; t < 1024; t += 256) xsh[t] = x1[node0*64 + t];
  __syncthreads();
  int n_l = tid >> 4, cg = tid & 15;
  const float* xr = xsh + n_l*64;
  float4 acc = make_float4(0.f,0.f,0.f,0.f);
  #pragma unroll 8
  for (int d = 0; d < 64; d++){
    float v = xr[d];
    float4 w = *(const float4*)(Wbh + d*64 + cg*4);
    acc.x += v*w.x; acc.y += v*w.y; acc.z += v*w.z; acc.w += v*w.w;
  }
  *(float4*)(B2H + (node0 + n_l)*64 + cg*4) = acc;
}

// ---------------- fast path: x2 half = (x1_i@Wd + bc2) + max_j B2H[j] ----------------
__global__ __launch_bounds__(256) void k_x2h(const float* x1, const float* B2H,
                                             const float* inb, const int* idx2,
                                             int q, float* x2){
  __shared__ __align__(16) float Wdh[4096];
  __shared__ __align__(16) float xsh[256];
  int tid = threadIdx.x;
  const float* Wd = inb + IN_WBUF + WB_WD;
  for (int t = tid; t < 4096; t += 256){
    int r = t >> 6, cl = t & 63;
    Wdh[t] = Wd[r*128 + q*64 + cl];
  }
  int node0 = blockIdx.x * 4;
  xsh[tid] = x1[node0*64 + tid];
  __syncthreads();
  int n_l = tid >> 6, cl = tid & 63;
  int i = node0 + n_l;
  int b = i >> 10;
  const float* xr = xsh + n_l*64;
  float acc = inb[IN_BC2 + q*64 + cl];
  #pragma unroll 8
  for (int d = 0; d < 64; d++) acc += xr[d]*Wdh[d*64 + cl];
  float m = -FLT_MAX;
  for (int kk = 0; kk < KNN; kk++){
    int j = idx2[i*KNN + kk];
    m = fmaxf(m, B2H[((b<<10)+j)*64 + cl]);
  }
  x2[i*128 + q*64 + cl] = acc + m;
}

// ---------------- slow fallback: x2 direct, LDS-staged, no B2H buffer ----------------
__global__ __launch_bounds__(256) void k_x2d(const float* x1, const float* inb,
                                             const int* idx2, float* x2){
  __shared__ __align__(16) float Wdh[4096], Wbh[4096];
  __shared__ __align__(16) float xis[1024], xjs[1024];
  int tid = threadIdx.x;
  int q = blockIdx.x & 1;
  int node0 = (blockIdx.x >> 1) * 16;
  const float* Wd = inb + IN_WBUF + WB_WD;
  const float* Wb = inb + IN_WBUF + WB_WBOT;
  for (int t = tid; t < 4096; t += 256){
    int r = t >> 6, cl = t & 63;
    Wdh[t] = Wd[r*128 + q*64 + cl];
    Wbh[t] = Wb[r*128 + q*64 + cl];
  }
  for (int t = tid; t < 1024; t += 256) xis[t] = x1[node0*64 + t];
  __syncthreads();
  int n_l = tid >> 4, cg = tid & 15;
  int i = node0 + n_l, b = i >> 10;
  const float* xr = xis + n_l*64;
  float4 af = make_float4(inb[IN_BC2 + q*64 + cg*4],   inb[IN_BC2 + q*64 + cg*4+1],
                          inb[IN_BC2 + q*64 + cg*4+2], inb[IN_BC2 + q*64 + cg*4+3]);
  #pragma unroll 8
  for (int d = 0; d < 64; d++){
    float v = xr[d];
    float4 w = *(const float4*)(Wdh + d*64 + cg*4);
    af.x += v*w.x; af.y += v*w.y; af.z += v*w.z; af.w += v*w.w;
  }
  float4 mx = make_float4(-FLT_MAX,-FLT_MAX,-FLT_MAX,-FLT_MAX);
  for (int kk = 0; kk < KNN; kk++){
    __syncthreads();
    for (int t = tid; t < 1024; t += 256){
      int nn = t >> 6, r = t & 63;
      int jj = idx2[(node0+nn)*KNN + kk];
      xjs[t] = x1[((((node0+nn) >> 10) << 10) + jj)*64 + r];
    }
    __syncthreads();
    const float* xj = xjs + n_l*64;
    float4 acc = make_float4(0.f,0.f,0.f,0.f);
    #pragma unroll 8
    for (int d = 0; d < 64; d++){
      float v = xj[d];
      float4 w = *(const float4*)(Wbh + d*64 + cg*4);
      acc.x += v*w.x; acc.y += v*w.y; acc.z += v*w.z; acc.w += v*w.w;
    }
    mx.x = fmaxf(mx.x, acc.x); mx.y = fmaxf(mx.y, acc.y);
    mx.z = fmaxf(mx.z, acc.z); mx.w = fmaxf(mx.w, acc.w);
  }
  *(float4*)(x2 + i*128 + q*64 + cg*4) =
      make_float4(af.x+mx.x, af.y+mx.y, af.z+mx.z, af.w+mx.w);
}

// ---------------- lin (192->1024) + partial max over n-quarter ----------------
__global__ __launch_bounds__(256) void k_linpool(const float* x1, const float* x2,
    const float* inb, float* pool4){
  __shared__ __align__(16) float fst[192*36];
  __shared__ float red2[1024];
  int tid = threadIdx.x;
  int b = blockIdx.x >> 4, cq = (blockIdx.x >> 2) & 3, nh = blockIdx.x & 3;
  int cg = tid & 63, n8 = tid >> 6;
  int cbase = cq*256 + cg*4;
  const float* Wl = inb + IN_WBUF + WB_WL;
  float m0 = -FLT_MAX, m1 = -FLT_MAX, m2 = -FLT_MAX, m3 = -FLT_MAX;
  for (int ng = 0; ng < 8; ng++){
    __syncthreads();
    for (int t = tid; t < 6144; t += 256){
      int n_l = t / 192, dd = t - n_l*192;
      int gi = b*1024 + nh*256 + ng*32 + n_l;
      fst[dd*36 + n_l] = (dd < 64) ? x1[gi*64 + dd] : x2[gi*128 + dd - 64];
    }
    __syncthreads();
    float acc[8][4];
    #pragma unroll
    for (int n = 0; n < 8; n++){ acc[n][0]=0; acc[n][1]=0; acc[n][2]=0; acc[n][3]=0; }
    #pragma unroll 4
    for (int d = 0; d < 192; d++){
      float4 w = *(const float4*)(Wl + d*1024 + cbase);
      const float* fr = fst + d*36 + n8*8;
      float4 f0 = *(const float4*)(fr);
      float4 f1 = *(const float4*)(fr + 4);
      float fv[8] = {f0.x, f0.y, f0.z, f0.w, f1.x, f1.y, f1.z, f1.w};
      #pragma unroll
      for (int n = 0; n < 8; n++){
        acc[n][0] += fv[n]*w.x; acc[n][1] += fv[n]*w.y;
        acc[n][2] += fv[n]*w.z; acc[n][3] += fv[n]*w.w;
      }
    }
    #pragma unroll
    for (int n = 0; n < 8; n++){
      m0 = fmaxf(m0, acc[n][0]); m1 = fmaxf(m1, acc[n][1]);
      m2 = fmaxf(m2, acc[n][2]); m3 = fmaxf(m3, acc[n][3]);
    }
  }
  red2[n8*256 + cg*4]   = m0;  red2[n8*256 + cg*4+1] = m1;
  red2[n8*256 + cg*4+2] = m2;  red2[n8*256 + cg*4+3] = m3;
  __syncthreads();
  if (n8 == 0){
    #pragma unroll
    for (int u = 0; u < 4; u++){
      int cc = cg*4 + u;
      float m = fmaxf(fmaxf(red2[cc], red2[256+cc]), fmaxf(red2[512+cc], red2[768+cc]));
      pool4[nh*32768 + b*1024 + cbase + u] = m;     // bias applied in k_head
    }
  }
}

// ---------------- head MLP: reduce pool4 + 1024->512->256->40 (fp32 out) ----------------
__global__ __launch_bounds__(256) void k_head(const float* pool4, const float* inb,
                                              float* out){
  __shared__ float pl[1024];
  __shared__ float s1[512];
  __shared__ float s2[256];
  int b = blockIdx.x, tid = threadIdx.x;
  const float* Wm1 = inb + IN_WBUF + WB_WM1;
  const float* Wm2 = inb + IN_WBUF + WB_WM2;
  const float* Wm3 = inb + IN_WBUF + WB_WM3;
  for (int t = tid; t < 1024; t += 256){
    float m = fmaxf(fmaxf(pool4[b*1024 + t],         pool4[32768 + b*1024 + t]),
                    fmaxf(pool4[65536 + b*1024 + t], pool4[98304 + b*1024 + t]));
    pl[t] = m + inb[IN_BL + t];
  }
  __syncthreads();
  for (int c = tid; c < 512; c += 256){
    float acc = inb[IN_BM1 + c];
    #pragma unroll 4
    for (int d = 0; d < 1024; d++) acc += pl[d]*Wm1[d*512 + c];
    s1[c] = fmaxf(acc, 0.f);
  }
  __syncthreads();
  {
    int c = tid;
    float acc = inb[IN_BM2 + c];
    #pragma unroll 4
    for (int d = 0; d < 512; d++) acc += s1[d]*Wm2[d*256 + c];
    s2[c] = fmaxf(acc, 0.f);
  }
  __syncthreads();
  if (tid < 40){
    float acc = inb[IN_BM3 + tid];
    #pragma unroll 4
    for (int d = 0; d < 256; d++) acc += s2[d]*Wm3[d*40 + tid];
    out[b*40 + tid] = acc;
  }
}

extern "C" void kernel_launch(void* const* d_in, const int* in_sizes, int n_in,
                              void* d_out, int out_size, void* d_ws, size_t ws_size,
                              hipStream_t stream){
  float* ws     = (float*)d_ws;
  double* stats = (double*)d_ws;
  int*   flag   = (int*)d_ws + OFF_FLAG;
  float* inb    = ws + OFF_INB;
  int*   idx    = (int*)d_ws + OFF_IDX;     // idx1 early, idx2 late
  float* x1p    = ws + OFF_X1;
  float* x2p    = ws + OFF_X2;
  float* a1     = ws + OFF_X2;              // a1/c1 alias x2 region (dead before x2 written)
  float* c1     = ws + OFF_C1;
  float* pool4  = ws + OFF_POOL;
  float* B2H    = ws + OFF_B2H;
  bool fast = ws_size >= (size_t)FAST_END * 4u;

  hipMemsetAsync(stats, 0, 256*sizeof(double), stream);
  k_sniff<<<1, 64, 0, stream>>>(d_in[0], flag);
  k_cvt<<<3859, 256, 0, stream>>>(
      d_in[0], d_in[1], d_in[2], d_in[3], d_in[4], d_in[5], d_in[6], d_in[7],
      d_in[8], d_in[9], d_in[10], d_in[11], d_in[12], d_in[13], d_in[14],
      d_in[15], d_in[16], d_in[17], d_in[18], d_in[19], d_in[20], flag, inb);
  k_prep1<<<8192, 256, 0, stream>>>(inb, a1, c1);
  k_knn1<<<512, 256, 0, stream>>>(inb, idx);
  k_stats1<<<640, 256, 0, stream>>>(a1, c1, idx, stats);
  k_stats2<<<2560, 256, 0, stream>>>(a1, c1, idx, inb, stats);
  k_x1<<<8192, 256, 0, stream>>>(a1, c1, idx, inb, stats, x1p);
  k_knn2<<<512, 256, 0, stream>>>(x1p, idx);
  if (fast){
    k_B2h<<<2048, 256, 0, stream>>>(x1p, inb, 0, B2H);
    k_x2h<<<8192, 256, 0, stream>>>(x1p, B2H, inb, idx, 0, x2p);
    k_B2h<<<2048, 256, 0, stream>>>(x1p, inb, 1, B2H);
    k_x2h<<<8192, 256, 0, stream>>>(x1p, B2H, inb, idx, 1, x2p);
  } else {
    k_x2d<<<4096, 256, 0, stream>>>(x1p, inb, idx, x2p);
  }
  k_linpool<<<512, 256, 0, stream>>>(x1p, x2p, inb, pool4);
  k_head<<<32, 256, 0, stream>>>(pool4, inb, (float*)d_out);
}

// Round 3
// 1573.470 us; speedup vs baseline: 2.8091x; 2.8091x over previous
//
#include <hip/hip_runtime.h>
#include <hip/hip_bf16.h>
#include <float.h>
#include <math.h>

typedef __hip_bfloat16 bf16;

#define BATCH 32
#define NPTS  1024
#define KNN   20
#define NB    (BATCH*NPTS)      // 32768 nodes
#define NEDGE (NB*KNN)          // 655360 edges

// ---- workspace layout (float units), ws_size-adaptive ----
#define OFF_FLAG 512u
#define OFF_INB  1024u
#define OFF_IDX  988928u          // 655360 ints (idx1 early, idx2 late)
#define OFF_X1   1644288u         // NB*64
#define OFF_X2   3741440u         // NB*128 ; a1 @ OFF_X2, c1 @ OFF_C1 (early)
#define OFF_C1   5838592u
#define OFF_POOL 7935744u         // pool4: 4 x 32*1024
#define SLOW_END 8066816u         // 32.3 MB
#define OFF_B2H  8066816u         // NB*64 (fast path only)
#define FAST_END 10163968u        // 40.7 MB
// ---- layout inside inb (canonical fp32 inputs) ----
#define IN_POSF 0u
#define IN_B1   98304u
#define IN_G1   98368u
#define IN_BE1  98432u
#define IN_B2   98496u
#define IN_G2   98560u
#define IN_BE2  98624u
#define IN_B3   98688u
#define IN_BC2  98752u
#define IN_BL   98880u
#define IN_BM1  99904u
#define IN_BM2  100416u
#define IN_BM3  100672u
#define IN_W1   100736u
#define IN_WBUF 101120u
#define WB_W2   0u
#define WB_W3   4096u
#define WB_WD   8192u            // Wc2 top-bot diff [64x128]
#define WB_WBOT 16384u           // Wc2 bottom      [64x128]
#define WB_WL   24576u
#define WB_WM1  221184u
#define WB_WM2  745472u
#define WB_WM3  876544u
#define IN_TOTAL 987904u

__device__ __forceinline__ float bf2f(bf16 v){ return __bfloat162float(v); }

// ======== register top-k via 20 NAMED scalars (macro-generated) ========
// Round-1 lesson: array-based lists went to scratch (1.9 GB spill traffic);
// named scalars cannot be demoted. Round-2 lesson: REP20 cannot appear inside
// a macro expanded BY REP20 (preprocessor blue-paint) -> the cross-slot merge
// uses a runtime for-loop calling INS_LEX at top level instead.
// Insert is branchless compare-and-shift, exactly equivalent to the sorted-
// insert walk with strict > (ties keep earlier candidate = top_k semantics).
#define REP20(M) M(0) M(1) M(2) M(3) M(4) M(5) M(6) M(7) M(8) M(9) \
                 M(10) M(11) M(12) M(13) M(14) M(15) M(16) M(17) M(18) M(19)
#define SH19(M) M(19,18) M(18,17) M(17,16) M(16,15) M(15,14) M(14,13) M(13,12) \
                M(12,11) M(11,10) M(10,9) M(9,8) M(8,7) M(7,6) M(6,5) M(5,4) \
                M(4,3) M(3,2) M(2,1) M(1,0)

#define KDECL(p) float rd##p = FLT_MAX; int ri##p = 65535;
#define KG_P(p)  bool gt##p = rd##p > _d;
#define KG_L(p)  bool gt##p = (rd##p > _d) || ((rd##p == _d) && (ri##p > _c));
#define KSH(p,pm) rd##p = gt##p ? (gt##pm ? rd##pm : _d) : rd##p; \
                  ri##p = gt##p ? (gt##pm ? ri##pm : _c) : ri##p;

#define INS_PLAIN(dv,cv) do{ float _d=(dv); int _c=(cv); \
  REP20(KG_P) SH19(KSH) \
  rd0 = gt0 ? _d : rd0; ri0 = gt0 ? _c : ri0; }while(0)

#define INS_LEX(dv,cv) do{ float _d=(dv); int _c=(cv); \
  REP20(KG_L) SH19(KSH) \
  rd0 = gt0 ? _d : rd0; ri0 = gt0 ? _c : ri0; }while(0)

#define KPUB(p)  dls[base+p] = rd##p; ils[base+p] = (unsigned short)ri##p;
#define KOUT(p)  optr[p] = ri##p;

// ---------------- dtype sniff (fp32 vs bf16 inputs) ----------------
__global__ void k_sniff(const void* pos_raw, int* flag){
  if (blockIdx.x == 0 && threadIdx.x == 0){
    const unsigned short* h = (const unsigned short*)pos_raw;
    int wild = 0;
    for (int k = 0; k < 16; k++){
      unsigned int bits = ((unsigned int)h[2*k]) << 16;
      float v = __uint_as_float(bits);
      float a = fabsf(v);
      if (a != 0.0f && (v != v || a > 1e10f || a < 1e-10f)) wild++;
    }
    *flag = (wild >= 4) ? 1 : 0;
  }
}

__device__ __forceinline__ float rdv(const void* p, int i, int f){
  return f ? ((const float*)p)[i] : bf2f(((const bf16*)p)[i]);
}

// ---------------- normalize ALL inputs to canonical fp32 buffer ----------------
__global__ __launch_bounds__(256) void k_cvt(
    const void* pos, const void* W1, const void* b1, const void* g1, const void* be1,
    const void* W2, const void* b2, const void* g2, const void* be2,
    const void* W3, const void* b3, const void* Wc2, const void* bc2,
    const void* Wl, const void* bl, const void* Wm1, const void* bm1,
    const void* Wm2, const void* bm2, const void* Wm3, const void* bm3,
    const int* flag, float* inb){
  int id = blockIdx.x*256 + threadIdx.x;
  if (id >= (int)IN_TOTAL) return;
  int f = *flag;
  float v;
  if      (id < 98304)  v = rdv(pos, id, f);
  else if (id < 98368)  v = rdv(b1,  id-98304, f);
  else if (id < 98432)  v = rdv(g1,  id-98368, f);
  else if (id < 98496)  v = rdv(be1, id-98432, f);
  else if (id < 98560)  v = rdv(b2,  id-98496, f);
  else if (id < 98624)  v = rdv(g2,  id-98560, f);
  else if (id < 98688)  v = rdv(be2, id-98624, f);
  else if (id < 98752)  v = rdv(b3,  id-98688, f);
  else if (id < 98880)  v = rdv(bc2, id-98752, f);
  else if (id < 99904)  v = rdv(bl,  id-98880, f);
  else if (id < 100416) v = rdv(bm1, id-99904, f);
  else if (id < 100672) v = rdv(bm2, id-100416, f);
  else if (id < 100712) v = rdv(bm3, id-100672, f);
  else if (id < 100736) v = 0.0f;
  else if (id < 101120) v = rdv(W1,  id-100736, f);
  else {
    int t = id - 101120;
    if      (t < 4096)   v = rdv(W2, t, f);
    else if (t < 8192)   v = rdv(W3, t-4096, f);
    else if (t < 16384){ int u = t-8192;  v = rdv(Wc2, u, f) - rdv(Wc2, 8192+u, f); }
    else if (t < 24576){ int u = t-16384; v = rdv(Wc2, 8192+u, f); }
    else if (t < 221184) v = rdv(Wl,  t-24576, f);
    else if (t < 745472) v = rdv(Wm1, t-221184, f);
    else if (t < 876544) v = rdv(Wm2, t-745472, f);
    else                 v = rdv(Wm3, t-876544, f);
  }
  inb[id] = v;
}

// ---------------- a1/c1: affine decomposition of EdgeConv1 layer1 ----------------
__global__ __launch_bounds__(256) void k_prep1(const float* inb, float* a1, float* c1){
  const float* posf = inb + IN_POSF;
  const float* W1f  = inb + IN_W1;
  const float* b1f  = inb + IN_B1;
  int id = blockIdx.x*256 + threadIdx.x;
  int bn = id >> 6, c = id & 63;
  float p0 = posf[bn*3], p1 = posf[bn*3+1], p2 = posf[bn*3+2];
  float wt0 = W1f[c],     wt1 = W1f[64+c],  wt2 = W1f[128+c];
  float wb0 = W1f[192+c], wb1 = W1f[256+c], wb2 = W1f[320+c];
  float cv = p0*wb0 + p1*wb1 + p2*wb2;
  float av = p0*(wt0-wb0) + p1*(wt1-wb1) + p2*(wt2-wb2) + b1f[c];
  a1[id] = av;  c1[id] = cv;
}

// ---------------- kNN in coordinate space (named-scalar register top-k) ----------------
__global__ __launch_bounds__(256, 2) void k_knn1(const float* inb, int* idx1){
  const float* posf = inb + IN_POSF;
  __shared__ float psx[1024], psy[1024], psz[1024], sqs[1024];
  __shared__ float dls[256*21];
  __shared__ unsigned short ils[256*21];
  int bb = blockIdx.x >> 4;
  int qg = blockIdx.x & 15;
  int tid = threadIdx.x;
  int q_l = tid & 63;
  int slot = tid >> 6;
  for (int t = tid; t < 1024; t += 256){
    float x = posf[(bb*1024+t)*3], y = posf[(bb*1024+t)*3+1], z = posf[(bb*1024+t)*3+2];
    psx[t] = x; psy[t] = y; psz[t] = z; sqs[t] = x*x + y*y + z*z;
  }
  __syncthreads();
  int i_l = qg*64 + q_l;
  float xi0 = psx[i_l], xi1 = psy[i_l], xi2 = psz[i_l];
  float sqi = sqs[i_l];
  REP20(KDECL)
  // ascending jj per slot -> ties keep lower idx (matches top_k)
  for (int u = 0; u < 256; u++){
    int jj = 4*u + slot;
    float dot = xi0*psx[jj] + xi1*psy[jj] + xi2*psz[jj];
    float d = sqi + sqs[jj] - 2.0f*dot;
    INS_PLAIN(d, jj);
  }
  // slots 1..3 publish their lists; slot 0 merges in registers
  int base = tid*21;
  if (slot != 0){
    REP20(KPUB)
  }
  __syncthreads();
  if (slot == 0){
    for (int s = 1; s < 4; s++){
      int sb = (s*64 + q_l)*21;
      for (int p = 0; p < KNN; p++){
        float md = dls[sb+p];
        int   mi = (int)ils[sb+p];
        INS_LEX(md, mi);
      }
    }
    int gi = bb*1024 + i_l;
    int* optr = idx1 + gi*KNN;
    REP20(KOUT)
  }
}

// ---------------- BN1 stats ----------------
__global__ __launch_bounds__(256) void k_stats1(const float* a1, const float* c1,
                                                const int* idx1, double* stats){
  __shared__ float rs[256], rs2[256];
  int tid = threadIdx.x, c = tid & 63, slot = tid >> 6;
  int base = blockIdx.x * 1024;
  float s = 0.f, s2 = 0.f;
  for (int t = 0; t < 256; t++){
    unsigned e = (unsigned)(base + t*4 + slot);
    int i = (int)(e / 20u);
    int b = i >> 10;
    int j = idx1[e];
    float h = a1[i*64+c] + c1[((b<<10)+j)*64 + c];
    s += h; s2 += h*h;
  }
  rs[tid] = s; rs2[tid] = s2;
  __syncthreads();
  if (slot == 0){
    double ts  = (double)rs[c]  + (double)rs[64+c]  + (double)rs[128+c]  + (double)rs[192+c];
    double ts2 = (double)rs2[c] + (double)rs2[64+c] + (double)rs2[128+c] + (double)rs2[192+c];
    atomicAdd(&stats[c], ts);
    atomicAdd(&stats[64+c], ts2);
  }
}

// ---------------- BN2 stats (slot-stride 68: bank-conflict-free) ----------------
__global__ __launch_bounds__(256) void k_stats2(const float* a1, const float* c1,
    const int* idx1, const float* inb, double* stats){
  __shared__ __align__(16) float W2s[4096];
  __shared__ __align__(16) float buf[16*68];
  __shared__ float rs[64], rs2[64];
  int tid = threadIdx.x;
  const float* wbuf = inb + IN_WBUF;
  for (int t = tid; t < 4096; t += 256) W2s[t] = wbuf[WB_W2 + t];
  if (tid < 64){ rs[tid] = 0.f; rs2[tid] = 0.f; }
  int slot = tid >> 4;
  int cg = tid & 15;
  const double M = (double)NEDGE;
  float sc1[4], sh1[4], bb2[4];
  #pragma unroll
  for (int u = 0; u < 4; u++){
    int c = cg*4 + u;
    double mean = stats[c] / M;
    double var  = stats[64+c] / M - mean*mean;
    double rstd = 1.0 / sqrt(var + 1e-5);
    double g = (double)inb[IN_G1 + c];
    sc1[u] = (float)(g*rstd);
    sh1[u] = (float)((double)inb[IN_BE1 + c] - mean*g*rstd);
    bb2[u] = inb[IN_B2 + c];
  }
  float s[4] = {0,0,0,0}, s2[4] = {0,0,0,0};
  int base = blockIdx.x * 256;
  for (int it = 0; it < 16; it++){
    unsigned e = (unsigned)(base + it*16 + slot);
    int i = (int)(e / 20u);
    int b = i >> 10;
    int j = idx1[e];
    int gj = (b<<10) + j;
    float4 av = *(const float4*)(a1 + i*64 + cg*4);
    float4 cv = *(const float4*)(c1 + gj*64 + cg*4);
    float4 h;
    h.x = fmaxf(0.f, (av.x+cv.x)*sc1[0] + sh1[0]);
    h.y = fmaxf(0.f, (av.y+cv.y)*sc1[1] + sh1[1]);
    h.z = fmaxf(0.f, (av.z+cv.z)*sc1[2] + sh1[2]);
    h.w = fmaxf(0.f, (av.w+cv.w)*sc1[3] + sh1[3]);
    *(float4*)(buf + slot*68 + cg*4) = h;
    __syncthreads();
    float acc0 = bb2[0], acc1 = bb2[1], acc2 = bb2[2], acc3 = bb2[3];
    const float* bs = buf + slot*68;
    #pragma unroll
    for (int d4 = 0; d4 < 16; d4++){
      float4 hv = *(const float4*)(bs + d4*4);
      float4 w0 = *(const float4*)(W2s + (d4*4+0)*64 + cg*4);
      float4 w1 = *(const float4*)(W2s + (d4*4+1)*64 + cg*4);
      float4 w2 = *(const float4*)(W2s + (d4*4+2)*64 + cg*4);
      float4 w3 = *(const float4*)(W2s + (d4*4+3)*64 + cg*4);
      acc0 += hv.x*w0.x + hv.y*w1.x + hv.z*w2.x + hv.w*w3.x;
      acc1 += hv.x*w0.y + hv.y*w1.y + hv.z*w2.y + hv.w*w3.y;
      acc2 += hv.x*w0.z + hv.y*w1.z + hv.z*w2.z + hv.w*w3.z;
      acc3 += hv.x*w0.w + hv.y*w1.w + hv.z*w2.w + hv.w*w3.w;
    }
    s[0] += acc0; s2[0] += acc0*acc0;
    s[1] += acc1; s2[1] += acc1*acc1;
    s[2] += acc2; s2[2] += acc2*acc2;
    s[3] += acc3; s2[3] += acc3*acc3;
    __syncthreads();
  }
  #pragma unroll
  for (int u = 0; u < 4; u++){
    atomicAdd(&rs[cg*4+u], s[u]);
    atomicAdd(&rs2[cg*4+u], s2[u]);
  }
  __syncthreads();
  if (tid < 64){
    atomicAdd(&stats[128+tid], (double)rs[tid]);
    atomicAdd(&stats[192+tid], (double)rs2[tid]);
  }
}

// ---------------- full MLP1 + max over k -> x1 (slot-stride 68) ----------------
__global__ __launch_bounds__(256) void k_x1(const float* a1, const float* c1,
    const int* idx1, const float* inb, const double* stats, float* x1){
  __shared__ __align__(16) float W2s[4096], W3s[4096];
  __shared__ __align__(16) float buf1[16*68], buf2[16*68];
  __shared__ __align__(16) float red[16*64];
  int tid = threadIdx.x;
  const float* wbuf = inb + IN_WBUF;
  for (int t = tid; t < 4096; t += 256){ W2s[t] = wbuf[WB_W2+t]; W3s[t] = wbuf[WB_W3+t]; }
  int slotid = tid >> 4;
  int n_l = slotid >> 2, eslot = slotid & 3;
  int cg = tid & 15;
  const double M = (double)NEDGE;
  float sc1[4], sh1[4], bb2[4], sc2[4], sh2[4], bb3[4];
  #pragma unroll
  for (int u = 0; u < 4; u++){
    int c = cg*4 + u;
    double m1 = stats[c] / M;
    double v1 = stats[64+c] / M - m1*m1;
    double r1 = 1.0 / sqrt(v1 + 1e-5);
    double gg1 = (double)inb[IN_G1 + c];
    sc1[u] = (float)(gg1*r1);
    sh1[u] = (float)((double)inb[IN_BE1 + c] - m1*gg1*r1);
    bb2[u] = inb[IN_B2 + c];
    double m2 = stats[128+c] / M;
    double v2 = stats[192+c] / M - m2*m2;
    double r2 = 1.0 / sqrt(v2 + 1e-5);
    double gg2 = (double)inb[IN_G2 + c];
    sc2[u] = (float)(gg2*r2);
    sh2[u] = (float)((double)inb[IN_BE2 + c] - m2*gg2*r2);
    bb3[u] = inb[IN_B3 + c];
  }
  __syncthreads();
  int i = blockIdx.x*4 + n_l;
  int b = i >> 10;
  float mx[4] = {-FLT_MAX, -FLT_MAX, -FLT_MAX, -FLT_MAX};
  for (int it = 0; it < 5; it++){
    int kk = it*4 + eslot;
    int j = idx1[i*KNN + kk];
    int gj = (b<<10) + j;
    float4 av = *(const float4*)(a1 + i*64 + cg*4);
    float4 cv = *(const float4*)(c1 + gj*64 + cg*4);
    float4 h;
    h.x = fmaxf(0.f, (av.x+cv.x)*sc1[0] + sh1[0]);
    h.y = fmaxf(0.f, (av.y+cv.y)*sc1[1] + sh1[1]);
    h.z = fmaxf(0.f, (av.z+cv.z)*sc1[2] + sh1[2]);
    h.w = fmaxf(0.f, (av.w+cv.w)*sc1[3] + sh1[3]);
    *(float4*)(buf1 + slotid*68 + cg*4) = h;
    __syncthreads();
    float a0 = bb2[0], a1v = bb2[1], a2v = bb2[2], a3v = bb2[3];
    const float* bs = buf1 + slotid*68;
    #pragma unroll
    for (int d4 = 0; d4 < 16; d4++){
      float4 hv = *(const float4*)(bs + d4*4);
      float4 w0 = *(const float4*)(W2s + (d4*4+0)*64 + cg*4);
      float4 w1 = *(const float4*)(W2s + (d4*4+1)*64 + cg*4);
      float4 w2 = *(const float4*)(W2s + (d4*4+2)*64 + cg*4);
      float4 w3 = *(const float4*)(W2s + (d4*4+3)*64 + cg*4);
      a0  += hv.x*w0.x + hv.y*w1.x + hv.z*w2.x + hv.w*w3.x;
      a1v += hv.x*w0.y + hv.y*w1.y + hv.z*w2.y + hv.w*w3.y;
      a2v += hv.x*w0.z + hv.y*w1.z + hv.z*w2.z + hv.w*w3.z;
      a3v += hv.x*w0.w + hv.y*w1.w + hv.z*w2.w + hv.w*w3.w;
    }
    float4 h2;
    h2.x = fmaxf(0.f, a0*sc2[0] + sh2[0]);
    h2.y = fmaxf(0.f, a1v*sc2[1] + sh2[1]);
    h2.z = fmaxf(0.f, a2v*sc2[2] + sh2[2]);
    h2.w = fmaxf(0.f, a3v*sc2[3] + sh2[3]);
    *(float4*)(buf2 + slotid*68 + cg*4) = h2;
    __syncthreads();
    float c0 = bb3[0], c1v = bb3[1], c2v = bb3[2], c3v = bb3[3];
    const float* bs2 = buf2 + slotid*68;
    #pragma unroll
    for (int d4 = 0; d4 < 16; d4++){
      float4 hv = *(const float4*)(bs2 + d4*4);
      float4 w0 = *(const float4*)(W3s + (d4*4+0)*64 + cg*4);
      float4 w1 = *(const float4*)(W3s + (d4*4+1)*64 + cg*4);
      float4 w2 = *(const float4*)(W3s + (d4*4+2)*64 + cg*4);
      float4 w3 = *(const float4*)(W3s + (d4*4+3)*64 + cg*4);
      c0  += hv.x*w0.x + hv.y*w1.x + hv.z*w2.x + hv.w*w3.x;
      c1v += hv.x*w0.y + hv.y*w1.y + hv.z*w2.y + hv.w*w3.y;
      c2v += hv.x*w0.z + hv.y*w1.z + hv.z*w2.z + hv.w*w3.z;
      c3v += hv.x*w0.w + hv.y*w1.w + hv.z*w2.w + hv.w*w3.w;
    }
    mx[0] = fmaxf(mx[0], c0);  mx[1] = fmaxf(mx[1], c1v);
    mx[2] = fmaxf(mx[2], c2v); mx[3] = fmaxf(mx[3], c3v);
  }
  *(float4*)(red + slotid*64 + cg*4) = make_float4(mx[0], mx[1], mx[2], mx[3]);
  __syncthreads();
  if (eslot == 0){
    #pragma unroll
    for (int u = 0; u < 4; u++){
      int c = cg*4 + u;
      float m = fmaxf(fmaxf(red[(n_l*4+0)*64+c], red[(n_l*4+1)*64+c]),
                      fmaxf(red[(n_l*4+2)*64+c], red[(n_l*4+3)*64+c]));
      x1[i*64 + c] = m;
    }
  }
}

// ---------------- kNN in 64-d feature space (named-scalar register top-k) ----------------
// Scan geometry: 64 queries x 4 slots, broadcast xs reads, 2-candidate ILP,
// ascending jj order. Top-20 list in 40 named VGPRs; insert is branchless
// compare-and-shift (no LDS latency chain, no scratch).
__global__ __launch_bounds__(256, 2) void k_knn2(const float* x1, int* idx2){
  __shared__ __align__(16) float xs[64*68];          // 17408 B
  __shared__ float sqc[64];
  __shared__ float dls[256*21];                      // 21504 B
  __shared__ unsigned short ils[256*21];             // 10752 B
  int bb = blockIdx.x >> 4;          // batch
  int qg = blockIdx.x & 15;          // query group of 64
  int tid = threadIdx.x;
  int q_l = tid & 63;
  int slot = tid >> 6;               // wave index == slot
  int gi = bb*1024 + qg*64 + q_l;
  float4 xiv[16];
  #pragma unroll
  for (int d4 = 0; d4 < 16; d4++)
    xiv[d4] = *(const float4*)(x1 + gi*64 + d4*4);
  float sqi = 0.f;
  #pragma unroll
  for (int d4 = 0; d4 < 16; d4++)
    sqi += xiv[d4].x*xiv[d4].x + xiv[d4].y*xiv[d4].y
         + xiv[d4].z*xiv[d4].z + xiv[d4].w*xiv[d4].w;
  REP20(KDECL)
  for (int c0 = 0; c0 < 1024; c0 += 64){
    __syncthreads();
    for (int t = tid; t < 4096; t += 256){
      int r = t >> 6, d = t & 63;
      xs[r*68 + d] = x1[(bb*1024 + c0 + r)*64 + d];
    }
    __syncthreads();
    if (tid < 64){
      float s = 0.f;
      #pragma unroll 16
      for (int d = 0; d < 64; d++) s += xs[tid*68+d]*xs[tid*68+d];
      sqc[tid] = s;
    }
    __syncthreads();
    for (int u = 0; u < 16; u += 2){
      int jj0 = 4*u + slot;
      int jj1 = 4*(u+1) + slot;
      const float* xr0 = xs + jj0*68;
      const float* xr1 = xs + jj1*68;
      float dot0 = 0.f, dot1 = 0.f;
      #pragma unroll
      for (int d4 = 0; d4 < 16; d4++){
        float4 v0 = *(const float4*)(xr0 + d4*4);
        float4 v1 = *(const float4*)(xr1 + d4*4);
        dot0 += xiv[d4].x*v0.x + xiv[d4].y*v0.y + xiv[d4].z*v0.z + xiv[d4].w*v0.w;
        dot1 += xiv[d4].x*v1.x + xiv[d4].y*v1.y + xiv[d4].z*v1.z + xiv[d4].w*v1.w;
      }
      float d0 = sqi + sqc[jj0] - 2.0f*dot0;
      float d1 = sqi + sqc[jj1] - 2.0f*dot1;
      // ascending per-slot candidate order -> ties keep lower idx (= top_k)
      INS_PLAIN(d0, c0 + jj0);
      INS_PLAIN(d1, c0 + jj1);
    }
  }
  // slots 1..3 publish; slot 0 merges in registers with lexicographic comparator
  int base = tid*21;
  if (slot != 0){
    REP20(KPUB)
  }
  __syncthreads();
  if (slot == 0){
    for (int s = 1; s < 4; s++){
      int sb = (s*64 + q_l)*21;
      for (int p = 0; p < KNN; p++){
        float md = dls[sb+p];
        int   mi = (int)ils[sb+p];
        INS_LEX(md, mi);
      }
    }
    int* optr = idx2 + gi*KNN;
    REP20(KOUT)
  }
}

// ---------------- fast path: B2H = x1 @ Wbot[:, q-half] ----------------
__global__ __launch_bounds__(256) void k_B2h(const float* x1, const float* inb,
                                             int q, float* B2H){
  __shared__ __align__(16) float Wbh[4096];
  __shared__ __align__(16) float xsh[1024];
  int tid = threadIdx.x;
  const float* Wb = inb + IN_WBUF + WB_WBOT;
  for (int t = tid; t < 4096; t += 256){
    int r = t >> 6, cl = t & 63;
    Wbh[t] = Wb[r*128 + q*64 + cl];
  }
  int node0 = blockIdx.x * 16;
  for (int t = tid; t < 1024; t += 256) xsh[t] = x1[node0*64 + t];
  __syncthreads();
  int n_l = tid >> 4, cg = tid & 15;
  const float* xr = xsh + n_l*64;
  float4 acc = make_float4(0.f,0.f,0.f,0.f);
  #pragma unroll 8
  for (int d = 0; d < 64; d++){
    float v = xr[d];
    float4 w = *(const float4*)(Wbh + d*64 + cg*4);
    acc.x += v*w.x; acc.y += v*w.y; acc.z += v*w.z; acc.w += v*w.w;
  }
  *(float4*)(B2H + (node0 + n_l)*64 + cg*4) = acc;
}

// ---------------- fast path: x2 half = (x1_i@Wd + bc2) + max_j B2H[j] ----------------
__global__ __launch_bounds__(256) void k_x2h(const float* x1, const float* B2H,
                                             const float* inb, const int* idx2,
                                             int q, float* x2){
  __shared__ __align__(16) float Wdh[4096];
  __shared__ __align__(16) float xsh[256];
  int tid = threadIdx.x;
  const float* Wd = inb + IN_WBUF + WB_WD;
  for (int t = tid; t < 4096; t += 256){
    int r = t >> 6, cl = t & 63;
    Wdh[t] = Wd[r*128 + q*64 + cl];
  }
  int node0 = blockIdx.x * 4;
  xsh[tid] = x1[node0*64 + tid];
  __syncthreads();
  int n_l = tid >> 6, cl = tid & 63;
  int i = node0 + n_l;
  int b = i >> 10;
  const float* xr = xsh + n_l*64;
  float acc = inb[IN_BC2 + q*64 + cl];
  #pragma unroll 8
  for (int d = 0; d < 64; d++) acc += xr[d]*Wdh[d*64 + cl];
  float m = -FLT_MAX;
  for (int kk = 0; kk < KNN; kk++){
    int j = idx2[i*KNN + kk];
    m = fmaxf(m, B2H[((b<<10)+j)*64 + cl]);
  }
  x2[i*128 + q*64 + cl] = acc + m;
}

// ---------------- slow fallback: x2 direct, LDS-staged, no B2H buffer ----------------
__global__ __launch_bounds__(256) void k_x2d(const float* x1, const float* inb,
                                             const int* idx2, float* x2){
  __shared__ __align__(16) float Wdh[4096], Wbh[4096];
  __shared__ __align__(16) float xis[1024], xjs[1024];
  int tid = threadIdx.x;
  int q = blockIdx.x & 1;
  int node0 = (blockIdx.x >> 1) * 16;
  const float* Wd = inb + IN_WBUF + WB_WD;
  const float* Wb = inb + IN_WBUF + WB_WBOT;
  for (int t = tid; t < 4096; t += 256){
    int r = t >> 6, cl = t & 63;
    Wdh[t] = Wd[r*128 + q*64 + cl];
    Wbh[t] = Wb[r*128 + q*64 + cl];
  }
  for (int t = tid; t < 1024; t += 256) xis[t] = x1[node0*64 + t];
  __syncthreads();
  int n_l = tid >> 4, cg = tid & 15;
  int i = node0 + n_l, b = i >> 10;
  const float* xr = xis + n_l*64;
  float4 af = make_float4(inb[IN_BC2 + q*64 + cg*4],   inb[IN_BC2 + q*64 + cg*4+1],
                          inb[IN_BC2 + q*64 + cg*4+2], inb[IN_BC2 + q*64 + cg*4+3]);
  #pragma unroll 8
  for (int d = 0; d < 64; d++){
    float v = xr[d];
    float4 w = *(const float4*)(Wdh + d*64 + cg*4);
    af.x += v*w.x; af.y += v*w.y; af.z += v*w.z; af.w += v*w.w;
  }
  float4 mx = make_float4(-FLT_MAX,-FLT_MAX,-FLT_MAX,-FLT_MAX);
  for (int kk = 0; kk < KNN; kk++){
    __syncthreads();
    for (int t = tid; t < 1024; t += 256){
      int nn = t >> 6, r = t & 63;
      int jj = idx2[(node0+nn)*KNN + kk];
      xjs[t] = x1[((((node0+nn) >> 10) << 10) + jj)*64 + r];
    }
    __syncthreads();
    const float* xj = xjs + n_l*64;
    float4 acc = make_float4(0.f,0.f,0.f,0.f);
    #pragma unroll 8
    for (int d = 0; d < 64; d++){
      float v = xj[d];
      float4 w = *(const float4*)(Wbh + d*64 + cg*4);
      acc.x += v*w.x; acc.y += v*w.y; acc.z += v*w.z; acc.w += v*w.w;
    }
    mx.x = fmaxf(mx.x, acc.x); mx.y = fmaxf(mx.y, acc.y);
    mx.z = fmaxf(mx.z, acc.z); mx.w = fmaxf(mx.w, acc.w);
  }
  *(float4*)(x2 + i*128 + q*64 + cg*4) =
      make_float4(af.x+mx.x, af.y+mx.y, af.z+mx.z, af.w+mx.w);
}

// ---------------- lin (192->1024) + partial max over n-quarter ----------------
__global__ __launch_bounds__(256) void k_linpool(const float* x1, const float* x2,
    const float* inb, float* pool4){
  __shared__ __align__(16) float fst[192*36];
  __shared__ float red2[1024];
  int tid = threadIdx.x;
  int b = blockIdx.x >> 4, cq = (blockIdx.x >> 2) & 3, nh = blockIdx.x & 3;
  int cg = tid & 63, n8 = tid >> 6;
  int cbase = cq*256 + cg*4;
  const float* Wl = inb + IN_WBUF + WB_WL;
  float m0 = -FLT_MAX, m1 = -FLT_MAX, m2 = -FLT_MAX, m3 = -FLT_MAX;
  for (int ng = 0; ng < 8; ng++){
    __syncthreads();
    for (int t = tid; t < 6144; t += 256){
      int n_l = t / 192, dd = t - n_l*192;
      int gi = b*1024 + nh*256 + ng*32 + n_l;
      fst[dd*36 + n_l] = (dd < 64) ? x1[gi*64 + dd] : x2[gi*128 + dd - 64];
    }
    __syncthreads();
    float acc[8][4];
    #pragma unroll
    for (int n = 0; n < 8; n++){ acc[n][0]=0; acc[n][1]=0; acc[n][2]=0; acc[n][3]=0; }
    #pragma unroll 4
    for (int d = 0; d < 192; d++){
      float4 w = *(const float4*)(Wl + d*1024 + cbase);
      const float* fr = fst + d*36 + n8*8;
      float4 f0 = *(const float4*)(fr);
      float4 f1 = *(const float4*)(fr + 4);
      float fv[8] = {f0.x, f0.y, f0.z, f0.w, f1.x, f1.y, f1.z, f1.w};
      #pragma unroll
      for (int n = 0; n < 8; n++){
        acc[n][0] += fv[n]*w.x; acc[n][1] += fv[n]*w.y;
        acc[n][2] += fv[n]*w.z; acc[n][3] += fv[n]*w.w;
      }
    }
    #pragma unroll
    for (int n = 0; n < 8; n++){
      m0 = fmaxf(m0, acc[n][0]); m1 = fmaxf(m1, acc[n][1]);
      m2 = fmaxf(m2, acc[n][2]); m3 = fmaxf(m3, acc[n][3]);
    }
  }
  red2[n8*256 + cg*4]   = m0;  red2[n8*256 + cg*4+1] = m1;
  red2[n8*256 + cg*4+2] = m2;  red2[n8*256 + cg*4+3] = m3;
  __syncthreads();
  if (n8 == 0){
    #pragma unroll
    for (int u = 0; u < 4; u++){
      int cc = cg*4 + u;
      float m = fmaxf(fmaxf(red2[cc], red2[256+cc]), fmaxf(red2[512+cc], red2[768+cc]));
      pool4[nh*32768 + b*1024 + cbase + u] = m;     // bias applied in k_head
    }
  }
}

// ---------------- head MLP: reduce pool4 + 1024->512->256->40 (fp32 out) ----------------
__global__ __launch_bounds__(256) void k_head(const float* pool4, const float* inb,
                                              float* out){
  __shared__ float pl[1024];
  __shared__ float s1[512];
  __shared__ float s2[256];
  int b = blockIdx.x, tid = threadIdx.x;
  const float* Wm1 = inb + IN_WBUF + WB_WM1;
  const float* Wm2 = inb + IN_WBUF + WB_WM2;
  const float* Wm3 = inb + IN_WBUF + WB_WM3;
  for (int t = tid; t < 1024; t += 256){
    float m = fmaxf(fmaxf(pool4[b*1024 + t],         pool4[32768 + b*1024 + t]),
                    fmaxf(pool4[65536 + b*1024 + t], pool4[98304 + b*1024 + t]));
    pl[t] = m + inb[IN_BL + t];
  }
  __syncthreads();
  for (int c = tid; c < 512; c += 256){
    float acc = inb[IN_BM1 + c];
    #pragma unroll 4
    for (int d = 0; d < 1024; d++) acc += pl[d]*Wm1[d*512 + c];
    s1[c] = fmaxf(acc, 0.f);
  }
  __syncthreads();
  {
    int c = tid;
    float acc = inb[IN_BM2 + c];
    #pragma unroll 4
    for (int d = 0; d < 512; d++) acc += s1[d]*Wm2[d*256 + c];
    s2[c] = fmaxf(acc, 0.f);
  }
  __syncthreads();
  if (tid < 40){
    float acc = inb[IN_BM3 + tid];
    #pragma unroll 4
    for (int d = 0; d < 256; d++) acc += s2[d]*Wm3[d*40 + tid];
    out[b*40 + tid] = acc;
  }
}

extern "C" void kernel_launch(void* const* d_in, const int* in_sizes, int n_in,
                              void* d_out, int out_size, void* d_ws, size_t ws_size,
                              hipStream_t stream){
  float* ws     = (float*)d_ws;
  double* stats = (double*)d_ws;
  int*   flag   = (int*)d_ws + OFF_FLAG;
  float* inb    = ws + OFF_INB;
  int*   idx    = (int*)d_ws + OFF_IDX;     // idx1 early, idx2 late
  float* x1p    = ws + OFF_X1;
  float* x2p    = ws + OFF_X2;
  float* a1     = ws + OFF_X2;              // a1/c1 alias x2 region (dead before x2 written)
  float* c1     = ws + OFF_C1;
  float* pool4  = ws + OFF_POOL;
  float* B2H    = ws + OFF_B2H;
  bool fast = ws_size >= (size_t)FAST_END * 4u;

  hipMemsetAsync(stats, 0, 256*sizeof(double), stream);
  k_sniff<<<1, 64, 0, stream>>>(d_in[0], flag);
  k_cvt<<<3859, 256, 0, stream>>>(
      d_in[0], d_in[1], d_in[2], d_in[3], d_in[4], d_in[5], d_in[6], d_in[7],
      d_in[8], d_in[9], d_in[10], d_in[11], d_in[12], d_in[13], d_in[14],
      d_in[15], d_in[16], d_in[17], d_in[18], d_in[19], d_in[20], flag, inb);
  k_prep1<<<8192, 256, 0, stream>>>(inb, a1, c1);
  k_knn1<<<512, 256, 0, stream>>>(inb, idx);
  k_stats1<<<640, 256, 0, stream>>>(a1, c1, idx, stats);
  k_stats2<<<2560, 256, 0, stream>>>(a1, c1, idx, inb, stats);
  k_x1<<<8192, 256, 0, stream>>>(a1, c1, idx, inb, stats, x1p);
  k_knn2<<<512, 256, 0, stream>>>(x1p, idx);
  if (fast){
    k_B2h<<<2048, 256, 0, stream>>>(x1p, inb, 0, B2H);
    k_x2h<<<8192, 256, 0, stream>>>(x1p, B2H, inb, idx, 0, x2p);
    k_B2h<<<2048, 256, 0, stream>>>(x1p, inb, 1, B2H);
    k_x2h<<<8192, 256, 0, stream>>>(x1p, B2H, inb, idx, 1, x2p);
  } else {
    k_x2d<<<4096, 256, 0, stream>>>(x1p, inb, idx, x2p);
  }
  k_linpool<<<512, 256, 0, stream>>>(x1p, x2p, inb, pool4);
  k_head<<<32, 256, 0, stream>>>(pool4, inb, (float*)d_out);
}

// Round 4
// 1511.400 us; speedup vs baseline: 2.9245x; 1.0411x over previous
//
#include <hip/hip_runtime.h>
#include <hip/hip_bf16.h>
#include <float.h>
#include <math.h>

typedef __hip_bfloat16 bf16;
typedef unsigned long long u64;

#define BATCH 32
#define NPTS  1024
#define KNN   20
#define NB    (BATCH*NPTS)      // 32768 nodes
#define NEDGE (NB*KNN)          // 655360 edges

// ---- workspace layout (float units), ws_size-adaptive ----
#define OFF_FLAG 512u
#define OFF_INB  1024u
#define OFF_IDX  988928u          // 655360 ints (idx1 early, idx2 late)
#define OFF_X1   1644288u         // NB*64
#define OFF_X2   3741440u         // NB*128 ; a1 @ OFF_X2, c1 @ OFF_C1 (early)
#define OFF_C1   5838592u
#define OFF_POOL 7935744u         // pool4: 4 x 32*1024
#define SLOW_END 8066816u         // 32.3 MB
#define OFF_B2H  8066816u         // NB*64 (fast path only)
#define FAST_END 10163968u        // 40.7 MB
// kNN partial lists (u64): 32768 queries x 2 halves x 20 = 10.5 MB.
// Lives at OFF_X2 (a1/c1/x2 region): dead during knn1 (prep1 runs after merge1)
// and during knn2 (a1/c1 dead after k_x1, x2 written after merge2).
// ---- layout inside inb (canonical fp32 inputs) ----
#define IN_POSF 0u
#define IN_B1   98304u
#define IN_G1   98368u
#define IN_BE1  98432u
#define IN_B2   98496u
#define IN_G2   98560u
#define IN_BE2  98624u
#define IN_B3   98688u
#define IN_BC2  98752u
#define IN_BL   98880u
#define IN_BM1  99904u
#define IN_BM2  100416u
#define IN_BM3  100672u
#define IN_W1   100736u
#define IN_WBUF 101120u
#define WB_W2   0u
#define WB_W3   4096u
#define WB_WD   8192u            // Wc2 top-bot diff [64x128]
#define WB_WBOT 16384u           // Wc2 bottom      [64x128]
#define WB_WL   24576u
#define WB_WM1  221184u
#define WB_WM2  745472u
#define WB_WM3  876544u
#define IN_TOTAL 987904u

__device__ __forceinline__ float bf2f(bf16 v){ return __bfloat162float(v); }

// monotone float->u32 map: preserves IEEE-754 total order for all finite values
__device__ __forceinline__ unsigned int mono32(float f){
  unsigned int b = __float_as_uint(f);
  return b ^ ((unsigned int)((int)b >> 31) | 0x80000000u);
}

// ======== register top-k via 20 NAMED scalars (macro-generated) ========
// Round-1: arrays spill to scratch; named scalars cannot. Round-2: REP20 can't
// nest inside a macro expanded by REP20 (blue-paint) -> runtime loops call the
// insert macros only at top level. Branchless compare-and-shift == sorted-insert
// walk with strict > (ties keep earlier candidate = top_k semantics).
#define REP20(M) M(0) M(1) M(2) M(3) M(4) M(5) M(6) M(7) M(8) M(9) \
                 M(10) M(11) M(12) M(13) M(14) M(15) M(16) M(17) M(18) M(19)
#define SH19(M) M(19,18) M(18,17) M(17,16) M(16,15) M(15,14) M(14,13) M(13,12) \
                M(12,11) M(11,10) M(10,9) M(9,8) M(8,7) M(7,6) M(6,5) M(5,4) \
                M(4,3) M(3,2) M(2,1) M(1,0)

#define KDECL(p) float rd##p = FLT_MAX; int ri##p = 65535;
#define KG_P(p)  bool gt##p = rd##p > _d;
#define KSH(p,pm) rd##p = gt##p ? (gt##pm ? rd##pm : _d) : rd##p; \
                  ri##p = gt##p ? (gt##pm ? ri##pm : _c) : ri##p;
#define INS_PLAIN(dv,cv) do{ float _d=(dv); int _c=(cv); \
  REP20(KG_P) SH19(KSH) \
  rd0 = gt0 ? _d : rd0; ri0 = gt0 ? _c : ri0; }while(0)

// u64-key list (key = mono32(d)<<32 | idx; strict > == lexicographic (d,idx))
#define KCNV(p)  u64 mk##p = ((u64)mono32(rd##p) << 32) | (unsigned int)ri##p;
#define KG_U(p)  bool gu##p = mk##p > _k;
#define KSH_U(p,pm) mk##p = gu##p ? (gu##pm ? mk##pm : _k) : mk##p;
#define INS_U64(kv) do{ u64 _k=(kv); \
  REP20(KG_U) SH19(KSH_U) \
  mk0 = gu0 ? _k : mk0; }while(0)

#define KPUB_A(p) mrgA[q_l*21+p] = mk##p;
#define KPUB_B(p) mrgB[q_l*21+p] = mk##p;
#define KSTG(p)   gpart[p] = mk##p;
#define KLDA(p)   u64 mk##p = pa[p];
#define KOUTU(p)  optr[p] = (int)(unsigned int)(mk##p & 0xFFFFFFFFull);

// ---------------- dtype sniff (fp32 vs bf16 inputs) ----------------
__global__ void k_sniff(const void* pos_raw, int* flag){
  if (blockIdx.x == 0 && threadIdx.x == 0){
    const unsigned short* h = (const unsigned short*)pos_raw;
    int wild = 0;
    for (int k = 0; k < 16; k++){
      unsigned int bits = ((unsigned int)h[2*k]) << 16;
      float v = __uint_as_float(bits);
      float a = fabsf(v);
      if (a != 0.0f && (v != v || a > 1e10f || a < 1e-10f)) wild++;
    }
    *flag = (wild >= 4) ? 1 : 0;
  }
}

__device__ __forceinline__ float rdv(const void* p, int i, int f){
  return f ? ((const float*)p)[i] : bf2f(((const bf16*)p)[i]);
}

// ---------------- normalize ALL inputs to canonical fp32 buffer ----------------
__global__ __launch_bounds__(256) void k_cvt(
    const void* pos, const void* W1, const void* b1, const void* g1, const void* be1,
    const void* W2, const void* b2, const void* g2, const void* be2,
    const void* W3, const void* b3, const void* Wc2, const void* bc2,
    const void* Wl, const void* bl, const void* Wm1, const void* bm1,
    const void* Wm2, const void* bm2, const void* Wm3, const void* bm3,
    const int* flag, float* inb){
  int id = blockIdx.x*256 + threadIdx.x;
  if (id >= (int)IN_TOTAL) return;
  int f = *flag;
  float v;
  if      (id < 98304)  v = rdv(pos, id, f);
  else if (id < 98368)  v = rdv(b1,  id-98304, f);
  else if (id < 98432)  v = rdv(g1,  id-98368, f);
  else if (id < 98496)  v = rdv(be1, id-98432, f);
  else if (id < 98560)  v = rdv(b2,  id-98496, f);
  else if (id < 98624)  v = rdv(g2,  id-98560, f);
  else if (id < 98688)  v = rdv(be2, id-98624, f);
  else if (id < 98752)  v = rdv(b3,  id-98688, f);
  else if (id < 98880)  v = rdv(bc2, id-98752, f);
  else if (id < 99904)  v = rdv(bl,  id-98880, f);
  else if (id < 100416) v = rdv(bm1, id-99904, f);
  else if (id < 100672) v = rdv(bm2, id-100416, f);
  else if (id < 100712) v = rdv(bm3, id-100672, f);
  else if (id < 100736) v = 0.0f;
  else if (id < 101120) v = rdv(W1,  id-100736, f);
  else {
    int t = id - 101120;
    if      (t < 4096)   v = rdv(W2, t, f);
    else if (t < 8192)   v = rdv(W3, t-4096, f);
    else if (t < 16384){ int u = t-8192;  v = rdv(Wc2, u, f) - rdv(Wc2, 8192+u, f); }
    else if (t < 24576){ int u = t-16384; v = rdv(Wc2, 8192+u, f); }
    else if (t < 221184) v = rdv(Wl,  t-24576, f);
    else if (t < 745472) v = rdv(Wm1, t-221184, f);
    else if (t < 876544) v = rdv(Wm2, t-745472, f);
    else                 v = rdv(Wm3, t-876544, f);
  }
  inb[id] = v;
}

// ---------------- a1/c1: affine decomposition of EdgeConv1 layer1 ----------------
__global__ __launch_bounds__(256) void k_prep1(const float* inb, float* a1, float* c1){
  const float* posf = inb + IN_POSF;
  const float* W1f  = inb + IN_W1;
  const float* b1f  = inb + IN_B1;
  int id = blockIdx.x*256 + threadIdx.x;
  int bn = id >> 6, c = id & 63;
  float p0 = posf[bn*3], p1 = posf[bn*3+1], p2 = posf[bn*3+2];
  float wt0 = W1f[c],     wt1 = W1f[64+c],  wt2 = W1f[128+c];
  float wb0 = W1f[192+c], wb1 = W1f[256+c], wb2 = W1f[320+c];
  float cv = p0*wb0 + p1*wb1 + p2*wb2;
  float av = p0*(wt0-wb0) + p1*(wt1-wb1) + p2*(wt2-wb2) + b1f[c];
  a1[id] = av;  c1[id] = cv;
}

// ---------------- kNN in coordinate space (half-split, register top-k) ----------------
// grid 1024: 32 batches x 16 query-groups x 2 candidate halves. Each block:
// 64 queries x 4 slots, each slot scans 128 candidates of its half. In-block
// u64 tree merge (slot1->A, slot3->B; slot0+=A, slot2+=B; slot2->B; slot0+=B),
// then slot0 writes the sorted half-list to global; k_mrg combines halves.
__global__ __launch_bounds__(256, 2) void k_knn1(const float* inb, u64* part){
  const float* posf = inb + IN_POSF;
  __shared__ float psx[1024], psy[1024], psz[1024], sqs[1024];
  __shared__ u64 mrgA[64*21];
  __shared__ u64 mrgB[64*21];
  int bb   = blockIdx.x >> 5;
  int qg   = (blockIdx.x >> 1) & 15;
  int half = blockIdx.x & 1;
  int tid = threadIdx.x;
  int q_l = tid & 63;
  int slot = tid >> 6;
  for (int t = tid; t < 1024; t += 256){
    float x = posf[(bb*1024+t)*3], y = posf[(bb*1024+t)*3+1], z = posf[(bb*1024+t)*3+2];
    psx[t] = x; psy[t] = y; psz[t] = z; sqs[t] = x*x + y*y + z*z;
  }
  __syncthreads();
  int i_l = qg*64 + q_l;
  float xi0 = psx[i_l], xi1 = psy[i_l], xi2 = psz[i_l];
  float sqi = sqs[i_l];
  REP20(KDECL)
  int cbase = half*512;
  // ascending jj per slot -> ties keep lower idx (matches top_k)
  for (int u = 0; u < 128; u++){
    int jj = cbase + 4*u + slot;
    float dot = xi0*psx[jj] + xi1*psy[jj] + xi2*psz[jj];
    float d = sqi + sqs[jj] - 2.0f*dot;
    INS_PLAIN(d, jj);
  }
  // convert to u64 keys, tree-merge the 4 slot lists
  REP20(KCNV)
  if (slot == 1){ REP20(KPUB_A) }
  if (slot == 3){ REP20(KPUB_B) }
  __syncthreads();
  if ((slot & 1) == 0){
    const u64* src = (slot == 0) ? &mrgA[q_l*21] : &mrgB[q_l*21];
    for (int p = 0; p < KNN; p++){
      u64 kv = src[p];
      if (kv > mk19) break;          // sorted source: rest are worse
      INS_U64(kv);
    }
  }
  __syncthreads();
  if (slot == 2){ REP20(KPUB_B) }
  __syncthreads();
  if (slot == 0){
    const u64* src = &mrgB[q_l*21];
    for (int p = 0; p < KNN; p++){
      u64 kv = src[p];
      if (kv > mk19) break;
      INS_U64(kv);
    }
    int gi = bb*1024 + i_l;
    u64* gpart = part + ((size_t)gi*2 + half)*KNN;
    REP20(KSTG)
  }
}

// ---------------- merge two sorted 20-entry half-lists per query ----------------
__global__ __launch_bounds__(256) void k_mrg(const u64* part, int* out){
  int gi = blockIdx.x*256 + threadIdx.x;    // grid 128 -> 32768 queries
  const u64* pa = part + (size_t)gi*2*KNN;
  REP20(KLDA)                                // init from half-0 list (sorted)
  for (int p = 0; p < KNN; p++){
    u64 kv = pa[KNN + p];
    if (kv > mk19) break;                    // sorted source: rest are worse
    INS_U64(kv);
  }
  int* optr = out + gi*KNN;
  REP20(KOUTU)
}

// ---------------- BN1 stats ----------------
__global__ __launch_bounds__(256) void k_stats1(const float* a1, const float* c1,
                                                const int* idx1, double* stats){
  __shared__ float rs[256], rs2[256];
  int tid = threadIdx.x, c = tid & 63, slot = tid >> 6;
  int base = blockIdx.x * 1024;
  float s = 0.f, s2 = 0.f;
  for (int t = 0; t < 256; t++){
    unsigned e = (unsigned)(base + t*4 + slot);
    int i = (int)(e / 20u);
    int b = i >> 10;
    int j = idx1[e];
    float h = a1[i*64+c] + c1[((b<<10)+j)*64 + c];
    s += h; s2 += h*h;
  }
  rs[tid] = s; rs2[tid] = s2;
  __syncthreads();
  if (slot == 0){
    double ts  = (double)rs[c]  + (double)rs[64+c]  + (double)rs[128+c]  + (double)rs[192+c];
    double ts2 = (double)rs2[c] + (double)rs2[64+c] + (double)rs2[128+c] + (double)rs2[192+c];
    atomicAdd(&stats[c], ts);
    atomicAdd(&stats[64+c], ts2);
  }
}

// ---------------- BN2 stats (slot-stride 68: bank-conflict-free) ----------------
__global__ __launch_bounds__(256) void k_stats2(const float* a1, const float* c1,
    const int* idx1, const float* inb, double* stats){
  __shared__ __align__(16) float W2s[4096];
  __shared__ __align__(16) float buf[16*68];
  __shared__ float rs[64], rs2[64];
  int tid = threadIdx.x;
  const float* wbuf = inb + IN_WBUF;
  for (int t = tid; t < 4096; t += 256) W2s[t] = wbuf[WB_W2 + t];
  if (tid < 64){ rs[tid] = 0.f; rs2[tid] = 0.f; }
  int slot = tid >> 4;
  int cg = tid & 15;
  const double M = (double)NEDGE;
  float sc1[4], sh1[4], bb2[4];
  #pragma unroll
  for (int u = 0; u < 4; u++){
    int c = cg*4 + u;
    double mean = stats[c] / M;
    double var  = stats[64+c] / M - mean*mean;
    double rstd = 1.0 / sqrt(var + 1e-5);
    double g = (double)inb[IN_G1 + c];
    sc1[u] = (float)(g*rstd);
    sh1[u] = (float)((double)inb[IN_BE1 + c] - mean*g*rstd);
    bb2[u] = inb[IN_B2 + c];
  }
  float s[4] = {0,0,0,0}, s2[4] = {0,0,0,0};
  int base = blockIdx.x * 256;
  for (int it = 0; it < 16; it++){
    unsigned e = (unsigned)(base + it*16 + slot);
    int i = (int)(e / 20u);
    int b = i >> 10;
    int j = idx1[e];
    int gj = (b<<10) + j;
    float4 av = *(const float4*)(a1 + i*64 + cg*4);
    float4 cv = *(const float4*)(c1 + gj*64 + cg*4);
    float4 h;
    h.x = fmaxf(0.f, (av.x+cv.x)*sc1[0] + sh1[0]);
    h.y = fmaxf(0.f, (av.y+cv.y)*sc1[1] + sh1[1]);
    h.z = fmaxf(0.f, (av.z+cv.z)*sc1[2] + sh1[2]);
    h.w = fmaxf(0.f, (av.w+cv.w)*sc1[3] + sh1[3]);
    *(float4*)(buf + slot*68 + cg*4) = h;
    __syncthreads();
    float acc0 = bb2[0], acc1 = bb2[1], acc2 = bb2[2], acc3 = bb2[3];
    const float* bs = buf + slot*68;
    #pragma unroll
    for (int d4 = 0; d4 < 16; d4++){
      float4 hv = *(const float4*)(bs + d4*4);
      float4 w0 = *(const float4*)(W2s + (d4*4+0)*64 + cg*4);
      float4 w1 = *(const float4*)(W2s + (d4*4+1)*64 + cg*4);
      float4 w2 = *(const float4*)(W2s + (d4*4+2)*64 + cg*4);
      float4 w3 = *(const float4*)(W2s + (d4*4+3)*64 + cg*4);
      acc0 += hv.x*w0.x + hv.y*w1.x + hv.z*w2.x + hv.w*w3.x;
      acc1 += hv.x*w0.y + hv.y*w1.y + hv.z*w2.y + hv.w*w3.y;
      acc2 += hv.x*w0.z + hv.y*w1.z + hv.z*w2.z + hv.w*w3.z;
      acc3 += hv.x*w0.w + hv.y*w1.w + hv.z*w2.w + hv.w*w3.w;
    }
    s[0] += acc0; s2[0] += acc0*acc0;
    s[1] += acc1; s2[1] += acc1*acc1;
    s[2] += acc2; s2[2] += acc2*acc2;
    s[3] += acc3; s2[3] += acc3*acc3;
    __syncthreads();
  }
  #pragma unroll
  for (int u = 0; u < 4; u++){
    atomicAdd(&rs[cg*4+u], s[u]);
    atomicAdd(&rs2[cg*4+u], s2[u]);
  }
  __syncthreads();
  if (tid < 64){
    atomicAdd(&stats[128+tid], (double)rs[tid]);
    atomicAdd(&stats[192+tid], (double)rs2[tid]);
  }
}

// ---------------- full MLP1 + max over k -> x1 (slot-stride 68) ----------------
__global__ __launch_bounds__(256) void k_x1(const float* a1, const float* c1,
    const int* idx1, const float* inb, const double* stats, float* x1){
  __shared__ __align__(16) float W2s[4096], W3s[4096];
  __shared__ __align__(16) float buf1[16*68], buf2[16*68];
  __shared__ __align__(16) float red[16*64];
  int tid = threadIdx.x;
  const float* wbuf = inb + IN_WBUF;
  for (int t = tid; t < 4096; t += 256){ W2s[t] = wbuf[WB_W2+t]; W3s[t] = wbuf[WB_W3+t]; }
  int slotid = tid >> 4;
  int n_l = slotid >> 2, eslot = slotid & 3;
  int cg = tid & 15;
  const double M = (double)NEDGE;
  float sc1[4], sh1[4], bb2[4], sc2[4], sh2[4], bb3[4];
  #pragma unroll
  for (int u = 0; u < 4; u++){
    int c = cg*4 + u;
    double m1 = stats[c] / M;
    double v1 = stats[64+c] / M - m1*m1;
    double r1 = 1.0 / sqrt(v1 + 1e-5);
    double gg1 = (double)inb[IN_G1 + c];
    sc1[u] = (float)(gg1*r1);
    sh1[u] = (float)((double)inb[IN_BE1 + c] - m1*gg1*r1);
    bb2[u] = inb[IN_B2 + c];
    double m2 = stats[128+c] / M;
    double v2 = stats[192+c] / M - m2*m2;
    double r2 = 1.0 / sqrt(v2 + 1e-5);
    double gg2 = (double)inb[IN_G2 + c];
    sc2[u] = (float)(gg2*r2);
    sh2[u] = (float)((double)inb[IN_BE2 + c] - m2*gg2*r2);
    bb3[u] = inb[IN_B3 + c];
  }
  __syncthreads();
  int i = blockIdx.x*4 + n_l;
  int b = i >> 10;
  float mx[4] = {-FLT_MAX, -FLT_MAX, -FLT_MAX, -FLT_MAX};
  for (int it = 0; it < 5; it++){
    int kk = it*4 + eslot;
    int j = idx1[i*KNN + kk];
    int gj = (b<<10) + j;
    float4 av = *(const float4*)(a1 + i*64 + cg*4);
    float4 cv = *(const float4*)(c1 + gj*64 + cg*4);
    float4 h;
    h.x = fmaxf(0.f, (av.x+cv.x)*sc1[0] + sh1[0]);
    h.y = fmaxf(0.f, (av.y+cv.y)*sc1[1] + sh1[1]);
    h.z = fmaxf(0.f, (av.z+cv.z)*sc1[2] + sh1[2]);
    h.w = fmaxf(0.f, (av.w+cv.w)*sc1[3] + sh1[3]);
    *(float4*)(buf1 + slotid*68 + cg*4) = h;
    __syncthreads();
    float a0 = bb2[0], a1v = bb2[1], a2v = bb2[2], a3v = bb2[3];
    const float* bs = buf1 + slotid*68;
    #pragma unroll
    for (int d4 = 0; d4 < 16; d4++){
      float4 hv = *(const float4*)(bs + d4*4);
      float4 w0 = *(const float4*)(W2s + (d4*4+0)*64 + cg*4);
      float4 w1 = *(const float4*)(W2s + (d4*4+1)*64 + cg*4);
      float4 w2 = *(const float4*)(W2s + (d4*4+2)*64 + cg*4);
      float4 w3 = *(const float4*)(W2s + (d4*4+3)*64 + cg*4);
      a0  += hv.x*w0.x + hv.y*w1.x + hv.z*w2.x + hv.w*w3.x;
      a1v += hv.x*w0.y + hv.y*w1.y + hv.z*w2.y + hv.w*w3.y;
      a2v += hv.x*w0.z + hv.y*w1.z + hv.z*w2.z + hv.w*w3.z;
      a3v += hv.x*w0.w + hv.y*w1.w + hv.z*w2.w + hv.w*w3.w;
    }
    float4 h2;
    h2.x = fmaxf(0.f, a0*sc2[0] + sh2[0]);
    h2.y = fmaxf(0.f, a1v*sc2[1] + sh2[1]);
    h2.z = fmaxf(0.f, a2v*sc2[2] + sh2[2]);
    h2.w = fmaxf(0.f, a3v*sc2[3] + sh2[3]);
    *(float4*)(buf2 + slotid*68 + cg*4) = h2;
    __syncthreads();
    float c0 = bb3[0], c1v = bb3[1], c2v = bb3[2], c3v = bb3[3];
    const float* bs2 = buf2 + slotid*68;
    #pragma unroll
    for (int d4 = 0; d4 < 16; d4++){
      float4 hv = *(const float4*)(bs2 + d4*4);
      float4 w0 = *(const float4*)(W3s + (d4*4+0)*64 + cg*4);
      float4 w1 = *(const float4*)(W3s + (d4*4+1)*64 + cg*4);
      float4 w2 = *(const float4*)(W3s + (d4*4+2)*64 + cg*4);
      float4 w3 = *(const float4*)(W3s + (d4*4+3)*64 + cg*4);
      c0  += hv.x*w0.x + hv.y*w1.x + hv.z*w2.x + hv.w*w3.x;
      c1v += hv.x*w0.y + hv.y*w1.y + hv.z*w2.y + hv.w*w3.y;
      c2v += hv.x*w0.z + hv.y*w1.z + hv.z*w2.z + hv.w*w3.z;
      c3v += hv.x*w0.w + hv.y*w1.w + hv.z*w2.w + hv.w*w3.w;
    }
    mx[0] = fmaxf(mx[0], c0);  mx[1] = fmaxf(mx[1], c1v);
    mx[2] = fmaxf(mx[2], c2v); mx[3] = fmaxf(mx[3], c3v);
  }
  *(float4*)(red + slotid*64 + cg*4) = make_float4(mx[0], mx[1], mx[2], mx[3]);
  __syncthreads();
  if (eslot == 0){
    #pragma unroll
    for (int u = 0; u < 4; u++){
      int c = cg*4 + u;
      float m = fmaxf(fmaxf(red[(n_l*4+0)*64+c], red[(n_l*4+1)*64+c]),
                      fmaxf(red[(n_l*4+2)*64+c], red[(n_l*4+3)*64+c]));
      x1[i*64 + c] = m;
    }
  }
}

// ---------------- kNN in 64-d feature space (half-split, register top-k) ----------------
// grid 1024: 32 batches x 16 query-groups x 2 candidate halves. Each slot scans
// 128 candidates (8 chunks of 64 staged in LDS, broadcast reads, 2-cand ILP).
// Top-20 in 40 named VGPRs; branchless insert; u64 tree merge as in k_knn1.
__global__ __launch_bounds__(256, 2) void k_knn2(const float* x1, u64* part){
  __shared__ __align__(16) float xs[64*68];          // 17408 B
  __shared__ float sqc[64];
  __shared__ u64 mrgA[64*21];                        // 10752 B
  __shared__ u64 mrgB[64*21];                        // 10752 B
  int bb   = blockIdx.x >> 5;
  int qg   = (blockIdx.x >> 1) & 15;
  int half = blockIdx.x & 1;
  int tid = threadIdx.x;
  int q_l = tid & 63;
  int slot = tid >> 6;               // wave index == slot
  int gi = bb*1024 + qg*64 + q_l;
  float4 xiv[16];
  #pragma unroll
  for (int d4 = 0; d4 < 16; d4++)
    xiv[d4] = *(const float4*)(x1 + gi*64 + d4*4);
  float sqi = 0.f;
  #pragma unroll
  for (int d4 = 0; d4 < 16; d4++)
    sqi += xiv[d4].x*xiv[d4].x + xiv[d4].y*xiv[d4].y
         + xiv[d4].z*xiv[d4].z + xiv[d4].w*xiv[d4].w;
  REP20(KDECL)
  for (int ch = 0; ch < 8; ch++){
    int c0 = half*512 + ch*64;
    __syncthreads();
    for (int t = tid; t < 4096; t += 256){
      int r = t >> 6, d = t & 63;
      xs[r*68 + d] = x1[(bb*1024 + c0 + r)*64 + d];
    }
    __syncthreads();
    if (tid < 64){
      float s = 0.f;
      #pragma unroll 16
      for (int d = 0; d < 64; d++) s += xs[tid*68+d]*xs[tid*68+d];
      sqc[tid] = s;
    }
    __syncthreads();
    for (int u = 0; u < 16; u += 2){
      int jj0 = 4*u + slot;
      int jj1 = 4*(u+1) + slot;
      const float* xr0 = xs + jj0*68;
      const float* xr1 = xs + jj1*68;
      float dot0 = 0.f, dot1 = 0.f;
      #pragma unroll
      for (int d4 = 0; d4 < 16; d4++){
        float4 v0 = *(const float4*)(xr0 + d4*4);
        float4 v1 = *(const float4*)(xr1 + d4*4);
        dot0 += xiv[d4].x*v0.x + xiv[d4].y*v0.y + xiv[d4].z*v0.z + xiv[d4].w*v0.w;
        dot1 += xiv[d4].x*v1.x + xiv[d4].y*v1.y + xiv[d4].z*v1.z + xiv[d4].w*v1.w;
      }
      float d0 = sqi + sqc[jj0] - 2.0f*dot0;
      float d1 = sqi + sqc[jj1] - 2.0f*dot1;
      // ascending per-slot candidate order -> ties keep lower idx (= top_k)
      INS_PLAIN(d0, c0 + jj0);
      INS_PLAIN(d1, c0 + jj1);
    }
  }
  __syncthreads();
  REP20(KCNV)
  if (slot == 1){ REP20(KPUB_A) }
  if (slot == 3){ REP20(KPUB_B) }
  __syncthreads();
  if ((slot & 1) == 0){
    const u64* src = (slot == 0) ? &mrgA[q_l*21] : &mrgB[q_l*21];
    for (int p = 0; p < KNN; p++){
      u64 kv = src[p];
      if (kv > mk19) break;
      INS_U64(kv);
    }
  }
  __syncthreads();
  if (slot == 2){ REP20(KPUB_B) }
  __syncthreads();
  if (slot == 0){
    const u64* src = &mrgB[q_l*21];
    for (int p = 0; p < KNN; p++){
      u64 kv = src[p];
      if (kv > mk19) break;
      INS_U64(kv);
    }
    u64* gpart = part + ((size_t)gi*2 + half)*KNN;
    REP20(KSTG)
  }
}

// ---------------- fast path: B2H = x1 @ Wbot[:, q-half] ----------------
__global__ __launch_bounds__(256) void k_B2h(const float* x1, const float* inb,
                                             int q, float* B2H){
  __shared__ __align__(16) float Wbh[4096];
  __shared__ __align__(16) float xsh[1024];
  int tid = threadIdx.x;
  const float* Wb = inb + IN_WBUF + WB_WBOT;
  for (int t = tid; t < 4096; t += 256){
    int r = t >> 6, cl = t & 63;
    Wbh[t] = Wb[r*128 + q*64 + cl];
  }
  int node0 = blockIdx.x * 16;
  for (int t = tid; t < 1024; t += 256) xsh[t] = x1[node0*64 + t];
  __syncthreads();
  int n_l = tid >> 4, cg = tid & 15;
  const float* xr = xsh + n_l*64;
  float4 acc = make_float4(0.f,0.f,0.f,0.f);
  #pragma unroll 8
  for (int d = 0; d < 64; d++){
    float v = xr[d];
    float4 w = *(const float4*)(Wbh + d*64 + cg*4);
    acc.x += v*w.x; acc.y += v*w.y; acc.z += v*w.z; acc.w += v*w.w;
  }
  *(float4*)(B2H + (node0 + n_l)*64 + cg*4) = acc;
}

// ---------------- fast path: x2 half = (x1_i@Wd + bc2) + max_j B2H[j] ----------------
__global__ __launch_bounds__(256) void k_x2h(const float* x1, const float* B2H,
                                             const float* inb, const int* idx2,
                                             int q, float* x2){
  __shared__ __align__(16) float Wdh[4096];
  __shared__ __align__(16) float xsh[256];
  int tid = threadIdx.x;
  const float* Wd = inb + IN_WBUF + WB_WD;
  for (int t = tid; t < 4096; t += 256){
    int r = t >> 6, cl = t & 63;
    Wdh[t] = Wd[r*128 + q*64 + cl];
  }
  int node0 = blockIdx.x * 4;
  xsh[tid] = x1[node0*64 + tid];
  __syncthreads();
  int n_l = tid >> 6, cl = tid & 63;
  int i = node0 + n_l;
  int b = i >> 10;
  const float* xr = xsh + n_l*64;
  float acc = inb[IN_BC2 + q*64 + cl];
  #pragma unroll 8
  for (int d = 0; d < 64; d++) acc += xr[d]*Wdh[d*64 + cl];
  float m = -FLT_MAX;
  for (int kk = 0; kk < KNN; kk++){
    int j = idx2[i*KNN + kk];
    m = fmaxf(m, B2H[((b<<10)+j)*64 + cl]);
  }
  x2[i*128 + q*64 + cl] = acc + m;
}

// ---------------- slow fallback: x2 direct, LDS-staged, no B2H buffer ----------------
__global__ __launch_bounds__(256) void k_x2d(const float* x1, const float* inb,
                                             const int* idx2, float* x2){
  __shared__ __align__(16) float Wdh[4096], Wbh[4096];
  __shared__ __align__(16) float xis[1024], xjs[1024];
  int tid = threadIdx.x;
  int q = blockIdx.x & 1;
  int node0 = (blockIdx.x >> 1) * 16;
  const float* Wd = inb + IN_WBUF + WB_WD;
  const float* Wb = inb + IN_WBUF + WB_WBOT;
  for (int t = tid; t < 4096; t += 256){
    int r = t >> 6, cl = t & 63;
    Wdh[t] = Wd[r*128 + q*64 + cl];
    Wbh[t] = Wb[r*128 + q*64 + cl];
  }
  for (int t = tid; t < 1024; t += 256) xis[t] = x1[node0*64 + t];
  __syncthreads();
  int n_l = tid >> 4, cg = tid & 15;
  int i = node0 + n_l, b = i >> 10;
  const float* xr = xis + n_l*64;
  float4 af = make_float4(inb[IN_BC2 + q*64 + cg*4],   inb[IN_BC2 + q*64 + cg*4+1],
                          inb[IN_BC2 + q*64 + cg*4+2], inb[IN_BC2 + q*64 + cg*4+3]);
  #pragma unroll 8
  for (int d = 0; d < 64; d++){
    float v = xr[d];
    float4 w = *(const float4*)(Wdh + d*64 + cg*4);
    af.x += v*w.x; af.y += v*w.y; af.z += v*w.z; af.w += v*w.w;
  }
  float4 mx = make_float4(-FLT_MAX,-FLT_MAX,-FLT_MAX,-FLT_MAX);
  for (int kk = 0; kk < KNN; kk++){
    __syncthreads();
    for (int t = tid; t < 1024; t += 256){
      int nn = t >> 6, r = t & 63;
      int jj = idx2[(node0+nn)*KNN + kk];
      xjs[t] = x1[((((node0+nn) >> 10) << 10) + jj)*64 + r];
    }
    __syncthreads();
    const float* xj = xjs + n_l*64;
    float4 acc = make_float4(0.f,0.f,0.f,0.f);
    #pragma unroll 8
    for (int d = 0; d < 64; d++){
      float v = xj[d];
      float4 w = *(const float4*)(Wbh + d*64 + cg*4);
      acc.x += v*w.x; acc.y += v*w.y; acc.z += v*w.z; acc.w += v*w.w;
    }
    mx.x = fmaxf(mx.x, acc.x); mx.y = fmaxf(mx.y, acc.y);
    mx.z = fmaxf(mx.z, acc.z); mx.w = fmaxf(mx.w, acc.w);
  }
  *(float4*)(x2 + i*128 + q*64 + cg*4) =
      make_float4(af.x+mx.x, af.y+mx.y, af.z+mx.z, af.w+mx.w);
}

// ---------------- lin (192->1024) + partial max over n-quarter ----------------
__global__ __launch_bounds__(256) void k_linpool(const float* x1, const float* x2,
    const float* inb, float* pool4){
  __shared__ __align__(16) float fst[192*36];
  __shared__ float red2[1024];
  int tid = threadIdx.x;
  int b = blockIdx.x >> 4, cq = (blockIdx.x >> 2) & 3, nh = blockIdx.x & 3;
  int cg = tid & 63, n8 = tid >> 6;
  int cbase = cq*256 + cg*4;
  const float* Wl = inb + IN_WBUF + WB_WL;
  float m0 = -FLT_MAX, m1 = -FLT_MAX, m2 = -FLT_MAX, m3 = -FLT_MAX;
  for (int ng = 0; ng < 8; ng++){
    __syncthreads();
    for (int t = tid; t < 6144; t += 256){
      int n_l = t / 192, dd = t - n_l*192;
      int gi = b*1024 + nh*256 + ng*32 + n_l;
      fst[dd*36 + n_l] = (dd < 64) ? x1[gi*64 + dd] : x2[gi*128 + dd - 64];
    }
    __syncthreads();
    float acc[8][4];
    #pragma unroll
    for (int n = 0; n < 8; n++){ acc[n][0]=0; acc[n][1]=0; acc[n][2]=0; acc[n][3]=0; }
    #pragma unroll 4
    for (int d = 0; d < 192; d++){
      float4 w = *(const float4*)(Wl + d*1024 + cbase);
      const float* fr = fst + d*36 + n8*8;
      float4 f0 = *(const float4*)(fr);
      float4 f1 = *(const float4*)(fr + 4);
      float fv[8] = {f0.x, f0.y, f0.z, f0.w, f1.x, f1.y, f1.z, f1.w};
      #pragma unroll
      for (int n = 0; n < 8; n++){
        acc[n][0] += fv[n]*w.x; acc[n][1] += fv[n]*w.y;
        acc[n][2] += fv[n]*w.z; acc[n][3] += fv[n]*w.w;
      }
    }
    #pragma unroll
    for (int n = 0; n < 8; n++){
      m0 = fmaxf(m0, acc[n][0]); m1 = fmaxf(m1, acc[n][1]);
      m2 = fmaxf(m2, acc[n][2]); m3 = fmaxf(m3, acc[n][3]);
    }
  }
  red2[n8*256 + cg*4]   = m0;  red2[n8*256 + cg*4+1] = m1;
  red2[n8*256 + cg*4+2] = m2;  red2[n8*256 + cg*4+3] = m3;
  __syncthreads();
  if (n8 == 0){
    #pragma unroll
    for (int u = 0; u < 4; u++){
      int cc = cg*4 + u;
      float m = fmaxf(fmaxf(red2[cc], red2[256+cc]), fmaxf(red2[512+cc], red2[768+cc]));
      pool4[nh*32768 + b*1024 + cbase + u] = m;     // bias applied in k_head
    }
  }
}

// ---------------- head MLP: reduce pool4 + 1024->512->256->40 (fp32 out) ----------------
__global__ __launch_bounds__(256) void k_head(const float* pool4, const float* inb,
                                              float* out){
  __shared__ float pl[1024];
  __shared__ float s1[512];
  __shared__ float s2[256];
  int b = blockIdx.x, tid = threadIdx.x;
  const float* Wm1 = inb + IN_WBUF + WB_WM1;
  const float* Wm2 = inb + IN_WBUF + WB_WM2;
  const float* Wm3 = inb + IN_WBUF + WB_WM3;
  for (int t = tid; t < 1024; t += 256){
    float m = fmaxf(fmaxf(pool4[b*1024 + t],         pool4[32768 + b*1024 + t]),
                    fmaxf(pool4[65536 + b*1024 + t], pool4[98304 + b*1024 + t]));
    pl[t] = m + inb[IN_BL + t];
  }
  __syncthreads();
  for (int c = tid; c < 512; c += 256){
    float acc = inb[IN_BM1 + c];
    #pragma unroll 4
    for (int d = 0; d < 1024; d++) acc += pl[d]*Wm1[d*512 + c];
    s1[c] = fmaxf(acc, 0.f);
  }
  __syncthreads();
  {
    int c = tid;
    float acc = inb[IN_BM2 + c];
    #pragma unroll 4
    for (int d = 0; d < 512; d++) acc += s1[d]*Wm2[d*256 + c];
    s2[c] = fmaxf(acc, 0.f);
  }
  __syncthreads();
  if (tid < 40){
    float acc = inb[IN_BM3 + tid];
    #pragma unroll 4
    for (int d = 0; d < 256; d++) acc += s2[d]*Wm3[d*40 + tid];
    out[b*40 + tid] = acc;
  }
}

extern "C" void kernel_launch(void* const* d_in, const int* in_sizes, int n_in,
                              void* d_out, int out_size, void* d_ws, size_t ws_size,
                              hipStream_t stream){
  float* ws     = (float*)d_ws;
  double* stats = (double*)d_ws;
  int*   flag   = (int*)d_ws + OFF_FLAG;
  float* inb    = ws + OFF_INB;
  int*   idx    = (int*)d_ws + OFF_IDX;     // idx1 early, idx2 late
  float* x1p    = ws + OFF_X1;
  float* x2p    = ws + OFF_X2;
  float* a1     = ws + OFF_X2;              // a1/c1 alias x2 region (dead before x2 written)
  float* c1     = ws + OFF_C1;
  u64*   part   = (u64*)(ws + OFF_X2);      // kNN partials alias a1/c1 (see layout note)
  float* pool4  = ws + OFF_POOL;
  float* B2H    = ws + OFF_B2H;
  bool fast = ws_size >= (size_t)FAST_END * 4u;

  hipMemsetAsync(stats, 0, 256*sizeof(double), stream);
  k_sniff<<<1, 64, 0, stream>>>(d_in[0], flag);
  k_cvt<<<3859, 256, 0, stream>>>(
      d_in[0], d_in[1], d_in[2], d_in[3], d_in[4], d_in[5], d_in[6], d_in[7],
      d_in[8], d_in[9], d_in[10], d_in[11], d_in[12], d_in[13], d_in[14],
      d_in[15], d_in[16], d_in[17], d_in[18], d_in[19], d_in[20], flag, inb);
  k_knn1<<<1024, 256, 0, stream>>>(inb, part);      // partials in a1/c1 region
  k_mrg<<<128, 256, 0, stream>>>(part, idx);        // -> idx1
  k_prep1<<<8192, 256, 0, stream>>>(inb, a1, c1);   // overwrites dead partials
  k_stats1<<<640, 256, 0, stream>>>(a1, c1, idx, stats);
  k_stats2<<<2560, 256, 0, stream>>>(a1, c1, idx, inb, stats);
  k_x1<<<8192, 256, 0, stream>>>(a1, c1, idx, inb, stats, x1p);
  k_knn2<<<1024, 256, 0, stream>>>(x1p, part);      // a1/c1 dead after k_x1
  k_mrg<<<128, 256, 0, stream>>>(part, idx);        // -> idx2
  if (fast){
    k_B2h<<<2048, 256, 0, stream>>>(x1p, inb, 0, B2H);
    k_x2h<<<8192, 256, 0, stream>>>(x1p, B2H, inb, idx, 0, x2p);
    k_B2h<<<2048, 256, 0, stream>>>(x1p, inb, 1, B2H);
    k_x2h<<<8192, 256, 0, stream>>>(x1p, B2H, inb, idx, 1, x2p);
  } else {
    k_x2d<<<4096, 256, 0, stream>>>(x1p, inb, idx, x2p);
  }
  k_linpool<<<512, 256, 0, stream>>>(x1p, x2p, inb, pool4);
  k_head<<<32, 256, 0, stream>>>(pool4, inb, (float*)d_out);
}

// Round 5
// 1350.772 us; speedup vs baseline: 3.2723x; 1.1189x over previous
//
#include <hip/hip_runtime.h>
#include <hip/hip_bf16.h>
#include <float.h>
#include <math.h>

typedef __hip_bfloat16 bf16;
typedef unsigned long long u64;

#define BATCH 32
#define NPTS  1024
#define KNN   20
#define NB    (BATCH*NPTS)      // 32768 nodes
#define NEDGE (NB*KNN)          // 655360 edges

// ---- workspace layout (float units), ws_size-adaptive ----
#define OFF_FLAG 512u
#define OFF_INB  1024u
#define OFF_IDX  988928u          // 655360 ints (idx1 early, idx2 late)
#define OFF_X1   1644288u         // NB*64
#define OFF_X2   3741440u         // NB*128 ; a1 @ OFF_X2, c1 @ OFF_C1 (early)
#define OFF_C1   5838592u
#define OFF_POOL 7935744u         // pool4: 4 x 32*1024
#define SLOW_END 8066816u         // 32.3 MB
#define OFF_B2H  8066816u         // NB*64 (fast path only)
#define FAST_END 10163968u        // 40.7 MB
// kNN partial lists (u64) alias OFF_X2 (dead there at both kNN points).
// ---- layout inside inb (canonical fp32 inputs) ----
#define IN_POSF 0u
#define IN_B1   98304u
#define IN_G1   98368u
#define IN_BE1  98432u
#define IN_B2   98496u
#define IN_G2   98560u
#define IN_BE2  98624u
#define IN_B3   98688u
#define IN_BC2  98752u
#define IN_BL   98880u
#define IN_BM1  99904u
#define IN_BM2  100416u
#define IN_BM3  100672u
#define IN_W1   100736u
#define IN_WBUF 101120u
#define WB_W2   0u
#define WB_W3   4096u
#define WB_WD   8192u            // Wc2 top-bot diff [64x128]
#define WB_WBOT 16384u           // Wc2 bottom      [64x128]
#define WB_WL   24576u
#define WB_WM1  221184u
#define WB_WM2  745472u
#define WB_WM3  876544u
#define IN_TOTAL 987904u

__device__ __forceinline__ float bf2f(bf16 v){ return __bfloat162float(v); }

// monotone float->u32 map: preserves IEEE-754 total order for all finite values
__device__ __forceinline__ unsigned int mono32(float f){
  unsigned int b = __float_as_uint(f);
  return b ^ ((unsigned int)((int)b >> 31) | 0x80000000u);
}

// ======== MFMA edge-MLP machinery (bf16 hi/lo split, fp32-accurate) ========
typedef __attribute__((ext_vector_type(8))) short bf16x8;
typedef __attribute__((ext_vector_type(4))) float f32x4;

__device__ __forceinline__ unsigned short bfhi(float f){
  unsigned int u = __float_as_uint(f);
  u += 0x7FFFu + ((u >> 16) & 1u);      // RNE to bf16
  return (unsigned short)(u >> 16);
}
__device__ __forceinline__ void bfsplit(float f, unsigned short& h, unsigned short& l){
  h = bfhi(f);
  float fh = __uint_as_float(((unsigned int)h) << 16);
  l = bfhi(f - fh);
}

// ======== register top-k via 20 NAMED scalars (macro-generated) ========
#define REP20(M) M(0) M(1) M(2) M(3) M(4) M(5) M(6) M(7) M(8) M(9) \
                 M(10) M(11) M(12) M(13) M(14) M(15) M(16) M(17) M(18) M(19)
#define SH19(M) M(19,18) M(18,17) M(17,16) M(16,15) M(15,14) M(14,13) M(13,12) \
                M(12,11) M(11,10) M(10,9) M(9,8) M(8,7) M(7,6) M(6,5) M(5,4) \
                M(4,3) M(3,2) M(2,1) M(1,0)

#define KDECL(p) float rd##p = FLT_MAX; int ri##p = 65535;
#define KG_P(p)  bool gt##p = rd##p > _d;
#define KSH(p,pm) rd##p = gt##p ? (gt##pm ? rd##pm : _d) : rd##p; \
                  ri##p = gt##p ? (gt##pm ? ri##pm : _c) : ri##p;
#define INS_PLAIN(dv,cv) do{ float _d=(dv); int _c=(cv); \
  REP20(KG_P) SH19(KSH) \
  rd0 = gt0 ? _d : rd0; ri0 = gt0 ? _c : ri0; }while(0)

// u64-key list (key = mono32(d)<<32 | idx; strict > == lexicographic (d,idx))
#define KCNV(p)  u64 mk##p = ((u64)mono32(rd##p) << 32) | (unsigned int)ri##p;
#define KG_U(p)  bool gu##p = mk##p > _k;
#define KSH_U(p,pm) mk##p = gu##p ? (gu##pm ? mk##pm : _k) : mk##p;
#define INS_U64(kv) do{ u64 _k=(kv); \
  REP20(KG_U) SH19(KSH_U) \
  mk0 = gu0 ? _k : mk0; }while(0)

#define KPUB_A(p) mrgA[q_l*21+p] = mk##p;
#define KPUB_B(p) mrgB[q_l*21+p] = mk##p;
#define KSTG(p)   gpart[p] = mk##p;
#define KLDA(p)   u64 mk##p = pa[p];
#define KOUTU(p)  optr[p] = (int)(unsigned int)(mk##p & 0xFFFFFFFFull);

// ---------------- dtype sniff (fp32 vs bf16 inputs) ----------------
__global__ void k_sniff(const void* pos_raw, int* flag){
  if (blockIdx.x == 0 && threadIdx.x == 0){
    const unsigned short* h = (const unsigned short*)pos_raw;
    int wild = 0;
    for (int k = 0; k < 16; k++){
      unsigned int bits = ((unsigned int)h[2*k]) << 16;
      float v = __uint_as_float(bits);
      float a = fabsf(v);
      if (a != 0.0f && (v != v || a > 1e10f || a < 1e-10f)) wild++;
    }
    *flag = (wild >= 4) ? 1 : 0;
  }
}

__device__ __forceinline__ float rdv(const void* p, int i, int f){
  return f ? ((const float*)p)[i] : bf2f(((const bf16*)p)[i]);
}

// ---------------- normalize ALL inputs to canonical fp32 buffer ----------------
__global__ __launch_bounds__(256) void k_cvt(
    const void* pos, const void* W1, const void* b1, const void* g1, const void* be1,
    const void* W2, const void* b2, const void* g2, const void* be2,
    const void* W3, const void* b3, const void* Wc2, const void* bc2,
    const void* Wl, const void* bl, const void* Wm1, const void* bm1,
    const void* Wm2, const void* bm2, const void* Wm3, const void* bm3,
    const int* flag, float* inb){
  int id = blockIdx.x*256 + threadIdx.x;
  if (id >= (int)IN_TOTAL) return;
  int f = *flag;
  float v;
  if      (id < 98304)  v = rdv(pos, id, f);
  else if (id < 98368)  v = rdv(b1,  id-98304, f);
  else if (id < 98432)  v = rdv(g1,  id-98368, f);
  else if (id < 98496)  v = rdv(be1, id-98432, f);
  else if (id < 98560)  v = rdv(b2,  id-98496, f);
  else if (id < 98624)  v = rdv(g2,  id-98560, f);
  else if (id < 98688)  v = rdv(be2, id-98624, f);
  else if (id < 98752)  v = rdv(b3,  id-98688, f);
  else if (id < 98880)  v = rdv(bc2, id-98752, f);
  else if (id < 99904)  v = rdv(bl,  id-98880, f);
  else if (id < 100416) v = rdv(bm1, id-99904, f);
  else if (id < 100672) v = rdv(bm2, id-100416, f);
  else if (id < 100712) v = rdv(bm3, id-100672, f);
  else if (id < 100736) v = 0.0f;
  else if (id < 101120) v = rdv(W1,  id-100736, f);
  else {
    int t = id - 101120;
    if      (t < 4096)   v = rdv(W2, t, f);
    else if (t < 8192)   v = rdv(W3, t-4096, f);
    else if (t < 16384){ int u = t-8192;  v = rdv(Wc2, u, f) - rdv(Wc2, 8192+u, f); }
    else if (t < 24576){ int u = t-16384; v = rdv(Wc2, 8192+u, f); }
    else if (t < 221184) v = rdv(Wl,  t-24576, f);
    else if (t < 745472) v = rdv(Wm1, t-221184, f);
    else if (t < 876544) v = rdv(Wm2, t-745472, f);
    else                 v = rdv(Wm3, t-876544, f);
  }
  inb[id] = v;
}

// ---------------- a1/c1: affine decomposition of EdgeConv1 layer1 ----------------
__global__ __launch_bounds__(256) void k_prep1(const float* inb, float* a1, float* c1){
  const float* posf = inb + IN_POSF;
  const float* W1f  = inb + IN_W1;
  const float* b1f  = inb + IN_B1;
  int id = blockIdx.x*256 + threadIdx.x;
  int bn = id >> 6, c = id & 63;
  float p0 = posf[bn*3], p1 = posf[bn*3+1], p2 = posf[bn*3+2];
  float wt0 = W1f[c],     wt1 = W1f[64+c],  wt2 = W1f[128+c];
  float wb0 = W1f[192+c], wb1 = W1f[256+c], wb2 = W1f[320+c];
  float cv = p0*wb0 + p1*wb1 + p2*wb2;
  float av = p0*(wt0-wb0) + p1*(wt1-wb1) + p2*(wt2-wb2) + b1f[c];
  a1[id] = av;  c1[id] = cv;
}

// ---------------- kNN in coordinate space (half-split, register top-k) ----------------
__global__ __launch_bounds__(256, 2) void k_knn1(const float* inb, u64* part){
  const float* posf = inb + IN_POSF;
  __shared__ float psx[1024], psy[1024], psz[1024], sqs[1024];
  __shared__ u64 mrgA[64*21];
  __shared__ u64 mrgB[64*21];
  int bb   = blockIdx.x >> 5;
  int qg   = (blockIdx.x >> 1) & 15;
  int half = blockIdx.x & 1;
  int tid = threadIdx.x;
  int q_l = tid & 63;
  int slot = tid >> 6;
  for (int t = tid; t < 1024; t += 256){
    float x = posf[(bb*1024+t)*3], y = posf[(bb*1024+t)*3+1], z = posf[(bb*1024+t)*3+2];
    psx[t] = x; psy[t] = y; psz[t] = z; sqs[t] = x*x + y*y + z*z;
  }
  __syncthreads();
  int i_l = qg*64 + q_l;
  float xi0 = psx[i_l], xi1 = psy[i_l], xi2 = psz[i_l];
  float sqi = sqs[i_l];
  REP20(KDECL)
  int cbase = half*512;
  for (int u = 0; u < 128; u++){
    int jj = cbase + 4*u + slot;
    float dot = xi0*psx[jj] + xi1*psy[jj] + xi2*psz[jj];
    float d = sqi + sqs[jj] - 2.0f*dot;
    INS_PLAIN(d, jj);
  }
  REP20(KCNV)
  if (slot == 1){ REP20(KPUB_A) }
  if (slot == 3){ REP20(KPUB_B) }
  __syncthreads();
  if ((slot & 1) == 0){
    const u64* src = (slot == 0) ? &mrgA[q_l*21] : &mrgB[q_l*21];
    for (int p = 0; p < KNN; p++){
      u64 kv = src[p];
      if (kv > mk19) break;
      INS_U64(kv);
    }
  }
  __syncthreads();
  if (slot == 2){ REP20(KPUB_B) }
  __syncthreads();
  if (slot == 0){
    const u64* src = &mrgB[q_l*21];
    for (int p = 0; p < KNN; p++){
      u64 kv = src[p];
      if (kv > mk19) break;
      INS_U64(kv);
    }
    int gi = bb*1024 + i_l;
    u64* gpart = part + ((size_t)gi*2 + half)*KNN;
    REP20(KSTG)
  }
}

// ---------------- merge two sorted 20-entry half-lists per query ----------------
__global__ __launch_bounds__(256) void k_mrg(const u64* part, int* out){
  int gi = blockIdx.x*256 + threadIdx.x;    // grid 128 -> 32768 queries
  const u64* pa = part + (size_t)gi*2*KNN;
  REP20(KLDA)
  for (int p = 0; p < KNN; p++){
    u64 kv = pa[KNN + p];
    if (kv > mk19) break;
    INS_U64(kv);
  }
  int* optr = out + gi*KNN;
  REP20(KOUTU)
}

// ---------------- BN1 stats ----------------
__global__ __launch_bounds__(256) void k_stats1(const float* a1, const float* c1,
                                                const int* idx1, double* stats){
  __shared__ float rs[256], rs2[256];
  int tid = threadIdx.x, c = tid & 63, slot = tid >> 6;
  int base = blockIdx.x * 1024;
  float s = 0.f, s2 = 0.f;
  for (int t = 0; t < 256; t++){
    unsigned e = (unsigned)(base + t*4 + slot);
    int i = (int)(e / 20u);
    int b = i >> 10;
    int j = idx1[e];
    float h = a1[i*64+c] + c1[((b<<10)+j)*64 + c];
    s += h; s2 += h*h;
  }
  rs[tid] = s; rs2[tid] = s2;
  __syncthreads();
  if (slot == 0){
    double ts  = (double)rs[c]  + (double)rs[64+c]  + (double)rs[128+c]  + (double)rs[192+c];
    double ts2 = (double)rs2[c] + (double)rs2[64+c] + (double)rs2[128+c] + (double)rs2[192+c];
    atomicAdd(&stats[c], ts);
    atomicAdd(&stats[64+c], ts2);
  }
}

// ================= MFMA edge-MLP =================
// Geometry (both kernels): block = 8 nodes; each node padded 20->32 edge rows.
// 256 rows = 16 M-tiles of 16; 4 waves x 4 tiles (tile T = t4*4 + wv).
// Tile T: node_l = T>>1, half = T&1; lane's edge-row krow = half*16 + (lane&15),
// real iff krow < 20. A-fragment (16x16x32 bf16): lane holds
// H1[lane&15][(lane>>4)*8 + e] (+32 for k-slice 1); built in registers from
// a1/c1 gathers. B-fragment: lane holds W[k][lane&15 + nt*16], k = (lane>>4)*8+e.
// fp32 accuracy via hi/lo bf16 split: P = Ah*Bh + Ah*Bl + Al*Bh (err ~2^-17).
// b2 cancels in BN2 (stats are of raw P); b3 added after the max.

// ---------------- BN2 stats over P = H1 @ W2 (raw, no b2) ----------------
__global__ __launch_bounds__(256) void k_stats2m(const float* a1, const float* c1,
    const int* idx1, const float* inb, double* stats){
  __shared__ __align__(16) float W2s[4096];
  __shared__ float sc1s[64], sh1s[64];
  __shared__ float rs[4][64], rs2[4][64];
  int tid = threadIdx.x;
  const float* wbuf = inb + IN_WBUF;
  for (int t = tid; t < 4096; t += 256) W2s[t] = wbuf[WB_W2 + t];
  if (tid < 64){
    int c = tid;
    const double M = (double)NEDGE;
    double m1 = stats[c]/M;
    double v1 = stats[64+c]/M - m1*m1;
    double r1 = 1.0/sqrt(v1 + 1e-5);
    double g1 = (double)inb[IN_G1 + c];
    sc1s[c] = (float)(g1*r1);
    sh1s[c] = (float)((double)inb[IN_BE1 + c] - m1*g1*r1);
  }
  __syncthreads();
  int lane = tid & 63, wv = tid >> 6;
  int c16 = lane & 15, ag = lane >> 4, kb0 = ag*8;
  bf16x8 w2h[4][2], w2l[4][2];
  #pragma unroll
  for (int nt = 0; nt < 4; nt++){
    #pragma unroll
    for (int ks = 0; ks < 2; ks++){
      bf16x8 h8, l8;
      #pragma unroll
      for (int e = 0; e < 8; e++){
        unsigned short hh, ll;
        bfsplit(W2s[(ks*32 + kb0 + e)*64 + nt*16 + c16], hh, ll);
        h8[e] = (short)hh; l8[e] = (short)ll;
      }
      w2h[nt][ks] = h8; w2l[nt][ks] = l8;
    }
  }
  float sa[4] = {0,0,0,0}, qa[4] = {0,0,0,0};
  for (int t4 = 0; t4 < 4; t4++){
    int T = t4*4 + wv;
    int node_l = T >> 1, half = T & 1;
    int nodeg = blockIdx.x*8 + node_l;
    int krow = half*16 + c16;
    int rr = (krow < 20);
    int j = idx1[nodeg*20 + (rr ? krow : 0)];
    int gj = ((nodeg >> 10) << 10) + j;
    const float* ar = a1 + (size_t)nodeg*64;
    const float* cr = c1 + (size_t)gj*64;
    f32x4 av0 = *(const f32x4*)(ar + kb0);
    f32x4 av1 = *(const f32x4*)(ar + kb0 + 4);
    f32x4 av2 = *(const f32x4*)(ar + 32 + kb0);
    f32x4 av3 = *(const f32x4*)(ar + 36 + kb0);
    f32x4 cv0 = *(const f32x4*)(cr + kb0);
    f32x4 cv1 = *(const f32x4*)(cr + kb0 + 4);
    f32x4 cv2 = *(const f32x4*)(cr + 32 + kb0);
    f32x4 cv3 = *(const f32x4*)(cr + 36 + kb0);
    bf16x8 a0h, a0l, a1h_, a1l_;
    #pragma unroll
    for (int e = 0; e < 4; e++){
      unsigned short hh, ll;
      float h;
      h = rr ? fmaxf((av0[e]+cv0[e])*sc1s[kb0+e] + sh1s[kb0+e], 0.f) : 0.f;
      bfsplit(h, hh, ll); a0h[e] = (short)hh; a0l[e] = (short)ll;
      h = rr ? fmaxf((av1[e]+cv1[e])*sc1s[kb0+4+e] + sh1s[kb0+4+e], 0.f) : 0.f;
      bfsplit(h, hh, ll); a0h[4+e] = (short)hh; a0l[4+e] = (short)ll;
      h = rr ? fmaxf((av2[e]+cv2[e])*sc1s[32+kb0+e] + sh1s[32+kb0+e], 0.f) : 0.f;
      bfsplit(h, hh, ll); a1h_[e] = (short)hh; a1l_[e] = (short)ll;
      h = rr ? fmaxf((av3[e]+cv3[e])*sc1s[36+kb0+e] + sh1s[36+kb0+e], 0.f) : 0.f;
      bfsplit(h, hh, ll); a1h_[4+e] = (short)hh; a1l_[4+e] = (short)ll;
    }
    #pragma unroll
    for (int nt = 0; nt < 4; nt++){
      f32x4 acc = {0.f, 0.f, 0.f, 0.f};
      acc = __builtin_amdgcn_mfma_f32_16x16x32_bf16(a0h,  w2h[nt][0], acc, 0, 0, 0);
      acc = __builtin_amdgcn_mfma_f32_16x16x32_bf16(a1h_, w2h[nt][1], acc, 0, 0, 0);
      acc = __builtin_amdgcn_mfma_f32_16x16x32_bf16(a0h,  w2l[nt][0], acc, 0, 0, 0);
      acc = __builtin_amdgcn_mfma_f32_16x16x32_bf16(a1h_, w2l[nt][1], acc, 0, 0, 0);
      acc = __builtin_amdgcn_mfma_f32_16x16x32_bf16(a0l,  w2h[nt][0], acc, 0, 0, 0);
      acc = __builtin_amdgcn_mfma_f32_16x16x32_bf16(a1l_, w2h[nt][1], acc, 0, 0, 0);
      #pragma unroll
      for (int r = 0; r < 4; r++){
        int kr = half*16 + 4*ag + r;        // D row m=(lane>>4)*4+r -> edge slot
        float v = (kr < 20) ? acc[r] : 0.f;
        sa[nt] += v; qa[nt] += v*v;
      }
    }
  }
  #pragma unroll
  for (int nt = 0; nt < 4; nt++){
    sa[nt] += __shfl_xor(sa[nt], 16); sa[nt] += __shfl_xor(sa[nt], 32);
    qa[nt] += __shfl_xor(qa[nt], 16); qa[nt] += __shfl_xor(qa[nt], 32);
  }
  if (ag == 0){
    #pragma unroll
    for (int nt = 0; nt < 4; nt++){
      rs[wv][nt*16+c16] = sa[nt];
      rs2[wv][nt*16+c16] = qa[nt];
    }
  }
  __syncthreads();
  if (tid < 64){
    double ts = (double)rs[0][tid] + (double)rs[1][tid]
              + (double)rs[2][tid] + (double)rs[3][tid];
    double tq = (double)rs2[0][tid] + (double)rs2[1][tid]
              + (double)rs2[2][tid] + (double)rs2[3][tid];
    atomicAdd(&stats[128+tid], ts);
    atomicAdd(&stats[192+tid], tq);
  }
}

// ---------------- full MLP1 via MFMA + max over k -> x1 ----------------
__global__ __launch_bounds__(256, 2) void k_x1m(const float* a1, const float* c1,
    const int* idx1, const float* inb, const double* stats, float* x1){
  __shared__ __align__(16) float W2s[4096];
  __shared__ __align__(16) float W3s[4096];
  __shared__ __align__(16) float scr[4][16*68];     // per-wave H2 relayout scratch
  __shared__ unsigned int mxp[4][8][64];            // per-wave node maxes (mono32)
  __shared__ float sc1s[64], sh1s[64], sc2s[64], sh2s[64];
  int tid = threadIdx.x;
  const float* wbuf = inb + IN_WBUF;
  for (int t = tid; t < 4096; t += 256){ W2s[t] = wbuf[WB_W2+t]; W3s[t] = wbuf[WB_W3+t]; }
  {
    unsigned int* mf = &mxp[0][0][0];
    for (int t = tid; t < 2048; t += 256) mf[t] = 0u;
  }
  if (tid < 64){
    int c = tid;
    const double M = (double)NEDGE;
    double m1 = stats[c]/M;
    double v1 = stats[64+c]/M - m1*m1;
    double r1 = 1.0/sqrt(v1 + 1e-5);
    double g1 = (double)inb[IN_G1 + c];
    sc1s[c] = (float)(g1*r1);
    sh1s[c] = (float)((double)inb[IN_BE1 + c] - m1*g1*r1);
    double mp = stats[128+c]/M;                  // mean of raw P (b2 cancels in BN)
    double v2 = stats[192+c]/M - mp*mp;
    double r2 = 1.0/sqrt(v2 + 1e-5);
    double g2 = (double)inb[IN_G2 + c];
    sc2s[c] = (float)(g2*r2);
    sh2s[c] = (float)((double)inb[IN_BE2 + c] - mp*g2*r2);
  }
  __syncthreads();
  int lane = tid & 63, wv = tid >> 6;
  int c16 = lane & 15, ag = lane >> 4, kb0 = ag*8;
  // weight fragments (hi/lo) for both layers
  bf16x8 w2h[4][2], w2l[4][2], w3h[4][2], w3l[4][2];
  #pragma unroll
  for (int nt = 0; nt < 4; nt++){
    #pragma unroll
    for (int ks = 0; ks < 2; ks++){
      bf16x8 h8, l8, h9, l9;
      #pragma unroll
      for (int e = 0; e < 8; e++){
        unsigned short hh, ll;
        bfsplit(W2s[(ks*32 + kb0 + e)*64 + nt*16 + c16], hh, ll);
        h8[e] = (short)hh; l8[e] = (short)ll;
        bfsplit(W3s[(ks*32 + kb0 + e)*64 + nt*16 + c16], hh, ll);
        h9[e] = (short)hh; l9[e] = (short)ll;
      }
      w2h[nt][ks] = h8; w2l[nt][ks] = l8;
      w3h[nt][ks] = h9; w3l[nt][ks] = l9;
    }
  }
  float scn[4], shn[4];
  #pragma unroll
  for (int nt = 0; nt < 4; nt++){
    scn[nt] = sc2s[nt*16 + c16];
    shn[nt] = sh2s[nt*16 + c16];
  }
  float* sw = &scr[wv][0];
  for (int t4 = 0; t4 < 4; t4++){
    int T = t4*4 + wv;
    int node_l = T >> 1, half = T & 1;
    int nodeg = blockIdx.x*8 + node_l;
    int krow = half*16 + c16;
    int rr = (krow < 20);
    int j = idx1[nodeg*20 + (rr ? krow : 0)];
    int gj = ((nodeg >> 10) << 10) + j;
    const float* ar = a1 + (size_t)nodeg*64;
    const float* cr = c1 + (size_t)gj*64;
    f32x4 av0 = *(const f32x4*)(ar + kb0);
    f32x4 av1 = *(const f32x4*)(ar + kb0 + 4);
    f32x4 av2 = *(const f32x4*)(ar + 32 + kb0);
    f32x4 av3 = *(const f32x4*)(ar + 36 + kb0);
    f32x4 cv0 = *(const f32x4*)(cr + kb0);
    f32x4 cv1 = *(const f32x4*)(cr + kb0 + 4);
    f32x4 cv2 = *(const f32x4*)(cr + 32 + kb0);
    f32x4 cv3 = *(const f32x4*)(cr + 36 + kb0);
    bf16x8 a0h, a0l, a1h_, a1l_;
    #pragma unroll
    for (int e = 0; e < 4; e++){
      unsigned short hh, ll;
      float h;
      h = rr ? fmaxf((av0[e]+cv0[e])*sc1s[kb0+e] + sh1s[kb0+e], 0.f) : 0.f;
      bfsplit(h, hh, ll); a0h[e] = (short)hh; a0l[e] = (short)ll;
      h = rr ? fmaxf((av1[e]+cv1[e])*sc1s[kb0+4+e] + sh1s[kb0+4+e], 0.f) : 0.f;
      bfsplit(h, hh, ll); a0h[4+e] = (short)hh; a0l[4+e] = (short)ll;
      h = rr ? fmaxf((av2[e]+cv2[e])*sc1s[32+kb0+e] + sh1s[32+kb0+e], 0.f) : 0.f;
      bfsplit(h, hh, ll); a1h_[e] = (short)hh; a1l_[e] = (short)ll;
      h = rr ? fmaxf((av3[e]+cv3[e])*sc1s[36+kb0+e] + sh1s[36+kb0+e], 0.f) : 0.f;
      bfsplit(h, hh, ll); a1h_[4+e] = (short)hh; a1l_[4+e] = (short)ll;
    }
    // ---- GEMM1: P = H1 @ W2 ----
    f32x4 pacc[4];
    #pragma unroll
    for (int nt = 0; nt < 4; nt++){
      f32x4 acc = {0.f, 0.f, 0.f, 0.f};
      acc = __builtin_amdgcn_mfma_f32_16x16x32_bf16(a0h,  w2h[nt][0], acc, 0, 0, 0);
      acc = __builtin_amdgcn_mfma_f32_16x16x32_bf16(a1h_, w2h[nt][1], acc, 0, 0, 0);
      acc = __builtin_amdgcn_mfma_f32_16x16x32_bf16(a0h,  w2l[nt][0], acc, 0, 0, 0);
      acc = __builtin_amdgcn_mfma_f32_16x16x32_bf16(a1h_, w2l[nt][1], acc, 0, 0, 0);
      acc = __builtin_amdgcn_mfma_f32_16x16x32_bf16(a0l,  w2h[nt][0], acc, 0, 0, 0);
      acc = __builtin_amdgcn_mfma_f32_16x16x32_bf16(a1l_, w2h[nt][1], acc, 0, 0, 0);
      pacc[nt] = acc;
    }
    // ---- BN2 + relu, relayout D->A via per-wave LDS scratch ----
    #pragma unroll
    for (int nt = 0; nt < 4; nt++){
      #pragma unroll
      for (int r = 0; r < 4; r++){
        float v = fmaxf(pacc[nt][r]*scn[nt] + shn[nt], 0.f);
        sw[(4*ag + r)*68 + nt*16 + c16] = v;
      }
    }
    f32x4 h20 = *(const f32x4*)(sw + c16*68 + kb0);
    f32x4 h21 = *(const f32x4*)(sw + c16*68 + kb0 + 4);
    f32x4 h22 = *(const f32x4*)(sw + c16*68 + 32 + kb0);
    f32x4 h23 = *(const f32x4*)(sw + c16*68 + 36 + kb0);
    bf16x8 b0h, b0l, b1h, b1l;
    #pragma unroll
    for (int e = 0; e < 4; e++){
      unsigned short hh, ll;
      bfsplit(h20[e], hh, ll); b0h[e] = (short)hh; b0l[e] = (short)ll;
      bfsplit(h21[e], hh, ll); b0h[4+e] = (short)hh; b0l[4+e] = (short)ll;
      bfsplit(h22[e], hh, ll); b1h[e] = (short)hh; b1l[e] = (short)ll;
      bfsplit(h23[e], hh, ll); b1h[4+e] = (short)hh; b1l[4+e] = (short)ll;
    }
    // ---- GEMM2: Q = H2 @ W3, masked max into per-wave node slots ----
    #pragma unroll
    for (int nt = 0; nt < 4; nt++){
      f32x4 acc = {0.f, 0.f, 0.f, 0.f};
      acc = __builtin_amdgcn_mfma_f32_16x16x32_bf16(b0h, w3h[nt][0], acc, 0, 0, 0);
      acc = __builtin_amdgcn_mfma_f32_16x16x32_bf16(b1h, w3h[nt][1], acc, 0, 0, 0);
      acc = __builtin_amdgcn_mfma_f32_16x16x32_bf16(b0h, w3l[nt][0], acc, 0, 0, 0);
      acc = __builtin_amdgcn_mfma_f32_16x16x32_bf16(b1h, w3l[nt][1], acc, 0, 0, 0);
      acc = __builtin_amdgcn_mfma_f32_16x16x32_bf16(b0l, w3h[nt][0], acc, 0, 0, 0);
      acc = __builtin_amdgcn_mfma_f32_16x16x32_bf16(b1l, w3h[nt][1], acc, 0, 0, 0);
      float vmx = -FLT_MAX;
      #pragma unroll
      for (int r = 0; r < 4; r++){
        int kr = half*16 + 4*ag + r;
        vmx = (kr < 20) ? fmaxf(vmx, acc[r]) : vmx;
      }
      vmx = fmaxf(vmx, __shfl_xor(vmx, 16));
      vmx = fmaxf(vmx, __shfl_xor(vmx, 32));
      if (ag == 0){
        unsigned int u = mono32(vmx);
        unsigned int* sl = &mxp[wv][node_l][nt*16 + c16];
        if (u > *sl) *sl = u;
      }
    }
  }
  __syncthreads();
  for (int s = tid; s < 512; s += 256){
    int nl = s >> 6, c = s & 63;
    unsigned int u = mxp[0][nl][c];
    unsigned int u1 = mxp[1][nl][c]; u = (u1 > u) ? u1 : u;
    unsigned int u2 = mxp[2][nl][c]; u = (u2 > u) ? u2 : u;
    unsigned int u3 = mxp[3][nl][c]; u = (u3 > u) ? u3 : u;
    unsigned int bts = (u & 0x80000000u) ? (u ^ 0x80000000u) : ~u;
    x1[(size_t)(blockIdx.x*8 + nl)*64 + c] = __uint_as_float(bts) + inb[IN_B3 + c];
  }
}

// ---------------- kNN in 64-d feature space (half-split, register top-k) ----------------
__global__ __launch_bounds__(256, 2) void k_knn2(const float* x1, u64* part){
  __shared__ __align__(16) float xs[64*68];          // 17408 B
  __shared__ float sqc[64];
  __shared__ u64 mrgA[64*21];                        // 10752 B
  __shared__ u64 mrgB[64*21];                        // 10752 B
  int bb   = blockIdx.x >> 5;
  int qg   = (blockIdx.x >> 1) & 15;
  int half = blockIdx.x & 1;
  int tid = threadIdx.x;
  int q_l = tid & 63;
  int slot = tid >> 6;               // wave index == slot
  int gi = bb*1024 + qg*64 + q_l;
  float4 xiv[16];
  #pragma unroll
  for (int d4 = 0; d4 < 16; d4++)
    xiv[d4] = *(const float4*)(x1 + gi*64 + d4*4);
  float sqi = 0.f;
  #pragma unroll
  for (int d4 = 0; d4 < 16; d4++)
    sqi += xiv[d4].x*xiv[d4].x + xiv[d4].y*xiv[d4].y
         + xiv[d4].z*xiv[d4].z + xiv[d4].w*xiv[d4].w;
  REP20(KDECL)
  for (int ch = 0; ch < 8; ch++){
    int c0 = half*512 + ch*64;
    __syncthreads();
    for (int t = tid; t < 4096; t += 256){
      int r = t >> 6, d = t & 63;
      xs[r*68 + d] = x1[(bb*1024 + c0 + r)*64 + d];
    }
    __syncthreads();
    if (tid < 64){
      float s = 0.f;
      #pragma unroll 16
      for (int d = 0; d < 64; d++) s += xs[tid*68+d]*xs[tid*68+d];
      sqc[tid] = s;
    }
    __syncthreads();
    for (int u = 0; u < 16; u += 2){
      int jj0 = 4*u + slot;
      int jj1 = 4*(u+1) + slot;
      const float* xr0 = xs + jj0*68;
      const float* xr1 = xs + jj1*68;
      float dot0 = 0.f, dot1 = 0.f;
      #pragma unroll
      for (int d4 = 0; d4 < 16; d4++){
        float4 v0 = *(const float4*)(xr0 + d4*4);
        float4 v1 = *(const float4*)(xr1 + d4*4);
        dot0 += xiv[d4].x*v0.x + xiv[d4].y*v0.y + xiv[d4].z*v0.z + xiv[d4].w*v0.w;
        dot1 += xiv[d4].x*v1.x + xiv[d4].y*v1.y + xiv[d4].z*v1.z + xiv[d4].w*v1.w;
      }
      float d0 = sqi + sqc[jj0] - 2.0f*dot0;
      float d1 = sqi + sqc[jj1] - 2.0f*dot1;
      INS_PLAIN(d0, c0 + jj0);
      INS_PLAIN(d1, c0 + jj1);
    }
  }
  __syncthreads();
  REP20(KCNV)
  if (slot == 1){ REP20(KPUB_A) }
  if (slot == 3){ REP20(KPUB_B) }
  __syncthreads();
  if ((slot & 1) == 0){
    const u64* src = (slot == 0) ? &mrgA[q_l*21] : &mrgB[q_l*21];
    for (int p = 0; p < KNN; p++){
      u64 kv = src[p];
      if (kv > mk19) break;
      INS_U64(kv);
    }
  }
  __syncthreads();
  if (slot == 2){ REP20(KPUB_B) }
  __syncthreads();
  if (slot == 0){
    const u64* src = &mrgB[q_l*21];
    for (int p = 0; p < KNN; p++){
      u64 kv = src[p];
      if (kv > mk19) break;
      INS_U64(kv);
    }
    u64* gpart = part + ((size_t)gi*2 + half)*KNN;
    REP20(KSTG)
  }
}

// ---------------- fast path: B2H = x1 @ Wbot[:, q-half] ----------------
__global__ __launch_bounds__(256) void k_B2h(const float* x1, const float* inb,
                                             int q, float* B2H){
  __shared__ __align__(16) float Wbh[4096];
  __shared__ __align__(16) float xsh[1024];
  int tid = threadIdx.x;
  const float* Wb = inb + IN_WBUF + WB_WBOT;
  for (int t = tid; t < 4096; t += 256){
    int r = t >> 6, cl = t & 63;
    Wbh[t] = Wb[r*128 + q*64 + cl];
  }
  int node0 = blockIdx.x * 16;
  for (int t = tid; t < 1024; t += 256) xsh[t] = x1[node0*64 + t];
  __syncthreads();
  int n_l = tid >> 4, cg = tid & 15;
  const float* xr = xsh + n_l*64;
  float4 acc = make_float4(0.f,0.f,0.f,0.f);
  #pragma unroll 8
  for (int d = 0; d < 64; d++){
    float v = xr[d];
    float4 w = *(const float4*)(Wbh + d*64 + cg*4);
    acc.x += v*w.x; acc.y += v*w.y; acc.z += v*w.z; acc.w += v*w.w;
  }
  *(float4*)(B2H + (node0 + n_l)*64 + cg*4) = acc;
}

// ---------------- fast path: x2 half = (x1_i@Wd + bc2) + max_j B2H[j] ----------------
__global__ __launch_bounds__(256) void k_x2h(const float* x1, const float* B2H,
                                             const float* inb, const int* idx2,
                                             int q, float* x2){
  __shared__ __align__(16) float Wdh[4096];
  __shared__ __align__(16) float xsh[256];
  int tid = threadIdx.x;
  const float* Wd = inb + IN_WBUF + WB_WD;
  for (int t = tid; t < 4096; t += 256){
    int r = t >> 6, cl = t & 63;
    Wdh[t] = Wd[r*128 + q*64 + cl];
  }
  int node0 = blockIdx.x * 4;
  xsh[tid] = x1[node0*64 + tid];
  __syncthreads();
  int n_l = tid >> 6, cl = tid & 63;
  int i = node0 + n_l;
  int b = i >> 10;
  const float* xr = xsh + n_l*64;
  float acc = inb[IN_BC2 + q*64 + cl];
  #pragma unroll 8
  for (int d = 0; d < 64; d++) acc += xr[d]*Wdh[d*64 + cl];
  float m = -FLT_MAX;
  for (int kk = 0; kk < KNN; kk++){
    int j = idx2[i*KNN + kk];
    m = fmaxf(m, B2H[((b<<10)+j)*64 + cl]);
  }
  x2[i*128 + q*64 + cl] = acc + m;
}

// ---------------- slow fallback: x2 direct, LDS-staged, no B2H buffer ----------------
__global__ __launch_bounds__(256) void k_x2d(const float* x1, const float* inb,
                                             const int* idx2, float* x2){
  __shared__ __align__(16) float Wdh[4096], Wbh[4096];
  __shared__ __align__(16) float xis[1024], xjs[1024];
  int tid = threadIdx.x;
  int q = blockIdx.x & 1;
  int node0 = (blockIdx.x >> 1) * 16;
  const float* Wd = inb + IN_WBUF + WB_WD;
  const float* Wb = inb + IN_WBUF + WB_WBOT;
  for (int t = tid; t < 4096; t += 256){
    int r = t >> 6, cl = t & 63;
    Wdh[t] = Wd[r*128 + q*64 + cl];
    Wbh[t] = Wb[r*128 + q*64 + cl];
  }
  for (int t = tid; t < 1024; t += 256) xis[t] = x1[node0*64 + t];
  __syncthreads();
  int n_l = tid >> 4, cg = tid & 15;
  int i = node0 + n_l, b = i >> 10;
  const float* xr = xis + n_l*64;
  float4 af = make_float4(inb[IN_BC2 + q*64 + cg*4],   inb[IN_BC2 + q*64 + cg*4+1],
                          inb[IN_BC2 + q*64 + cg*4+2], inb[IN_BC2 + q*64 + cg*4+3]);
  #pragma unroll 8
  for (int d = 0; d < 64; d++){
    float v = xr[d];
    float4 w = *(const float4*)(Wdh + d*64 + cg*4);
    af.x += v*w.x; af.y += v*w.y; af.z += v*w.z; af.w += v*w.w;
  }
  float4 mx = make_float4(-FLT_MAX,-FLT_MAX,-FLT_MAX,-FLT_MAX);
  for (int kk = 0; kk < KNN; kk++){
    __syncthreads();
    for (int t = tid; t < 1024; t += 256){
      int nn = t >> 6, r = t & 63;
      int jj = idx2[(node0+nn)*KNN + kk];
      xjs[t] = x1[((((node0+nn) >> 10) << 10) + jj)*64 + r];
    }
    __syncthreads();
    const float* xj = xjs + n_l*64;
    float4 acc = make_float4(0.f,0.f,0.f,0.f);
    #pragma unroll 8
    for (int d = 0; d < 64; d++){
      float v = xj[d];
      float4 w = *(const float4*)(Wbh + d*64 + cg*4);
      acc.x += v*w.x; acc.y += v*w.y; acc.z += v*w.z; acc.w += v*w.w;
    }
    mx.x = fmaxf(mx.x, acc.x); mx.y = fmaxf(mx.y, acc.y);
    mx.z = fmaxf(mx.z, acc.z); mx.w = fmaxf(mx.w, acc.w);
  }
  *(float4*)(x2 + i*128 + q*64 + cg*4) =
      make_float4(af.x+mx.x, af.y+mx.y, af.z+mx.z, af.w+mx.w);
}

// ---------------- lin (192->1024) + partial max over n-quarter ----------------
__global__ __launch_bounds__(256) void k_linpool(const float* x1, const float* x2,
    const float* inb, float* pool4){
  __shared__ __align__(16) float fst[192*36];
  __shared__ float red2[1024];
  int tid = threadIdx.x;
  int b = blockIdx.x >> 4, cq = (blockIdx.x >> 2) & 3, nh = blockIdx.x & 3;
  int cg = tid & 63, n8 = tid >> 6;
  int cbase = cq*256 + cg*4;
  const float* Wl = inb + IN_WBUF + WB_WL;
  float m0 = -FLT_MAX, m1 = -FLT_MAX, m2 = -FLT_MAX, m3 = -FLT_MAX;
  for (int ng = 0; ng < 8; ng++){
    __syncthreads();
    for (int t = tid; t < 6144; t += 256){
      int n_l = t / 192, dd = t - n_l*192;
      int gi = b*1024 + nh*256 + ng*32 + n_l;
      fst[dd*36 + n_l] = (dd < 64) ? x1[gi*64 + dd] : x2[gi*128 + dd - 64];
    }
    __syncthreads();
    float acc[8][4];
    #pragma unroll
    for (int n = 0; n < 8; n++){ acc[n][0]=0; acc[n][1]=0; acc[n][2]=0; acc[n][3]=0; }
    #pragma unroll 4
    for (int d = 0; d < 192; d++){
      float4 w = *(const float4*)(Wl + d*1024 + cbase);
      const float* fr = fst + d*36 + n8*8;
      float4 f0 = *(const float4*)(fr);
      float4 f1 = *(const float4*)(fr + 4);
      float fv[8] = {f0.x, f0.y, f0.z, f0.w, f1.x, f1.y, f1.z, f1.w};
      #pragma unroll
      for (int n = 0; n < 8; n++){
        acc[n][0] += fv[n]*w.x; acc[n][1] += fv[n]*w.y;
        acc[n][2] += fv[n]*w.z; acc[n][3] += fv[n]*w.w;
      }
    }
    #pragma unroll
    for (int n = 0; n < 8; n++){
      m0 = fmaxf(m0, acc[n][0]); m1 = fmaxf(m1, acc[n][1]);
      m2 = fmaxf(m2, acc[n][2]); m3 = fmaxf(m3, acc[n][3]);
    }
  }
  red2[n8*256 + cg*4]   = m0;  red2[n8*256 + cg*4+1] = m1;
  red2[n8*256 + cg*4+2] = m2;  red2[n8*256 + cg*4+3] = m3;
  __syncthreads();
  if (n8 == 0){
    #pragma unroll
    for (int u = 0; u < 4; u++){
      int cc = cg*4 + u;
      float m = fmaxf(fmaxf(red2[cc], red2[256+cc]), fmaxf(red2[512+cc], red2[768+cc]));
      pool4[nh*32768 + b*1024 + cbase + u] = m;     // bias applied in k_head
    }
  }
}

// ---------------- head MLP: reduce pool4 + 1024->512->256->40 (fp32 out) ----------------
__global__ __launch_bounds__(256) void k_head(const float* pool4, const float* inb,
                                              float* out){
  __shared__ float pl[1024];
  __shared__ float s1[512];
  __shared__ float s2[256];
  int b = blockIdx.x, tid = threadIdx.x;
  const float* Wm1 = inb + IN_WBUF + WB_WM1;
  const float* Wm2 = inb + IN_WBUF + WB_WM2;
  const float* Wm3 = inb + IN_WBUF + WB_WM3;
  for (int t = tid; t < 1024; t += 256){
    float m = fmaxf(fmaxf(pool4[b*1024 + t],         pool4[32768 + b*1024 + t]),
                    fmaxf(pool4[65536 + b*1024 + t], pool4[98304 + b*1024 + t]));
    pl[t] = m + inb[IN_BL + t];
  }
  __syncthreads();
  for (int c = tid; c < 512; c += 256){
    float acc = inb[IN_BM1 + c];
    #pragma unroll 4
    for (int d = 0; d < 1024; d++) acc += pl[d]*Wm1[d*512 + c];
    s1[c] = fmaxf(acc, 0.f);
  }
  __syncthreads();
  {
    int c = tid;
    float acc = inb[IN_BM2 + c];
    #pragma unroll 4
    for (int d = 0; d < 512; d++) acc += s1[d]*Wm2[d*256 + c];
    s2[c] = fmaxf(acc, 0.f);
  }
  __syncthreads();
  if (tid < 40){
    float acc = inb[IN_BM3 + tid];
    #pragma unroll 4
    for (int d = 0; d < 256; d++) acc += s2[d]*Wm3[d*40 + tid];
    out[b*40 + tid] = acc;
  }
}

extern "C" void kernel_launch(void* const* d_in, const int* in_sizes, int n_in,
                              void* d_out, int out_size, void* d_ws, size_t ws_size,
                              hipStream_t stream){
  float* ws     = (float*)d_ws;
  double* stats = (double*)d_ws;
  int*   flag   = (int*)d_ws + OFF_FLAG;
  float* inb    = ws + OFF_INB;
  int*   idx    = (int*)d_ws + OFF_IDX;     // idx1 early, idx2 late
  float* x1p    = ws + OFF_X1;
  float* x2p    = ws + OFF_X2;
  float* a1     = ws + OFF_X2;              // a1/c1 alias x2 region (dead before x2 written)
  float* c1     = ws + OFF_C1;
  u64*   part   = (u64*)(ws + OFF_X2);      // kNN partials alias a1/c1 (see layout note)
  float* pool4  = ws + OFF_POOL;
  float* B2H    = ws + OFF_B2H;
  bool fast = ws_size >= (size_t)FAST_END * 4u;

  hipMemsetAsync(stats, 0, 256*sizeof(double), stream);
  k_sniff<<<1, 64, 0, stream>>>(d_in[0], flag);
  k_cvt<<<3859, 256, 0, stream>>>(
      d_in[0], d_in[1], d_in[2], d_in[3], d_in[4], d_in[5], d_in[6], d_in[7],
      d_in[8], d_in[9], d_in[10], d_in[11], d_in[12], d_in[13], d_in[14],
      d_in[15], d_in[16], d_in[17], d_in[18], d_in[19], d_in[20], flag, inb);
  k_knn1<<<1024, 256, 0, stream>>>(inb, part);      // partials in a1/c1 region
  k_mrg<<<128, 256, 0, stream>>>(part, idx);        // -> idx1
  k_prep1<<<8192, 256, 0, stream>>>(inb, a1, c1);   // overwrites dead partials
  k_stats1<<<640, 256, 0, stream>>>(a1, c1, idx, stats);
  k_stats2m<<<4096, 256, 0, stream>>>(a1, c1, idx, inb, stats);
  k_x1m<<<4096, 256, 0, stream>>>(a1, c1, idx, inb, stats, x1p);
  k_knn2<<<1024, 256, 0, stream>>>(x1p, part);      // a1/c1 dead after k_x1m
  k_mrg<<<128, 256, 0, stream>>>(part, idx);        // -> idx2
  if (fast){
    k_B2h<<<2048, 256, 0, stream>>>(x1p, inb, 0, B2H);
    k_x2h<<<8192, 256, 0, stream>>>(x1p, B2H, inb, idx, 0, x2p);
    k_B2h<<<2048, 256, 0, stream>>>(x1p, inb, 1, B2H);
    k_x2h<<<8192, 256, 0, stream>>>(x1p, B2H, inb, idx, 1, x2p);
  } else {
    k_x2d<<<4096, 256, 0, stream>>>(x1p, inb, idx, x2p);
  }
  k_linpool<<<512, 256, 0, stream>>>(x1p, x2p, inb, pool4);
  k_head<<<32, 256, 0, stream>>>(pool4, inb, (float*)d_out);
}

// Round 6
// 1278.638 us; speedup vs baseline: 3.4569x; 1.0564x over previous
//
#include <hip/hip_runtime.h>
#include <hip/hip_bf16.h>
#include <float.h>
#include <math.h>

typedef __hip_bfloat16 bf16;
typedef unsigned long long u64;

#define BATCH 32
#define NPTS  1024
#define KNN   20
#define NB    (BATCH*NPTS)      // 32768 nodes
#define NEDGE (NB*KNN)          // 655360 edges

// ---- workspace layout (float units), ws_size-adaptive ----
#define OFF_FLAG 512u
#define OFF_INB  1024u
#define OFF_IDX  988928u          // 655360 ints (idx1 early, idx2 late)
#define OFF_X1   1644288u         // NB*64
#define OFF_X2   3741440u         // NB*128 ; a1 @ OFF_X2, c1 @ OFF_C1 (early)
#define OFF_C1   5838592u
#define OFF_POOL 7935744u         // pool4: 4 x 32*1024
#define SLOW_END 8066816u         // 32.3 MB
#define OFF_B2H  8066816u         // NB*64 (fast path only)
#define FAST_END 10163968u        // 40.7 MB
// kNN partial lists (u64) alias OFF_X2 (dead there at both kNN points).
// ---- layout inside inb (canonical fp32 inputs) ----
#define IN_POSF 0u
#define IN_B1   98304u
#define IN_G1   98368u
#define IN_BE1  98432u
#define IN_B2   98496u
#define IN_G2   98560u
#define IN_BE2  98624u
#define IN_B3   98688u
#define IN_BC2  98752u
#define IN_BL   98880u
#define IN_BM1  99904u
#define IN_BM2  100416u
#define IN_BM3  100672u
#define IN_W1   100736u
#define IN_WBUF 101120u
#define WB_W2   0u
#define WB_W3   4096u
#define WB_WD   8192u            // Wc2 top-bot diff [64x128]
#define WB_WBOT 16384u           // Wc2 bottom      [64x128]
#define WB_WL   24576u
#define WB_WM1  221184u
#define WB_WM2  745472u
#define WB_WM3  876544u
#define IN_TOTAL 987904u

__device__ __forceinline__ float bf2f(bf16 v){ return __bfloat162float(v); }

// monotone float->u32 map: preserves IEEE-754 total order for all finite values
__device__ __forceinline__ unsigned int mono32(float f){
  unsigned int b = __float_as_uint(f);
  return b ^ ((unsigned int)((int)b >> 31) | 0x80000000u);
}

// ======== MFMA edge-MLP machinery (bf16 hi/lo split, fp32-accurate) ========
typedef __attribute__((ext_vector_type(8))) short bf16x8;
typedef __attribute__((ext_vector_type(4))) float f32x4;

__device__ __forceinline__ unsigned short bfhi(float f){
  unsigned int u = __float_as_uint(f);
  u += 0x7FFFu + ((u >> 16) & 1u);      // RNE to bf16
  return (unsigned short)(u >> 16);
}
__device__ __forceinline__ void bfsplit(float f, unsigned short& h, unsigned short& l){
  h = bfhi(f);
  float fh = __uint_as_float(((unsigned int)h) << 16);
  l = bfhi(f - fh);
}

// ======== exact top-k via f64-packed keys + min/max sorted-insert ========
// Key bits = (1<<62) | (f32bits(max(d,0)) << 20) | idx.  All keys are positive
// normal doubles -> value order == bit order == lexicographic (d, idx), which
// is exactly jax top_k semantics (ascending d, ties -> lower idx). Keys are
// globally unique (idx embedded), so multiset insert identity
//   new_rp = min(rp, max(rp-1, k))   (p descending, in-place; r0 = min(r0,k))
// is exact: 39 v_min_f64/v_max_f64 per insert, no bools, no shifts.
// Round-1 lesson: lists must be NAMED scalars (arrays spill to scratch).
// Round-2 lesson: REP20 can't nest inside a macro expanded by REP20.
#define REP20(M) M(0) M(1) M(2) M(3) M(4) M(5) M(6) M(7) M(8) M(9) \
                 M(10) M(11) M(12) M(13) M(14) M(15) M(16) M(17) M(18) M(19)
#define SH19(M) M(19,18) M(18,17) M(17,16) M(16,15) M(15,14) M(14,13) M(13,12) \
                M(12,11) M(11,10) M(10,9) M(9,8) M(8,7) M(7,6) M(6,5) M(5,4) \
                M(4,3) M(3,2) M(2,1) M(1,0)

__device__ __forceinline__ double packkey(float d, int idx){
  unsigned int b = __float_as_uint(fmaxf(d, 0.0f));
  u64 k = 0x4000000000000000ULL | ((u64)b << 20) | (unsigned int)idx;
  return __longlong_as_double((long long)k);
}

#define KDECLD(p) double rk##p = DBL_MAX;
#define KMM(p,pm) rk##p = fmin(rk##p, fmax(rk##pm, _k));
#define INS_MM(kv) do{ double _k=(kv); SH19(KMM) rk0 = fmin(rk0, _k); }while(0)

#define KPUB_A(p) mrgA[q_l*21+p] = (u64)__double_as_longlong(rk##p);
#define KPUB_B(p) mrgB[q_l*21+p] = (u64)__double_as_longlong(rk##p);
#define KSTG(p)   gpart[p] = (u64)__double_as_longlong(rk##p);
#define KLDAD(p)  double rk##p = __longlong_as_double((long long)pa[p]);
#define KOUTU(p)  optr[p] = (int)((u64)__double_as_longlong(rk##p) & 1023ULL);

// ---------------- dtype sniff (fp32 vs bf16 inputs) ----------------
__global__ void k_sniff(const void* pos_raw, int* flag){
  if (blockIdx.x == 0 && threadIdx.x == 0){
    const unsigned short* h = (const unsigned short*)pos_raw;
    int wild = 0;
    for (int k = 0; k < 16; k++){
      unsigned int bits = ((unsigned int)h[2*k]) << 16;
      float v = __uint_as_float(bits);
      float a = fabsf(v);
      if (a != 0.0f && (v != v || a > 1e10f || a < 1e-10f)) wild++;
    }
    *flag = (wild >= 4) ? 1 : 0;
  }
}

__device__ __forceinline__ float rdv(const void* p, int i, int f){
  return f ? ((const float*)p)[i] : bf2f(((const bf16*)p)[i]);
}

// ---------------- normalize ALL inputs to canonical fp32 buffer ----------------
__global__ __launch_bounds__(256) void k_cvt(
    const void* pos, const void* W1, const void* b1, const void* g1, const void* be1,
    const void* W2, const void* b2, const void* g2, const void* be2,
    const void* W3, const void* b3, const void* Wc2, const void* bc2,
    const void* Wl, const void* bl, const void* Wm1, const void* bm1,
    const void* Wm2, const void* bm2, const void* Wm3, const void* bm3,
    const int* flag, float* inb){
  int id = blockIdx.x*256 + threadIdx.x;
  if (id >= (int)IN_TOTAL) return;
  int f = *flag;
  float v;
  if      (id < 98304)  v = rdv(pos, id, f);
  else if (id < 98368)  v = rdv(b1,  id-98304, f);
  else if (id < 98432)  v = rdv(g1,  id-98368, f);
  else if (id < 98496)  v = rdv(be1, id-98432, f);
  else if (id < 98560)  v = rdv(b2,  id-98496, f);
  else if (id < 98624)  v = rdv(g2,  id-98560, f);
  else if (id < 98688)  v = rdv(be2, id-98624, f);
  else if (id < 98752)  v = rdv(b3,  id-98688, f);
  else if (id < 98880)  v = rdv(bc2, id-98752, f);
  else if (id < 99904)  v = rdv(bl,  id-98880, f);
  else if (id < 100416) v = rdv(bm1, id-99904, f);
  else if (id < 100672) v = rdv(bm2, id-100416, f);
  else if (id < 100712) v = rdv(bm3, id-100672, f);
  else if (id < 100736) v = 0.0f;
  else if (id < 101120) v = rdv(W1,  id-100736, f);
  else {
    int t = id - 101120;
    if      (t < 4096)   v = rdv(W2, t, f);
    else if (t < 8192)   v = rdv(W3, t-4096, f);
    else if (t < 16384){ int u = t-8192;  v = rdv(Wc2, u, f) - rdv(Wc2, 8192+u, f); }
    else if (t < 24576){ int u = t-16384; v = rdv(Wc2, 8192+u, f); }
    else if (t < 221184) v = rdv(Wl,  t-24576, f);
    else if (t < 745472) v = rdv(Wm1, t-221184, f);
    else if (t < 876544) v = rdv(Wm2, t-745472, f);
    else                 v = rdv(Wm3, t-876544, f);
  }
  inb[id] = v;
}

// ---------------- a1/c1: affine decomposition of EdgeConv1 layer1 ----------------
__global__ __launch_bounds__(256) void k_prep1(const float* inb, float* a1, float* c1){
  const float* posf = inb + IN_POSF;
  const float* W1f  = inb + IN_W1;
  const float* b1f  = inb + IN_B1;
  int id = blockIdx.x*256 + threadIdx.x;
  int bn = id >> 6, c = id & 63;
  float p0 = posf[bn*3], p1 = posf[bn*3+1], p2 = posf[bn*3+2];
  float wt0 = W1f[c],     wt1 = W1f[64+c],  wt2 = W1f[128+c];
  float wb0 = W1f[192+c], wb1 = W1f[256+c], wb2 = W1f[320+c];
  float cv = p0*wb0 + p1*wb1 + p2*wb2;
  float av = p0*(wt0-wb0) + p1*(wt1-wb1) + p2*(wt2-wb2) + b1f[c];
  a1[id] = av;  c1[id] = cv;
}

// ---------------- kNN in coordinate space (half-split, f64-key min/max top-k) ----------------
__global__ __launch_bounds__(256, 2) void k_knn1(const float* inb, u64* part){
  const float* posf = inb + IN_POSF;
  __shared__ float psx[1024], psy[1024], psz[1024], sqs[1024];
  __shared__ u64 mrgA[64*21];
  __shared__ u64 mrgB[64*21];
  int bb   = blockIdx.x >> 5;
  int qg   = (blockIdx.x >> 1) & 15;
  int half = blockIdx.x & 1;
  int tid = threadIdx.x;
  int q_l = tid & 63;
  int slot = tid >> 6;
  for (int t = tid; t < 1024; t += 256){
    float x = posf[(bb*1024+t)*3], y = posf[(bb*1024+t)*3+1], z = posf[(bb*1024+t)*3+2];
    psx[t] = x; psy[t] = y; psz[t] = z; sqs[t] = x*x + y*y + z*z;
  }
  __syncthreads();
  int i_l = qg*64 + q_l;
  float xi0 = psx[i_l], xi1 = psy[i_l], xi2 = psz[i_l];
  float sqi = sqs[i_l];
  REP20(KDECLD)
  int cbase = half*512;
  for (int u = 0; u < 128; u++){
    int jj = cbase + 4*u + slot;
    float dot = xi0*psx[jj] + xi1*psy[jj] + xi2*psz[jj];
    float d = sqi + sqs[jj] - 2.0f*dot;
    INS_MM(packkey(d, jj));
  }
  // tree-merge the 4 slot lists (slot1->A, slot3->B; 0+=A, 2+=B; 2->B; 0+=B)
  if (slot == 1){ REP20(KPUB_A) }
  if (slot == 3){ REP20(KPUB_B) }
  __syncthreads();
  if ((slot & 1) == 0){
    const u64* src = (slot == 0) ? &mrgA[q_l*21] : &mrgB[q_l*21];
    for (int p = 0; p < KNN; p++){
      double kv = __longlong_as_double((long long)src[p]);
      if (kv > rk19) break;          // sorted source: rest are worse
      INS_MM(kv);
    }
  }
  __syncthreads();
  if (slot == 2){ REP20(KPUB_B) }
  __syncthreads();
  if (slot == 0){
    const u64* src = &mrgB[q_l*21];
    for (int p = 0; p < KNN; p++){
      double kv = __longlong_as_double((long long)src[p]);
      if (kv > rk19) break;
      INS_MM(kv);
    }
    int gi = bb*1024 + i_l;
    u64* gpart = part + ((size_t)gi*2 + half)*KNN;
    REP20(KSTG)
  }
}

// ---------------- merge two sorted 20-entry half-lists per query ----------------
__global__ __launch_bounds__(256) void k_mrg(const u64* part, int* out){
  int gi = blockIdx.x*256 + threadIdx.x;    // grid 128 -> 32768 queries
  const u64* pa = part + (size_t)gi*2*KNN;
  REP20(KLDAD)                               // init from half-0 list (sorted)
  for (int p = 0; p < KNN; p++){
    double kv = __longlong_as_double((long long)pa[KNN + p]);
    if (kv > rk19) break;                    // sorted source: rest are worse
    INS_MM(kv);
  }
  int* optr = out + gi*KNN;
  REP20(KOUTU)
}

// ---------------- BN1 stats ----------------
__global__ __launch_bounds__(256) void k_stats1(const float* a1, const float* c1,
                                                const int* idx1, double* stats){
  __shared__ float rs[256], rs2[256];
  int tid = threadIdx.x, c = tid & 63, slot = tid >> 6;
  int base = blockIdx.x * 1024;
  float s = 0.f, s2 = 0.f;
  for (int t = 0; t < 256; t++){
    unsigned e = (unsigned)(base + t*4 + slot);
    int i = (int)(e / 20u);
    int b = i >> 10;
    int j = idx1[e];
    float h = a1[i*64+c] + c1[((b<<10)+j)*64 + c];
    s += h; s2 += h*h;
  }
  rs[tid] = s; rs2[tid] = s2;
  __syncthreads();
  if (slot == 0){
    double ts  = (double)rs[c]  + (double)rs[64+c]  + (double)rs[128+c]  + (double)rs[192+c];
    double ts2 = (double)rs2[c] + (double)rs2[64+c] + (double)rs2[128+c] + (double)rs2[192+c];
    atomicAdd(&stats[c], ts);
    atomicAdd(&stats[64+c], ts2);
  }
}

// ================= MFMA edge-MLP =================
// Geometry: block = 8 nodes; node padded 20->32 edge rows; 16 M-tiles of 16;
// 4 waves x 4 tiles. fp32 accuracy via hi/lo bf16 split (3-term). b2 cancels
// in BN2 (stats of raw P); b3 added after the max.

// ---------------- BN2 stats over P = H1 @ W2 (raw, no b2) ----------------
__global__ __launch_bounds__(256) void k_stats2m(const float* a1, const float* c1,
    const int* idx1, const float* inb, double* stats){
  __shared__ __align__(16) float W2s[4096];
  __shared__ float sc1s[64], sh1s[64];
  __shared__ float rs[4][64], rs2[4][64];
  int tid = threadIdx.x;
  const float* wbuf = inb + IN_WBUF;
  for (int t = tid; t < 4096; t += 256) W2s[t] = wbuf[WB_W2 + t];
  if (tid < 64){
    int c = tid;
    const double M = (double)NEDGE;
    double m1 = stats[c]/M;
    double v1 = stats[64+c]/M - m1*m1;
    double r1 = 1.0/sqrt(v1 + 1e-5);
    double g1 = (double)inb[IN_G1 + c];
    sc1s[c] = (float)(g1*r1);
    sh1s[c] = (float)((double)inb[IN_BE1 + c] - m1*g1*r1);
  }
  __syncthreads();
  int lane = tid & 63, wv = tid >> 6;
  int c16 = lane & 15, ag = lane >> 4, kb0 = ag*8;
  bf16x8 w2h[4][2], w2l[4][2];
  #pragma unroll
  for (int nt = 0; nt < 4; nt++){
    #pragma unroll
    for (int ks = 0; ks < 2; ks++){
      bf16x8 h8, l8;
      #pragma unroll
      for (int e = 0; e < 8; e++){
        unsigned short hh, ll;
        bfsplit(W2s[(ks*32 + kb0 + e)*64 + nt*16 + c16], hh, ll);
        h8[e] = (short)hh; l8[e] = (short)ll;
      }
      w2h[nt][ks] = h8; w2l[nt][ks] = l8;
    }
  }
  float sa[4] = {0,0,0,0}, qa[4] = {0,0,0,0};
  for (int t4 = 0; t4 < 4; t4++){
    int T = t4*4 + wv;
    int node_l = T >> 1, half = T & 1;
    int nodeg = blockIdx.x*8 + node_l;
    int krow = half*16 + c16;
    int rr = (krow < 20);
    int j = idx1[nodeg*20 + (rr ? krow : 0)];
    int gj = ((nodeg >> 10) << 10) + j;
    const float* ar = a1 + (size_t)nodeg*64;
    const float* cr = c1 + (size_t)gj*64;
    f32x4 av0 = *(const f32x4*)(ar + kb0);
    f32x4 av1 = *(const f32x4*)(ar + kb0 + 4);
    f32x4 av2 = *(const f32x4*)(ar + 32 + kb0);
    f32x4 av3 = *(const f32x4*)(ar + 36 + kb0);
    f32x4 cv0 = *(const f32x4*)(cr + kb0);
    f32x4 cv1 = *(const f32x4*)(cr + kb0 + 4);
    f32x4 cv2 = *(const f32x4*)(cr + 32 + kb0);
    f32x4 cv3 = *(const f32x4*)(cr + 36 + kb0);
    bf16x8 a0h, a0l, a1h_, a1l_;
    #pragma unroll
    for (int e = 0; e < 4; e++){
      unsigned short hh, ll;
      float h;
      h = rr ? fmaxf((av0[e]+cv0[e])*sc1s[kb0+e] + sh1s[kb0+e], 0.f) : 0.f;
      bfsplit(h, hh, ll); a0h[e] = (short)hh; a0l[e] = (short)ll;
      h = rr ? fmaxf((av1[e]+cv1[e])*sc1s[kb0+4+e] + sh1s[kb0+4+e], 0.f) : 0.f;
      bfsplit(h, hh, ll); a0h[4+e] = (short)hh; a0l[4+e] = (short)ll;
      h = rr ? fmaxf((av2[e]+cv2[e])*sc1s[32+kb0+e] + sh1s[32+kb0+e], 0.f) : 0.f;
      bfsplit(h, hh, ll); a1h_[e] = (short)hh; a1l_[e] = (short)ll;
      h = rr ? fmaxf((av3[e]+cv3[e])*sc1s[36+kb0+e] + sh1s[36+kb0+e], 0.f) : 0.f;
      bfsplit(h, hh, ll); a1h_[4+e] = (short)hh; a1l_[4+e] = (short)ll;
    }
    #pragma unroll
    for (int nt = 0; nt < 4; nt++){
      f32x4 acc = {0.f, 0.f, 0.f, 0.f};
      acc = __builtin_amdgcn_mfma_f32_16x16x32_bf16(a0h,  w2h[nt][0], acc, 0, 0, 0);
      acc = __builtin_amdgcn_mfma_f32_16x16x32_bf16(a1h_, w2h[nt][1], acc, 0, 0, 0);
      acc = __builtin_amdgcn_mfma_f32_16x16x32_bf16(a0h,  w2l[nt][0], acc, 0, 0, 0);
      acc = __builtin_amdgcn_mfma_f32_16x16x32_bf16(a1h_, w2l[nt][1], acc, 0, 0, 0);
      acc = __builtin_amdgcn_mfma_f32_16x16x32_bf16(a0l,  w2h[nt][0], acc, 0, 0, 0);
      acc = __builtin_amdgcn_mfma_f32_16x16x32_bf16(a1l_, w2h[nt][1], acc, 0, 0, 0);
      #pragma unroll
      for (int r = 0; r < 4; r++){
        int kr = half*16 + 4*ag + r;        // D row m=(lane>>4)*4+r -> edge slot
        float v = (kr < 20) ? acc[r] : 0.f;
        sa[nt] += v; qa[nt] += v*v;
      }
    }
  }
  #pragma unroll
  for (int nt = 0; nt < 4; nt++){
    sa[nt] += __shfl_xor(sa[nt], 16); sa[nt] += __shfl_xor(sa[nt], 32);
    qa[nt] += __shfl_xor(qa[nt], 16); qa[nt] += __shfl_xor(qa[nt], 32);
  }
  if (ag == 0){
    #pragma unroll
    for (int nt = 0; nt < 4; nt++){
      rs[wv][nt*16+c16] = sa[nt];
      rs2[wv][nt*16+c16] = qa[nt];
    }
  }
  __syncthreads();
  if (tid < 64){
    double ts = (double)rs[0][tid] + (double)rs[1][tid]
              + (double)rs[2][tid] + (double)rs[3][tid];
    double tq = (double)rs2[0][tid] + (double)rs2[1][tid]
              + (double)rs2[2][tid] + (double)rs2[3][tid];
    atomicAdd(&stats[128+tid], ts);
    atomicAdd(&stats[192+tid], tq);
  }
}

// ---------------- full MLP1 via MFMA + max over k -> x1 ----------------
__global__ __launch_bounds__(256, 2) void k_x1m(const float* a1, const float* c1,
    const int* idx1, const float* inb, const double* stats, float* x1){
  __shared__ __align__(16) float W2s[4096];
  __shared__ __align__(16) float W3s[4096];
  __shared__ __align__(16) float scr[4][16*68];     // per-wave H2 relayout scratch
  __shared__ unsigned int mxp[4][8][64];            // per-wave node maxes (mono32)
  __shared__ float sc1s[64], sh1s[64], sc2s[64], sh2s[64];
  int tid = threadIdx.x;
  const float* wbuf = inb + IN_WBUF;
  for (int t = tid; t < 4096; t += 256){ W2s[t] = wbuf[WB_W2+t]; W3s[t] = wbuf[WB_W3+t]; }
  {
    unsigned int* mf = &mxp[0][0][0];
    for (int t = tid; t < 2048; t += 256) mf[t] = 0u;
  }
  if (tid < 64){
    int c = tid;
    const double M = (double)NEDGE;
    double m1 = stats[c]/M;
    double v1 = stats[64+c]/M - m1*m1;
    double r1 = 1.0/sqrt(v1 + 1e-5);
    double g1 = (double)inb[IN_G1 + c];
    sc1s[c] = (float)(g1*r1);
    sh1s[c] = (float)((double)inb[IN_BE1 + c] - m1*g1*r1);
    double mp = stats[128+c]/M;                  // mean of raw P (b2 cancels in BN)
    double v2 = stats[192+c]/M - mp*mp;
    double r2 = 1.0/sqrt(v2 + 1e-5);
    double g2 = (double)inb[IN_G2 + c];
    sc2s[c] = (float)(g2*r2);
    sh2s[c] = (float)((double)inb[IN_BE2 + c] - mp*g2*r2);
  }
  __syncthreads();
  int lane = tid & 63, wv = tid >> 6;
  int c16 = lane & 15, ag = lane >> 4, kb0 = ag*8;
  // weight fragments (hi/lo) for both layers
  bf16x8 w2h[4][2], w2l[4][2], w3h[4][2], w3l[4][2];
  #pragma unroll
  for (int nt = 0; nt < 4; nt++){
    #pragma unroll
    for (int ks = 0; ks < 2; ks++){
      bf16x8 h8, l8, h9, l9;
      #pragma unroll
      for (int e = 0; e < 8; e++){
        unsigned short hh, ll;
        bfsplit(W2s[(ks*32 + kb0 + e)*64 + nt*16 + c16], hh, ll);
        h8[e] = (short)hh; l8[e] = (short)ll;
        bfsplit(W3s[(ks*32 + kb0 + e)*64 + nt*16 + c16], hh, ll);
        h9[e] = (short)hh; l9[e] = (short)ll;
      }
      w2h[nt][ks] = h8; w2l[nt][ks] = l8;
      w3h[nt][ks] = h9; w3l[nt][ks] = l9;
    }
  }
  float scn[4], shn[4];
  #pragma unroll
  for (int nt = 0; nt < 4; nt++){
    scn[nt] = sc2s[nt*16 + c16];
    shn[nt] = sh2s[nt*16 + c16];
  }
  float* sw = &scr[wv][0];
  for (int t4 = 0; t4 < 4; t4++){
    int T = t4*4 + wv;
    int node_l = T >> 1, half = T & 1;
    int nodeg = blockIdx.x*8 + node_l;
    int krow = half*16 + c16;
    int rr = (krow < 20);
    int j = idx1[nodeg*20 + (rr ? krow : 0)];
    int gj = ((nodeg >> 10) << 10) + j;
    const float* ar = a1 + (size_t)nodeg*64;
    const float* cr = c1 + (size_t)gj*64;
    f32x4 av0 = *(const f32x4*)(ar + kb0);
    f32x4 av1 = *(const f32x4*)(ar + kb0 + 4);
    f32x4 av2 = *(const f32x4*)(ar + 32 + kb0);
    f32x4 av3 = *(const f32x4*)(ar + 36 + kb0);
    f32x4 cv0 = *(const f32x4*)(cr + kb0);
    f32x4 cv1 = *(const f32x4*)(cr + kb0 + 4);
    f32x4 cv2 = *(const f32x4*)(cr + 32 + kb0);
    f32x4 cv3 = *(const f32x4*)(cr + 36 + kb0);
    bf16x8 a0h, a0l, a1h_, a1l_;
    #pragma unroll
    for (int e = 0; e < 4; e++){
      unsigned short hh, ll;
      float h;
      h = rr ? fmaxf((av0[e]+cv0[e])*sc1s[kb0+e] + sh1s[kb0+e], 0.f) : 0.f;
      bfsplit(h, hh, ll); a0h[e] = (short)hh; a0l[e] = (short)ll;
      h = rr ? fmaxf((av1[e]+cv1[e])*sc1s[kb0+4+e] + sh1s[kb0+4+e], 0.f) : 0.f;
      bfsplit(h, hh, ll); a0h[4+e] = (short)hh; a0l[4+e] = (short)ll;
      h = rr ? fmaxf((av2[e]+cv2[e])*sc1s[32+kb0+e] + sh1s[32+kb0+e], 0.f) : 0.f;
      bfsplit(h, hh, ll); a1h_[e] = (short)hh; a1l_[e] = (short)ll;
      h = rr ? fmaxf((av3[e]+cv3[e])*sc1s[36+kb0+e] + sh1s[36+kb0+e], 0.f) : 0.f;
      bfsplit(h, hh, ll); a1h_[4+e] = (short)hh; a1l_[4+e] = (short)ll;
    }
    // ---- GEMM1: P = H1 @ W2 ----
    f32x4 pacc[4];
    #pragma unroll
    for (int nt = 0; nt < 4; nt++){
      f32x4 acc = {0.f, 0.f, 0.f, 0.f};
      acc = __builtin_amdgcn_mfma_f32_16x16x32_bf16(a0h,  w2h[nt][0], acc, 0, 0, 0);
      acc = __builtin_amdgcn_mfma_f32_16x16x32_bf16(a1h_, w2h[nt][1], acc, 0, 0, 0);
      acc = __builtin_amdgcn_mfma_f32_16x16x32_bf16(a0h,  w2l[nt][0], acc, 0, 0, 0);
      acc = __builtin_amdgcn_mfma_f32_16x16x32_bf16(a1h_, w2l[nt][1], acc, 0, 0, 0);
      acc = __builtin_amdgcn_mfma_f32_16x16x32_bf16(a0l,  w2h[nt][0], acc, 0, 0, 0);
      acc = __builtin_amdgcn_mfma_f32_16x16x32_bf16(a1l_, w2h[nt][1], acc, 0, 0, 0);
      pacc[nt] = acc;
    }
    // ---- BN2 + relu, relayout D->A via per-wave LDS scratch ----
    #pragma unroll
    for (int nt = 0; nt < 4; nt++){
      #pragma unroll
      for (int r = 0; r < 4; r++){
        float v = fmaxf(pacc[nt][r]*scn[nt] + shn[nt], 0.f);
        sw[(4*ag + r)*68 + nt*16 + c16] = v;
      }
    }
    f32x4 h20 = *(const f32x4*)(sw + c16*68 + kb0);
    f32x4 h21 = *(const f32x4*)(sw + c16*68 + kb0 + 4);
    f32x4 h22 = *(const f32x4*)(sw + c16*68 + 32 + kb0);
    f32x4 h23 = *(const f32x4*)(sw + c16*68 + 36 + kb0);
    bf16x8 b0h, b0l, b1h, b1l;
    #pragma unroll
    for (int e = 0; e < 4; e++){
      unsigned short hh, ll;
      bfsplit(h20[e], hh, ll); b0h[e] = (short)hh; b0l[e] = (short)ll;
      bfsplit(h21[e], hh, ll); b0h[4+e] = (short)hh; b0l[4+e] = (short)ll;
      bfsplit(h22[e], hh, ll); b1h[e] = (short)hh; b1l[e] = (short)ll;
      bfsplit(h23[e], hh, ll); b1h[4+e] = (short)hh; b1l[4+e] = (short)ll;
    }
    // ---- GEMM2: Q = H2 @ W3, masked max into per-wave node slots ----
    #pragma unroll
    for (int nt = 0; nt < 4; nt++){
      f32x4 acc = {0.f, 0.f, 0.f, 0.f};
      acc = __builtin_amdgcn_mfma_f32_16x16x32_bf16(b0h, w3h[nt][0], acc, 0, 0, 0);
      acc = __builtin_amdgcn_mfma_f32_16x16x32_bf16(b1h, w3h[nt][1], acc, 0, 0, 0);
      acc = __builtin_amdgcn_mfma_f32_16x16x32_bf16(b0h, w3l[nt][0], acc, 0, 0, 0);
      acc = __builtin_amdgcn_mfma_f32_16x16x32_bf16(b1h, w3l[nt][1], acc, 0, 0, 0);
      acc = __builtin_amdgcn_mfma_f32_16x16x32_bf16(b0l, w3h[nt][0], acc, 0, 0, 0);
      acc = __builtin_amdgcn_mfma_f32_16x16x32_bf16(b1l, w3h[nt][1], acc, 0, 0, 0);
      float vmx = -FLT_MAX;
      #pragma unroll
      for (int r = 0; r < 4; r++){
        int kr = half*16 + 4*ag + r;
        vmx = (kr < 20) ? fmaxf(vmx, acc[r]) : vmx;
      }
      vmx = fmaxf(vmx, __shfl_xor(vmx, 16));
      vmx = fmaxf(vmx, __shfl_xor(vmx, 32));
      if (ag == 0){
        unsigned int u = mono32(vmx);
        unsigned int* sl = &mxp[wv][node_l][nt*16 + c16];
        if (u > *sl) *sl = u;
      }
    }
  }
  __syncthreads();
  for (int s = tid; s < 512; s += 256){
    int nl = s >> 6, c = s & 63;
    unsigned int u = mxp[0][nl][c];
    unsigned int u1 = mxp[1][nl][c]; u = (u1 > u) ? u1 : u;
    unsigned int u2 = mxp[2][nl][c]; u = (u2 > u) ? u2 : u;
    unsigned int u3 = mxp[3][nl][c]; u = (u3 > u) ? u3 : u;
    unsigned int bts = (u & 0x80000000u) ? (u ^ 0x80000000u) : ~u;
    x1[(size_t)(blockIdx.x*8 + nl)*64 + c] = __uint_as_float(bts) + inb[IN_B3 + c];
  }
}

// ---------------- kNN in 64-d feature space (half-split, f64-key min/max top-k) ----------------
__global__ __launch_bounds__(256, 2) void k_knn2(const float* x1, u64* part){
  __shared__ __align__(16) float xs[64*68];          // 17408 B
  __shared__ float sqc[64];
  __shared__ u64 mrgA[64*21];                        // 10752 B
  __shared__ u64 mrgB[64*21];                        // 10752 B
  int bb   = blockIdx.x >> 5;
  int qg   = (blockIdx.x >> 1) & 15;
  int half = blockIdx.x & 1;
  int tid = threadIdx.x;
  int q_l = tid & 63;
  int slot = tid >> 6;               // wave index == slot
  int gi = bb*1024 + qg*64 + q_l;
  float4 xiv[16];
  #pragma unroll
  for (int d4 = 0; d4 < 16; d4++)
    xiv[d4] = *(const float4*)(x1 + gi*64 + d4*4);
  float sqi = 0.f;
  #pragma unroll
  for (int d4 = 0; d4 < 16; d4++)
    sqi += xiv[d4].x*xiv[d4].x + xiv[d4].y*xiv[d4].y
         + xiv[d4].z*xiv[d4].z + xiv[d4].w*xiv[d4].w;
  REP20(KDECLD)
  for (int ch = 0; ch < 8; ch++){
    int c0 = half*512 + ch*64;
    __syncthreads();
    for (int t = tid; t < 4096; t += 256){
      int r = t >> 6, d = t & 63;
      xs[r*68 + d] = x1[(bb*1024 + c0 + r)*64 + d];
    }
    __syncthreads();
    if (tid < 64){
      float s = 0.f;
      #pragma unroll 16
      for (int d = 0; d < 64; d++) s += xs[tid*68+d]*xs[tid*68+d];
      sqc[tid] = s;
    }
    __syncthreads();
    for (int u = 0; u < 16; u += 2){
      int jj0 = 4*u + slot;
      int jj1 = 4*(u+1) + slot;
      const float* xr0 = xs + jj0*68;
      const float* xr1 = xs + jj1*68;
      float dot0 = 0.f, dot1 = 0.f;
      #pragma unroll
      for (int d4 = 0; d4 < 16; d4++){
        float4 v0 = *(const float4*)(xr0 + d4*4);
        float4 v1 = *(const float4*)(xr1 + d4*4);
        dot0 += xiv[d4].x*v0.x + xiv[d4].y*v0.y + xiv[d4].z*v0.z + xiv[d4].w*v0.w;
        dot1 += xiv[d4].x*v1.x + xiv[d4].y*v1.y + xiv[d4].z*v1.z + xiv[d4].w*v1.w;
      }
      float d0 = sqi + sqc[jj0] - 2.0f*dot0;
      float d1 = sqi + sqc[jj1] - 2.0f*dot1;
      INS_MM(packkey(d0, c0 + jj0));
      INS_MM(packkey(d1, c0 + jj1));
    }
  }
  __syncthreads();
  if (slot == 1){ REP20(KPUB_A) }
  if (slot == 3){ REP20(KPUB_B) }
  __syncthreads();
  if ((slot & 1) == 0){
    const u64* src = (slot == 0) ? &mrgA[q_l*21] : &mrgB[q_l*21];
    for (int p = 0; p < KNN; p++){
      double kv = __longlong_as_double((long long)src[p]);
      if (kv > rk19) break;
      INS_MM(kv);
    }
  }
  __syncthreads();
  if (slot == 2){ REP20(KPUB_B) }
  __syncthreads();
  if (slot == 0){
    const u64* src = &mrgB[q_l*21];
    for (int p = 0; p < KNN; p++){
      double kv = __longlong_as_double((long long)src[p]);
      if (kv > rk19) break;
      INS_MM(kv);
    }
    u64* gpart = part + ((size_t)gi*2 + half)*KNN;
    REP20(KSTG)
  }
}

// ---------------- fast path: B2H = x1 @ Wbot[:, q-half] ----------------
__global__ __launch_bounds__(256) void k_B2h(const float* x1, const float* inb,
                                             int q, float* B2H){
  __shared__ __align__(16) float Wbh[4096];
  __shared__ __align__(16) float xsh[1024];
  int tid = threadIdx.x;
  const float* Wb = inb + IN_WBUF + WB_WBOT;
  for (int t = tid; t < 4096; t += 256){
    int r = t >> 6, cl = t & 63;
    Wbh[t] = Wb[r*128 + q*64 + cl];
  }
  int node0 = blockIdx.x * 16;
  for (int t = tid; t < 1024; t += 256) xsh[t] = x1[node0*64 + t];
  __syncthreads();
  int n_l = tid >> 4, cg = tid & 15;
  const float* xr = xsh + n_l*64;
  float4 acc = make_float4(0.f,0.f,0.f,0.f);
  #pragma unroll 8
  for (int d = 0; d < 64; d++){
    float v = xr[d];
    float4 w = *(const float4*)(Wbh + d*64 + cg*4);
    acc.x += v*w.x; acc.y += v*w.y; acc.z += v*w.z; acc.w += v*w.w;
  }
  *(float4*)(B2H + (node0 + n_l)*64 + cg*4) = acc;
}

// ---------------- fast path: x2 half = (x1_i@Wd + bc2) + max_j B2H[j] ----------------
__global__ __launch_bounds__(256) void k_x2h(const float* x1, const float* B2H,
                                             const float* inb, const int* idx2,
                                             int q, float* x2){
  __shared__ __align__(16) float Wdh[4096];
  __shared__ __align__(16) float xsh[256];
  int tid = threadIdx.x;
  const float* Wd = inb + IN_WBUF + WB_WD;
  for (int t = tid; t < 4096; t += 256){
    int r = t >> 6, cl = t & 63;
    Wdh[t] = Wd[r*128 + q*64 + cl];
  }
  int node0 = blockIdx.x * 4;
  xsh[tid] = x1[node0*64 + tid];
  __syncthreads();
  int n_l = tid >> 6, cl = tid & 63;
  int i = node0 + n_l;
  int b = i >> 10;
  const float* xr = xsh + n_l*64;
  float acc = inb[IN_BC2 + q*64 + cl];
  #pragma unroll 8
  for (int d = 0; d < 64; d++) acc += xr[d]*Wdh[d*64 + cl];
  float m = -FLT_MAX;
  for (int kk = 0; kk < KNN; kk++){
    int j = idx2[i*KNN + kk];
    m = fmaxf(m, B2H[((b<<10)+j)*64 + cl]);
  }
  x2[i*128 + q*64 + cl] = acc + m;
}

// ---------------- slow fallback: x2 direct, LDS-staged, no B2H buffer ----------------
__global__ __launch_bounds__(256) void k_x2d(const float* x1, const float* inb,
                                             const int* idx2, float* x2){
  __shared__ __align__(16) float Wdh[4096], Wbh[4096];
  __shared__ __align__(16) float xis[1024], xjs[1024];
  int tid = threadIdx.x;
  int q = blockIdx.x & 1;
  int node0 = (blockIdx.x >> 1) * 16;
  const float* Wd = inb + IN_WBUF + WB_WD;
  const float* Wb = inb + IN_WBUF + WB_WBOT;
  for (int t = tid; t < 4096; t += 256){
    int r = t >> 6, cl = t & 63;
    Wdh[t] = Wd[r*128 + q*64 + cl];
    Wbh[t] = Wb[r*128 + q*64 + cl];
  }
  for (int t = tid; t < 1024; t += 256) xis[t] = x1[node0*64 + t];
  __syncthreads();
  int n_l = tid >> 4, cg = tid & 15;
  int i = node0 + n_l, b = i >> 10;
  const float* xr = xis + n_l*64;
  float4 af = make_float4(inb[IN_BC2 + q*64 + cg*4],   inb[IN_BC2 + q*64 + cg*4+1],
                          inb[IN_BC2 + q*64 + cg*4+2], inb[IN_BC2 + q*64 + cg*4+3]);
  #pragma unroll 8
  for (int d = 0; d < 64; d++){
    float v = xr[d];
    float4 w = *(const float4*)(Wdh + d*64 + cg*4);
    af.x += v*w.x; af.y += v*w.y; af.z += v*w.z; af.w += v*w.w;
  }
  float4 mx = make_float4(-FLT_MAX,-FLT_MAX,-FLT_MAX,-FLT_MAX);
  for (int kk = 0; kk < KNN; kk++){
    __syncthreads();
    for (int t = tid; t < 1024; t += 256){
      int nn = t >> 6, r = t & 63;
      int jj = idx2[(node0+nn)*KNN + kk];
      xjs[t] = x1[((((node0+nn) >> 10) << 10) + jj)*64 + r];
    }
    __syncthreads();
    const float* xj = xjs + n_l*64;
    float4 acc = make_float4(0.f,0.f,0.f,0.f);
    #pragma unroll 8
    for (int d = 0; d < 64; d++){
      float v = xj[d];
      float4 w = *(const float4*)(Wbh + d*64 + cg*4);
      acc.x += v*w.x; acc.y += v*w.y; acc.z += v*w.z; acc.w += v*w.w;
    }
    mx.x = fmaxf(mx.x, acc.x); mx.y = fmaxf(mx.y, acc.y);
    mx.z = fmaxf(mx.z, acc.z); mx.w = fmaxf(mx.w, acc.w);
  }
  *(float4*)(x2 + i*128 + q*64 + cg*4) =
      make_float4(af.x+mx.x, af.y+mx.y, af.z+mx.z, af.w+mx.w);
}

// ---------------- lin (192->1024) + partial max over n-quarter ----------------
__global__ __launch_bounds__(256) void k_linpool(const float* x1, const float* x2,
    const float* inb, float* pool4){
  __shared__ __align__(16) float fst[192*36];
  __shared__ float red2[1024];
  int tid = threadIdx.x;
  int b = blockIdx.x >> 4, cq = (blockIdx.x >> 2) & 3, nh = blockIdx.x & 3;
  int cg = tid & 63, n8 = tid >> 6;
  int cbase = cq*256 + cg*4;
  const float* Wl = inb + IN_WBUF + WB_WL;
  float m0 = -FLT_MAX, m1 = -FLT_MAX, m2 = -FLT_MAX, m3 = -FLT_MAX;
  for (int ng = 0; ng < 8; ng++){
    __syncthreads();
    for (int t = tid; t < 6144; t += 256){
      int n_l = t / 192, dd = t - n_l*192;
      int gi = b*1024 + nh*256 + ng*32 + n_l;
      fst[dd*36 + n_l] = (dd < 64) ? x1[gi*64 + dd] : x2[gi*128 + dd - 64];
    }
    __syncthreads();
    float acc[8][4];
    #pragma unroll
    for (int n = 0; n < 8; n++){ acc[n][0]=0; acc[n][1]=0; acc[n][2]=0; acc[n][3]=0; }
    #pragma unroll 4
    for (int d = 0; d < 192; d++){
      float4 w = *(const float4*)(Wl + d*1024 + cbase);
      const float* fr = fst + d*36 + n8*8;
      float4 f0 = *(const float4*)(fr);
      float4 f1 = *(const float4*)(fr + 4);
      float fv[8] = {f0.x, f0.y, f0.z, f0.w, f1.x, f1.y, f1.z, f1.w};
      #pragma unroll
      for (int n = 0; n < 8; n++){
        acc[n][0] += fv[n]*w.x; acc[n][1] += fv[n]*w.y;
        acc[n][2] += fv[n]*w.z; acc[n][3] += fv[n]*w.w;
      }
    }
    #pragma unroll
    for (int n = 0; n < 8; n++){
      m0 = fmaxf(m0, acc[n][0]); m1 = fmaxf(m1, acc[n][1]);
      m2 = fmaxf(m2, acc[n][2]); m3 = fmaxf(m3, acc[n][3]);
    }
  }
  red2[n8*256 + cg*4]   = m0;  red2[n8*256 + cg*4+1] = m1;
  red2[n8*256 + cg*4+2] = m2;  red2[n8*256 + cg*4+3] = m3;
  __syncthreads();
  if (n8 == 0){
    #pragma unroll
    for (int u = 0; u < 4; u++){
      int cc = cg*4 + u;
      float m = fmaxf(fmaxf(red2[cc], red2[256+cc]), fmaxf(red2[512+cc], red2[768+cc]));
      pool4[nh*32768 + b*1024 + cbase + u] = m;     // bias applied in k_head
    }
  }
}

// ---------------- head MLP: reduce pool4 + 1024->512->256->40 (fp32 out) ----------------
__global__ __launch_bounds__(256) void k_head(const float* pool4, const float* inb,
                                              float* out){
  __shared__ float pl[1024];
  __shared__ float s1[512];
  __shared__ float s2[256];
  int b = blockIdx.x, tid = threadIdx.x;
  const float* Wm1 = inb + IN_WBUF + WB_WM1;
  const float* Wm2 = inb + IN_WBUF + WB_WM2;
  const float* Wm3 = inb + IN_WBUF + WB_WM3;
  for (int t = tid; t < 1024; t += 256){
    float m = fmaxf(fmaxf(pool4[b*1024 + t],         pool4[32768 + b*1024 + t]),
                    fmaxf(pool4[65536 + b*1024 + t], pool4[98304 + b*1024 + t]));
    pl[t] = m + inb[IN_BL + t];
  }
  __syncthreads();
  for (int c = tid; c < 512; c += 256){
    float acc = inb[IN_BM1 + c];
    #pragma unroll 4
    for (int d = 0; d < 1024; d++) acc += pl[d]*Wm1[d*512 + c];
    s1[c] = fmaxf(acc, 0.f);
  }
  __syncthreads();
  {
    int c = tid;
    float acc = inb[IN_BM2 + c];
    #pragma unroll 4
    for (int d = 0; d < 512; d++) acc += s1[d]*Wm2[d*256 + c];
    s2[c] = fmaxf(acc, 0.f);
  }
  __syncthreads();
  if (tid < 40){
    float acc = inb[IN_BM3 + tid];
    #pragma unroll 4
    for (int d = 0; d < 256; d++) acc += s2[d]*Wm3[d*40 + tid];
    out[b*40 + tid] = acc;
  }
}

extern "C" void kernel_launch(void* const* d_in, const int* in_sizes, int n_in,
                              void* d_out, int out_size, void* d_ws, size_t ws_size,
                              hipStream_t stream){
  float* ws     = (float*)d_ws;
  double* stats = (double*)d_ws;
  int*   flag   = (int*)d_ws + OFF_FLAG;
  float* inb    = ws + OFF_INB;
  int*   idx    = (int*)d_ws + OFF_IDX;     // idx1 early, idx2 late
  float* x1p    = ws + OFF_X1;
  float* x2p    = ws + OFF_X2;
  float* a1     = ws + OFF_X2;              // a1/c1 alias x2 region (dead before x2 written)
  float* c1     = ws + OFF_C1;
  u64*   part   = (u64*)(ws + OFF_X2);      // kNN partials alias a1/c1 (see layout note)
  float* pool4  = ws + OFF_POOL;
  float* B2H    = ws + OFF_B2H;
  bool fast = ws_size >= (size_t)FAST_END * 4u;

  hipMemsetAsync(stats, 0, 256*sizeof(double), stream);
  k_sniff<<<1, 64, 0, stream>>>(d_in[0], flag);
  k_cvt<<<3859, 256, 0, stream>>>(
      d_in[0], d_in[1], d_in[2], d_in[3], d_in[4], d_in[5], d_in[6], d_in[7],
      d_in[8], d_in[9], d_in[10], d_in[11], d_in[12], d_in[13], d_in[14],
      d_in[15], d_in[16], d_in[17], d_in[18], d_in[19], d_in[20], flag, inb);
  k_knn1<<<1024, 256, 0, stream>>>(inb, part);      // partials in a1/c1 region
  k_mrg<<<128, 256, 0, stream>>>(part, idx);        // -> idx1
  k_prep1<<<8192, 256, 0, stream>>>(inb, a1, c1);   // overwrites dead partials
  k_stats1<<<640, 256, 0, stream>>>(a1, c1, idx, stats);
  k_stats2m<<<4096, 256, 0, stream>>>(a1, c1, idx, inb, stats);
  k_x1m<<<4096, 256, 0, stream>>>(a1, c1, idx, inb, stats, x1p);
  k_knn2<<<1024, 256, 0, stream>>>(x1p, part);      // a1/c1 dead after k_x1m
  k_mrg<<<128, 256, 0, stream>>>(part, idx);        // -> idx2
  if (fast){
    k_B2h<<<2048, 256, 0, stream>>>(x1p, inb, 0, B2H);
    k_x2h<<<8192, 256, 0, stream>>>(x1p, B2H, inb, idx, 0, x2p);
    k_B2h<<<2048, 256, 0, stream>>>(x1p, inb, 1, B2H);
    k_x2h<<<8192, 256, 0, stream>>>(x1p, B2H, inb, idx, 1, x2p);
  } else {
    k_x2d<<<4096, 256, 0, stream>>>(x1p, inb, idx, x2p);
  }
  k_linpool<<<512, 256, 0, stream>>>(x1p, x2p, inb, pool4);
  k_head<<<32, 256, 0, stream>>>(pool4, inb, (float*)d_out);
}

// Round 7
// 1184.258 us; speedup vs baseline: 3.7324x; 1.0797x over previous
//
#include <hip/hip_runtime.h>
#include <hip/hip_bf16.h>
#include <float.h>
#include <math.h>

typedef __hip_bfloat16 bf16;
typedef unsigned long long u64;

#define BATCH 32
#define NPTS  1024
#define KNN   20
#define NB    (BATCH*NPTS)      // 32768 nodes
#define NEDGE (NB*KNN)          // 655360 edges

// ---- workspace layout (float units), ws_size-adaptive ----
#define OFF_FLAG 512u
#define OFF_INB  1024u
#define OFF_IDX  988928u          // 655360 ints (idx1 early, idx2 late)
#define OFF_X1   1644288u         // NB*64
#define OFF_X2   3741440u         // NB*128 ; a1 @ OFF_X2, c1 @ OFF_C1 (early)
#define OFF_C1   5838592u
#define OFF_POOL 7935744u         // pool4: 4 x 32*1024
#define SLOW_END 8066816u         // 32.3 MB
#define OFF_B2H  8066816u         // NB*64 (fast path only)
#define FAST_END 10163968u        // 40.7 MB
// kNN partial lists (u64) alias OFF_X2 (dead there at both kNN points).
// ---- layout inside inb (canonical fp32 inputs) ----
#define IN_POSF 0u
#define IN_B1   98304u
#define IN_G1   98368u
#define IN_BE1  98432u
#define IN_B2   98496u
#define IN_G2   98560u
#define IN_BE2  98624u
#define IN_B3   98688u
#define IN_BC2  98752u
#define IN_BL   98880u
#define IN_BM1  99904u
#define IN_BM2  100416u
#define IN_BM3  100672u
#define IN_W1   100736u
#define IN_WBUF 101120u
#define WB_W2   0u
#define WB_W3   4096u
#define WB_WD   8192u            // Wc2 top-bot diff [64x128]
#define WB_WBOT 16384u           // Wc2 bottom      [64x128]
#define WB_WL   24576u
#define WB_WM1  221184u
#define WB_WM2  745472u
#define WB_WM3  876544u
#define IN_TOTAL 987904u

__device__ __forceinline__ float bf2f(bf16 v){ return __bfloat162float(v); }

// monotone float->u32 map: preserves IEEE-754 total order for all finite values
__device__ __forceinline__ unsigned int mono32(float f){
  unsigned int b = __float_as_uint(f);
  return b ^ ((unsigned int)((int)b >> 31) | 0x80000000u);
}

// ======== MFMA machinery (bf16 hi/lo split, fp32-accurate) ========
typedef __attribute__((ext_vector_type(8))) short bf16x8;
typedef __attribute__((ext_vector_type(4))) float f32x4;

__device__ __forceinline__ unsigned short bfhi(float f){
  unsigned int u = __float_as_uint(f);
  u += 0x7FFFu + ((u >> 16) & 1u);      // RNE to bf16
  return (unsigned short)(u >> 16);
}
__device__ __forceinline__ void bfsplit(float f, unsigned short& h, unsigned short& l){
  h = bfhi(f);
  float fh = __uint_as_float(((unsigned int)h) << 16);
  l = bfhi(f - fh);
}

// ======== exact top-k via f64-packed keys + min/max sorted-insert ========
// Key bits = (1<<62) | (f32bits(max(d,0)) << 20) | idx -> positive doubles,
// value order == lexicographic (d, idx) == top_k semantics, globally unique.
// Insert: new_rp = min(rp, max(rp-1, k)) descending (exact multiset identity).
#define REP20(M) M(0) M(1) M(2) M(3) M(4) M(5) M(6) M(7) M(8) M(9) \
                 M(10) M(11) M(12) M(13) M(14) M(15) M(16) M(17) M(18) M(19)
#define SH19(M) M(19,18) M(18,17) M(17,16) M(16,15) M(15,14) M(14,13) M(13,12) \
                M(12,11) M(11,10) M(10,9) M(9,8) M(8,7) M(7,6) M(6,5) M(5,4) \
                M(4,3) M(3,2) M(2,1) M(1,0)

__device__ __forceinline__ double packkey(float d, int idx){
  unsigned int b = __float_as_uint(fmaxf(d, 0.0f));
  u64 k = 0x4000000000000000ULL | ((u64)b << 20) | (unsigned int)idx;
  return __longlong_as_double((long long)k);
}

#define KDECLD(p) double rk##p = DBL_MAX;
#define KMM(p,pm) rk##p = fmin(rk##p, fmax(rk##pm, _k));
#define INS_MM(kv) do{ double _k=(kv); SH19(KMM) rk0 = fmin(rk0, _k); }while(0)

#define KPUB_A(p) mrgA[q_l*21+p] = (u64)__double_as_longlong(rk##p);
#define KPUB_B(p) mrgB[q_l*21+p] = (u64)__double_as_longlong(rk##p);
#define KSTG(p)   gpart[p] = (u64)__double_as_longlong(rk##p);
#define KLDAD(p)  double rk##p = __longlong_as_double((long long)pa[p]);
#define KOUTU(p)  optr[p] = (int)((u64)__double_as_longlong(rk##p) & 1023ULL);

// ---------------- dtype sniff (fp32 vs bf16 inputs) ----------------
__global__ void k_sniff(const void* pos_raw, int* flag){
  if (blockIdx.x == 0 && threadIdx.x == 0){
    const unsigned short* h = (const unsigned short*)pos_raw;
    int wild = 0;
    for (int k = 0; k < 16; k++){
      unsigned int bits = ((unsigned int)h[2*k]) << 16;
      float v = __uint_as_float(bits);
      float a = fabsf(v);
      if (a != 0.0f && (v != v || a > 1e10f || a < 1e-10f)) wild++;
    }
    *flag = (wild >= 4) ? 1 : 0;
  }
}

__device__ __forceinline__ float rdv(const void* p, int i, int f){
  return f ? ((const float*)p)[i] : bf2f(((const bf16*)p)[i]);
}

// ---------------- normalize ALL inputs to canonical fp32 buffer ----------------
__global__ __launch_bounds__(256) void k_cvt(
    const void* pos, const void* W1, const void* b1, const void* g1, const void* be1,
    const void* W2, const void* b2, const void* g2, const void* be2,
    const void* W3, const void* b3, const void* Wc2, const void* bc2,
    const void* Wl, const void* bl, const void* Wm1, const void* bm1,
    const void* Wm2, const void* bm2, const void* Wm3, const void* bm3,
    const int* flag, float* inb){
  int id = blockIdx.x*256 + threadIdx.x;
  if (id >= (int)IN_TOTAL) return;
  int f = *flag;
  float v;
  if      (id < 98304)  v = rdv(pos, id, f);
  else if (id < 98368)  v = rdv(b1,  id-98304, f);
  else if (id < 98432)  v = rdv(g1,  id-98368, f);
  else if (id < 98496)  v = rdv(be1, id-98432, f);
  else if (id < 98560)  v = rdv(b2,  id-98496, f);
  else if (id < 98624)  v = rdv(g2,  id-98560, f);
  else if (id < 98688)  v = rdv(be2, id-98624, f);
  else if (id < 98752)  v = rdv(b3,  id-98688, f);
  else if (id < 98880)  v = rdv(bc2, id-98752, f);
  else if (id < 99904)  v = rdv(bl,  id-98880, f);
  else if (id < 100416) v = rdv(bm1, id-99904, f);
  else if (id < 100672) v = rdv(bm2, id-100416, f);
  else if (id < 100712) v = rdv(bm3, id-100672, f);
  else if (id < 100736) v = 0.0f;
  else if (id < 101120) v = rdv(W1,  id-100736, f);
  else {
    int t = id - 101120;
    if      (t < 4096)   v = rdv(W2, t, f);
    else if (t < 8192)   v = rdv(W3, t-4096, f);
    else if (t < 16384){ int u = t-8192;  v = rdv(Wc2, u, f) - rdv(Wc2, 8192+u, f); }
    else if (t < 24576){ int u = t-16384; v = rdv(Wc2, 8192+u, f); }
    else if (t < 221184) v = rdv(Wl,  t-24576, f);
    else if (t < 745472) v = rdv(Wm1, t-221184, f);
    else if (t < 876544) v = rdv(Wm2, t-745472, f);
    else                 v = rdv(Wm3, t-876544, f);
  }
  inb[id] = v;
}

// ---------------- a1/c1: affine decomposition of EdgeConv1 layer1 ----------------
__global__ __launch_bounds__(256) void k_prep1(const float* inb, float* a1, float* c1){
  const float* posf = inb + IN_POSF;
  const float* W1f  = inb + IN_W1;
  const float* b1f  = inb + IN_B1;
  int id = blockIdx.x*256 + threadIdx.x;
  int bn = id >> 6, c = id & 63;
  float p0 = posf[bn*3], p1 = posf[bn*3+1], p2 = posf[bn*3+2];
  float wt0 = W1f[c],     wt1 = W1f[64+c],  wt2 = W1f[128+c];
  float wb0 = W1f[192+c], wb1 = W1f[256+c], wb2 = W1f[320+c];
  float cv = p0*wb0 + p1*wb1 + p2*wb2;
  float av = p0*(wt0-wb0) + p1*(wt1-wb1) + p2*(wt2-wb2) + b1f[c];
  a1[id] = av;  c1[id] = cv;
}

// ---------------- kNN in coordinate space (half-split, LDS-union, f64-key top-k) ----------------
// LDS union: scan arrays (psx/psy/psz/sqs, 16KB) are dead once all waves pass
// the post-scan barrier; merge arrays (21.5KB) overlay them. 21.5KB total.
__global__ __launch_bounds__(256, 2) void k_knn1(const float* inb, u64* part){
  const float* posf = inb + IN_POSF;
  __shared__ __align__(16) char sm1[21504];
  float* psx = (float*)sm1;
  float* psy = psx + 1024;
  float* psz = psy + 1024;
  float* sqs = psz + 1024;
  u64* mrgA = (u64*)sm1;              // overlay (post-scan only)
  u64* mrgB = (u64*)(sm1 + 10752);
  int bb   = blockIdx.x >> 5;
  int qg   = (blockIdx.x >> 1) & 15;
  int half = blockIdx.x & 1;
  int tid = threadIdx.x;
  int q_l = tid & 63;
  int slot = tid >> 6;
  for (int t = tid; t < 1024; t += 256){
    float x = posf[(bb*1024+t)*3], y = posf[(bb*1024+t)*3+1], z = posf[(bb*1024+t)*3+2];
    psx[t] = x; psy[t] = y; psz[t] = z; sqs[t] = x*x + y*y + z*z;
  }
  __syncthreads();
  int i_l = qg*64 + q_l;
  float xi0 = psx[i_l], xi1 = psy[i_l], xi2 = psz[i_l];
  float sqi = sqs[i_l];
  REP20(KDECLD)
  int cbase = half*512;
  for (int u = 0; u < 128; u++){
    int jj = cbase + 4*u + slot;
    float dot = xi0*psx[jj] + xi1*psy[jj] + xi2*psz[jj];
    float d = sqi + sqs[jj] - 2.0f*dot;
    INS_MM(packkey(d, jj));
  }
  __syncthreads();                    // scan arrays dead from here (union!)
  // tree-merge the 4 slot lists (slot1->A, slot3->B; 0+=A, 2+=B; 2->B; 0+=B)
  if (slot == 1){ REP20(KPUB_A) }
  if (slot == 3){ REP20(KPUB_B) }
  __syncthreads();
  if ((slot & 1) == 0){
    const u64* src = (slot == 0) ? &mrgA[q_l*21] : &mrgB[q_l*21];
    for (int p = 0; p < KNN; p++){
      double kv = __longlong_as_double((long long)src[p]);
      if (kv > rk19) break;          // sorted source: rest are worse
      INS_MM(kv);
    }
  }
  __syncthreads();
  if (slot == 2){ REP20(KPUB_B) }
  __syncthreads();
  if (slot == 0){
    const u64* src = &mrgB[q_l*21];
    for (int p = 0; p < KNN; p++){
      double kv = __longlong_as_double((long long)src[p]);
      if (kv > rk19) break;
      INS_MM(kv);
    }
    int gi = bb*1024 + i_l;
    u64* gpart = part + ((size_t)gi*2 + half)*KNN;
    REP20(KSTG)
  }
}

// ---------------- merge two sorted 20-entry half-lists per query ----------------
__global__ __launch_bounds__(256) void k_mrg(const u64* part, int* out){
  int gi = blockIdx.x*256 + threadIdx.x;    // grid 128 -> 32768 queries
  const u64* pa = part + (size_t)gi*2*KNN;
  REP20(KLDAD)                               // init from half-0 list (sorted)
  for (int p = 0; p < KNN; p++){
    double kv = __longlong_as_double((long long)pa[KNN + p]);
    if (kv > rk19) break;                    // sorted source: rest are worse
    INS_MM(kv);
  }
  int* optr = out + gi*KNN;
  REP20(KOUTU)
}

// ---------------- BN1 stats ----------------
__global__ __launch_bounds__(256) void k_stats1(const float* a1, const float* c1,
                                                const int* idx1, double* stats){
  __shared__ float rs[256], rs2[256];
  int tid = threadIdx.x, c = tid & 63, slot = tid >> 6;
  int base = blockIdx.x * 1024;
  float s = 0.f, s2 = 0.f;
  for (int t = 0; t < 256; t++){
    unsigned e = (unsigned)(base + t*4 + slot);
    int i = (int)(e / 20u);
    int b = i >> 10;
    int j = idx1[e];
    float h = a1[i*64+c] + c1[((b<<10)+j)*64 + c];
    s += h; s2 += h*h;
  }
  rs[tid] = s; rs2[tid] = s2;
  __syncthreads();
  if (slot == 0){
    double ts  = (double)rs[c]  + (double)rs[64+c]  + (double)rs[128+c]  + (double)rs[192+c];
    double ts2 = (double)rs2[c] + (double)rs2[64+c] + (double)rs2[128+c] + (double)rs2[192+c];
    atomicAdd(&stats[c], ts);
    atomicAdd(&stats[64+c], ts2);
  }
}

// ================= MFMA edge-MLP =================
// Geometry: block = 8 nodes; node padded 20->32 edge rows; 16 M-tiles of 16;
// 4 waves x 4 tiles. fp32 accuracy via hi/lo bf16 split (3-term). b2 cancels
// in BN2 (stats of raw P); b3 added after the max.

// ---------------- BN2 stats over P = H1 @ W2 (raw, no b2) ----------------
__global__ __launch_bounds__(256) void k_stats2m(const float* a1, const float* c1,
    const int* idx1, const float* inb, double* stats){
  __shared__ __align__(16) float W2s[4096];
  __shared__ float sc1s[64], sh1s[64];
  __shared__ float rs[4][64], rs2[4][64];
  int tid = threadIdx.x;
  const float* wbuf = inb + IN_WBUF;
  for (int t = tid; t < 4096; t += 256) W2s[t] = wbuf[WB_W2 + t];
  if (tid < 64){
    int c = tid;
    const double M = (double)NEDGE;
    double m1 = stats[c]/M;
    double v1 = stats[64+c]/M - m1*m1;
    double r1 = 1.0/sqrt(v1 + 1e-5);
    double g1 = (double)inb[IN_G1 + c];
    sc1s[c] = (float)(g1*r1);
    sh1s[c] = (float)((double)inb[IN_BE1 + c] - m1*g1*r1);
  }
  __syncthreads();
  int lane = tid & 63, wv = tid >> 6;
  int c16 = lane & 15, ag = lane >> 4, kb0 = ag*8;
  bf16x8 w2h[4][2], w2l[4][2];
  #pragma unroll
  for (int nt = 0; nt < 4; nt++){
    #pragma unroll
    for (int ks = 0; ks < 2; ks++){
      bf16x8 h8, l8;
      #pragma unroll
      for (int e = 0; e < 8; e++){
        unsigned short hh, ll;
        bfsplit(W2s[(ks*32 + kb0 + e)*64 + nt*16 + c16], hh, ll);
        h8[e] = (short)hh; l8[e] = (short)ll;
      }
      w2h[nt][ks] = h8; w2l[nt][ks] = l8;
    }
  }
  float sa[4] = {0,0,0,0}, qa[4] = {0,0,0,0};
  for (int t4 = 0; t4 < 4; t4++){
    int T = t4*4 + wv;
    int node_l = T >> 1, half = T & 1;
    int nodeg = blockIdx.x*8 + node_l;
    int krow = half*16 + c16;
    int rr = (krow < 20);
    int j = idx1[nodeg*20 + (rr ? krow : 0)];
    int gj = ((nodeg >> 10) << 10) + j;
    const float* ar = a1 + (size_t)nodeg*64;
    const float* cr = c1 + (size_t)gj*64;
    f32x4 av0 = *(const f32x4*)(ar + kb0);
    f32x4 av1 = *(const f32x4*)(ar + kb0 + 4);
    f32x4 av2 = *(const f32x4*)(ar + 32 + kb0);
    f32x4 av3 = *(const f32x4*)(ar + 36 + kb0);
    f32x4 cv0 = *(const f32x4*)(cr + kb0);
    f32x4 cv1 = *(const f32x4*)(cr + kb0 + 4);
    f32x4 cv2 = *(const f32x4*)(cr + 32 + kb0);
    f32x4 cv3 = *(const f32x4*)(cr + 36 + kb0);
    bf16x8 a0h, a0l, a1h_, a1l_;
    #pragma unroll
    for (int e = 0; e < 4; e++){
      unsigned short hh, ll;
      float h;
      h = rr ? fmaxf((av0[e]+cv0[e])*sc1s[kb0+e] + sh1s[kb0+e], 0.f) : 0.f;
      bfsplit(h, hh, ll); a0h[e] = (short)hh; a0l[e] = (short)ll;
      h = rr ? fmaxf((av1[e]+cv1[e])*sc1s[kb0+4+e] + sh1s[kb0+4+e], 0.f) : 0.f;
      bfsplit(h, hh, ll); a0h[4+e] = (short)hh; a0l[4+e] = (short)ll;
      h = rr ? fmaxf((av2[e]+cv2[e])*sc1s[32+kb0+e] + sh1s[32+kb0+e], 0.f) : 0.f;
      bfsplit(h, hh, ll); a1h_[e] = (short)hh; a1l_[e] = (short)ll;
      h = rr ? fmaxf((av3[e]+cv3[e])*sc1s[36+kb0+e] + sh1s[36+kb0+e], 0.f) : 0.f;
      bfsplit(h, hh, ll); a1h_[4+e] = (short)hh; a1l_[4+e] = (short)ll;
    }
    #pragma unroll
    for (int nt = 0; nt < 4; nt++){
      f32x4 acc = {0.f, 0.f, 0.f, 0.f};
      acc = __builtin_amdgcn_mfma_f32_16x16x32_bf16(a0h,  w2h[nt][0], acc, 0, 0, 0);
      acc = __builtin_amdgcn_mfma_f32_16x16x32_bf16(a1h_, w2h[nt][1], acc, 0, 0, 0);
      acc = __builtin_amdgcn_mfma_f32_16x16x32_bf16(a0h,  w2l[nt][0], acc, 0, 0, 0);
      acc = __builtin_amdgcn_mfma_f32_16x16x32_bf16(a1h_, w2l[nt][1], acc, 0, 0, 0);
      acc = __builtin_amdgcn_mfma_f32_16x16x32_bf16(a0l,  w2h[nt][0], acc, 0, 0, 0);
      acc = __builtin_amdgcn_mfma_f32_16x16x32_bf16(a1l_, w2h[nt][1], acc, 0, 0, 0);
      #pragma unroll
      for (int r = 0; r < 4; r++){
        int kr = half*16 + 4*ag + r;        // D row m=(lane>>4)*4+r -> edge slot
        float v = (kr < 20) ? acc[r] : 0.f;
        sa[nt] += v; qa[nt] += v*v;
      }
    }
  }
  #pragma unroll
  for (int nt = 0; nt < 4; nt++){
    sa[nt] += __shfl_xor(sa[nt], 16); sa[nt] += __shfl_xor(sa[nt], 32);
    qa[nt] += __shfl_xor(qa[nt], 16); qa[nt] += __shfl_xor(qa[nt], 32);
  }
  if (ag == 0){
    #pragma unroll
    for (int nt = 0; nt < 4; nt++){
      rs[wv][nt*16+c16] = sa[nt];
      rs2[wv][nt*16+c16] = qa[nt];
    }
  }
  __syncthreads();
  if (tid < 64){
    double ts = (double)rs[0][tid] + (double)rs[1][tid]
              + (double)rs[2][tid] + (double)rs[3][tid];
    double tq = (double)rs2[0][tid] + (double)rs2[1][tid]
              + (double)rs2[2][tid] + (double)rs2[3][tid];
    atomicAdd(&stats[128+tid], ts);
    atomicAdd(&stats[192+tid], tq);
  }
}

// ---------------- full MLP1 via MFMA + max over k -> x1 ----------------
__global__ __launch_bounds__(256, 2) void k_x1m(const float* a1, const float* c1,
    const int* idx1, const float* inb, const double* stats, float* x1){
  __shared__ __align__(16) float W2s[4096];
  __shared__ __align__(16) float W3s[4096];
  __shared__ __align__(16) float scr[4][16*68];     // per-wave H2 relayout scratch
  __shared__ unsigned int mxp[4][8][64];            // per-wave node maxes (mono32)
  __shared__ float sc1s[64], sh1s[64], sc2s[64], sh2s[64];
  int tid = threadIdx.x;
  const float* wbuf = inb + IN_WBUF;
  for (int t = tid; t < 4096; t += 256){ W2s[t] = wbuf[WB_W2+t]; W3s[t] = wbuf[WB_W3+t]; }
  {
    unsigned int* mf = &mxp[0][0][0];
    for (int t = tid; t < 2048; t += 256) mf[t] = 0u;
  }
  if (tid < 64){
    int c = tid;
    const double M = (double)NEDGE;
    double m1 = stats[c]/M;
    double v1 = stats[64+c]/M - m1*m1;
    double r1 = 1.0/sqrt(v1 + 1e-5);
    double g1 = (double)inb[IN_G1 + c];
    sc1s[c] = (float)(g1*r1);
    sh1s[c] = (float)((double)inb[IN_BE1 + c] - m1*g1*r1);
    double mp = stats[128+c]/M;                  // mean of raw P (b2 cancels in BN)
    double v2 = stats[192+c]/M - mp*mp;
    double r2 = 1.0/sqrt(v2 + 1e-5);
    double g2 = (double)inb[IN_G2 + c];
    sc2s[c] = (float)(g2*r2);
    sh2s[c] = (float)((double)inb[IN_BE2 + c] - mp*g2*r2);
  }
  __syncthreads();
  int lane = tid & 63, wv = tid >> 6;
  int c16 = lane & 15, ag = lane >> 4, kb0 = ag*8;
  // weight fragments (hi/lo) for both layers
  bf16x8 w2h[4][2], w2l[4][2], w3h[4][2], w3l[4][2];
  #pragma unroll
  for (int nt = 0; nt < 4; nt++){
    #pragma unroll
    for (int ks = 0; ks < 2; ks++){
      bf16x8 h8, l8, h9, l9;
      #pragma unroll
      for (int e = 0; e < 8; e++){
        unsigned short hh, ll;
        bfsplit(W2s[(ks*32 + kb0 + e)*64 + nt*16 + c16], hh, ll);
        h8[e] = (short)hh; l8[e] = (short)ll;
        bfsplit(W3s[(ks*32 + kb0 + e)*64 + nt*16 + c16], hh, ll);
        h9[e] = (short)hh; l9[e] = (short)ll;
      }
      w2h[nt][ks] = h8; w2l[nt][ks] = l8;
      w3h[nt][ks] = h9; w3l[nt][ks] = l9;
    }
  }
  float scn[4], shn[4];
  #pragma unroll
  for (int nt = 0; nt < 4; nt++){
    scn[nt] = sc2s[nt*16 + c16];
    shn[nt] = sh2s[nt*16 + c16];
  }
  float* sw = &scr[wv][0];
  for (int t4 = 0; t4 < 4; t4++){
    int T = t4*4 + wv;
    int node_l = T >> 1, half = T & 1;
    int nodeg = blockIdx.x*8 + node_l;
    int krow = half*16 + c16;
    int rr = (krow < 20);
    int j = idx1[nodeg*20 + (rr ? krow : 0)];
    int gj = ((nodeg >> 10) << 10) + j;
    const float* ar = a1 + (size_t)nodeg*64;
    const float* cr = c1 + (size_t)gj*64;
    f32x4 av0 = *(const f32x4*)(ar + kb0);
    f32x4 av1 = *(const f32x4*)(ar + kb0 + 4);
    f32x4 av2 = *(const f32x4*)(ar + 32 + kb0);
    f32x4 av3 = *(const f32x4*)(ar + 36 + kb0);
    f32x4 cv0 = *(const f32x4*)(cr + kb0);
    f32x4 cv1 = *(const f32x4*)(cr + kb0 + 4);
    f32x4 cv2 = *(const f32x4*)(cr + 32 + kb0);
    f32x4 cv3 = *(const f32x4*)(cr + 36 + kb0);
    bf16x8 a0h, a0l, a1h_, a1l_;
    #pragma unroll
    for (int e = 0; e < 4; e++){
      unsigned short hh, ll;
      float h;
      h = rr ? fmaxf((av0[e]+cv0[e])*sc1s[kb0+e] + sh1s[kb0+e], 0.f) : 0.f;
      bfsplit(h, hh, ll); a0h[e] = (short)hh; a0l[e] = (short)ll;
      h = rr ? fmaxf((av1[e]+cv1[e])*sc1s[kb0+4+e] + sh1s[kb0+4+e], 0.f) : 0.f;
      bfsplit(h, hh, ll); a0h[4+e] = (short)hh; a0l[4+e] = (short)ll;
      h = rr ? fmaxf((av2[e]+cv2[e])*sc1s[32+kb0+e] + sh1s[32+kb0+e], 0.f) : 0.f;
      bfsplit(h, hh, ll); a1h_[e] = (short)hh; a1l_[e] = (short)ll;
      h = rr ? fmaxf((av3[e]+cv3[e])*sc1s[36+kb0+e] + sh1s[36+kb0+e], 0.f) : 0.f;
      bfsplit(h, hh, ll); a1h_[4+e] = (short)hh; a1l_[4+e] = (short)ll;
    }
    // ---- GEMM1: P = H1 @ W2 ----
    f32x4 pacc[4];
    #pragma unroll
    for (int nt = 0; nt < 4; nt++){
      f32x4 acc = {0.f, 0.f, 0.f, 0.f};
      acc = __builtin_amdgcn_mfma_f32_16x16x32_bf16(a0h,  w2h[nt][0], acc, 0, 0, 0);
      acc = __builtin_amdgcn_mfma_f32_16x16x32_bf16(a1h_, w2h[nt][1], acc, 0, 0, 0);
      acc = __builtin_amdgcn_mfma_f32_16x16x32_bf16(a0h,  w2l[nt][0], acc, 0, 0, 0);
      acc = __builtin_amdgcn_mfma_f32_16x16x32_bf16(a1h_, w2l[nt][1], acc, 0, 0, 0);
      acc = __builtin_amdgcn_mfma_f32_16x16x32_bf16(a0l,  w2h[nt][0], acc, 0, 0, 0);
      acc = __builtin_amdgcn_mfma_f32_16x16x32_bf16(a1l_, w2h[nt][1], acc, 0, 0, 0);
      pacc[nt] = acc;
    }
    // ---- BN2 + relu, relayout D->A via per-wave LDS scratch ----
    #pragma unroll
    for (int nt = 0; nt < 4; nt++){
      #pragma unroll
      for (int r = 0; r < 4; r++){
        float v = fmaxf(pacc[nt][r]*scn[nt] + shn[nt], 0.f);
        sw[(4*ag + r)*68 + nt*16 + c16] = v;
      }
    }
    f32x4 h20 = *(const f32x4*)(sw + c16*68 + kb0);
    f32x4 h21 = *(const f32x4*)(sw + c16*68 + kb0 + 4);
    f32x4 h22 = *(const f32x4*)(sw + c16*68 + 32 + kb0);
    f32x4 h23 = *(const f32x4*)(sw + c16*68 + 36 + kb0);
    bf16x8 b0h, b0l, b1h, b1l;
    #pragma unroll
    for (int e = 0; e < 4; e++){
      unsigned short hh, ll;
      bfsplit(h20[e], hh, ll); b0h[e] = (short)hh; b0l[e] = (short)ll;
      bfsplit(h21[e], hh, ll); b0h[4+e] = (short)hh; b0l[4+e] = (short)ll;
      bfsplit(h22[e], hh, ll); b1h[e] = (short)hh; b1l[e] = (short)ll;
      bfsplit(h23[e], hh, ll); b1h[4+e] = (short)hh; b1l[4+e] = (short)ll;
    }
    // ---- GEMM2: Q = H2 @ W3, masked max into per-wave node slots ----
    #pragma unroll
    for (int nt = 0; nt < 4; nt++){
      f32x4 acc = {0.f, 0.f, 0.f, 0.f};
      acc = __builtin_amdgcn_mfma_f32_16x16x32_bf16(b0h, w3h[nt][0], acc, 0, 0, 0);
      acc = __builtin_amdgcn_mfma_f32_16x16x32_bf16(b1h, w3h[nt][1], acc, 0, 0, 0);
      acc = __builtin_amdgcn_mfma_f32_16x16x32_bf16(b0h, w3l[nt][0], acc, 0, 0, 0);
      acc = __builtin_amdgcn_mfma_f32_16x16x32_bf16(b1h, w3l[nt][1], acc, 0, 0, 0);
      acc = __builtin_amdgcn_mfma_f32_16x16x32_bf16(b0l, w3h[nt][0], acc, 0, 0, 0);
      acc = __builtin_amdgcn_mfma_f32_16x16x32_bf16(b1l, w3h[nt][1], acc, 0, 0, 0);
      float vmx = -FLT_MAX;
      #pragma unroll
      for (int r = 0; r < 4; r++){
        int kr = half*16 + 4*ag + r;
        vmx = (kr < 20) ? fmaxf(vmx, acc[r]) : vmx;
      }
      vmx = fmaxf(vmx, __shfl_xor(vmx, 16));
      vmx = fmaxf(vmx, __shfl_xor(vmx, 32));
      if (ag == 0){
        unsigned int u = mono32(vmx);
        unsigned int* sl = &mxp[wv][node_l][nt*16 + c16];
        if (u > *sl) *sl = u;
      }
    }
  }
  __syncthreads();
  for (int s = tid; s < 512; s += 256){
    int nl = s >> 6, c = s & 63;
    unsigned int u = mxp[0][nl][c];
    unsigned int u1 = mxp[1][nl][c]; u = (u1 > u) ? u1 : u;
    unsigned int u2 = mxp[2][nl][c]; u = (u2 > u) ? u2 : u;
    unsigned int u3 = mxp[3][nl][c]; u = (u3 > u) ? u3 : u;
    unsigned int bts = (u & 0x80000000u) ? (u ^ 0x80000000u) : ~u;
    x1[(size_t)(blockIdx.x*8 + nl)*64 + c] = __uint_as_float(bts) + inb[IN_B3 + c];
  }
}

// ---------------- kNN in 64-d feature space (half-split, LDS-union, f64-key top-k) ----------------
__global__ __launch_bounds__(256, 2) void k_knn2(const float* x1, u64* part){
  __shared__ __align__(16) char sm2[21504];
  float* xs  = (float*)sm2;                 // 64*68 floats = 17408B (scan)
  float* sqc = (float*)(sm2 + 17408);       // 256B (scan)
  u64* mrgA = (u64*)sm2;                    // overlay (post-scan only)
  u64* mrgB = (u64*)(sm2 + 10752);
  int bb   = blockIdx.x >> 5;
  int qg   = (blockIdx.x >> 1) & 15;
  int half = blockIdx.x & 1;
  int tid = threadIdx.x;
  int q_l = tid & 63;
  int slot = tid >> 6;               // wave index == slot
  int gi = bb*1024 + qg*64 + q_l;
  float4 xiv[16];
  #pragma unroll
  for (int d4 = 0; d4 < 16; d4++)
    xiv[d4] = *(const float4*)(x1 + gi*64 + d4*4);
  float sqi = 0.f;
  #pragma unroll
  for (int d4 = 0; d4 < 16; d4++)
    sqi += xiv[d4].x*xiv[d4].x + xiv[d4].y*xiv[d4].y
         + xiv[d4].z*xiv[d4].z + xiv[d4].w*xiv[d4].w;
  REP20(KDECLD)
  for (int ch = 0; ch < 8; ch++){
    int c0 = half*512 + ch*64;
    __syncthreads();
    for (int t = tid; t < 4096; t += 256){
      int r = t >> 6, d = t & 63;
      xs[r*68 + d] = x1[(bb*1024 + c0 + r)*64 + d];
    }
    __syncthreads();
    if (tid < 64){
      float s = 0.f;
      #pragma unroll 16
      for (int d = 0; d < 64; d++) s += xs[tid*68+d]*xs[tid*68+d];
      sqc[tid] = s;
    }
    __syncthreads();
    for (int u = 0; u < 16; u += 2){
      int jj0 = 4*u + slot;
      int jj1 = 4*(u+1) + slot;
      const float* xr0 = xs + jj0*68;
      const float* xr1 = xs + jj1*68;
      float dot0 = 0.f, dot1 = 0.f;
      #pragma unroll
      for (int d4 = 0; d4 < 16; d4++){
        float4 v0 = *(const float4*)(xr0 + d4*4);
        float4 v1 = *(const float4*)(xr1 + d4*4);
        dot0 += xiv[d4].x*v0.x + xiv[d4].y*v0.y + xiv[d4].z*v0.z + xiv[d4].w*v0.w;
        dot1 += xiv[d4].x*v1.x + xiv[d4].y*v1.y + xiv[d4].z*v1.z + xiv[d4].w*v1.w;
      }
      float d0 = sqi + sqc[jj0] - 2.0f*dot0;
      float d1 = sqi + sqc[jj1] - 2.0f*dot1;
      INS_MM(packkey(d0, c0 + jj0));
      INS_MM(packkey(d1, c0 + jj1));
    }
  }
  __syncthreads();                    // scan arrays dead from here (union!)
  if (slot == 1){ REP20(KPUB_A) }
  if (slot == 3){ REP20(KPUB_B) }
  __syncthreads();
  if ((slot & 1) == 0){
    const u64* src = (slot == 0) ? &mrgA[q_l*21] : &mrgB[q_l*21];
    for (int p = 0; p < KNN; p++){
      double kv = __longlong_as_double((long long)src[p]);
      if (kv > rk19) break;
      INS_MM(kv);
    }
  }
  __syncthreads();
  if (slot == 2){ REP20(KPUB_B) }
  __syncthreads();
  if (slot == 0){
    const u64* src = &mrgB[q_l*21];
    for (int p = 0; p < KNN; p++){
      double kv = __longlong_as_double((long long)src[p]);
      if (kv > rk19) break;
      INS_MM(kv);
    }
    u64* gpart = part + ((size_t)gi*2 + half)*KNN;
    REP20(KSTG)
  }
}

// ---------------- fast path: B2H = x1 @ Wbot[:, q-half] ----------------
__global__ __launch_bounds__(256) void k_B2h(const float* x1, const float* inb,
                                             int q, float* B2H){
  __shared__ __align__(16) float Wbh[4096];
  __shared__ __align__(16) float xsh[1024];
  int tid = threadIdx.x;
  const float* Wb = inb + IN_WBUF + WB_WBOT;
  for (int t = tid; t < 4096; t += 256){
    int r = t >> 6, cl = t & 63;
    Wbh[t] = Wb[r*128 + q*64 + cl];
  }
  int node0 = blockIdx.x * 16;
  for (int t = tid; t < 1024; t += 256) xsh[t] = x1[node0*64 + t];
  __syncthreads();
  int n_l = tid >> 4, cg = tid & 15;
  const float* xr = xsh + n_l*64;
  float4 acc = make_float4(0.f,0.f,0.f,0.f);
  #pragma unroll 8
  for (int d = 0; d < 64; d++){
    float v = xr[d];
    float4 w = *(const float4*)(Wbh + d*64 + cg*4);
    acc.x += v*w.x; acc.y += v*w.y; acc.z += v*w.z; acc.w += v*w.w;
  }
  *(float4*)(B2H + (node0 + n_l)*64 + cg*4) = acc;
}

// ---------------- fast path: x2 half = (x1_i@Wd + bc2) + max_j B2H[j] ----------------
__global__ __launch_bounds__(256) void k_x2h(const float* x1, const float* B2H,
                                             const float* inb, const int* idx2,
                                             int q, float* x2){
  __shared__ __align__(16) float Wdh[4096];
  __shared__ __align__(16) float xsh[256];
  int tid = threadIdx.x;
  const float* Wd = inb + IN_WBUF + WB_WD;
  for (int t = tid; t < 4096; t += 256){
    int r = t >> 6, cl = t & 63;
    Wdh[t] = Wd[r*128 + q*64 + cl];
  }
  int node0 = blockIdx.x * 4;
  xsh[tid] = x1[node0*64 + tid];
  __syncthreads();
  int n_l = tid >> 6, cl = tid & 63;
  int i = node0 + n_l;
  int b = i >> 10;
  const float* xr = xsh + n_l*64;
  float acc = inb[IN_BC2 + q*64 + cl];
  #pragma unroll 8
  for (int d = 0; d < 64; d++) acc += xr[d]*Wdh[d*64 + cl];
  float m = -FLT_MAX;
  for (int kk = 0; kk < KNN; kk++){
    int j = idx2[i*KNN + kk];
    m = fmaxf(m, B2H[((b<<10)+j)*64 + cl]);
  }
  x2[i*128 + q*64 + cl] = acc + m;
}

// ---------------- slow fallback: x2 direct, LDS-staged, no B2H buffer ----------------
__global__ __launch_bounds__(256) void k_x2d(const float* x1, const float* inb,
                                             const int* idx2, float* x2){
  __shared__ __align__(16) float Wdh[4096], Wbh[4096];
  __shared__ __align__(16) float xis[1024], xjs[1024];
  int tid = threadIdx.x;
  int q = blockIdx.x & 1;
  int node0 = (blockIdx.x >> 1) * 16;
  const float* Wd = inb + IN_WBUF + WB_WD;
  const float* Wb = inb + IN_WBUF + WB_WBOT;
  for (int t = tid; t < 4096; t += 256){
    int r = t >> 6, cl = t & 63;
    Wdh[t] = Wd[r*128 + q*64 + cl];
    Wbh[t] = Wb[r*128 + q*64 + cl];
  }
  for (int t = tid; t < 1024; t += 256) xis[t] = x1[node0*64 + t];
  __syncthreads();
  int n_l = tid >> 4, cg = tid & 15;
  int i = node0 + n_l, b = i >> 10;
  const float* xr = xis + n_l*64;
  float4 af = make_float4(inb[IN_BC2 + q*64 + cg*4],   inb[IN_BC2 + q*64 + cg*4+1],
                          inb[IN_BC2 + q*64 + cg*4+2], inb[IN_BC2 + q*64 + cg*4+3]);
  #pragma unroll 8
  for (int d = 0; d < 64; d++){
    float v = xr[d];
    float4 w = *(const float4*)(Wdh + d*64 + cg*4);
    af.x += v*w.x; af.y += v*w.y; af.z += v*w.z; af.w += v*w.w;
  }
  float4 mx = make_float4(-FLT_MAX,-FLT_MAX,-FLT_MAX,-FLT_MAX);
  for (int kk = 0; kk < KNN; kk++){
    __syncthreads();
    for (int t = tid; t < 1024; t += 256){
      int nn = t >> 6, r = t & 63;
      int jj = idx2[(node0+nn)*KNN + kk];
      xjs[t] = x1[((((node0+nn) >> 10) << 10) + jj)*64 + r];
    }
    __syncthreads();
    const float* xj = xjs + n_l*64;
    float4 acc = make_float4(0.f,0.f,0.f,0.f);
    #pragma unroll 8
    for (int d = 0; d < 64; d++){
      float v = xj[d];
      float4 w = *(const float4*)(Wbh + d*64 + cg*4);
      acc.x += v*w.x; acc.y += v*w.y; acc.z += v*w.z; acc.w += v*w.w;
    }
    mx.x = fmaxf(mx.x, acc.x); mx.y = fmaxf(mx.y, acc.y);
    mx.z = fmaxf(mx.z, acc.z); mx.w = fmaxf(mx.w, acc.w);
  }
  *(float4*)(x2 + i*128 + q*64 + cg*4) =
      make_float4(af.x+mx.x, af.y+mx.y, af.z+mx.z, af.w+mx.w);
}

// ---------------- lin (192->1024) via MFMA + max over node-quarter ----------------
// Block = 512 threads (8 waves), grid 512 = (b, cq=256ch, nh=256 nodes).
// K=192 (x1:64 + x2:128). Wave owns 2 N-tiles (32 ch); B-frags (Wl hi/lo)
// built once per block from global (Wl is L2-resident, shared across batches).
// M streamed: 16 chunks of 16 nodes staged in LDS (stride 196: 2-way banks).
// 3-term bf16 split in 3 independent accumulator chains; max over D rows
// (nodes) via acc-fold + shfl_xor(16,32).
__global__ __launch_bounds__(512, 2) void k_linpoolm(const float* x1, const float* x2,
    const float* inb, float* pool4){
  __shared__ __align__(16) float F[16*196];         // 12544B
  int tid = threadIdx.x;
  int b = blockIdx.x >> 4, cq = (blockIdx.x >> 2) & 3, nh = blockIdx.x & 3;
  int lane = tid & 63, wv = tid >> 6;
  int c16 = lane & 15, ag = lane >> 4;
  const float* Wl = inb + IN_WBUF + WB_WL;
  // B-fragments once per block
  bf16x8 w_h[2][6], w_l[2][6];
  #pragma unroll
  for (int nt = 0; nt < 2; nt++){
    int col = cq*256 + (wv*2+nt)*16 + c16;
    #pragma unroll
    for (int ks = 0; ks < 6; ks++){
      bf16x8 h8, l8;
      #pragma unroll
      for (int e = 0; e < 8; e++){
        unsigned short hh, ll;
        bfsplit(Wl[(ks*32 + ag*8 + e)*1024 + col], hh, ll);
        h8[e] = (short)hh; l8[e] = (short)ll;
      }
      w_h[nt][ks] = h8; w_l[nt][ks] = l8;
    }
  }
  float rmax[2] = {-FLT_MAX, -FLT_MAX};
  int n0 = b*1024 + nh*256;
  for (int chk = 0; chk < 16; chk++){
    int nb = n0 + chk*16;
    __syncthreads();
    {
      int row = tid >> 5;
      int d0 = (tid & 31)*6;
      #pragma unroll
      for (int u = 0; u < 6; u++){
        int d = d0 + u;
        F[row*196 + d] = (d < 64) ? x1[(size_t)(nb+row)*64 + d]
                                  : x2[(size_t)(nb+row)*128 + d - 64];
      }
    }
    __syncthreads();
    // A-fragments: row = c16 (node), k = ks*32 + ag*8 + e
    bf16x8 a_h[6], a_l[6];
    #pragma unroll
    for (int ks = 0; ks < 6; ks++){
      f32x4 v0 = *(const f32x4*)(F + c16*196 + ks*32 + ag*8);
      f32x4 v1 = *(const f32x4*)(F + c16*196 + ks*32 + ag*8 + 4);
      bf16x8 h8, l8;
      #pragma unroll
      for (int e = 0; e < 4; e++){
        unsigned short hh, ll;
        bfsplit(v0[e], hh, ll); h8[e] = (short)hh; l8[e] = (short)ll;
        bfsplit(v1[e], hh, ll); h8[4+e] = (short)hh; l8[4+e] = (short)ll;
      }
      a_h[ks] = h8; a_l[ks] = l8;
    }
    #pragma unroll
    for (int nt = 0; nt < 2; nt++){
      f32x4 p0 = {0.f,0.f,0.f,0.f}, p1 = {0.f,0.f,0.f,0.f}, p2 = {0.f,0.f,0.f,0.f};
      #pragma unroll
      for (int ks = 0; ks < 6; ks++){
        p0 = __builtin_amdgcn_mfma_f32_16x16x32_bf16(a_h[ks], w_h[nt][ks], p0, 0, 0, 0);
        p1 = __builtin_amdgcn_mfma_f32_16x16x32_bf16(a_h[ks], w_l[nt][ks], p1, 0, 0, 0);
        p2 = __builtin_amdgcn_mfma_f32_16x16x32_bf16(a_l[ks], w_h[nt][ks], p2, 0, 0, 0);
      }
      float m = -FLT_MAX;
      #pragma unroll
      for (int r = 0; r < 4; r++) m = fmaxf(m, p0[r] + p1[r] + p2[r]);
      m = fmaxf(m, __shfl_xor(m, 16));
      m = fmaxf(m, __shfl_xor(m, 32));
      rmax[nt] = fmaxf(rmax[nt], m);
    }
  }
  if (ag == 0){
    #pragma unroll
    for (int nt = 0; nt < 2; nt++)
      pool4[nh*32768 + b*1024 + cq*256 + (wv*2+nt)*16 + c16] = rmax[nt];
  }
}

// ---------------- head MLP: reduce pool4 + 1024->512->256->40 (fp32 out) ----------------
__global__ __launch_bounds__(256) void k_head(const float* pool4, const float* inb,
                                              float* out){
  __shared__ float pl[1024];
  __shared__ float s1[512];
  __shared__ float s2[256];
  int b = blockIdx.x, tid = threadIdx.x;
  const float* Wm1 = inb + IN_WBUF + WB_WM1;
  const float* Wm2 = inb + IN_WBUF + WB_WM2;
  const float* Wm3 = inb + IN_WBUF + WB_WM3;
  for (int t = tid; t < 1024; t += 256){
    float m = fmaxf(fmaxf(pool4[b*1024 + t],         pool4[32768 + b*1024 + t]),
                    fmaxf(pool4[65536 + b*1024 + t], pool4[98304 + b*1024 + t]));
    pl[t] = m + inb[IN_BL + t];
  }
  __syncthreads();
  for (int c = tid; c < 512; c += 256){
    float acc = inb[IN_BM1 + c];
    #pragma unroll 4
    for (int d = 0; d < 1024; d++) acc += pl[d]*Wm1[d*512 + c];
    s1[c] = fmaxf(acc, 0.f);
  }
  __syncthreads();
  {
    int c = tid;
    float acc = inb[IN_BM2 + c];
    #pragma unroll 4
    for (int d = 0; d < 512; d++) acc += s1[d]*Wm2[d*256 + c];
    s2[c] = fmaxf(acc, 0.f);
  }
  __syncthreads();
  if (tid < 40){
    float acc = inb[IN_BM3 + tid];
    #pragma unroll 4
    for (int d = 0; d < 256; d++) acc += s2[d]*Wm3[d*40 + tid];
    out[b*40 + tid] = acc;
  }
}

extern "C" void kernel_launch(void* const* d_in, const int* in_sizes, int n_in,
                              void* d_out, int out_size, void* d_ws, size_t ws_size,
                              hipStream_t stream){
  float* ws     = (float*)d_ws;
  double* stats = (double*)d_ws;
  int*   flag   = (int*)d_ws + OFF_FLAG;
  float* inb    = ws + OFF_INB;
  int*   idx    = (int*)d_ws + OFF_IDX;     // idx1 early, idx2 late
  float* x1p    = ws + OFF_X1;
  float* x2p    = ws + OFF_X2;
  float* a1     = ws + OFF_X2;              // a1/c1 alias x2 region (dead before x2 written)
  float* c1     = ws + OFF_C1;
  u64*   part   = (u64*)(ws + OFF_X2);      // kNN partials alias a1/c1 (see layout note)
  float* pool4  = ws + OFF_POOL;
  float* B2H    = ws + OFF_B2H;
  bool fast = ws_size >= (size_t)FAST_END * 4u;

  hipMemsetAsync(stats, 0, 256*sizeof(double), stream);
  k_sniff<<<1, 64, 0, stream>>>(d_in[0], flag);
  k_cvt<<<3859, 256, 0, stream>>>(
      d_in[0], d_in[1], d_in[2], d_in[3], d_in[4], d_in[5], d_in[6], d_in[7],
      d_in[8], d_in[9], d_in[10], d_in[11], d_in[12], d_in[13], d_in[14],
      d_in[15], d_in[16], d_in[17], d_in[18], d_in[19], d_in[20], flag, inb);
  k_knn1<<<1024, 256, 0, stream>>>(inb, part);      // partials in a1/c1 region
  k_mrg<<<128, 256, 0, stream>>>(part, idx);        // -> idx1
  k_prep1<<<8192, 256, 0, stream>>>(inb, a1, c1);   // overwrites dead partials
  k_stats1<<<640, 256, 0, stream>>>(a1, c1, idx, stats);
  k_stats2m<<<4096, 256, 0, stream>>>(a1, c1, idx, inb, stats);
  k_x1m<<<4096, 256, 0, stream>>>(a1, c1, idx, inb, stats, x1p);
  k_knn2<<<1024, 256, 0, stream>>>(x1p, part);      // a1/c1 dead after k_x1m
  k_mrg<<<128, 256, 0, stream>>>(part, idx);        // -> idx2
  if (fast){
    k_B2h<<<2048, 256, 0, stream>>>(x1p, inb, 0, B2H);
    k_x2h<<<8192, 256, 0, stream>>>(x1p, B2H, inb, idx, 0, x2p);
    k_B2h<<<2048, 256, 0, stream>>>(x1p, inb, 1, B2H);
    k_x2h<<<8192, 256, 0, stream>>>(x1p, B2H, inb, idx, 1, x2p);
  } else {
    k_x2d<<<4096, 256, 0, stream>>>(x1p, inb, idx, x2p);
  }
  k_linpoolm<<<512, 512, 0, stream>>>(x1p, x2p, inb, pool4);
  k_head<<<32, 256, 0, stream>>>(pool4, inb, (float*)d_out);
}

// Round 8
// 1089.382 us; speedup vs baseline: 4.0574x; 1.0871x over previous
//
#include <hip/hip_runtime.h>
#include <hip/hip_bf16.h>
#include <float.h>
#include <math.h>

typedef __hip_bfloat16 bf16;
typedef unsigned long long u64;

#define BATCH 32
#define NPTS  1024
#define KNN   20
#define NB    (BATCH*NPTS)      // 32768 nodes
#define NEDGE (NB*KNN)          // 655360 edges

// ---- workspace layout (float units), ws_size-adaptive ----
#define OFF_FLAG 512u
#define OFF_INB  1024u
#define OFF_IDX  988928u          // 655360 ints (idx1 early, idx2 late)
#define OFF_X1   1644288u         // NB*64
#define OFF_X2   3741440u         // NB*128 ; a1 @ OFF_X2, c1 @ OFF_C1 (early)
#define OFF_C1   5838592u
#define OFF_POOL 7935744u         // pool4: 4 x 32*1024
#define SLOW_END 8066816u         // 32.3 MB
#define OFF_B2H  8066816u         // NB*64 (fast path only)
#define FAST_END 10163968u        // 40.7 MB
// kNN partial lists (u64) alias OFF_X2 (dead there at both kNN points).
// ---- layout inside inb (canonical fp32 inputs) ----
#define IN_POSF 0u
#define IN_B1   98304u
#define IN_G1   98368u
#define IN_BE1  98432u
#define IN_B2   98496u
#define IN_G2   98560u
#define IN_BE2  98624u
#define IN_B3   98688u
#define IN_BC2  98752u
#define IN_BL   98880u
#define IN_BM1  99904u
#define IN_BM2  100416u
#define IN_BM3  100672u
#define IN_W1   100736u
#define IN_WBUF 101120u
#define WB_W2   0u
#define WB_W3   4096u
#define WB_WD   8192u            // Wc2 top-bot diff [64x128]
#define WB_WBOT 16384u           // Wc2 bottom      [64x128]
#define WB_WL   24576u
#define WB_WM1  221184u
#define WB_WM2  745472u
#define WB_WM3  876544u
#define IN_TOTAL 987904u

__device__ __forceinline__ float bf2f(bf16 v){ return __bfloat162float(v); }

// monotone float->u32 map: preserves IEEE-754 total order for all finite values
__device__ __forceinline__ unsigned int mono32(float f){
  unsigned int b = __float_as_uint(f);
  return b ^ ((unsigned int)((int)b >> 31) | 0x80000000u);
}

// ======== MFMA machinery (bf16 hi/lo split, fp32-accurate) ========
typedef __attribute__((ext_vector_type(8))) short bf16x8;
typedef __attribute__((ext_vector_type(4))) float f32x4;

__device__ __forceinline__ unsigned short bfhi(float f){
  unsigned int u = __float_as_uint(f);
  u += 0x7FFFu + ((u >> 16) & 1u);      // RNE to bf16
  return (unsigned short)(u >> 16);
}
__device__ __forceinline__ void bfsplit(float f, unsigned short& h, unsigned short& l){
  h = bfhi(f);
  float fh = __uint_as_float(((unsigned int)h) << 16);
  l = bfhi(f - fh);
}

// ======== exact top-k via f64-packed keys + min/max sorted-insert ========
// Key bits = (1<<62) | (f32bits(max(d,0)) << 20) | idx -> positive doubles,
// value order == lexicographic (d, idx) == top_k semantics, globally unique.
// Insert: new_rp = min(rp, max(rp-1, k)) descending (exact multiset identity).
#define REP20(M) M(0) M(1) M(2) M(3) M(4) M(5) M(6) M(7) M(8) M(9) \
                 M(10) M(11) M(12) M(13) M(14) M(15) M(16) M(17) M(18) M(19)
#define SH19(M) M(19,18) M(18,17) M(17,16) M(16,15) M(15,14) M(14,13) M(13,12) \
                M(12,11) M(11,10) M(10,9) M(9,8) M(8,7) M(7,6) M(6,5) M(5,4) \
                M(4,3) M(3,2) M(2,1) M(1,0)

__device__ __forceinline__ double packkey(float d, int idx){
  unsigned int b = __float_as_uint(fmaxf(d, 0.0f));
  u64 k = 0x4000000000000000ULL | ((u64)b << 20) | (unsigned int)idx;
  return __longlong_as_double((long long)k);
}

#define KDECLD(p) double rk##p = DBL_MAX;
#define KMM(p,pm) rk##p = fmin(rk##p, fmax(rk##pm, _k));
#define INS_MM(kv) do{ double _k=(kv); SH19(KMM) rk0 = fmin(rk0, _k); }while(0)

#define KPUB_A(p) mrgA[q_l*21+p] = (u64)__double_as_longlong(rk##p);
#define KPUB_B(p) mrgB[q_l*21+p] = (u64)__double_as_longlong(rk##p);
#define KSTG(p)   gpart[p] = (u64)__double_as_longlong(rk##p);
#define KLDAD(p)  double rk##p = __longlong_as_double((long long)pa[p]);
#define KOUTU(p)  optr[p] = (int)((u64)__double_as_longlong(rk##p) & 1023ULL);

// ---------------- dtype sniff (fp32 vs bf16 inputs) ----------------
__global__ void k_sniff(const void* pos_raw, int* flag){
  if (blockIdx.x == 0 && threadIdx.x == 0){
    const unsigned short* h = (const unsigned short*)pos_raw;
    int wild = 0;
    for (int k = 0; k < 16; k++){
      unsigned int bits = ((unsigned int)h[2*k]) << 16;
      float v = __uint_as_float(bits);
      float a = fabsf(v);
      if (a != 0.0f && (v != v || a > 1e10f || a < 1e-10f)) wild++;
    }
    *flag = (wild >= 4) ? 1 : 0;
  }
}

__device__ __forceinline__ float rdv(const void* p, int i, int f){
  return f ? ((const float*)p)[i] : bf2f(((const bf16*)p)[i]);
}

// ---------------- normalize ALL inputs to canonical fp32 buffer ----------------
__global__ __launch_bounds__(256) void k_cvt(
    const void* pos, const void* W1, const void* b1, const void* g1, const void* be1,
    const void* W2, const void* b2, const void* g2, const void* be2,
    const void* W3, const void* b3, const void* Wc2, const void* bc2,
    const void* Wl, const void* bl, const void* Wm1, const void* bm1,
    const void* Wm2, const void* bm2, const void* Wm3, const void* bm3,
    const int* flag, float* inb){
  int id = blockIdx.x*256 + threadIdx.x;
  if (id >= (int)IN_TOTAL) return;
  int f = *flag;
  float v;
  if      (id < 98304)  v = rdv(pos, id, f);
  else if (id < 98368)  v = rdv(b1,  id-98304, f);
  else if (id < 98432)  v = rdv(g1,  id-98368, f);
  else if (id < 98496)  v = rdv(be1, id-98432, f);
  else if (id < 98560)  v = rdv(b2,  id-98496, f);
  else if (id < 98624)  v = rdv(g2,  id-98560, f);
  else if (id < 98688)  v = rdv(be2, id-98624, f);
  else if (id < 98752)  v = rdv(b3,  id-98688, f);
  else if (id < 98880)  v = rdv(bc2, id-98752, f);
  else if (id < 99904)  v = rdv(bl,  id-98880, f);
  else if (id < 100416) v = rdv(bm1, id-99904, f);
  else if (id < 100672) v = rdv(bm2, id-100416, f);
  else if (id < 100712) v = rdv(bm3, id-100672, f);
  else if (id < 100736) v = 0.0f;
  else if (id < 101120) v = rdv(W1,  id-100736, f);
  else {
    int t = id - 101120;
    if      (t < 4096)   v = rdv(W2, t, f);
    else if (t < 8192)   v = rdv(W3, t-4096, f);
    else if (t < 16384){ int u = t-8192;  v = rdv(Wc2, u, f) - rdv(Wc2, 8192+u, f); }
    else if (t < 24576){ int u = t-16384; v = rdv(Wc2, 8192+u, f); }
    else if (t < 221184) v = rdv(Wl,  t-24576, f);
    else if (t < 745472) v = rdv(Wm1, t-221184, f);
    else if (t < 876544) v = rdv(Wm2, t-745472, f);
    else                 v = rdv(Wm3, t-876544, f);
  }
  inb[id] = v;
}

// ---------------- a1/c1: affine decomposition of EdgeConv1 layer1 ----------------
__global__ __launch_bounds__(256) void k_prep1(const float* inb, float* a1, float* c1){
  const float* posf = inb + IN_POSF;
  const float* W1f  = inb + IN_W1;
  const float* b1f  = inb + IN_B1;
  int id = blockIdx.x*256 + threadIdx.x;
  int bn = id >> 6, c = id & 63;
  float p0 = posf[bn*3], p1 = posf[bn*3+1], p2 = posf[bn*3+2];
  float wt0 = W1f[c],     wt1 = W1f[64+c],  wt2 = W1f[128+c];
  float wb0 = W1f[192+c], wb1 = W1f[256+c], wb2 = W1f[320+c];
  float cv = p0*wb0 + p1*wb1 + p2*wb2;
  float av = p0*(wt0-wb0) + p1*(wt1-wb1) + p2*(wt2-wb2) + b1f[c];
  a1[id] = av;  c1[id] = cv;
}

// ---------------- kNN in coordinate space (half-split, LDS-union, f64-key top-k) ----------------
// Not LDS-BW-bound (16B/candidate) -> stays in the scalar-dot form.
__global__ __launch_bounds__(256, 2) void k_knn1(const float* inb, u64* part){
  const float* posf = inb + IN_POSF;
  __shared__ __align__(16) char sm1[21504];
  float* psx = (float*)sm1;
  float* psy = psx + 1024;
  float* psz = psy + 1024;
  float* sqs = psz + 1024;
  u64* mrgA = (u64*)sm1;              // overlay (post-scan only)
  u64* mrgB = (u64*)(sm1 + 10752);
  int bb   = blockIdx.x >> 5;
  int qg   = (blockIdx.x >> 1) & 15;
  int half = blockIdx.x & 1;
  int tid = threadIdx.x;
  int q_l = tid & 63;
  int slot = tid >> 6;
  for (int t = tid; t < 1024; t += 256){
    float x = posf[(bb*1024+t)*3], y = posf[(bb*1024+t)*3+1], z = posf[(bb*1024+t)*3+2];
    psx[t] = x; psy[t] = y; psz[t] = z; sqs[t] = x*x + y*y + z*z;
  }
  __syncthreads();
  int i_l = qg*64 + q_l;
  float xi0 = psx[i_l], xi1 = psy[i_l], xi2 = psz[i_l];
  float sqi = sqs[i_l];
  REP20(KDECLD)
  int cbase = half*512;
  for (int u = 0; u < 128; u++){
    int jj = cbase + 4*u + slot;
    float dot = xi0*psx[jj] + xi1*psy[jj] + xi2*psz[jj];
    float d = sqi + sqs[jj] - 2.0f*dot;
    INS_MM(packkey(d, jj));
  }
  __syncthreads();                    // scan arrays dead from here (union!)
  // tree-merge the 4 slot lists (slot1->A, slot3->B; 0+=A, 2+=B; 2->B; 0+=B)
  if (slot == 1){ REP20(KPUB_A) }
  if (slot == 3){ REP20(KPUB_B) }
  __syncthreads();
  if ((slot & 1) == 0){
    const u64* src = (slot == 0) ? &mrgA[q_l*21] : &mrgB[q_l*21];
    for (int p = 0; p < KNN; p++){
      double kv = __longlong_as_double((long long)src[p]);
      if (kv > rk19) break;          // sorted source: rest are worse
      INS_MM(kv);
    }
  }
  __syncthreads();
  if (slot == 2){ REP20(KPUB_B) }
  __syncthreads();
  if (slot == 0){
    const u64* src = &mrgB[q_l*21];
    for (int p = 0; p < KNN; p++){
      double kv = __longlong_as_double((long long)src[p]);
      if (kv > rk19) break;
      INS_MM(kv);
    }
    int gi = bb*1024 + i_l;
    u64* gpart = part + ((size_t)gi*2 + half)*KNN;
    REP20(KSTG)
  }
}

// ---------------- merge two sorted 20-entry half-lists per query ----------------
__global__ __launch_bounds__(256) void k_mrg(const u64* part, int* out){
  int gi = blockIdx.x*256 + threadIdx.x;    // grid 128 -> 32768 queries
  const u64* pa = part + (size_t)gi*2*KNN;
  REP20(KLDAD)                               // init from half-0 list (sorted)
  for (int p = 0; p < KNN; p++){
    double kv = __longlong_as_double((long long)pa[KNN + p]);
    if (kv > rk19) break;                    // sorted source: rest are worse
    INS_MM(kv);
  }
  int* optr = out + gi*KNN;
  REP20(KOUTU)
}

// ---------------- BN1 stats ----------------
__global__ __launch_bounds__(256) void k_stats1(const float* a1, const float* c1,
                                                const int* idx1, double* stats){
  __shared__ float rs[256], rs2[256];
  int tid = threadIdx.x, c = tid & 63, slot = tid >> 6;
  int base = blockIdx.x * 1024;
  float s = 0.f, s2 = 0.f;
  for (int t = 0; t < 256; t++){
    unsigned e = (unsigned)(base + t*4 + slot);
    int i = (int)(e / 20u);
    int b = i >> 10;
    int j = idx1[e];
    float h = a1[i*64+c] + c1[((b<<10)+j)*64 + c];
    s += h; s2 += h*h;
  }
  rs[tid] = s; rs2[tid] = s2;
  __syncthreads();
  if (slot == 0){
    double ts  = (double)rs[c]  + (double)rs[64+c]  + (double)rs[128+c]  + (double)rs[192+c];
    double ts2 = (double)rs2[c] + (double)rs2[64+c] + (double)rs2[128+c] + (double)rs2[192+c];
    atomicAdd(&stats[c], ts);
    atomicAdd(&stats[64+c], ts2);
  }
}

// ================= MFMA edge-MLP =================
// Geometry: block = 8 nodes; node padded 20->32 edge rows; 16 M-tiles of 16;
// 4 waves x 4 tiles. fp32 accuracy via hi/lo bf16 split (3-term). b2 cancels
// in BN2 (stats of raw P); b3 added after the max.

// ---------------- BN2 stats over P = H1 @ W2 (raw, no b2) ----------------
__global__ __launch_bounds__(256) void k_stats2m(const float* a1, const float* c1,
    const int* idx1, const float* inb, double* stats){
  __shared__ __align__(16) float W2s[4096];
  __shared__ float sc1s[64], sh1s[64];
  __shared__ float rs[4][64], rs2[4][64];
  int tid = threadIdx.x;
  const float* wbuf = inb + IN_WBUF;
  for (int t = tid; t < 4096; t += 256) W2s[t] = wbuf[WB_W2 + t];
  if (tid < 64){
    int c = tid;
    const double M = (double)NEDGE;
    double m1 = stats[c]/M;
    double v1 = stats[64+c]/M - m1*m1;
    double r1 = 1.0/sqrt(v1 + 1e-5);
    double g1 = (double)inb[IN_G1 + c];
    sc1s[c] = (float)(g1*r1);
    sh1s[c] = (float)((double)inb[IN_BE1 + c] - m1*g1*r1);
  }
  __syncthreads();
  int lane = tid & 63, wv = tid >> 6;
  int c16 = lane & 15, ag = lane >> 4, kb0 = ag*8;
  bf16x8 w2h[4][2], w2l[4][2];
  #pragma unroll
  for (int nt = 0; nt < 4; nt++){
    #pragma unroll
    for (int ks = 0; ks < 2; ks++){
      bf16x8 h8, l8;
      #pragma unroll
      for (int e = 0; e < 8; e++){
        unsigned short hh, ll;
        bfsplit(W2s[(ks*32 + kb0 + e)*64 + nt*16 + c16], hh, ll);
        h8[e] = (short)hh; l8[e] = (short)ll;
      }
      w2h[nt][ks] = h8; w2l[nt][ks] = l8;
    }
  }
  float sa[4] = {0,0,0,0}, qa[4] = {0,0,0,0};
  for (int t4 = 0; t4 < 4; t4++){
    int T = t4*4 + wv;
    int node_l = T >> 1, half = T & 1;
    int nodeg = blockIdx.x*8 + node_l;
    int krow = half*16 + c16;
    int rr = (krow < 20);
    int j = idx1[nodeg*20 + (rr ? krow : 0)];
    int gj = ((nodeg >> 10) << 10) + j;
    const float* ar = a1 + (size_t)nodeg*64;
    const float* cr = c1 + (size_t)gj*64;
    f32x4 av0 = *(const f32x4*)(ar + kb0);
    f32x4 av1 = *(const f32x4*)(ar + kb0 + 4);
    f32x4 av2 = *(const f32x4*)(ar + 32 + kb0);
    f32x4 av3 = *(const f32x4*)(ar + 36 + kb0);
    f32x4 cv0 = *(const f32x4*)(cr + kb0);
    f32x4 cv1 = *(const f32x4*)(cr + kb0 + 4);
    f32x4 cv2 = *(const f32x4*)(cr + 32 + kb0);
    f32x4 cv3 = *(const f32x4*)(cr + 36 + kb0);
    bf16x8 a0h, a0l, a1h_, a1l_;
    #pragma unroll
    for (int e = 0; e < 4; e++){
      unsigned short hh, ll;
      float h;
      h = rr ? fmaxf((av0[e]+cv0[e])*sc1s[kb0+e] + sh1s[kb0+e], 0.f) : 0.f;
      bfsplit(h, hh, ll); a0h[e] = (short)hh; a0l[e] = (short)ll;
      h = rr ? fmaxf((av1[e]+cv1[e])*sc1s[kb0+4+e] + sh1s[kb0+4+e], 0.f) : 0.f;
      bfsplit(h, hh, ll); a0h[4+e] = (short)hh; a0l[4+e] = (short)ll;
      h = rr ? fmaxf((av2[e]+cv2[e])*sc1s[32+kb0+e] + sh1s[32+kb0+e], 0.f) : 0.f;
      bfsplit(h, hh, ll); a1h_[e] = (short)hh; a1l_[e] = (short)ll;
      h = rr ? fmaxf((av3[e]+cv3[e])*sc1s[36+kb0+e] + sh1s[36+kb0+e], 0.f) : 0.f;
      bfsplit(h, hh, ll); a1h_[4+e] = (short)hh; a1l_[4+e] = (short)ll;
    }
    #pragma unroll
    for (int nt = 0; nt < 4; nt++){
      f32x4 acc = {0.f, 0.f, 0.f, 0.f};
      acc = __builtin_amdgcn_mfma_f32_16x16x32_bf16(a0h,  w2h[nt][0], acc, 0, 0, 0);
      acc = __builtin_amdgcn_mfma_f32_16x16x32_bf16(a1h_, w2h[nt][1], acc, 0, 0, 0);
      acc = __builtin_amdgcn_mfma_f32_16x16x32_bf16(a0h,  w2l[nt][0], acc, 0, 0, 0);
      acc = __builtin_amdgcn_mfma_f32_16x16x32_bf16(a1h_, w2l[nt][1], acc, 0, 0, 0);
      acc = __builtin_amdgcn_mfma_f32_16x16x32_bf16(a0l,  w2h[nt][0], acc, 0, 0, 0);
      acc = __builtin_amdgcn_mfma_f32_16x16x32_bf16(a1l_, w2h[nt][1], acc, 0, 0, 0);
      #pragma unroll
      for (int r = 0; r < 4; r++){
        int kr = half*16 + 4*ag + r;        // D row m=(lane>>4)*4+r -> edge slot
        float v = (kr < 20) ? acc[r] : 0.f;
        sa[nt] += v; qa[nt] += v*v;
      }
    }
  }
  #pragma unroll
  for (int nt = 0; nt < 4; nt++){
    sa[nt] += __shfl_xor(sa[nt], 16); sa[nt] += __shfl_xor(sa[nt], 32);
    qa[nt] += __shfl_xor(qa[nt], 16); qa[nt] += __shfl_xor(qa[nt], 32);
  }
  if (ag == 0){
    #pragma unroll
    for (int nt = 0; nt < 4; nt++){
      rs[wv][nt*16+c16] = sa[nt];
      rs2[wv][nt*16+c16] = qa[nt];
    }
  }
  __syncthreads();
  if (tid < 64){
    double ts = (double)rs[0][tid] + (double)rs[1][tid]
              + (double)rs[2][tid] + (double)rs[3][tid];
    double tq = (double)rs2[0][tid] + (double)rs2[1][tid]
              + (double)rs2[2][tid] + (double)rs2[3][tid];
    atomicAdd(&stats[128+tid], ts);
    atomicAdd(&stats[192+tid], tq);
  }
}

// ---------------- full MLP1 via MFMA + max over k -> x1 ----------------
__global__ __launch_bounds__(256, 2) void k_x1m(const float* a1, const float* c1,
    const int* idx1, const float* inb, const double* stats, float* x1){
  __shared__ __align__(16) float W2s[4096];
  __shared__ __align__(16) float W3s[4096];
  __shared__ __align__(16) float scr[4][16*68];     // per-wave H2 relayout scratch
  __shared__ unsigned int mxp[4][8][64];            // per-wave node maxes (mono32)
  __shared__ float sc1s[64], sh1s[64], sc2s[64], sh2s[64];
  int tid = threadIdx.x;
  const float* wbuf = inb + IN_WBUF;
  for (int t = tid; t < 4096; t += 256){ W2s[t] = wbuf[WB_W2+t]; W3s[t] = wbuf[WB_W3+t]; }
  {
    unsigned int* mf = &mxp[0][0][0];
    for (int t = tid; t < 2048; t += 256) mf[t] = 0u;
  }
  if (tid < 64){
    int c = tid;
    const double M = (double)NEDGE;
    double m1 = stats[c]/M;
    double v1 = stats[64+c]/M - m1*m1;
    double r1 = 1.0/sqrt(v1 + 1e-5);
    double g1 = (double)inb[IN_G1 + c];
    sc1s[c] = (float)(g1*r1);
    sh1s[c] = (float)((double)inb[IN_BE1 + c] - m1*g1*r1);
    double mp = stats[128+c]/M;                  // mean of raw P (b2 cancels in BN)
    double v2 = stats[192+c]/M - mp*mp;
    double r2 = 1.0/sqrt(v2 + 1e-5);
    double g2 = (double)inb[IN_G2 + c];
    sc2s[c] = (float)(g2*r2);
    sh2s[c] = (float)((double)inb[IN_BE2 + c] - mp*g2*r2);
  }
  __syncthreads();
  int lane = tid & 63, wv = tid >> 6;
  int c16 = lane & 15, ag = lane >> 4, kb0 = ag*8;
  // weight fragments (hi/lo) for both layers
  bf16x8 w2h[4][2], w2l[4][2], w3h[4][2], w3l[4][2];
  #pragma unroll
  for (int nt = 0; nt < 4; nt++){
    #pragma unroll
    for (int ks = 0; ks < 2; ks++){
      bf16x8 h8, l8, h9, l9;
      #pragma unroll
      for (int e = 0; e < 8; e++){
        unsigned short hh, ll;
        bfsplit(W2s[(ks*32 + kb0 + e)*64 + nt*16 + c16], hh, ll);
        h8[e] = (short)hh; l8[e] = (short)ll;
        bfsplit(W3s[(ks*32 + kb0 + e)*64 + nt*16 + c16], hh, ll);
        h9[e] = (short)hh; l9[e] = (short)ll;
      }
      w2h[nt][ks] = h8; w2l[nt][ks] = l8;
      w3h[nt][ks] = h9; w3l[nt][ks] = l9;
    }
  }
  float scn[4], shn[4];
  #pragma unroll
  for (int nt = 0; nt < 4; nt++){
    scn[nt] = sc2s[nt*16 + c16];
    shn[nt] = sh2s[nt*16 + c16];
  }
  float* sw = &scr[wv][0];
  for (int t4 = 0; t4 < 4; t4++){
    int T = t4*4 + wv;
    int node_l = T >> 1, half = T & 1;
    int nodeg = blockIdx.x*8 + node_l;
    int krow = half*16 + c16;
    int rr = (krow < 20);
    int j = idx1[nodeg*20 + (rr ? krow : 0)];
    int gj = ((nodeg >> 10) << 10) + j;
    const float* ar = a1 + (size_t)nodeg*64;
    const float* cr = c1 + (size_t)gj*64;
    f32x4 av0 = *(const f32x4*)(ar + kb0);
    f32x4 av1 = *(const f32x4*)(ar + kb0 + 4);
    f32x4 av2 = *(const f32x4*)(ar + 32 + kb0);
    f32x4 av3 = *(const f32x4*)(ar + 36 + kb0);
    f32x4 cv0 = *(const f32x4*)(cr + kb0);
    f32x4 cv1 = *(const f32x4*)(cr + kb0 + 4);
    f32x4 cv2 = *(const f32x4*)(cr + 32 + kb0);
    f32x4 cv3 = *(const f32x4*)(cr + 36 + kb0);
    bf16x8 a0h, a0l, a1h_, a1l_;
    #pragma unroll
    for (int e = 0; e < 4; e++){
      unsigned short hh, ll;
      float h;
      h = rr ? fmaxf((av0[e]+cv0[e])*sc1s[kb0+e] + sh1s[kb0+e], 0.f) : 0.f;
      bfsplit(h, hh, ll); a0h[e] = (short)hh; a0l[e] = (short)ll;
      h = rr ? fmaxf((av1[e]+cv1[e])*sc1s[kb0+4+e] + sh1s[kb0+4+e], 0.f) : 0.f;
      bfsplit(h, hh, ll); a0h[4+e] = (short)hh; a0l[4+e] = (short)ll;
      h = rr ? fmaxf((av2[e]+cv2[e])*sc1s[32+kb0+e] + sh1s[32+kb0+e], 0.f) : 0.f;
      bfsplit(h, hh, ll); a1h_[e] = (short)hh; a1l_[e] = (short)ll;
      h = rr ? fmaxf((av3[e]+cv3[e])*sc1s[36+kb0+e] + sh1s[36+kb0+e], 0.f) : 0.f;
      bfsplit(h, hh, ll); a1h_[4+e] = (short)hh; a1l_[4+e] = (short)ll;
    }
    // ---- GEMM1: P = H1 @ W2 ----
    f32x4 pacc[4];
    #pragma unroll
    for (int nt = 0; nt < 4; nt++){
      f32x4 acc = {0.f, 0.f, 0.f, 0.f};
      acc = __builtin_amdgcn_mfma_f32_16x16x32_bf16(a0h,  w2h[nt][0], acc, 0, 0, 0);
      acc = __builtin_amdgcn_mfma_f32_16x16x32_bf16(a1h_, w2h[nt][1], acc, 0, 0, 0);
      acc = __builtin_amdgcn_mfma_f32_16x16x32_bf16(a0h,  w2l[nt][0], acc, 0, 0, 0);
      acc = __builtin_amdgcn_mfma_f32_16x16x32_bf16(a1h_, w2l[nt][1], acc, 0, 0, 0);
      acc = __builtin_amdgcn_mfma_f32_16x16x32_bf16(a0l,  w2h[nt][0], acc, 0, 0, 0);
      acc = __builtin_amdgcn_mfma_f32_16x16x32_bf16(a1l_, w2h[nt][1], acc, 0, 0, 0);
      pacc[nt] = acc;
    }
    // ---- BN2 + relu, relayout D->A via per-wave LDS scratch ----
    #pragma unroll
    for (int nt = 0; nt < 4; nt++){
      #pragma unroll
      for (int r = 0; r < 4; r++){
        float v = fmaxf(pacc[nt][r]*scn[nt] + shn[nt], 0.f);
        sw[(4*ag + r)*68 + nt*16 + c16] = v;
      }
    }
    f32x4 h20 = *(const f32x4*)(sw + c16*68 + kb0);
    f32x4 h21 = *(const f32x4*)(sw + c16*68 + kb0 + 4);
    f32x4 h22 = *(const f32x4*)(sw + c16*68 + 32 + kb0);
    f32x4 h23 = *(const f32x4*)(sw + c16*68 + 36 + kb0);
    bf16x8 b0h, b0l, b1h, b1l;
    #pragma unroll
    for (int e = 0; e < 4; e++){
      unsigned short hh, ll;
      bfsplit(h20[e], hh, ll); b0h[e] = (short)hh; b0l[e] = (short)ll;
      bfsplit(h21[e], hh, ll); b0h[4+e] = (short)hh; b0l[4+e] = (short)ll;
      bfsplit(h22[e], hh, ll); b1h[e] = (short)hh; b1l[e] = (short)ll;
      bfsplit(h23[e], hh, ll); b1h[4+e] = (short)hh; b1l[4+e] = (short)ll;
    }
    // ---- GEMM2: Q = H2 @ W3, masked max into per-wave node slots ----
    #pragma unroll
    for (int nt = 0; nt < 4; nt++){
      f32x4 acc = {0.f, 0.f, 0.f, 0.f};
      acc = __builtin_amdgcn_mfma_f32_16x16x32_bf16(b0h, w3h[nt][0], acc, 0, 0, 0);
      acc = __builtin_amdgcn_mfma_f32_16x16x32_bf16(b1h, w3h[nt][1], acc, 0, 0, 0);
      acc = __builtin_amdgcn_mfma_f32_16x16x32_bf16(b0h, w3l[nt][0], acc, 0, 0, 0);
      acc = __builtin_amdgcn_mfma_f32_16x16x32_bf16(b1h, w3l[nt][1], acc, 0, 0, 0);
      acc = __builtin_amdgcn_mfma_f32_16x16x32_bf16(b0l, w3h[nt][0], acc, 0, 0, 0);
      acc = __builtin_amdgcn_mfma_f32_16x16x32_bf16(b1l, w3h[nt][1], acc, 0, 0, 0);
      float vmx = -FLT_MAX;
      #pragma unroll
      for (int r = 0; r < 4; r++){
        int kr = half*16 + 4*ag + r;
        vmx = (kr < 20) ? fmaxf(vmx, acc[r]) : vmx;
      }
      vmx = fmaxf(vmx, __shfl_xor(vmx, 16));
      vmx = fmaxf(vmx, __shfl_xor(vmx, 32));
      if (ag == 0){
        unsigned int u = mono32(vmx);
        unsigned int* sl = &mxp[wv][node_l][nt*16 + c16];
        if (u > *sl) *sl = u;
      }
    }
  }
  __syncthreads();
  for (int s = tid; s < 512; s += 256){
    int nl = s >> 6, c = s & 63;
    unsigned int u = mxp[0][nl][c];
    unsigned int u1 = mxp[1][nl][c]; u = (u1 > u) ? u1 : u;
    unsigned int u2 = mxp[2][nl][c]; u = (u2 > u) ? u2 : u;
    unsigned int u3 = mxp[3][nl][c]; u = (u3 > u) ? u3 : u;
    unsigned int bts = (u & 0x80000000u) ? (u ^ 0x80000000u) : ~u;
    x1[(size_t)(blockIdx.x*8 + nl)*64 + c] = __uint_as_float(bts) + inb[IN_B3 + c];
  }
}

// ---------------- kNN in 64-d feature space: MFMA distance tiles + f64-key top-k ----------------
// Round-7 lesson: the scalar-dot scan read 256B of LDS per (query,candidate)
// (8.6 GB/dispatch) -> LDS-BW-bound at ~231us. MFMA tiles cut LDS traffic to
// ~8B/output. Per chunk of 64 candidates: stage C pre-split (Ch/Cl bf16),
// compute S = Q*C^T via 16x16x32 MFMA (3-term hi/lo split, ~2^-17 rel err --
// distances only gate neighbor-set membership; downstream aggregation is
// order-invariant max/sum), assemble d into LDS D-tile (stride 65: selection
// reads are 2-way bank = free), then the f64-key min/max insert per candidate.
__global__ __launch_bounds__(256, 4) void k_knn2(const float* x1, u64* part){
  __shared__ __align__(16) char sm2[35584];
  unsigned short* Ch = (unsigned short*)sm2;            // [64][72] bf16-hi 9216B
  unsigned short* Cl = (unsigned short*)(sm2 + 9216);   // [64][72] bf16-lo 9216B
  float* Dd  = (float*)(sm2 + 18432);                   // [64*65] dist tile 16640B
  float* sqc = (float*)(sm2 + 35072);                   // [64]
  float* sqq = (float*)(sm2 + 35328);                   // [64]
  u64* mrgA = (u64*)sm2;                                // overlay (post-scan)
  u64* mrgB = (u64*)(sm2 + 10752);
  int bb   = blockIdx.x >> 5;
  int qg   = (blockIdx.x >> 1) & 15;
  int half = blockIdx.x & 1;
  int tid = threadIdx.x;
  int q_l = tid & 63;
  int wv = tid >> 6;                 // wave index == selection slot
  int lane = tid & 63;
  int c16 = lane & 15, ag = lane >> 4, kb0 = ag*8;
  int qbase = bb*1024 + qg*64;
  // A-fragments: wave wv owns query rows wv*16..+16; lane row = c16
  bf16x8 qh0, qh1, ql0, ql1;
  {
    const float* qr = x1 + (size_t)(qbase + wv*16 + c16)*64;
    f32x4 v0 = *(const f32x4*)(qr + kb0);
    f32x4 v1 = *(const f32x4*)(qr + kb0 + 4);
    f32x4 v2 = *(const f32x4*)(qr + 32 + kb0);
    f32x4 v3 = *(const f32x4*)(qr + 36 + kb0);
    #pragma unroll
    for (int e = 0; e < 4; e++){
      unsigned short hh, ll;
      bfsplit(v0[e], hh, ll); qh0[e] = (short)hh; ql0[e] = (short)ll;
      bfsplit(v1[e], hh, ll); qh0[4+e] = (short)hh; ql0[4+e] = (short)ll;
      bfsplit(v2[e], hh, ll); qh1[e] = (short)hh; ql1[e] = (short)ll;
      bfsplit(v3[e], hh, ll); qh1[4+e] = (short)hh; ql1[4+e] = (short)ll;
    }
  }
  if (tid < 64){
    const float* xr = x1 + (size_t)(qbase + tid)*64;
    float s = 0.f;
    #pragma unroll
    for (int d4 = 0; d4 < 16; d4++){
      f32x4 v = *(const f32x4*)(xr + d4*4);
      s += v[0]*v[0] + v[1]*v[1] + v[2]*v[2] + v[3]*v[3];
    }
    sqq[tid] = s;
  }
  REP20(KDECLD)
  for (int ch = 0; ch < 8; ch++){
    int c0 = half*512 + ch*64;
    __syncthreads();                 // prev D consumed (and sqq ready on ch=0)
    // stage C chunk pre-split: 2048 float-pairs / 256 threads
    for (int pp = tid; pp < 2048; pp += 256){
      int row = pp >> 5, cp = pp & 31;
      const float* src = x1 + (size_t)(bb*1024 + c0 + row)*64 + cp*2;
      float v0 = src[0], v1 = src[1];
      unsigned short h0, l0, h1, l1;
      bfsplit(v0, h0, l0); bfsplit(v1, h1, l1);
      ((unsigned int*)Ch)[row*36 + cp] = (unsigned int)h0 | ((unsigned int)h1 << 16);
      ((unsigned int*)Cl)[row*36 + cp] = (unsigned int)l0 | ((unsigned int)l1 << 16);
    }
    __syncthreads();
    if (tid < 64){                   // sqc from exact split reconstruction
      float s = 0.f;
      for (int dw = 0; dw < 32; dw++){
        unsigned int hw = ((unsigned int*)Ch)[tid*36 + dw];
        unsigned int lw = ((unsigned int*)Cl)[tid*36 + dw];
        float a0 = __uint_as_float(hw << 16) + __uint_as_float(lw << 16);
        float a1 = __uint_as_float(hw & 0xFFFF0000u) + __uint_as_float(lw & 0xFFFF0000u);
        s += a0*a0 + a1*a1;
      }
      sqc[tid] = s;
    }
    __syncthreads();
    // MFMA phase: wave wv computes D rows [wv*16, wv*16+16) x 64 cands
    #pragma unroll
    for (int nt = 0; nt < 4; nt++){
      bf16x8 bh0 = *(const bf16x8*)(Ch + (nt*16 + c16)*72 + kb0);
      bf16x8 bh1 = *(const bf16x8*)(Ch + (nt*16 + c16)*72 + 32 + kb0);
      bf16x8 bl0 = *(const bf16x8*)(Cl + (nt*16 + c16)*72 + kb0);
      bf16x8 bl1 = *(const bf16x8*)(Cl + (nt*16 + c16)*72 + 32 + kb0);
      f32x4 p0 = {0.f,0.f,0.f,0.f}, p1 = {0.f,0.f,0.f,0.f}, p2 = {0.f,0.f,0.f,0.f};
      p0 = __builtin_amdgcn_mfma_f32_16x16x32_bf16(qh0, bh0, p0, 0, 0, 0);
      p0 = __builtin_amdgcn_mfma_f32_16x16x32_bf16(qh1, bh1, p0, 0, 0, 0);
      p1 = __builtin_amdgcn_mfma_f32_16x16x32_bf16(qh0, bl0, p1, 0, 0, 0);
      p1 = __builtin_amdgcn_mfma_f32_16x16x32_bf16(qh1, bl1, p1, 0, 0, 0);
      p2 = __builtin_amdgcn_mfma_f32_16x16x32_bf16(ql0, bh0, p2, 0, 0, 0);
      p2 = __builtin_amdgcn_mfma_f32_16x16x32_bf16(ql1, bh1, p2, 0, 0, 0);
      #pragma unroll
      for (int r = 0; r < 4; r++){
        int qrow = wv*16 + 4*ag + r;
        float d = sqq[qrow] + sqc[nt*16 + c16] - 2.0f*(p0[r] + p1[r] + p2[r]);
        Dd[qrow*65 + nt*16 + c16] = d;
      }
    }
    __syncthreads();
    // selection: lane = query q_l, wave = candidate slot (c = 4u+wv)
    for (int u = 0; u < 16; u += 2){
      int cA = 4*u + wv, cB = 4*(u+1) + wv;
      float dA = Dd[q_l*65 + cA];
      float dB = Dd[q_l*65 + cB];
      INS_MM(packkey(dA, c0 + cA));
      INS_MM(packkey(dB, c0 + cB));
    }
  }
  __syncthreads();                   // scan arrays dead from here (union!)
  if (wv == 1){ REP20(KPUB_A) }
  if (wv == 3){ REP20(KPUB_B) }
  __syncthreads();
  if ((wv & 1) == 0){
    const u64* src = (wv == 0) ? &mrgA[q_l*21] : &mrgB[q_l*21];
    for (int p = 0; p < KNN; p++){
      double kv = __longlong_as_double((long long)src[p]);
      if (kv > rk19) break;
      INS_MM(kv);
    }
  }
  __syncthreads();
  if (wv == 2){ REP20(KPUB_B) }
  __syncthreads();
  if (wv == 0){
    const u64* src = &mrgB[q_l*21];
    for (int p = 0; p < KNN; p++){
      double kv = __longlong_as_double((long long)src[p]);
      if (kv > rk19) break;
      INS_MM(kv);
    }
    int gi = qbase + q_l;
    u64* gpart = part + ((size_t)gi*2 + half)*KNN;
    REP20(KSTG)
  }
}

// ---------------- fast path: B2H = x1 @ Wbot[:, q-half] ----------------
__global__ __launch_bounds__(256) void k_B2h(const float* x1, const float* inb,
                                             int q, float* B2H){
  __shared__ __align__(16) float Wbh[4096];
  __shared__ __align__(16) float xsh[1024];
  int tid = threadIdx.x;
  const float* Wb = inb + IN_WBUF + WB_WBOT;
  for (int t = tid; t < 4096; t += 256){
    int r = t >> 6, cl = t & 63;
    Wbh[t] = Wb[r*128 + q*64 + cl];
  }
  int node0 = blockIdx.x * 16;
  for (int t = tid; t < 1024; t += 256) xsh[t] = x1[node0*64 + t];
  __syncthreads();
  int n_l = tid >> 4, cg = tid & 15;
  const float* xr = xsh + n_l*64;
  float4 acc = make_float4(0.f,0.f,0.f,0.f);
  #pragma unroll 8
  for (int d = 0; d < 64; d++){
    float v = xr[d];
    float4 w = *(const float4*)(Wbh + d*64 + cg*4);
    acc.x += v*w.x; acc.y += v*w.y; acc.z += v*w.z; acc.w += v*w.w;
  }
  *(float4*)(B2H + (node0 + n_l)*64 + cg*4) = acc;
}

// ---------------- fast path: x2 half = (x1_i@Wd + bc2) + max_j B2H[j] ----------------
__global__ __launch_bounds__(256) void k_x2h(const float* x1, const float* B2H,
                                             const float* inb, const int* idx2,
                                             int q, float* x2){
  __shared__ __align__(16) float Wdh[4096];
  __shared__ __align__(16) float xsh[256];
  int tid = threadIdx.x;
  const float* Wd = inb + IN_WBUF + WB_WD;
  for (int t = tid; t < 4096; t += 256){
    int r = t >> 6, cl = t & 63;
    Wdh[t] = Wd[r*128 + q*64 + cl];
  }
  int node0 = blockIdx.x * 4;
  xsh[tid] = x1[node0*64 + tid];
  __syncthreads();
  int n_l = tid >> 6, cl = tid & 63;
  int i = node0 + n_l;
  int b = i >> 10;
  const float* xr = xsh + n_l*64;
  float acc = inb[IN_BC2 + q*64 + cl];
  #pragma unroll 8
  for (int d = 0; d < 64; d++) acc += xr[d]*Wdh[d*64 + cl];
  float m = -FLT_MAX;
  for (int kk = 0; kk < KNN; kk++){
    int j = idx2[i*KNN + kk];
    m = fmaxf(m, B2H[((b<<10)+j)*64 + cl]);
  }
  x2[i*128 + q*64 + cl] = acc + m;
}

// ---------------- slow fallback: x2 direct, LDS-staged, no B2H buffer ----------------
__global__ __launch_bounds__(256) void k_x2d(const float* x1, const float* inb,
                                             const int* idx2, float* x2){
  __shared__ __align__(16) float Wdh[4096], Wbh[4096];
  __shared__ __align__(16) float xis[1024], xjs[1024];
  int tid = threadIdx.x;
  int q = blockIdx.x & 1;
  int node0 = (blockIdx.x >> 1) * 16;
  const float* Wd = inb + IN_WBUF + WB_WD;
  const float* Wb = inb + IN_WBUF + WB_WBOT;
  for (int t = tid; t < 4096; t += 256){
    int r = t >> 6, cl = t & 63;
    Wdh[t] = Wd[r*128 + q*64 + cl];
    Wbh[t] = Wb[r*128 + q*64 + cl];
  }
  for (int t = tid; t < 1024; t += 256) xis[t] = x1[node0*64 + t];
  __syncthreads();
  int n_l = tid >> 4, cg = tid & 15;
  int i = node0 + n_l, b = i >> 10;
  const float* xr = xis + n_l*64;
  float4 af = make_float4(inb[IN_BC2 + q*64 + cg*4],   inb[IN_BC2 + q*64 + cg*4+1],
                          inb[IN_BC2 + q*64 + cg*4+2], inb[IN_BC2 + q*64 + cg*4+3]);
  #pragma unroll 8
  for (int d = 0; d < 64; d++){
    float v = xr[d];
    float4 w = *(const float4*)(Wdh + d*64 + cg*4);
    af.x += v*w.x; af.y += v*w.y; af.z += v*w.z; af.w += v*w.w;
  }
  float4 mx = make_float4(-FLT_MAX,-FLT_MAX,-FLT_MAX,-FLT_MAX);
  for (int kk = 0; kk < KNN; kk++){
    __syncthreads();
    for (int t = tid; t < 1024; t += 256){
      int nn = t >> 6, r = t & 63;
      int jj = idx2[(node0+nn)*KNN + kk];
      xjs[t] = x1[((((node0+nn) >> 10) << 10) + jj)*64 + r];
    }
    __syncthreads();
    const float* xj = xjs + n_l*64;
    float4 acc = make_float4(0.f,0.f,0.f,0.f);
    #pragma unroll 8
    for (int d = 0; d < 64; d++){
      float v = xj[d];
      float4 w = *(const float4*)(Wbh + d*64 + cg*4);
      acc.x += v*w.x; acc.y += v*w.y; acc.z += v*w.z; acc.w += v*w.w;
    }
    mx.x = fmaxf(mx.x, acc.x); mx.y = fmaxf(mx.y, acc.y);
    mx.z = fmaxf(mx.z, acc.z); mx.w = fmaxf(mx.w, acc.w);
  }
  *(float4*)(x2 + i*128 + q*64 + cg*4) =
      make_float4(af.x+mx.x, af.y+mx.y, af.z+mx.z, af.w+mx.w);
}

// ---------------- lin (192->1024) via MFMA + max over node-quarter ----------------
__global__ __launch_bounds__(512, 2) void k_linpoolm(const float* x1, const float* x2,
    const float* inb, float* pool4){
  __shared__ __align__(16) float F[16*196];         // 12544B
  int tid = threadIdx.x;
  int b = blockIdx.x >> 4, cq = (blockIdx.x >> 2) & 3, nh = blockIdx.x & 3;
  int lane = tid & 63, wv = tid >> 6;
  int c16 = lane & 15, ag = lane >> 4;
  const float* Wl = inb + IN_WBUF + WB_WL;
  // B-fragments once per block
  bf16x8 w_h[2][6], w_l[2][6];
  #pragma unroll
  for (int nt = 0; nt < 2; nt++){
    int col = cq*256 + (wv*2+nt)*16 + c16;
    #pragma unroll
    for (int ks = 0; ks < 6; ks++){
      bf16x8 h8, l8;
      #pragma unroll
      for (int e = 0; e < 8; e++){
        unsigned short hh, ll;
        bfsplit(Wl[(ks*32 + ag*8 + e)*1024 + col], hh, ll);
        h8[e] = (short)hh; l8[e] = (short)ll;
      }
      w_h[nt][ks] = h8; w_l[nt][ks] = l8;
    }
  }
  float rmax[2] = {-FLT_MAX, -FLT_MAX};
  int n0 = b*1024 + nh*256;
  for (int chk = 0; chk < 16; chk++){
    int nb = n0 + chk*16;
    __syncthreads();
    {
      int row = tid >> 5;
      int d0 = (tid & 31)*6;
      #pragma unroll
      for (int u = 0; u < 6; u++){
        int d = d0 + u;
        F[row*196 + d] = (d < 64) ? x1[(size_t)(nb+row)*64 + d]
                                  : x2[(size_t)(nb+row)*128 + d - 64];
      }
    }
    __syncthreads();
    // A-fragments: row = c16 (node), k = ks*32 + ag*8 + e
    bf16x8 a_h[6], a_l[6];
    #pragma unroll
    for (int ks = 0; ks < 6; ks++){
      f32x4 v0 = *(const f32x4*)(F + c16*196 + ks*32 + ag*8);
      f32x4 v1 = *(const f32x4*)(F + c16*196 + ks*32 + ag*8 + 4);
      bf16x8 h8, l8;
      #pragma unroll
      for (int e = 0; e < 4; e++){
        unsigned short hh, ll;
        bfsplit(v0[e], hh, ll); h8[e] = (short)hh; l8[e] = (short)ll;
        bfsplit(v1[e], hh, ll); h8[4+e] = (short)hh; l8[4+e] = (short)ll;
      }
      a_h[ks] = h8; a_l[ks] = l8;
    }
    #pragma unroll
    for (int nt = 0; nt < 2; nt++){
      f32x4 p0 = {0.f,0.f,0.f,0.f}, p1 = {0.f,0.f,0.f,0.f}, p2 = {0.f,0.f,0.f,0.f};
      #pragma unroll
      for (int ks = 0; ks < 6; ks++){
        p0 = __builtin_amdgcn_mfma_f32_16x16x32_bf16(a_h[ks], w_h[nt][ks], p0, 0, 0, 0);
        p1 = __builtin_amdgcn_mfma_f32_16x16x32_bf16(a_h[ks], w_l[nt][ks], p1, 0, 0, 0);
        p2 = __builtin_amdgcn_mfma_f32_16x16x32_bf16(a_l[ks], w_h[nt][ks], p2, 0, 0, 0);
      }
      float m = -FLT_MAX;
      #pragma unroll
      for (int r = 0; r < 4; r++) m = fmaxf(m, p0[r] + p1[r] + p2[r]);
      m = fmaxf(m, __shfl_xor(m, 16));
      m = fmaxf(m, __shfl_xor(m, 32));
      rmax[nt] = fmaxf(rmax[nt], m);
    }
  }
  if (ag == 0){
    #pragma unroll
    for (int nt = 0; nt < 2; nt++)
      pool4[nh*32768 + b*1024 + cq*256 + (wv*2+nt)*16 + c16] = rmax[nt];
  }
}

// ---------------- head MLP: reduce pool4 + 1024->512->256->40 (fp32 out) ----------------
__global__ __launch_bounds__(256) void k_head(const float* pool4, const float* inb,
                                              float* out){
  __shared__ float pl[1024];
  __shared__ float s1[512];
  __shared__ float s2[256];
  int b = blockIdx.x, tid = threadIdx.x;
  const float* Wm1 = inb + IN_WBUF + WB_WM1;
  const float* Wm2 = inb + IN_WBUF + WB_WM2;
  const float* Wm3 = inb + IN_WBUF + WB_WM3;
  for (int t = tid; t < 1024; t += 256){
    float m = fmaxf(fmaxf(pool4[b*1024 + t],         pool4[32768 + b*1024 + t]),
                    fmaxf(pool4[65536 + b*1024 + t], pool4[98304 + b*1024 + t]));
    pl[t] = m + inb[IN_BL + t];
  }
  __syncthreads();
  for (int c = tid; c < 512; c += 256){
    float acc = inb[IN_BM1 + c];
    #pragma unroll 4
    for (int d = 0; d < 1024; d++) acc += pl[d]*Wm1[d*512 + c];
    s1[c] = fmaxf(acc, 0.f);
  }
  __syncthreads();
  {
    int c = tid;
    float acc = inb[IN_BM2 + c];
    #pragma unroll 4
    for (int d = 0; d < 512; d++) acc += s1[d]*Wm2[d*256 + c];
    s2[c] = fmaxf(acc, 0.f);
  }
  __syncthreads();
  if (tid < 40){
    float acc = inb[IN_BM3 + tid];
    #pragma unroll 4
    for (int d = 0; d < 256; d++) acc += s2[d]*Wm3[d*40 + tid];
    out[b*40 + tid] = acc;
  }
}

extern "C" void kernel_launch(void* const* d_in, const int* in_sizes, int n_in,
                              void* d_out, int out_size, void* d_ws, size_t ws_size,
                              hipStream_t stream){
  float* ws     = (float*)d_ws;
  double* stats = (double*)d_ws;
  int*   flag   = (int*)d_ws + OFF_FLAG;
  float* inb    = ws + OFF_INB;
  int*   idx    = (int*)d_ws + OFF_IDX;     // idx1 early, idx2 late
  float* x1p    = ws + OFF_X1;
  float* x2p    = ws + OFF_X2;
  float* a1     = ws + OFF_X2;              // a1/c1 alias x2 region (dead before x2 written)
  float* c1     = ws + OFF_C1;
  u64*   part   = (u64*)(ws + OFF_X2);      // kNN partials alias a1/c1 (see layout note)
  float* pool4  = ws + OFF_POOL;
  float* B2H    = ws + OFF_B2H;
  bool fast = ws_size >= (size_t)FAST_END * 4u;

  hipMemsetAsync(stats, 0, 256*sizeof(double), stream);
  k_sniff<<<1, 64, 0, stream>>>(d_in[0], flag);
  k_cvt<<<3859, 256, 0, stream>>>(
      d_in[0], d_in[1], d_in[2], d_in[3], d_in[4], d_in[5], d_in[6], d_in[7],
      d_in[8], d_in[9], d_in[10], d_in[11], d_in[12], d_in[13], d_in[14],
      d_in[15], d_in[16], d_in[17], d_in[18], d_in[19], d_in[20], flag, inb);
  k_knn1<<<1024, 256, 0, stream>>>(inb, part);      // partials in a1/c1 region
  k_mrg<<<128, 256, 0, stream>>>(part, idx);        // -> idx1
  k_prep1<<<8192, 256, 0, stream>>>(inb, a1, c1);   // overwrites dead partials
  k_stats1<<<640, 256, 0, stream>>>(a1, c1, idx, stats);
  k_stats2m<<<4096, 256, 0, stream>>>(a1, c1, idx, inb, stats);
  k_x1m<<<4096, 256, 0, stream>>>(a1, c1, idx, inb, stats, x1p);
  k_knn2<<<1024, 256, 0, stream>>>(x1p, part);      // a1/c1 dead after k_x1m
  k_mrg<<<128, 256, 0, stream>>>(part, idx);        // -> idx2
  if (fast){
    k_B2h<<<2048, 256, 0, stream>>>(x1p, inb, 0, B2H);
    k_x2h<<<8192, 256, 0, stream>>>(x1p, B2H, inb, idx, 0, x2p);
    k_B2h<<<2048, 256, 0, stream>>>(x1p, inb, 1, B2H);
    k_x2h<<<8192, 256, 0, stream>>>(x1p, B2H, inb, idx, 1, x2p);
  } else {
    k_x2d<<<4096, 256, 0, stream>>>(x1p, inb, idx, x2p);
  }
  k_linpoolm<<<512, 512, 0, stream>>>(x1p, x2p, inb, pool4);
  k_head<<<32, 256, 0, stream>>>(pool4, inb, (float*)d_out);
}

// Round 9
// 892.423 us; speedup vs baseline: 4.9529x; 1.2207x over previous
//
#include <hip/hip_runtime.h>
#include <hip/hip_bf16.h>
#include <float.h>
#include <math.h>

typedef __hip_bfloat16 bf16;
typedef unsigned long long u64;

#define BATCH 32
#define NPTS  1024
#define KNN   20
#define NB    (BATCH*NPTS)      // 32768 nodes
#define NEDGE (NB*KNN)          // 655360 edges

// ---- workspace layout (float units), ws_size-adaptive ----
#define OFF_FLAG 512u
#define OFF_INB  1024u
#define OFF_IDX  988928u          // 655360 ints (idx1 early, idx2 late; s1/s2 after x2)
#define OFF_X1   1644288u         // NB*64
#define OFF_X2   3741440u         // NB*128 ; a1 @ OFF_X2, c1 @ OFF_C1 (early)
#define OFF_C1   5838592u
#define OFF_POOL 7935744u         // pool4: 4 x 32*1024
#define SLOW_END 8066816u         // 32.3 MB
#define OFF_B2H  8066816u         // NB*64 (fast path only)
#define FAST_END 10163968u        // 40.7 MB
// kNN partial lists (u64) alias OFF_X2 (dead there at both kNN points).
// Head activations s1[32*512], s2[32*256] alias OFF_IDX (idx2 dead after x2).
// ---- layout inside inb (canonical fp32 inputs) ----
#define IN_POSF 0u
#define IN_B1   98304u
#define IN_G1   98368u
#define IN_BE1  98432u
#define IN_B2   98496u
#define IN_G2   98560u
#define IN_BE2  98624u
#define IN_B3   98688u
#define IN_BC2  98752u
#define IN_BL   98880u
#define IN_BM1  99904u
#define IN_BM2  100416u
#define IN_BM3  100672u
#define IN_W1   100736u
#define IN_WBUF 101120u
#define WB_W2   0u
#define WB_W3   4096u
#define WB_WD   8192u            // Wc2 top-bot diff [64x128]
#define WB_WBOT 16384u           // Wc2 bottom      [64x128]
#define WB_WL   24576u
#define WB_WM1  221184u          // stored TRANSPOSED [512][1024] (head wave-dots)
#define WB_WM2  745472u          // stored TRANSPOSED [256][512]
#define WB_WM3  876544u          // stored TRANSPOSED [40][256]
#define IN_TOTAL 987904u

__device__ __forceinline__ float bf2f(bf16 v){ return __bfloat162float(v); }

// monotone float->u32 map: preserves IEEE-754 total order for all finite values
__device__ __forceinline__ unsigned int mono32(float f){
  unsigned int b = __float_as_uint(f);
  return b ^ ((unsigned int)((int)b >> 31) | 0x80000000u);
}

// ======== MFMA machinery (bf16 hi/lo split, fp32-accurate) ========
typedef __attribute__((ext_vector_type(8))) short bf16x8;
typedef __attribute__((ext_vector_type(4))) float f32x4;

__device__ __forceinline__ unsigned short bfhi(float f){
  unsigned int u = __float_as_uint(f);
  u += 0x7FFFu + ((u >> 16) & 1u);      // RNE to bf16
  return (unsigned short)(u >> 16);
}
__device__ __forceinline__ void bfsplit(float f, unsigned short& h, unsigned short& l){
  h = bfhi(f);
  float fh = __uint_as_float(((unsigned int)h) << 16);
  l = bfhi(f - fh);
}

// ======== exact top-k via f64-packed keys + min/max sorted-insert ========
// Key bits = (1<<62) | (f32bits(max(d,0)) << 20) | idx -> positive doubles,
// value order == lexicographic (d, idx) == top_k semantics, globally unique.
// Insert: new_rp = min(rp, max(rp-1, k)) descending (exact multiset identity).
#define REP20(M) M(0) M(1) M(2) M(3) M(4) M(5) M(6) M(7) M(8) M(9) \
                 M(10) M(11) M(12) M(13) M(14) M(15) M(16) M(17) M(18) M(19)
#define SH19(M) M(19,18) M(18,17) M(17,16) M(16,15) M(15,14) M(14,13) M(13,12) \
                M(12,11) M(11,10) M(10,9) M(9,8) M(8,7) M(7,6) M(6,5) M(5,4) \
                M(4,3) M(3,2) M(2,1) M(1,0)

__device__ __forceinline__ double packkey(float d, int idx){
  unsigned int b = __float_as_uint(fmaxf(d, 0.0f));
  u64 k = 0x4000000000000000ULL | ((u64)b << 20) | (unsigned int)idx;
  return __longlong_as_double((long long)k);
}

#define KDECLD(p) double rk##p = DBL_MAX;
#define KMM(p,pm) rk##p = fmin(rk##p, fmax(rk##pm, _k));
#define INS_MM(kv) do{ double _k=(kv); SH19(KMM) rk0 = fmin(rk0, _k); }while(0)

#define KPUB_A(p) mrgA[q_l*21+p] = (u64)__double_as_longlong(rk##p);
#define KPUB_B(p) mrgB[q_l*21+p] = (u64)__double_as_longlong(rk##p);
#define KSTG(p)   gpart[p] = (u64)__double_as_longlong(rk##p);
#define KLDAD(p)  double rk##p = __longlong_as_double((long long)pa[p]);
#define KOUTU(p)  optr[p] = (int)((u64)__double_as_longlong(rk##p) & 1023ULL);

// ---------------- dtype sniff (fp32 vs bf16 inputs) ----------------
__global__ void k_sniff(const void* pos_raw, int* flag){
  if (blockIdx.x == 0 && threadIdx.x == 0){
    const unsigned short* h = (const unsigned short*)pos_raw;
    int wild = 0;
    for (int k = 0; k < 16; k++){
      unsigned int bits = ((unsigned int)h[2*k]) << 16;
      float v = __uint_as_float(bits);
      float a = fabsf(v);
      if (a != 0.0f && (v != v || a > 1e10f || a < 1e-10f)) wild++;
    }
    *flag = (wild >= 4) ? 1 : 0;
  }
}

__device__ __forceinline__ float rdv(const void* p, int i, int f){
  return f ? ((const float*)p)[i] : bf2f(((const bf16*)p)[i]);
}

// ---------------- normalize ALL inputs to canonical fp32 buffer ----------------
// Head weights are stored TRANSPOSED (row per output col) so k_h* can do
// contiguous float4 row-dots. Gather reads are L2-resident (Wm1 = 2MB).
__global__ __launch_bounds__(256) void k_cvt(
    const void* pos, const void* W1, const void* b1, const void* g1, const void* be1,
    const void* W2, const void* b2, const void* g2, const void* be2,
    const void* W3, const void* b3, const void* Wc2, const void* bc2,
    const void* Wl, const void* bl, const void* Wm1, const void* bm1,
    const void* Wm2, const void* bm2, const void* Wm3, const void* bm3,
    const int* flag, float* inb){
  int id = blockIdx.x*256 + threadIdx.x;
  if (id >= (int)IN_TOTAL) return;
  int f = *flag;
  float v;
  if      (id < 98304)  v = rdv(pos, id, f);
  else if (id < 98368)  v = rdv(b1,  id-98304, f);
  else if (id < 98432)  v = rdv(g1,  id-98368, f);
  else if (id < 98496)  v = rdv(be1, id-98432, f);
  else if (id < 98560)  v = rdv(b2,  id-98496, f);
  else if (id < 98624)  v = rdv(g2,  id-98560, f);
  else if (id < 98688)  v = rdv(be2, id-98624, f);
  else if (id < 98752)  v = rdv(b3,  id-98688, f);
  else if (id < 98880)  v = rdv(bc2, id-98752, f);
  else if (id < 99904)  v = rdv(bl,  id-98880, f);
  else if (id < 100416) v = rdv(bm1, id-99904, f);
  else if (id < 100672) v = rdv(bm2, id-100416, f);
  else if (id < 100712) v = rdv(bm3, id-100672, f);
  else if (id < 100736) v = 0.0f;
  else if (id < 101120) v = rdv(W1,  id-100736, f);
  else {
    int t = id - 101120;
    if      (t < 4096)   v = rdv(W2, t, f);
    else if (t < 8192)   v = rdv(W3, t-4096, f);
    else if (t < 16384){ int u = t-8192;  v = rdv(Wc2, u, f) - rdv(Wc2, 8192+u, f); }
    else if (t < 24576){ int u = t-16384; v = rdv(Wc2, 8192+u, f); }
    else if (t < 221184) v = rdv(Wl,  t-24576, f);
    else if (t < 745472){ int u = t-221184; int c = u>>10, d = u&1023; v = rdv(Wm1, d*512+c, f); }
    else if (t < 876544){ int u = t-745472; int c = u>>9,  d = u&511;  v = rdv(Wm2, d*256+c, f); }
    else               { int u = t-876544; int c = u>>8,  d = u&255;  v = rdv(Wm3, d*40+c, f); }
  }
  inb[id] = v;
}

// ---------------- a1/c1: affine decomposition of EdgeConv1 layer1 ----------------
__global__ __launch_bounds__(256) void k_prep1(const float* inb, float* a1, float* c1){
  const float* posf = inb + IN_POSF;
  const float* W1f  = inb + IN_W1;
  const float* b1f  = inb + IN_B1;
  int id = blockIdx.x*256 + threadIdx.x;
  int bn = id >> 6, c = id & 63;
  float p0 = posf[bn*3], p1 = posf[bn*3+1], p2 = posf[bn*3+2];
  float wt0 = W1f[c],     wt1 = W1f[64+c],  wt2 = W1f[128+c];
  float wb0 = W1f[192+c], wb1 = W1f[256+c], wb2 = W1f[320+c];
  float cv = p0*wb0 + p1*wb1 + p2*wb2;
  float av = p0*(wt0-wb0) + p1*(wt1-wb1) + p2*(wt2-wb2) + b1f[c];
  a1[id] = av;  c1[id] = cv;
}

// ---------------- kNN in coordinate space (half-split, LDS-union, f64-key top-k) ----------------
__global__ __launch_bounds__(256, 2) void k_knn1(const float* inb, u64* part){
  const float* posf = inb + IN_POSF;
  __shared__ __align__(16) char sm1[21504];
  float* psx = (float*)sm1;
  float* psy = psx + 1024;
  float* psz = psy + 1024;
  float* sqs = psz + 1024;
  u64* mrgA = (u64*)sm1;              // overlay (post-scan only)
  u64* mrgB = (u64*)(sm1 + 10752);
  int bb   = blockIdx.x >> 5;
  int qg   = (blockIdx.x >> 1) & 15;
  int half = blockIdx.x & 1;
  int tid = threadIdx.x;
  int q_l = tid & 63;
  int slot = tid >> 6;
  for (int t = tid; t < 1024; t += 256){
    float x = posf[(bb*1024+t)*3], y = posf[(bb*1024+t)*3+1], z = posf[(bb*1024+t)*3+2];
    psx[t] = x; psy[t] = y; psz[t] = z; sqs[t] = x*x + y*y + z*z;
  }
  __syncthreads();
  int i_l = qg*64 + q_l;
  float xi0 = psx[i_l], xi1 = psy[i_l], xi2 = psz[i_l];
  float sqi = sqs[i_l];
  REP20(KDECLD)
  int cbase = half*512;
  for (int u = 0; u < 128; u++){
    int jj = cbase + 4*u + slot;
    float dot = xi0*psx[jj] + xi1*psy[jj] + xi2*psz[jj];
    float d = sqi + sqs[jj] - 2.0f*dot;
    INS_MM(packkey(d, jj));
  }
  __syncthreads();                    // scan arrays dead from here (union!)
  if (slot == 1){ REP20(KPUB_A) }
  if (slot == 3){ REP20(KPUB_B) }
  __syncthreads();
  if ((slot & 1) == 0){
    const u64* src = (slot == 0) ? &mrgA[q_l*21] : &mrgB[q_l*21];
    for (int p = 0; p < KNN; p++){
      double kv = __longlong_as_double((long long)src[p]);
      if (kv > rk19) break;          // sorted source: rest are worse
      INS_MM(kv);
    }
  }
  __syncthreads();
  if (slot == 2){ REP20(KPUB_B) }
  __syncthreads();
  if (slot == 0){
    const u64* src = &mrgB[q_l*21];
    for (int p = 0; p < KNN; p++){
      double kv = __longlong_as_double((long long)src[p]);
      if (kv > rk19) break;
      INS_MM(kv);
    }
    int gi = bb*1024 + i_l;
    u64* gpart = part + ((size_t)gi*2 + half)*KNN;
    REP20(KSTG)
  }
}

// ---------------- merge two sorted 20-entry half-lists per query ----------------
__global__ __launch_bounds__(256) void k_mrg(const u64* part, int* out){
  int gi = blockIdx.x*256 + threadIdx.x;    // grid 128 -> 32768 queries
  const u64* pa = part + (size_t)gi*2*KNN;
  REP20(KLDAD)                               // init from half-0 list (sorted)
  for (int p = 0; p < KNN; p++){
    double kv = __longlong_as_double((long long)pa[KNN + p]);
    if (kv > rk19) break;                    // sorted source: rest are worse
    INS_MM(kv);
  }
  int* optr = out + gi*KNN;
  REP20(KOUTU)
}

// ---------------- BN1 stats ----------------
__global__ __launch_bounds__(256) void k_stats1(const float* a1, const float* c1,
                                                const int* idx1, double* stats){
  __shared__ float rs[256], rs2[256];
  int tid = threadIdx.x, c = tid & 63, slot = tid >> 6;
  int base = blockIdx.x * 1024;
  float s = 0.f, s2 = 0.f;
  for (int t = 0; t < 256; t++){
    unsigned e = (unsigned)(base + t*4 + slot);
    int i = (int)(e / 20u);
    int b = i >> 10;
    int j = idx1[e];
    float h = a1[i*64+c] + c1[((b<<10)+j)*64 + c];
    s += h; s2 += h*h;
  }
  rs[tid] = s; rs2[tid] = s2;
  __syncthreads();
  if (slot == 0){
    double ts  = (double)rs[c]  + (double)rs[64+c]  + (double)rs[128+c]  + (double)rs[192+c];
    double ts2 = (double)rs2[c] + (double)rs2[64+c] + (double)rs2[128+c] + (double)rs2[192+c];
    atomicAdd(&stats[c], ts);
    atomicAdd(&stats[64+c], ts2);
  }
}

// ================= MFMA edge-MLP =================
// Geometry: block = 8 nodes; node padded 20->32 edge rows; 16 M-tiles of 16;
// 4 waves x 4 tiles. fp32 accuracy via hi/lo bf16 split (3-term). b2 cancels
// in BN2 (stats of raw P); b3 added after the max.

// ---------------- BN2 stats over P = H1 @ W2 (raw, no b2) ----------------
__global__ __launch_bounds__(256) void k_stats2m(const float* a1, const float* c1,
    const int* idx1, const float* inb, double* stats){
  __shared__ __align__(16) float W2s[4096];
  __shared__ float sc1s[64], sh1s[64];
  __shared__ float rs[4][64], rs2[4][64];
  int tid = threadIdx.x;
  const float* wbuf = inb + IN_WBUF;
  for (int t = tid; t < 4096; t += 256) W2s[t] = wbuf[WB_W2 + t];
  if (tid < 64){
    int c = tid;
    const double M = (double)NEDGE;
    double m1 = stats[c]/M;
    double v1 = stats[64+c]/M - m1*m1;
    double r1 = 1.0/sqrt(v1 + 1e-5);
    double g1 = (double)inb[IN_G1 + c];
    sc1s[c] = (float)(g1*r1);
    sh1s[c] = (float)((double)inb[IN_BE1 + c] - m1*g1*r1);
  }
  __syncthreads();
  int lane = tid & 63, wv = tid >> 6;
  int c16 = lane & 15, ag = lane >> 4, kb0 = ag*8;
  bf16x8 w2h[4][2], w2l[4][2];
  #pragma unroll
  for (int nt = 0; nt < 4; nt++){
    #pragma unroll
    for (int ks = 0; ks < 2; ks++){
      bf16x8 h8, l8;
      #pragma unroll
      for (int e = 0; e < 8; e++){
        unsigned short hh, ll;
        bfsplit(W2s[(ks*32 + kb0 + e)*64 + nt*16 + c16], hh, ll);
        h8[e] = (short)hh; l8[e] = (short)ll;
      }
      w2h[nt][ks] = h8; w2l[nt][ks] = l8;
    }
  }
  float sa[4] = {0,0,0,0}, qa[4] = {0,0,0,0};
  for (int t4 = 0; t4 < 4; t4++){
    int T = t4*4 + wv;
    int node_l = T >> 1, half = T & 1;
    int nodeg = blockIdx.x*8 + node_l;
    int krow = half*16 + c16;
    int rr = (krow < 20);
    int j = idx1[nodeg*20 + (rr ? krow : 0)];
    int gj = ((nodeg >> 10) << 10) + j;
    const float* ar = a1 + (size_t)nodeg*64;
    const float* cr = c1 + (size_t)gj*64;
    f32x4 av0 = *(const f32x4*)(ar + kb0);
    f32x4 av1 = *(const f32x4*)(ar + kb0 + 4);
    f32x4 av2 = *(const f32x4*)(ar + 32 + kb0);
    f32x4 av3 = *(const f32x4*)(ar + 36 + kb0);
    f32x4 cv0 = *(const f32x4*)(cr + kb0);
    f32x4 cv1 = *(const f32x4*)(cr + kb0 + 4);
    f32x4 cv2 = *(const f32x4*)(cr + 32 + kb0);
    f32x4 cv3 = *(const f32x4*)(cr + 36 + kb0);
    bf16x8 a0h, a0l, a1h_, a1l_;
    #pragma unroll
    for (int e = 0; e < 4; e++){
      unsigned short hh, ll;
      float h;
      h = rr ? fmaxf((av0[e]+cv0[e])*sc1s[kb0+e] + sh1s[kb0+e], 0.f) : 0.f;
      bfsplit(h, hh, ll); a0h[e] = (short)hh; a0l[e] = (short)ll;
      h = rr ? fmaxf((av1[e]+cv1[e])*sc1s[kb0+4+e] + sh1s[kb0+4+e], 0.f) : 0.f;
      bfsplit(h, hh, ll); a0h[4+e] = (short)hh; a0l[4+e] = (short)ll;
      h = rr ? fmaxf((av2[e]+cv2[e])*sc1s[32+kb0+e] + sh1s[32+kb0+e], 0.f) : 0.f;
      bfsplit(h, hh, ll); a1h_[e] = (short)hh; a1l_[e] = (short)ll;
      h = rr ? fmaxf((av3[e]+cv3[e])*sc1s[36+kb0+e] + sh1s[36+kb0+e], 0.f) : 0.f;
      bfsplit(h, hh, ll); a1h_[4+e] = (short)hh; a1l_[4+e] = (short)ll;
    }
    #pragma unroll
    for (int nt = 0; nt < 4; nt++){
      f32x4 acc = {0.f, 0.f, 0.f, 0.f};
      acc = __builtin_amdgcn_mfma_f32_16x16x32_bf16(a0h,  w2h[nt][0], acc, 0, 0, 0);
      acc = __builtin_amdgcn_mfma_f32_16x16x32_bf16(a1h_, w2h[nt][1], acc, 0, 0, 0);
      acc = __builtin_amdgcn_mfma_f32_16x16x32_bf16(a0h,  w2l[nt][0], acc, 0, 0, 0);
      acc = __builtin_amdgcn_mfma_f32_16x16x32_bf16(a1h_, w2l[nt][1], acc, 0, 0, 0);
      acc = __builtin_amdgcn_mfma_f32_16x16x32_bf16(a0l,  w2h[nt][0], acc, 0, 0, 0);
      acc = __builtin_amdgcn_mfma_f32_16x16x32_bf16(a1l_, w2h[nt][1], acc, 0, 0, 0);
      #pragma unroll
      for (int r = 0; r < 4; r++){
        int kr = half*16 + 4*ag + r;        // D row m=(lane>>4)*4+r -> edge slot
        float v = (kr < 20) ? acc[r] : 0.f;
        sa[nt] += v; qa[nt] += v*v;
      }
    }
  }
  #pragma unroll
  for (int nt = 0; nt < 4; nt++){
    sa[nt] += __shfl_xor(sa[nt], 16); sa[nt] += __shfl_xor(sa[nt], 32);
    qa[nt] += __shfl_xor(qa[nt], 16); qa[nt] += __shfl_xor(qa[nt], 32);
  }
  if (ag == 0){
    #pragma unroll
    for (int nt = 0; nt < 4; nt++){
      rs[wv][nt*16+c16] = sa[nt];
      rs2[wv][nt*16+c16] = qa[nt];
    }
  }
  __syncthreads();
  if (tid < 64){
    double ts = (double)rs[0][tid] + (double)rs[1][tid]
              + (double)rs[2][tid] + (double)rs[3][tid];
    double tq = (double)rs2[0][tid] + (double)rs2[1][tid]
              + (double)rs2[2][tid] + (double)rs2[3][tid];
    atomicAdd(&stats[128+tid], ts);
    atomicAdd(&stats[192+tid], tq);
  }
}

// ---------------- full MLP1 via MFMA + max over k -> x1 ----------------
__global__ __launch_bounds__(256, 2) void k_x1m(const float* a1, const float* c1,
    const int* idx1, const float* inb, const double* stats, float* x1){
  __shared__ __align__(16) float W2s[4096];
  __shared__ __align__(16) float W3s[4096];
  __shared__ __align__(16) float scr[4][16*68];     // per-wave H2 relayout scratch
  __shared__ unsigned int mxp[4][8][64];            // per-wave node maxes (mono32)
  __shared__ float sc1s[64], sh1s[64], sc2s[64], sh2s[64];
  int tid = threadIdx.x;
  const float* wbuf = inb + IN_WBUF;
  for (int t = tid; t < 4096; t += 256){ W2s[t] = wbuf[WB_W2+t]; W3s[t] = wbuf[WB_W3+t]; }
  {
    unsigned int* mf = &mxp[0][0][0];
    for (int t = tid; t < 2048; t += 256) mf[t] = 0u;
  }
  if (tid < 64){
    int c = tid;
    const double M = (double)NEDGE;
    double m1 = stats[c]/M;
    double v1 = stats[64+c]/M - m1*m1;
    double r1 = 1.0/sqrt(v1 + 1e-5);
    double g1 = (double)inb[IN_G1 + c];
    sc1s[c] = (float)(g1*r1);
    sh1s[c] = (float)((double)inb[IN_BE1 + c] - m1*g1*r1);
    double mp = stats[128+c]/M;                  // mean of raw P (b2 cancels in BN)
    double v2 = stats[192+c]/M - mp*mp;
    double r2 = 1.0/sqrt(v2 + 1e-5);
    double g2 = (double)inb[IN_G2 + c];
    sc2s[c] = (float)(g2*r2);
    sh2s[c] = (float)((double)inb[IN_BE2 + c] - mp*g2*r2);
  }
  __syncthreads();
  int lane = tid & 63, wv = tid >> 6;
  int c16 = lane & 15, ag = lane >> 4, kb0 = ag*8;
  // weight fragments (hi/lo) for both layers
  bf16x8 w2h[4][2], w2l[4][2], w3h[4][2], w3l[4][2];
  #pragma unroll
  for (int nt = 0; nt < 4; nt++){
    #pragma unroll
    for (int ks = 0; ks < 2; ks++){
      bf16x8 h8, l8, h9, l9;
      #pragma unroll
      for (int e = 0; e < 8; e++){
        unsigned short hh, ll;
        bfsplit(W2s[(ks*32 + kb0 + e)*64 + nt*16 + c16], hh, ll);
        h8[e] = (short)hh; l8[e] = (short)ll;
        bfsplit(W3s[(ks*32 + kb0 + e)*64 + nt*16 + c16], hh, ll);
        h9[e] = (short)hh; l9[e] = (short)ll;
      }
      w2h[nt][ks] = h8; w2l[nt][ks] = l8;
      w3h[nt][ks] = h9; w3l[nt][ks] = l9;
    }
  }
  float scn[4], shn[4];
  #pragma unroll
  for (int nt = 0; nt < 4; nt++){
    scn[nt] = sc2s[nt*16 + c16];
    shn[nt] = sh2s[nt*16 + c16];
  }
  float* sw = &scr[wv][0];
  for (int t4 = 0; t4 < 4; t4++){
    int T = t4*4 + wv;
    int node_l = T >> 1, half = T & 1;
    int nodeg = blockIdx.x*8 + node_l;
    int krow = half*16 + c16;
    int rr = (krow < 20);
    int j = idx1[nodeg*20 + (rr ? krow : 0)];
    int gj = ((nodeg >> 10) << 10) + j;
    const float* ar = a1 + (size_t)nodeg*64;
    const float* cr = c1 + (size_t)gj*64;
    f32x4 av0 = *(const f32x4*)(ar + kb0);
    f32x4 av1 = *(const f32x4*)(ar + kb0 + 4);
    f32x4 av2 = *(const f32x4*)(ar + 32 + kb0);
    f32x4 av3 = *(const f32x4*)(ar + 36 + kb0);
    f32x4 cv0 = *(const f32x4*)(cr + kb0);
    f32x4 cv1 = *(const f32x4*)(cr + kb0 + 4);
    f32x4 cv2 = *(const f32x4*)(cr + 32 + kb0);
    f32x4 cv3 = *(const f32x4*)(cr + 36 + kb0);
    bf16x8 a0h, a0l, a1h_, a1l_;
    #pragma unroll
    for (int e = 0; e < 4; e++){
      unsigned short hh, ll;
      float h;
      h = rr ? fmaxf((av0[e]+cv0[e])*sc1s[kb0+e] + sh1s[kb0+e], 0.f) : 0.f;
      bfsplit(h, hh, ll); a0h[e] = (short)hh; a0l[e] = (short)ll;
      h = rr ? fmaxf((av1[e]+cv1[e])*sc1s[kb0+4+e] + sh1s[kb0+4+e], 0.f) : 0.f;
      bfsplit(h, hh, ll); a0h[4+e] = (short)hh; a0l[4+e] = (short)ll;
      h = rr ? fmaxf((av2[e]+cv2[e])*sc1s[32+kb0+e] + sh1s[32+kb0+e], 0.f) : 0.f;
      bfsplit(h, hh, ll); a1h_[e] = (short)hh; a1l_[e] = (short)ll;
      h = rr ? fmaxf((av3[e]+cv3[e])*sc1s[36+kb0+e] + sh1s[36+kb0+e], 0.f) : 0.f;
      bfsplit(h, hh, ll); a1h_[4+e] = (short)hh; a1l_[4+e] = (short)ll;
    }
    // ---- GEMM1: P = H1 @ W2 ----
    f32x4 pacc[4];
    #pragma unroll
    for (int nt = 0; nt < 4; nt++){
      f32x4 acc = {0.f, 0.f, 0.f, 0.f};
      acc = __builtin_amdgcn_mfma_f32_16x16x32_bf16(a0h,  w2h[nt][0], acc, 0, 0, 0);
      acc = __builtin_amdgcn_mfma_f32_16x16x32_bf16(a1h_, w2h[nt][1], acc, 0, 0, 0);
      acc = __builtin_amdgcn_mfma_f32_16x16x32_bf16(a0h,  w2l[nt][0], acc, 0, 0, 0);
      acc = __builtin_amdgcn_mfma_f32_16x16x32_bf16(a1h_, w2l[nt][1], acc, 0, 0, 0);
      acc = __builtin_amdgcn_mfma_f32_16x16x32_bf16(a0l,  w2h[nt][0], acc, 0, 0, 0);
      acc = __builtin_amdgcn_mfma_f32_16x16x32_bf16(a1l_, w2h[nt][1], acc, 0, 0, 0);
      pacc[nt] = acc;
    }
    // ---- BN2 + relu, relayout D->A via per-wave LDS scratch ----
    #pragma unroll
    for (int nt = 0; nt < 4; nt++){
      #pragma unroll
      for (int r = 0; r < 4; r++){
        float v = fmaxf(pacc[nt][r]*scn[nt] + shn[nt], 0.f);
        sw[(4*ag + r)*68 + nt*16 + c16] = v;
      }
    }
    f32x4 h20 = *(const f32x4*)(sw + c16*68 + kb0);
    f32x4 h21 = *(const f32x4*)(sw + c16*68 + kb0 + 4);
    f32x4 h22 = *(const f32x4*)(sw + c16*68 + 32 + kb0);
    f32x4 h23 = *(const f32x4*)(sw + c16*68 + 36 + kb0);
    bf16x8 b0h, b0l, b1h, b1l;
    #pragma unroll
    for (int e = 0; e < 4; e++){
      unsigned short hh, ll;
      bfsplit(h20[e], hh, ll); b0h[e] = (short)hh; b0l[e] = (short)ll;
      bfsplit(h21[e], hh, ll); b0h[4+e] = (short)hh; b0l[4+e] = (short)ll;
      bfsplit(h22[e], hh, ll); b1h[e] = (short)hh; b1l[e] = (short)ll;
      bfsplit(h23[e], hh, ll); b1h[4+e] = (short)hh; b1l[4+e] = (short)ll;
    }
    // ---- GEMM2: Q = H2 @ W3, masked max into per-wave node slots ----
    #pragma unroll
    for (int nt = 0; nt < 4; nt++){
      f32x4 acc = {0.f, 0.f, 0.f, 0.f};
      acc = __builtin_amdgcn_mfma_f32_16x16x32_bf16(b0h, w3h[nt][0], acc, 0, 0, 0);
      acc = __builtin_amdgcn_mfma_f32_16x16x32_bf16(b1h, w3h[nt][1], acc, 0, 0, 0);
      acc = __builtin_amdgcn_mfma_f32_16x16x32_bf16(b0h, w3l[nt][0], acc, 0, 0, 0);
      acc = __builtin_amdgcn_mfma_f32_16x16x32_bf16(b1h, w3l[nt][1], acc, 0, 0, 0);
      acc = __builtin_amdgcn_mfma_f32_16x16x32_bf16(b0l, w3h[nt][0], acc, 0, 0, 0);
      acc = __builtin_amdgcn_mfma_f32_16x16x32_bf16(b1l, w3h[nt][1], acc, 0, 0, 0);
      float vmx = -FLT_MAX;
      #pragma unroll
      for (int r = 0; r < 4; r++){
        int kr = half*16 + 4*ag + r;
        vmx = (kr < 20) ? fmaxf(vmx, acc[r]) : vmx;
      }
      vmx = fmaxf(vmx, __shfl_xor(vmx, 16));
      vmx = fmaxf(vmx, __shfl_xor(vmx, 32));
      if (ag == 0){
        unsigned int u = mono32(vmx);
        unsigned int* sl = &mxp[wv][node_l][nt*16 + c16];
        if (u > *sl) *sl = u;
      }
    }
  }
  __syncthreads();
  for (int s = tid; s < 512; s += 256){
    int nl = s >> 6, c = s & 63;
    unsigned int u = mxp[0][nl][c];
    unsigned int u1 = mxp[1][nl][c]; u = (u1 > u) ? u1 : u;
    unsigned int u2 = mxp[2][nl][c]; u = (u2 > u) ? u2 : u;
    unsigned int u3 = mxp[3][nl][c]; u = (u3 > u) ? u3 : u;
    unsigned int bts = (u & 0x80000000u) ? (u ^ 0x80000000u) : ~u;
    x1[(size_t)(blockIdx.x*8 + nl)*64 + c] = __uint_as_float(bts) + inb[IN_B3 + c];
  }
}

// ---------------- kNN in 64-d feature space: MFMA distance tiles + f64-key top-k ----------------
__global__ __launch_bounds__(256, 4) void k_knn2(const float* x1, u64* part){
  __shared__ __align__(16) char sm2[35584];
  unsigned short* Ch = (unsigned short*)sm2;            // [64][72] bf16-hi 9216B
  unsigned short* Cl = (unsigned short*)(sm2 + 9216);   // [64][72] bf16-lo 9216B
  float* Dd  = (float*)(sm2 + 18432);                   // [64*65] dist tile 16640B
  float* sqc = (float*)(sm2 + 35072);                   // [64]
  float* sqq = (float*)(sm2 + 35328);                   // [64]
  u64* mrgA = (u64*)sm2;                                // overlay (post-scan)
  u64* mrgB = (u64*)(sm2 + 10752);
  int bb   = blockIdx.x >> 5;
  int qg   = (blockIdx.x >> 1) & 15;
  int half = blockIdx.x & 1;
  int tid = threadIdx.x;
  int q_l = tid & 63;
  int wv = tid >> 6;                 // wave index == selection slot
  int lane = tid & 63;
  int c16 = lane & 15, ag = lane >> 4, kb0 = ag*8;
  int qbase = bb*1024 + qg*64;
  // A-fragments: wave wv owns query rows wv*16..+16; lane row = c16
  bf16x8 qh0, qh1, ql0, ql1;
  {
    const float* qr = x1 + (size_t)(qbase + wv*16 + c16)*64;
    f32x4 v0 = *(const f32x4*)(qr + kb0);
    f32x4 v1 = *(const f32x4*)(qr + kb0 + 4);
    f32x4 v2 = *(const f32x4*)(qr + 32 + kb0);
    f32x4 v3 = *(const f32x4*)(qr + 36 + kb0);
    #pragma unroll
    for (int e = 0; e < 4; e++){
      unsigned short hh, ll;
      bfsplit(v0[e], hh, ll); qh0[e] = (short)hh; ql0[e] = (short)ll;
      bfsplit(v1[e], hh, ll); qh0[4+e] = (short)hh; ql0[4+e] = (short)ll;
      bfsplit(v2[e], hh, ll); qh1[e] = (short)hh; ql1[e] = (short)ll;
      bfsplit(v3[e], hh, ll); qh1[4+e] = (short)hh; ql1[4+e] = (short)ll;
    }
  }
  if (tid < 64){
    const float* xr = x1 + (size_t)(qbase + tid)*64;
    float s = 0.f;
    #pragma unroll
    for (int d4 = 0; d4 < 16; d4++){
      f32x4 v = *(const f32x4*)(xr + d4*4);
      s += v[0]*v[0] + v[1]*v[1] + v[2]*v[2] + v[3]*v[3];
    }
    sqq[tid] = s;
  }
  REP20(KDECLD)
  for (int ch = 0; ch < 8; ch++){
    int c0 = half*512 + ch*64;
    __syncthreads();                 // prev D consumed (and sqq ready on ch=0)
    // stage C chunk pre-split: 2048 float-pairs / 256 threads
    for (int pp = tid; pp < 2048; pp += 256){
      int row = pp >> 5, cp = pp & 31;
      const float* src = x1 + (size_t)(bb*1024 + c0 + row)*64 + cp*2;
      float v0 = src[0], v1 = src[1];
      unsigned short h0, l0, h1, l1;
      bfsplit(v0, h0, l0); bfsplit(v1, h1, l1);
      ((unsigned int*)Ch)[row*36 + cp] = (unsigned int)h0 | ((unsigned int)h1 << 16);
      ((unsigned int*)Cl)[row*36 + cp] = (unsigned int)l0 | ((unsigned int)l1 << 16);
    }
    __syncthreads();
    if (tid < 64){                   // sqc from exact split reconstruction
      float s = 0.f;
      for (int dw = 0; dw < 32; dw++){
        unsigned int hw = ((unsigned int*)Ch)[tid*36 + dw];
        unsigned int lw = ((unsigned int*)Cl)[tid*36 + dw];
        float a0 = __uint_as_float(hw << 16) + __uint_as_float(lw << 16);
        float a1 = __uint_as_float(hw & 0xFFFF0000u) + __uint_as_float(lw & 0xFFFF0000u);
        s += a0*a0 + a1*a1;
      }
      sqc[tid] = s;
    }
    __syncthreads();
    // MFMA phase: wave wv computes D rows [wv*16, wv*16+16) x 64 cands
    #pragma unroll
    for (int nt = 0; nt < 4; nt++){
      bf16x8 bh0 = *(const bf16x8*)(Ch + (nt*16 + c16)*72 + kb0);
      bf16x8 bh1 = *(const bf16x8*)(Ch + (nt*16 + c16)*72 + 32 + kb0);
      bf16x8 bl0 = *(const bf16x8*)(Cl + (nt*16 + c16)*72 + kb0);
      bf16x8 bl1 = *(const bf16x8*)(Cl + (nt*16 + c16)*72 + 32 + kb0);
      f32x4 p0 = {0.f,0.f,0.f,0.f}, p1 = {0.f,0.f,0.f,0.f}, p2 = {0.f,0.f,0.f,0.f};
      p0 = __builtin_amdgcn_mfma_f32_16x16x32_bf16(qh0, bh0, p0, 0, 0, 0);
      p0 = __builtin_amdgcn_mfma_f32_16x16x32_bf16(qh1, bh1, p0, 0, 0, 0);
      p1 = __builtin_amdgcn_mfma_f32_16x16x32_bf16(qh0, bl0, p1, 0, 0, 0);
      p1 = __builtin_amdgcn_mfma_f32_16x16x32_bf16(qh1, bl1, p1, 0, 0, 0);
      p2 = __builtin_amdgcn_mfma_f32_16x16x32_bf16(ql0, bh0, p2, 0, 0, 0);
      p2 = __builtin_amdgcn_mfma_f32_16x16x32_bf16(ql1, bh1, p2, 0, 0, 0);
      #pragma unroll
      for (int r = 0; r < 4; r++){
        int qrow = wv*16 + 4*ag + r;
        float d = sqq[qrow] + sqc[nt*16 + c16] - 2.0f*(p0[r] + p1[r] + p2[r]);
        Dd[qrow*65 + nt*16 + c16] = d;
      }
    }
    __syncthreads();
    // selection: lane = query q_l, wave = candidate slot (c = 4u+wv)
    for (int u = 0; u < 16; u += 2){
      int cA = 4*u + wv, cB = 4*(u+1) + wv;
      float dA = Dd[q_l*65 + cA];
      float dB = Dd[q_l*65 + cB];
      INS_MM(packkey(dA, c0 + cA));
      INS_MM(packkey(dB, c0 + cB));
    }
  }
  __syncthreads();                   // scan arrays dead from here (union!)
  if (wv == 1){ REP20(KPUB_A) }
  if (wv == 3){ REP20(KPUB_B) }
  __syncthreads();
  if ((wv & 1) == 0){
    const u64* src = (wv == 0) ? &mrgA[q_l*21] : &mrgB[q_l*21];
    for (int p = 0; p < KNN; p++){
      double kv = __longlong_as_double((long long)src[p]);
      if (kv > rk19) break;
      INS_MM(kv);
    }
  }
  __syncthreads();
  if (wv == 2){ REP20(KPUB_B) }
  __syncthreads();
  if (wv == 0){
    const u64* src = &mrgB[q_l*21];
    for (int p = 0; p < KNN; p++){
      double kv = __longlong_as_double((long long)src[p]);
      if (kv > rk19) break;
      INS_MM(kv);
    }
    int gi = qbase + q_l;
    u64* gpart = part + ((size_t)gi*2 + half)*KNN;
    REP20(KSTG)
  }
}

// ---------------- fast path: B2H = x1 @ Wbot[:, q-half] ----------------
__global__ __launch_bounds__(256) void k_B2h(const float* x1, const float* inb,
                                             int q, float* B2H){
  __shared__ __align__(16) float Wbh[4096];
  __shared__ __align__(16) float xsh[1024];
  int tid = threadIdx.x;
  const float* Wb = inb + IN_WBUF + WB_WBOT;
  for (int t = tid; t < 4096; t += 256){
    int r = t >> 6, cl = t & 63;
    Wbh[t] = Wb[r*128 + q*64 + cl];
  }
  int node0 = blockIdx.x * 16;
  for (int t = tid; t < 1024; t += 256) xsh[t] = x1[node0*64 + t];
  __syncthreads();
  int n_l = tid >> 4, cg = tid & 15;
  const float* xr = xsh + n_l*64;
  float4 acc = make_float4(0.f,0.f,0.f,0.f);
  #pragma unroll 8
  for (int d = 0; d < 64; d++){
    float v = xr[d];
    float4 w = *(const float4*)(Wbh + d*64 + cg*4);
    acc.x += v*w.x; acc.y += v*w.y; acc.z += v*w.z; acc.w += v*w.w;
  }
  *(float4*)(B2H + (node0 + n_l)*64 + cg*4) = acc;
}

// ---------------- fast path: x2 half = (x1_i@Wd + bc2) + max_j B2H[j] ----------------
__global__ __launch_bounds__(256) void k_x2h(const float* x1, const float* B2H,
                                             const float* inb, const int* idx2,
                                             int q, float* x2){
  __shared__ __align__(16) float Wdh[4096];
  __shared__ __align__(16) float xsh[256];
  int tid = threadIdx.x;
  const float* Wd = inb + IN_WBUF + WB_WD;
  for (int t = tid; t < 4096; t += 256){
    int r = t >> 6, cl = t & 63;
    Wdh[t] = Wd[r*128 + q*64 + cl];
  }
  int node0 = blockIdx.x * 4;
  xsh[tid] = x1[node0*64 + tid];
  __syncthreads();
  int n_l = tid >> 6, cl = tid & 63;
  int i = node0 + n_l;
  int b = i >> 10;
  const float* xr = xsh + n_l*64;
  float acc = inb[IN_BC2 + q*64 + cl];
  #pragma unroll 8
  for (int d = 0; d < 64; d++) acc += xr[d]*Wdh[d*64 + cl];
  float m = -FLT_MAX;
  for (int kk = 0; kk < KNN; kk++){
    int j = idx2[i*KNN + kk];
    m = fmaxf(m, B2H[((b<<10)+j)*64 + cl]);
  }
  x2[i*128 + q*64 + cl] = acc + m;
}

// ---------------- slow fallback: x2 direct, LDS-staged, no B2H buffer ----------------
__global__ __launch_bounds__(256) void k_x2d(const float* x1, const float* inb,
                                             const int* idx2, float* x2){
  __shared__ __align__(16) float Wdh[4096], Wbh[4096];
  __shared__ __align__(16) float xis[1024], xjs[1024];
  int tid = threadIdx.x;
  int q = blockIdx.x & 1;
  int node0 = (blockIdx.x >> 1) * 16;
  const float* Wd = inb + IN_WBUF + WB_WD;
  const float* Wb = inb + IN_WBUF + WB_WBOT;
  for (int t = tid; t < 4096; t += 256){
    int r = t >> 6, cl = t & 63;
    Wdh[t] = Wd[r*128 + q*64 + cl];
    Wbh[t] = Wb[r*128 + q*64 + cl];
  }
  for (int t = tid; t < 1024; t += 256) xis[t] = x1[node0*64 + t];
  __syncthreads();
  int n_l = tid >> 4, cg = tid & 15;
  int i = node0 + n_l, b = i >> 10;
  const float* xr = xis + n_l*64;
  float4 af = make_float4(inb[IN_BC2 + q*64 + cg*4],   inb[IN_BC2 + q*64 + cg*4+1],
                          inb[IN_BC2 + q*64 + cg*4+2], inb[IN_BC2 + q*64 + cg*4+3]);
  #pragma unroll 8
  for (int d = 0; d < 64; d++){
    float v = xr[d];
    float4 w = *(const float4*)(Wdh + d*64 + cg*4);
    af.x += v*w.x; af.y += v*w.y; af.z += v*w.z; af.w += v*w.w;
  }
  float4 mx = make_float4(-FLT_MAX,-FLT_MAX,-FLT_MAX,-FLT_MAX);
  for (int kk = 0; kk < KNN; kk++){
    __syncthreads();
    for (int t = tid; t < 1024; t += 256){
      int nn = t >> 6, r = t & 63;
      int jj = idx2[(node0+nn)*KNN + kk];
      xjs[t] = x1[((((node0+nn) >> 10) << 10) + jj)*64 + r];
    }
    __syncthreads();
    const float* xj = xjs + n_l*64;
    float4 acc = make_float4(0.f,0.f,0.f,0.f);
    #pragma unroll 8
    for (int d = 0; d < 64; d++){
      float v = xj[d];
      float4 w = *(const float4*)(Wbh + d*64 + cg*4);
      acc.x += v*w.x; acc.y += v*w.y; acc.z += v*w.z; acc.w += v*w.w;
    }
    mx.x = fmaxf(mx.x, acc.x); mx.y = fmaxf(mx.y, acc.y);
    mx.z = fmaxf(mx.z, acc.z); mx.w = fmaxf(mx.w, acc.w);
  }
  *(float4*)(x2 + i*128 + q*64 + cg*4) =
      make_float4(af.x+mx.x, af.y+mx.y, af.z+mx.z, af.w+mx.w);
}

// ---------------- lin (192->1024) via MFMA + max over node-quarter ----------------
__global__ __launch_bounds__(512, 2) void k_linpoolm(const float* x1, const float* x2,
    const float* inb, float* pool4){
  __shared__ __align__(16) float F[16*196];         // 12544B
  int tid = threadIdx.x;
  int b = blockIdx.x >> 4, cq = (blockIdx.x >> 2) & 3, nh = blockIdx.x & 3;
  int lane = tid & 63, wv = tid >> 6;
  int c16 = lane & 15, ag = lane >> 4;
  const float* Wl = inb + IN_WBUF + WB_WL;
  // B-fragments once per block
  bf16x8 w_h[2][6], w_l[2][6];
  #pragma unroll
  for (int nt = 0; nt < 2; nt++){
    int col = cq*256 + (wv*2+nt)*16 + c16;
    #pragma unroll
    for (int ks = 0; ks < 6; ks++){
      bf16x8 h8, l8;
      #pragma unroll
      for (int e = 0; e < 8; e++){
        unsigned short hh, ll;
        bfsplit(Wl[(ks*32 + ag*8 + e)*1024 + col], hh, ll);
        h8[e] = (short)hh; l8[e] = (short)ll;
      }
      w_h[nt][ks] = h8; w_l[nt][ks] = l8;
    }
  }
  float rmax[2] = {-FLT_MAX, -FLT_MAX};
  int n0 = b*1024 + nh*256;
  for (int chk = 0; chk < 16; chk++){
    int nb = n0 + chk*16;
    __syncthreads();
    {
      int row = tid >> 5;
      int d0 = (tid & 31)*6;
      #pragma unroll
      for (int u = 0; u < 6; u++){
        int d = d0 + u;
        F[row*196 + d] = (d < 64) ? x1[(size_t)(nb+row)*64 + d]
                                  : x2[(size_t)(nb+row)*128 + d - 64];
      }
    }
    __syncthreads();
    // A-fragments: row = c16 (node), k = ks*32 + ag*8 + e
    bf16x8 a_h[6], a_l[6];
    #pragma unroll
    for (int ks = 0; ks < 6; ks++){
      f32x4 v0 = *(const f32x4*)(F + c16*196 + ks*32 + ag*8);
      f32x4 v1 = *(const f32x4*)(F + c16*196 + ks*32 + ag*8 + 4);
      bf16x8 h8, l8;
      #pragma unroll
      for (int e = 0; e < 4; e++){
        unsigned short hh, ll;
        bfsplit(v0[e], hh, ll); h8[e] = (short)hh; l8[e] = (short)ll;
        bfsplit(v1[e], hh, ll); h8[4+e] = (short)hh; l8[4+e] = (short)ll;
      }
      a_h[ks] = h8; a_l[ks] = l8;
    }
    #pragma unroll
    for (int nt = 0; nt < 2; nt++){
      f32x4 p0 = {0.f,0.f,0.f,0.f}, p1 = {0.f,0.f,0.f,0.f}, p2 = {0.f,0.f,0.f,0.f};
      #pragma unroll
      for (int ks = 0; ks < 6; ks++){
        p0 = __builtin_amdgcn_mfma_f32_16x16x32_bf16(a_h[ks], w_h[nt][ks], p0, 0, 0, 0);
        p1 = __builtin_amdgcn_mfma_f32_16x16x32_bf16(a_h[ks], w_l[nt][ks], p1, 0, 0, 0);
        p2 = __builtin_amdgcn_mfma_f32_16x16x32_bf16(a_l[ks], w_h[nt][ks], p2, 0, 0, 0);
      }
      float m = -FLT_MAX;
      #pragma unroll
      for (int r = 0; r < 4; r++) m = fmaxf(m, p0[r] + p1[r] + p2[r]);
      m = fmaxf(m, __shfl_xor(m, 16));
      m = fmaxf(m, __shfl_xor(m, 32));
      rmax[nt] = fmaxf(rmax[nt], m);
    }
  }
  if (ag == 0){
    #pragma unroll
    for (int nt = 0; nt < 2; nt++)
      pool4[nh*32768 + b*1024 + cq*256 + (wv*2+nt)*16 + c16] = rmax[nt];
  }
}

// ================= head MLP, wave-per-column (round-8: was 32-block latency-bound) =================
// k_h1: grid 512 = (b, cg of 32 cols). Block stages pl (pool-reduce + bl,
// redundant x16 -- L2-hot, trivial); lane caches its 16-elem pl slice in regs;
// wave computes 8 cols as contiguous float4 row-dots on Wm1^T + shfl reduce.
__global__ __launch_bounds__(256) void k_h1(const float* pool4, const float* inb,
                                            float* s1g){
  __shared__ float pl[1024];
  int b = blockIdx.x >> 4, cg = blockIdx.x & 15;
  int tid = threadIdx.x;
  for (int t = tid; t < 1024; t += 256){
    float m = fmaxf(fmaxf(pool4[b*1024 + t],         pool4[32768 + b*1024 + t]),
                    fmaxf(pool4[65536 + b*1024 + t], pool4[98304 + b*1024 + t]));
    pl[t] = m + inb[IN_BL + t];
  }
  __syncthreads();
  int wv = tid >> 6, lane = tid & 63;
  f32x4 p0 = *(const f32x4*)(pl + lane*16);
  f32x4 p1 = *(const f32x4*)(pl + lane*16 + 4);
  f32x4 p2 = *(const f32x4*)(pl + lane*16 + 8);
  f32x4 p3 = *(const f32x4*)(pl + lane*16 + 12);
  const float* WT = inb + IN_WBUF + WB_WM1;    // [512][1024] transposed
  #pragma unroll
  for (int cc = 0; cc < 8; cc++){
    int c = cg*32 + wv*8 + cc;
    const float* wr = WT + (size_t)c*1024 + lane*16;
    f32x4 w0 = *(const f32x4*)(wr);
    f32x4 w1 = *(const f32x4*)(wr + 4);
    f32x4 w2 = *(const f32x4*)(wr + 8);
    f32x4 w3 = *(const f32x4*)(wr + 12);
    float acc = w0[0]*p0[0] + w0[1]*p0[1] + w0[2]*p0[2] + w0[3]*p0[3]
              + w1[0]*p1[0] + w1[1]*p1[1] + w1[2]*p1[2] + w1[3]*p1[3]
              + w2[0]*p2[0] + w2[1]*p2[1] + w2[2]*p2[2] + w2[3]*p2[3]
              + w3[0]*p3[0] + w3[1]*p3[1] + w3[2]*p3[2] + w3[3]*p3[3];
    acc += __shfl_xor(acc, 1);  acc += __shfl_xor(acc, 2);
    acc += __shfl_xor(acc, 4);  acc += __shfl_xor(acc, 8);
    acc += __shfl_xor(acc, 16); acc += __shfl_xor(acc, 32);
    if (lane == 0) s1g[b*512 + c] = fmaxf(acc + inb[IN_BM1 + c], 0.f);
  }
}

// k_h2: grid 256 = (b, cg of 32 cols of 256). K=512, lane slice 8.
__global__ __launch_bounds__(256) void k_h2(const float* s1g, const float* inb,
                                            float* s2g){
  __shared__ float s1[512];
  int b = blockIdx.x >> 3, cg = blockIdx.x & 7;
  int tid = threadIdx.x;
  for (int t = tid; t < 512; t += 256) s1[t] = s1g[b*512 + t];
  __syncthreads();
  int wv = tid >> 6, lane = tid & 63;
  f32x4 p0 = *(const f32x4*)(s1 + lane*8);
  f32x4 p1 = *(const f32x4*)(s1 + lane*8 + 4);
  const float* WT = inb + IN_WBUF + WB_WM2;    // [256][512] transposed
  #pragma unroll
  for (int cc = 0; cc < 8; cc++){
    int c = cg*32 + wv*8 + cc;
    const float* wr = WT + (size_t)c*512 + lane*8;
    f32x4 w0 = *(const f32x4*)(wr);
    f32x4 w1 = *(const f32x4*)(wr + 4);
    float acc = w0[0]*p0[0] + w0[1]*p0[1] + w0[2]*p0[2] + w0[3]*p0[3]
              + w1[0]*p1[0] + w1[1]*p1[1] + w1[2]*p1[2] + w1[3]*p1[3];
    acc += __shfl_xor(acc, 1);  acc += __shfl_xor(acc, 2);
    acc += __shfl_xor(acc, 4);  acc += __shfl_xor(acc, 8);
    acc += __shfl_xor(acc, 16); acc += __shfl_xor(acc, 32);
    if (lane == 0) s2g[b*256 + c] = fmaxf(acc + inb[IN_BM2 + c], 0.f);
  }
}

// k_h3: grid 32 (per batch). 40 cols, K=256, lane slice 4.
__global__ __launch_bounds__(256) void k_h3(const float* s2g, const float* inb,
                                            float* out){
  __shared__ float s2[256];
  int b = blockIdx.x;
  int tid = threadIdx.x;
  s2[tid] = s2g[b*256 + tid];
  __syncthreads();
  int wv = tid >> 6, lane = tid & 63;
  f32x4 p0 = *(const f32x4*)(s2 + lane*4);
  const float* WT = inb + IN_WBUF + WB_WM3;    // [40][256] transposed
  for (int cc = 0; cc < 10; cc++){
    int c = wv*10 + cc;
    const float* wr = WT + (size_t)c*256 + lane*4;
    f32x4 w0 = *(const f32x4*)(wr);
    float acc = w0[0]*p0[0] + w0[1]*p0[1] + w0[2]*p0[2] + w0[3]*p0[3];
    acc += __shfl_xor(acc, 1);  acc += __shfl_xor(acc, 2);
    acc += __shfl_xor(acc, 4);  acc += __shfl_xor(acc, 8);
    acc += __shfl_xor(acc, 16); acc += __shfl_xor(acc, 32);
    if (lane == 0) out[b*40 + c] = acc + inb[IN_BM3 + c];
  }
}

extern "C" void kernel_launch(void* const* d_in, const int* in_sizes, int n_in,
                              void* d_out, int out_size, void* d_ws, size_t ws_size,
                              hipStream_t stream){
  float* ws     = (float*)d_ws;
  double* stats = (double*)d_ws;
  int*   flag   = (int*)d_ws + OFF_FLAG;
  float* inb    = ws + OFF_INB;
  int*   idx    = (int*)d_ws + OFF_IDX;     // idx1 early, idx2 late
  float* x1p    = ws + OFF_X1;
  float* x2p    = ws + OFF_X2;
  float* a1     = ws + OFF_X2;              // a1/c1 alias x2 region (dead before x2 written)
  float* c1     = ws + OFF_C1;
  u64*   part   = (u64*)(ws + OFF_X2);      // kNN partials alias a1/c1 (see layout note)
  float* pool4  = ws + OFF_POOL;
  float* B2H    = ws + OFF_B2H;
  float* s1g    = ws + OFF_IDX;             // head acts alias idx (idx2 dead after x2)
  float* s2g    = ws + OFF_IDX + 16384;
  bool fast = ws_size >= (size_t)FAST_END * 4u;

  hipMemsetAsync(stats, 0, 256*sizeof(double), stream);
  k_sniff<<<1, 64, 0, stream>>>(d_in[0], flag);
  k_cvt<<<3859, 256, 0, stream>>>(
      d_in[0], d_in[1], d_in[2], d_in[3], d_in[4], d_in[5], d_in[6], d_in[7],
      d_in[8], d_in[9], d_in[10], d_in[11], d_in[12], d_in[13], d_in[14],
      d_in[15], d_in[16], d_in[17], d_in[18], d_in[19], d_in[20], flag, inb);
  k_knn1<<<1024, 256, 0, stream>>>(inb, part);      // partials in a1/c1 region
  k_mrg<<<128, 256, 0, stream>>>(part, idx);        // -> idx1
  k_prep1<<<8192, 256, 0, stream>>>(inb, a1, c1);   // overwrites dead partials
  k_stats1<<<640, 256, 0, stream>>>(a1, c1, idx, stats);
  k_stats2m<<<4096, 256, 0, stream>>>(a1, c1, idx, inb, stats);
  k_x1m<<<4096, 256, 0, stream>>>(a1, c1, idx, inb, stats, x1p);
  k_knn2<<<1024, 256, 0, stream>>>(x1p, part);      // a1/c1 dead after k_x1m
  k_mrg<<<128, 256, 0, stream>>>(part, idx);        // -> idx2
  if (fast){
    k_B2h<<<2048, 256, 0, stream>>>(x1p, inb, 0, B2H);
    k_x2h<<<8192, 256, 0, stream>>>(x1p, B2H, inb, idx, 0, x2p);
    k_B2h<<<2048, 256, 0, stream>>>(x1p, inb, 1, B2H);
    k_x2h<<<8192, 256, 0, stream>>>(x1p, B2H, inb, idx, 1, x2p);
  } else {
    k_x2d<<<4096, 256, 0, stream>>>(x1p, inb, idx, x2p);
  }
  k_linpoolm<<<512, 512, 0, stream>>>(x1p, x2p, inb, pool4);
  k_h1<<<512, 256, 0, stream>>>(pool4, inb, s1g);   // idx2 dead here
  k_h2<<<256, 256, 0, stream>>>(s1g, inb, s2g);
  k_h3<<<32, 256, 0, stream>>>(s2g, inb, (float*)d_out);
}

// Round 10
// 820.916 us; speedup vs baseline: 5.3843x; 1.0871x over previous
//
#include <hip/hip_runtime.h>
#include <hip/hip_bf16.h>
#include <float.h>
#include <math.h>

typedef __hip_bfloat16 bf16;
typedef unsigned long long u64;

#define BATCH 32
#define NPTS  1024
#define KNN   20
#define NB    (BATCH*NPTS)      // 32768 nodes
#define NEDGE (NB*KNN)          // 655360 edges

// ---- workspace layout (float units), ws_size-adaptive ----
#define OFF_FLAG 512u
#define OFF_INB  1024u
#define OFF_IDX  988928u          // 655360 ints (idx1 early, idx2 late; s1/s2 after x2)
#define OFF_X1   1644288u         // NB*64
#define OFF_X2   3741440u         // NB*128 ; a1 @ OFF_X2, c1 @ OFF_C1 (early)
#define OFF_C1   5838592u
#define OFF_POOL 7935744u         // pool4: 4 x 32*1024
#define SLOW_END 8066816u         // 32.3 MB
#define OFF_B2H  8066816u         // NB*64 (fast path only)
#define FAST_END 10163968u        // 40.7 MB
// kNN partial lists (u64) alias OFF_X2 (dead there at both kNN points).
// Head activations s1[32*512], s2[32*256] alias OFF_IDX (idx2 dead after x2).
// ---- layout inside inb (canonical fp32 inputs) ----
#define IN_POSF 0u
#define IN_B1   98304u
#define IN_G1   98368u
#define IN_BE1  98432u
#define IN_B2   98496u
#define IN_G2   98560u
#define IN_BE2  98624u
#define IN_B3   98688u
#define IN_BC2  98752u
#define IN_BL   98880u
#define IN_BM1  99904u
#define IN_BM2  100416u
#define IN_BM3  100672u
#define IN_W1   100736u
#define IN_WBUF 101120u
#define WB_W2   0u
#define WB_W3   4096u
#define WB_WD   8192u            // Wc2 top-bot diff [64x128]
#define WB_WBOT 16384u           // Wc2 bottom      [64x128]
#define WB_WL   24576u
#define WB_WM1  221184u          // stored TRANSPOSED [512][1024] (head wave-dots)
#define WB_WM2  745472u          // stored TRANSPOSED [256][512]
#define WB_WM3  876544u          // stored TRANSPOSED [40][256]
#define IN_TOTAL 987904u

__device__ __forceinline__ float bf2f(bf16 v){ return __bfloat162float(v); }

// monotone float->u32 map: preserves IEEE-754 total order for all finite values
__device__ __forceinline__ unsigned int mono32(float f){
  unsigned int b = __float_as_uint(f);
  return b ^ ((unsigned int)((int)b >> 31) | 0x80000000u);
}

// ======== MFMA machinery (bf16 hi/lo split, fp32-accurate) ========
typedef __attribute__((ext_vector_type(8))) short bf16x8;
typedef __attribute__((ext_vector_type(4))) float f32x4;

__device__ __forceinline__ unsigned short bfhi(float f){
  unsigned int u = __float_as_uint(f);
  u += 0x7FFFu + ((u >> 16) & 1u);      // RNE to bf16
  return (unsigned short)(u >> 16);
}
__device__ __forceinline__ void bfsplit(float f, unsigned short& h, unsigned short& l){
  h = bfhi(f);
  float fh = __uint_as_float(((unsigned int)h) << 16);
  l = bfhi(f - fh);
}

// ======== exact top-k via f64-packed keys + min/max sorted-insert ========
// Key bits = (1<<62) | (f32bits(max(d,0)) << 20) | idx -> positive doubles,
// value order == lexicographic (d, idx) == top_k semantics, globally unique.
// Insert: new_rp = min(rp, max(rp-1, k)) descending (exact multiset identity).
#define REP20(M) M(0) M(1) M(2) M(3) M(4) M(5) M(6) M(7) M(8) M(9) \
                 M(10) M(11) M(12) M(13) M(14) M(15) M(16) M(17) M(18) M(19)
#define SH19(M) M(19,18) M(18,17) M(17,16) M(16,15) M(15,14) M(14,13) M(13,12) \
                M(12,11) M(11,10) M(10,9) M(9,8) M(8,7) M(7,6) M(6,5) M(5,4) \
                M(4,3) M(3,2) M(2,1) M(1,0)

__device__ __forceinline__ double packkey(float d, int idx){
  unsigned int b = __float_as_uint(fmaxf(d, 0.0f));
  u64 k = 0x4000000000000000ULL | ((u64)b << 20) | (unsigned int)idx;
  return __longlong_as_double((long long)k);
}

#define KDECLD(p) double rk##p = DBL_MAX;
#define KMM(p,pm) rk##p = fmin(rk##p, fmax(rk##pm, _k));
#define INS_MM(kv) do{ double _k=(kv); SH19(KMM) rk0 = fmin(rk0, _k); }while(0)

#define KPUB_A(p) mrgA[q_l*21+p] = (u64)__double_as_longlong(rk##p);
#define KPUB_B(p) mrgB[q_l*21+p] = (u64)__double_as_longlong(rk##p);
#define KSTG(p)   gpart[p] = (u64)__double_as_longlong(rk##p);
#define KLDAD(p)  double rk##p = __longlong_as_double((long long)pa[p]);
#define KOUTU(p)  optr[p] = (int)((u64)__double_as_longlong(rk##p) & 1023ULL);

// ---------------- dtype sniff (fp32 vs bf16 inputs) ----------------
__global__ void k_sniff(const void* pos_raw, int* flag){
  if (blockIdx.x == 0 && threadIdx.x == 0){
    const unsigned short* h = (const unsigned short*)pos_raw;
    int wild = 0;
    for (int k = 0; k < 16; k++){
      unsigned int bits = ((unsigned int)h[2*k]) << 16;
      float v = __uint_as_float(bits);
      float a = fabsf(v);
      if (a != 0.0f && (v != v || a > 1e10f || a < 1e-10f)) wild++;
    }
    *flag = (wild >= 4) ? 1 : 0;
  }
}

__device__ __forceinline__ float rdv(const void* p, int i, int f){
  return f ? ((const float*)p)[i] : bf2f(((const bf16*)p)[i]);
}

// ---------------- normalize ALL inputs to canonical fp32 buffer ----------------
// Head weights are stored TRANSPOSED (row per output col) so k_h* can do
// contiguous float4 row-dots. Gather reads are L2-resident (Wm1 = 2MB).
__global__ __launch_bounds__(256) void k_cvt(
    const void* pos, const void* W1, const void* b1, const void* g1, const void* be1,
    const void* W2, const void* b2, const void* g2, const void* be2,
    const void* W3, const void* b3, const void* Wc2, const void* bc2,
    const void* Wl, const void* bl, const void* Wm1, const void* bm1,
    const void* Wm2, const void* bm2, const void* Wm3, const void* bm3,
    const int* flag, float* inb){
  int id = blockIdx.x*256 + threadIdx.x;
  if (id >= (int)IN_TOTAL) return;
  int f = *flag;
  float v;
  if      (id < 98304)  v = rdv(pos, id, f);
  else if (id < 98368)  v = rdv(b1,  id-98304, f);
  else if (id < 98432)  v = rdv(g1,  id-98368, f);
  else if (id < 98496)  v = rdv(be1, id-98432, f);
  else if (id < 98560)  v = rdv(b2,  id-98496, f);
  else if (id < 98624)  v = rdv(g2,  id-98560, f);
  else if (id < 98688)  v = rdv(be2, id-98624, f);
  else if (id < 98752)  v = rdv(b3,  id-98688, f);
  else if (id < 98880)  v = rdv(bc2, id-98752, f);
  else if (id < 99904)  v = rdv(bl,  id-98880, f);
  else if (id < 100416) v = rdv(bm1, id-99904, f);
  else if (id < 100672) v = rdv(bm2, id-100416, f);
  else if (id < 100712) v = rdv(bm3, id-100672, f);
  else if (id < 100736) v = 0.0f;
  else if (id < 101120) v = rdv(W1,  id-100736, f);
  else {
    int t = id - 101120;
    if      (t < 4096)   v = rdv(W2, t, f);
    else if (t < 8192)   v = rdv(W3, t-4096, f);
    else if (t < 16384){ int u = t-8192;  v = rdv(Wc2, u, f) - rdv(Wc2, 8192+u, f); }
    else if (t < 24576){ int u = t-16384; v = rdv(Wc2, 8192+u, f); }
    else if (t < 221184) v = rdv(Wl,  t-24576, f);
    else if (t < 745472){ int u = t-221184; int c = u>>10, d = u&1023; v = rdv(Wm1, d*512+c, f); }
    else if (t < 876544){ int u = t-745472; int c = u>>9,  d = u&511;  v = rdv(Wm2, d*256+c, f); }
    else               { int u = t-876544; int c = u>>8,  d = u&255;  v = rdv(Wm3, d*40+c, f); }
  }
  inb[id] = v;
}

// ---------------- a1/c1: affine decomposition of EdgeConv1 layer1 ----------------
__global__ __launch_bounds__(256) void k_prep1(const float* inb, float* a1, float* c1){
  const float* posf = inb + IN_POSF;
  const float* W1f  = inb + IN_W1;
  const float* b1f  = inb + IN_B1;
  int id = blockIdx.x*256 + threadIdx.x;
  int bn = id >> 6, c = id & 63;
  float p0 = posf[bn*3], p1 = posf[bn*3+1], p2 = posf[bn*3+2];
  float wt0 = W1f[c],     wt1 = W1f[64+c],  wt2 = W1f[128+c];
  float wb0 = W1f[192+c], wb1 = W1f[256+c], wb2 = W1f[320+c];
  float cv = p0*wb0 + p1*wb1 + p2*wb2;
  float av = p0*(wt0-wb0) + p1*(wt1-wb1) + p2*(wt2-wb2) + b1f[c];
  a1[id] = av;  c1[id] = cv;
}

// ---------------- kNN in coordinate space (half-split, LDS-union, f64-key top-k) ----------------
__global__ __launch_bounds__(256, 2) void k_knn1(const float* inb, u64* part){
  const float* posf = inb + IN_POSF;
  __shared__ __align__(16) char sm1[21504];
  float* psx = (float*)sm1;
  float* psy = psx + 1024;
  float* psz = psy + 1024;
  float* sqs = psz + 1024;
  u64* mrgA = (u64*)sm1;              // overlay (post-scan only)
  u64* mrgB = (u64*)(sm1 + 10752);
  int bb   = blockIdx.x >> 5;
  int qg   = (blockIdx.x >> 1) & 15;
  int half = blockIdx.x & 1;
  int tid = threadIdx.x;
  int q_l = tid & 63;
  int slot = tid >> 6;
  for (int t = tid; t < 1024; t += 256){
    float x = posf[(bb*1024+t)*3], y = posf[(bb*1024+t)*3+1], z = posf[(bb*1024+t)*3+2];
    psx[t] = x; psy[t] = y; psz[t] = z; sqs[t] = x*x + y*y + z*z;
  }
  __syncthreads();
  int i_l = qg*64 + q_l;
  float xi0 = psx[i_l], xi1 = psy[i_l], xi2 = psz[i_l];
  float sqi = sqs[i_l];
  REP20(KDECLD)
  int cbase = half*512;
  for (int u = 0; u < 128; u++){
    int jj = cbase + 4*u + slot;
    float dot = xi0*psx[jj] + xi1*psy[jj] + xi2*psz[jj];
    float d = sqi + sqs[jj] - 2.0f*dot;
    INS_MM(packkey(d, jj));
  }
  __syncthreads();                    // scan arrays dead from here (union!)
  if (slot == 1){ REP20(KPUB_A) }
  if (slot == 3){ REP20(KPUB_B) }
  __syncthreads();
  if ((slot & 1) == 0){
    const u64* src = (slot == 0) ? &mrgA[q_l*21] : &mrgB[q_l*21];
    for (int p = 0; p < KNN; p++){
      double kv = __longlong_as_double((long long)src[p]);
      if (kv > rk19) break;          // sorted source: rest are worse
      INS_MM(kv);
    }
  }
  __syncthreads();
  if (slot == 2){ REP20(KPUB_B) }
  __syncthreads();
  if (slot == 0){
    const u64* src = &mrgB[q_l*21];
    for (int p = 0; p < KNN; p++){
      double kv = __longlong_as_double((long long)src[p]);
      if (kv > rk19) break;
      INS_MM(kv);
    }
    int gi = bb*1024 + i_l;
    u64* gpart = part + ((size_t)gi*2 + half)*KNN;
    REP20(KSTG)
  }
}

// ---------------- merge two sorted 20-entry half-lists per query ----------------
__global__ __launch_bounds__(256) void k_mrg(const u64* part, int* out){
  int gi = blockIdx.x*256 + threadIdx.x;    // grid 128 -> 32768 queries
  const u64* pa = part + (size_t)gi*2*KNN;
  REP20(KLDAD)                               // init from half-0 list (sorted)
  for (int p = 0; p < KNN; p++){
    double kv = __longlong_as_double((long long)pa[KNN + p]);
    if (kv > rk19) break;                    // sorted source: rest are worse
    INS_MM(kv);
  }
  int* optr = out + gi*KNN;
  REP20(KOUTU)
}

// ---------------- BN1 stats ----------------
__global__ __launch_bounds__(256) void k_stats1(const float* a1, const float* c1,
                                                const int* idx1, double* stats){
  __shared__ float rs[256], rs2[256];
  int tid = threadIdx.x, c = tid & 63, slot = tid >> 6;
  int base = blockIdx.x * 1024;
  float s = 0.f, s2 = 0.f;
  for (int t = 0; t < 256; t++){
    unsigned e = (unsigned)(base + t*4 + slot);
    int i = (int)(e / 20u);
    int b = i >> 10;
    int j = idx1[e];
    float h = a1[i*64+c] + c1[((b<<10)+j)*64 + c];
    s += h; s2 += h*h;
  }
  rs[tid] = s; rs2[tid] = s2;
  __syncthreads();
  if (slot == 0){
    double ts  = (double)rs[c]  + (double)rs[64+c]  + (double)rs[128+c]  + (double)rs[192+c];
    double ts2 = (double)rs2[c] + (double)rs2[64+c] + (double)rs2[128+c] + (double)rs2[192+c];
    atomicAdd(&stats[c], ts);
    atomicAdd(&stats[64+c], ts2);
  }
}

// ================= MFMA edge-MLP =================
// Geometry: block = 8 nodes; node padded 20->32 edge rows; 16 M-tiles of 16;
// 4 waves x 4 tiles. fp32 accuracy via hi/lo bf16 split (3-term). b2 cancels
// in BN2 (stats of raw P); b3 added after the max.

// ---------------- BN2 stats over P = H1 @ W2 (raw, no b2) ----------------
__global__ __launch_bounds__(256) void k_stats2m(const float* a1, const float* c1,
    const int* idx1, const float* inb, double* stats){
  __shared__ __align__(16) float W2s[4096];
  __shared__ float sc1s[64], sh1s[64];
  __shared__ float rs[4][64], rs2[4][64];
  int tid = threadIdx.x;
  const float* wbuf = inb + IN_WBUF;
  for (int t = tid; t < 4096; t += 256) W2s[t] = wbuf[WB_W2 + t];
  if (tid < 64){
    int c = tid;
    const double M = (double)NEDGE;
    double m1 = stats[c]/M;
    double v1 = stats[64+c]/M - m1*m1;
    double r1 = 1.0/sqrt(v1 + 1e-5);
    double g1 = (double)inb[IN_G1 + c];
    sc1s[c] = (float)(g1*r1);
    sh1s[c] = (float)((double)inb[IN_BE1 + c] - m1*g1*r1);
  }
  __syncthreads();
  int lane = tid & 63, wv = tid >> 6;
  int c16 = lane & 15, ag = lane >> 4, kb0 = ag*8;
  bf16x8 w2h[4][2], w2l[4][2];
  #pragma unroll
  for (int nt = 0; nt < 4; nt++){
    #pragma unroll
    for (int ks = 0; ks < 2; ks++){
      bf16x8 h8, l8;
      #pragma unroll
      for (int e = 0; e < 8; e++){
        unsigned short hh, ll;
        bfsplit(W2s[(ks*32 + kb0 + e)*64 + nt*16 + c16], hh, ll);
        h8[e] = (short)hh; l8[e] = (short)ll;
      }
      w2h[nt][ks] = h8; w2l[nt][ks] = l8;
    }
  }
  float sa[4] = {0,0,0,0}, qa[4] = {0,0,0,0};
  for (int t4 = 0; t4 < 4; t4++){
    int T = t4*4 + wv;
    int node_l = T >> 1, half = T & 1;
    int nodeg = blockIdx.x*8 + node_l;
    int krow = half*16 + c16;
    int rr = (krow < 20);
    int j = idx1[nodeg*20 + (rr ? krow : 0)];
    int gj = ((nodeg >> 10) << 10) + j;
    const float* ar = a1 + (size_t)nodeg*64;
    const float* cr = c1 + (size_t)gj*64;
    f32x4 av0 = *(const f32x4*)(ar + kb0);
    f32x4 av1 = *(const f32x4*)(ar + kb0 + 4);
    f32x4 av2 = *(const f32x4*)(ar + 32 + kb0);
    f32x4 av3 = *(const f32x4*)(ar + 36 + kb0);
    f32x4 cv0 = *(const f32x4*)(cr + kb0);
    f32x4 cv1 = *(const f32x4*)(cr + kb0 + 4);
    f32x4 cv2 = *(const f32x4*)(cr + 32 + kb0);
    f32x4 cv3 = *(const f32x4*)(cr + 36 + kb0);
    bf16x8 a0h, a0l, a1h_, a1l_;
    #pragma unroll
    for (int e = 0; e < 4; e++){
      unsigned short hh, ll;
      float h;
      h = rr ? fmaxf((av0[e]+cv0[e])*sc1s[kb0+e] + sh1s[kb0+e], 0.f) : 0.f;
      bfsplit(h, hh, ll); a0h[e] = (short)hh; a0l[e] = (short)ll;
      h = rr ? fmaxf((av1[e]+cv1[e])*sc1s[kb0+4+e] + sh1s[kb0+4+e], 0.f) : 0.f;
      bfsplit(h, hh, ll); a0h[4+e] = (short)hh; a0l[4+e] = (short)ll;
      h = rr ? fmaxf((av2[e]+cv2[e])*sc1s[32+kb0+e] + sh1s[32+kb0+e], 0.f) : 0.f;
      bfsplit(h, hh, ll); a1h_[e] = (short)hh; a1l_[e] = (short)ll;
      h = rr ? fmaxf((av3[e]+cv3[e])*sc1s[36+kb0+e] + sh1s[36+kb0+e], 0.f) : 0.f;
      bfsplit(h, hh, ll); a1h_[4+e] = (short)hh; a1l_[4+e] = (short)ll;
    }
    #pragma unroll
    for (int nt = 0; nt < 4; nt++){
      f32x4 acc = {0.f, 0.f, 0.f, 0.f};
      acc = __builtin_amdgcn_mfma_f32_16x16x32_bf16(a0h,  w2h[nt][0], acc, 0, 0, 0);
      acc = __builtin_amdgcn_mfma_f32_16x16x32_bf16(a1h_, w2h[nt][1], acc, 0, 0, 0);
      acc = __builtin_amdgcn_mfma_f32_16x16x32_bf16(a0h,  w2l[nt][0], acc, 0, 0, 0);
      acc = __builtin_amdgcn_mfma_f32_16x16x32_bf16(a1h_, w2l[nt][1], acc, 0, 0, 0);
      acc = __builtin_amdgcn_mfma_f32_16x16x32_bf16(a0l,  w2h[nt][0], acc, 0, 0, 0);
      acc = __builtin_amdgcn_mfma_f32_16x16x32_bf16(a1l_, w2h[nt][1], acc, 0, 0, 0);
      #pragma unroll
      for (int r = 0; r < 4; r++){
        int kr = half*16 + 4*ag + r;        // D row m=(lane>>4)*4+r -> edge slot
        float v = (kr < 20) ? acc[r] : 0.f;
        sa[nt] += v; qa[nt] += v*v;
      }
    }
  }
  #pragma unroll
  for (int nt = 0; nt < 4; nt++){
    sa[nt] += __shfl_xor(sa[nt], 16); sa[nt] += __shfl_xor(sa[nt], 32);
    qa[nt] += __shfl_xor(qa[nt], 16); qa[nt] += __shfl_xor(qa[nt], 32);
  }
  if (ag == 0){
    #pragma unroll
    for (int nt = 0; nt < 4; nt++){
      rs[wv][nt*16+c16] = sa[nt];
      rs2[wv][nt*16+c16] = qa[nt];
    }
  }
  __syncthreads();
  if (tid < 64){
    double ts = (double)rs[0][tid] + (double)rs[1][tid]
              + (double)rs[2][tid] + (double)rs[3][tid];
    double tq = (double)rs2[0][tid] + (double)rs2[1][tid]
              + (double)rs2[2][tid] + (double)rs2[3][tid];
    atomicAdd(&stats[128+tid], ts);
    atomicAdd(&stats[192+tid], tq);
  }
}

// ---------------- full MLP1 via MFMA + max over k -> x1 ----------------
// Round-9 lesson: holding all 32 weight fragments in registers (128 VGPRs)
// spilled ~240B/thread to scratch (258MB of WRITE_SIZE). Weight fragments now
// live in LDS in exact fragment order [(nt*2+ks)*512 + lane*8]; each MFMA's
// B-operand is one conflict-free ds_read_b128 right before use.
__global__ __launch_bounds__(256, 2) void k_x1m(const float* a1, const float* c1,
    const int* idx1, const float* inb, const double* stats, float* x1){
  __shared__ __align__(16) unsigned short W2hF[4096], W2lF[4096];   // 8KB each
  __shared__ __align__(16) unsigned short W3hF[4096], W3lF[4096];
  __shared__ __align__(16) float scr[4][16*68];     // per-wave H2 relayout scratch
  __shared__ unsigned int mxp[4][8][64];            // per-wave node maxes (mono32)
  __shared__ float sc1s[64], sh1s[64], sc2s[64], sh2s[64];
  int tid = threadIdx.x;
  const float* wbuf = inb + IN_WBUF;
  // fill split weight fragments: t = nt*1024 + ks*512 + lane*8 + e
  for (int t = tid; t < 4096; t += 256){
    int nt = t >> 10, ks = (t >> 9) & 1, ln = (t >> 3) & 63, e = t & 7;
    int row = ks*32 + (ln >> 4)*8 + e;
    int col = nt*16 + (ln & 15);
    unsigned short hh, ll;
    bfsplit(wbuf[WB_W2 + row*64 + col], hh, ll);
    W2hF[t] = hh; W2lF[t] = ll;
    bfsplit(wbuf[WB_W3 + row*64 + col], hh, ll);
    W3hF[t] = hh; W3lF[t] = ll;
  }
  {
    unsigned int* mf = &mxp[0][0][0];
    for (int t = tid; t < 2048; t += 256) mf[t] = 0u;
  }
  if (tid < 64){
    int c = tid;
    const double M = (double)NEDGE;
    double m1 = stats[c]/M;
    double v1 = stats[64+c]/M - m1*m1;
    double r1 = 1.0/sqrt(v1 + 1e-5);
    double g1 = (double)inb[IN_G1 + c];
    sc1s[c] = (float)(g1*r1);
    sh1s[c] = (float)((double)inb[IN_BE1 + c] - m1*g1*r1);
    double mp = stats[128+c]/M;                  // mean of raw P (b2 cancels in BN)
    double v2 = stats[192+c]/M - mp*mp;
    double r2 = 1.0/sqrt(v2 + 1e-5);
    double g2 = (double)inb[IN_G2 + c];
    sc2s[c] = (float)(g2*r2);
    sh2s[c] = (float)((double)inb[IN_BE2 + c] - mp*g2*r2);
  }
  __syncthreads();
  int lane = tid & 63, wv = tid >> 6;
  int c16 = lane & 15, ag = lane >> 4, kb0 = ag*8;
  float scn[4], shn[4];
  #pragma unroll
  for (int nt = 0; nt < 4; nt++){
    scn[nt] = sc2s[nt*16 + c16];
    shn[nt] = sh2s[nt*16 + c16];
  }
  float* sw = &scr[wv][0];
  for (int t4 = 0; t4 < 4; t4++){
    int T = t4*4 + wv;
    int node_l = T >> 1, half = T & 1;
    int nodeg = blockIdx.x*8 + node_l;
    int krow = half*16 + c16;
    int rr = (krow < 20);
    int j = idx1[nodeg*20 + (rr ? krow : 0)];
    int gj = ((nodeg >> 10) << 10) + j;
    const float* ar = a1 + (size_t)nodeg*64;
    const float* cr = c1 + (size_t)gj*64;
    f32x4 av0 = *(const f32x4*)(ar + kb0);
    f32x4 av1 = *(const f32x4*)(ar + kb0 + 4);
    f32x4 av2 = *(const f32x4*)(ar + 32 + kb0);
    f32x4 av3 = *(const f32x4*)(ar + 36 + kb0);
    f32x4 cv0 = *(const f32x4*)(cr + kb0);
    f32x4 cv1 = *(const f32x4*)(cr + kb0 + 4);
    f32x4 cv2 = *(const f32x4*)(cr + 32 + kb0);
    f32x4 cv3 = *(const f32x4*)(cr + 36 + kb0);
    bf16x8 a0h, a0l, a1h_, a1l_;
    #pragma unroll
    for (int e = 0; e < 4; e++){
      unsigned short hh, ll;
      float h;
      h = rr ? fmaxf((av0[e]+cv0[e])*sc1s[kb0+e] + sh1s[kb0+e], 0.f) : 0.f;
      bfsplit(h, hh, ll); a0h[e] = (short)hh; a0l[e] = (short)ll;
      h = rr ? fmaxf((av1[e]+cv1[e])*sc1s[kb0+4+e] + sh1s[kb0+4+e], 0.f) : 0.f;
      bfsplit(h, hh, ll); a0h[4+e] = (short)hh; a0l[4+e] = (short)ll;
      h = rr ? fmaxf((av2[e]+cv2[e])*sc1s[32+kb0+e] + sh1s[32+kb0+e], 0.f) : 0.f;
      bfsplit(h, hh, ll); a1h_[e] = (short)hh; a1l_[e] = (short)ll;
      h = rr ? fmaxf((av3[e]+cv3[e])*sc1s[36+kb0+e] + sh1s[36+kb0+e], 0.f) : 0.f;
      bfsplit(h, hh, ll); a1h_[4+e] = (short)hh; a1l_[4+e] = (short)ll;
    }
    // ---- GEMM1: P = H1 @ W2 (B-fragments streamed from LDS) ----
    f32x4 pacc[4];
    #pragma unroll
    for (int nt = 0; nt < 4; nt++){
      bf16x8 wh0 = *(const bf16x8*)(W2hF + (nt*2+0)*512 + lane*8);
      bf16x8 wh1 = *(const bf16x8*)(W2hF + (nt*2+1)*512 + lane*8);
      bf16x8 wl0 = *(const bf16x8*)(W2lF + (nt*2+0)*512 + lane*8);
      bf16x8 wl1 = *(const bf16x8*)(W2lF + (nt*2+1)*512 + lane*8);
      f32x4 acc = {0.f, 0.f, 0.f, 0.f};
      acc = __builtin_amdgcn_mfma_f32_16x16x32_bf16(a0h,  wh0, acc, 0, 0, 0);
      acc = __builtin_amdgcn_mfma_f32_16x16x32_bf16(a1h_, wh1, acc, 0, 0, 0);
      acc = __builtin_amdgcn_mfma_f32_16x16x32_bf16(a0h,  wl0, acc, 0, 0, 0);
      acc = __builtin_amdgcn_mfma_f32_16x16x32_bf16(a1h_, wl1, acc, 0, 0, 0);
      acc = __builtin_amdgcn_mfma_f32_16x16x32_bf16(a0l,  wh0, acc, 0, 0, 0);
      acc = __builtin_amdgcn_mfma_f32_16x16x32_bf16(a1l_, wh1, acc, 0, 0, 0);
      pacc[nt] = acc;
    }
    // ---- BN2 + relu, relayout D->A via per-wave LDS scratch ----
    #pragma unroll
    for (int nt = 0; nt < 4; nt++){
      #pragma unroll
      for (int r = 0; r < 4; r++){
        float v = fmaxf(pacc[nt][r]*scn[nt] + shn[nt], 0.f);
        sw[(4*ag + r)*68 + nt*16 + c16] = v;
      }
    }
    f32x4 h20 = *(const f32x4*)(sw + c16*68 + kb0);
    f32x4 h21 = *(const f32x4*)(sw + c16*68 + kb0 + 4);
    f32x4 h22 = *(const f32x4*)(sw + c16*68 + 32 + kb0);
    f32x4 h23 = *(const f32x4*)(sw + c16*68 + 36 + kb0);
    bf16x8 b0h, b0l, b1h, b1l;
    #pragma unroll
    for (int e = 0; e < 4; e++){
      unsigned short hh, ll;
      bfsplit(h20[e], hh, ll); b0h[e] = (short)hh; b0l[e] = (short)ll;
      bfsplit(h21[e], hh, ll); b0h[4+e] = (short)hh; b0l[4+e] = (short)ll;
      bfsplit(h22[e], hh, ll); b1h[e] = (short)hh; b1l[e] = (short)ll;
      bfsplit(h23[e], hh, ll); b1h[4+e] = (short)hh; b1l[4+e] = (short)ll;
    }
    // ---- GEMM2: Q = H2 @ W3 (B-fragments streamed from LDS), masked max ----
    #pragma unroll
    for (int nt = 0; nt < 4; nt++){
      bf16x8 wh0 = *(const bf16x8*)(W3hF + (nt*2+0)*512 + lane*8);
      bf16x8 wh1 = *(const bf16x8*)(W3hF + (nt*2+1)*512 + lane*8);
      bf16x8 wl0 = *(const bf16x8*)(W3lF + (nt*2+0)*512 + lane*8);
      bf16x8 wl1 = *(const bf16x8*)(W3lF + (nt*2+1)*512 + lane*8);
      f32x4 acc = {0.f, 0.f, 0.f, 0.f};
      acc = __builtin_amdgcn_mfma_f32_16x16x32_bf16(b0h, wh0, acc, 0, 0, 0);
      acc = __builtin_amdgcn_mfma_f32_16x16x32_bf16(b1h, wh1, acc, 0, 0, 0);
      acc = __builtin_amdgcn_mfma_f32_16x16x32_bf16(b0h, wl0, acc, 0, 0, 0);
      acc = __builtin_amdgcn_mfma_f32_16x16x32_bf16(b1h, wl1, acc, 0, 0, 0);
      acc = __builtin_amdgcn_mfma_f32_16x16x32_bf16(b0l, wh0, acc, 0, 0, 0);
      acc = __builtin_amdgcn_mfma_f32_16x16x32_bf16(b1l, wh1, acc, 0, 0, 0);
      float vmx = -FLT_MAX;
      #pragma unroll
      for (int r = 0; r < 4; r++){
        int kr = half*16 + 4*ag + r;
        vmx = (kr < 20) ? fmaxf(vmx, acc[r]) : vmx;
      }
      vmx = fmaxf(vmx, __shfl_xor(vmx, 16));
      vmx = fmaxf(vmx, __shfl_xor(vmx, 32));
      if (ag == 0){
        unsigned int u = mono32(vmx);
        unsigned int* sl = &mxp[wv][node_l][nt*16 + c16];
        if (u > *sl) *sl = u;
      }
    }
  }
  __syncthreads();
  for (int s = tid; s < 512; s += 256){
    int nl = s >> 6, c = s & 63;
    unsigned int u = mxp[0][nl][c];
    unsigned int u1 = mxp[1][nl][c]; u = (u1 > u) ? u1 : u;
    unsigned int u2 = mxp[2][nl][c]; u = (u2 > u) ? u2 : u;
    unsigned int u3 = mxp[3][nl][c]; u = (u3 > u) ? u3 : u;
    unsigned int bts = (u & 0x80000000u) ? (u ^ 0x80000000u) : ~u;
    x1[(size_t)(blockIdx.x*8 + nl)*64 + c] = __uint_as_float(bts) + inb[IN_B3 + c];
  }
}

// ---------------- kNN in 64-d feature space: MFMA distance tiles + f64-key top-k ----------------
__global__ __launch_bounds__(256, 4) void k_knn2(const float* x1, u64* part){
  __shared__ __align__(16) char sm2[35584];
  unsigned short* Ch = (unsigned short*)sm2;            // [64][72] bf16-hi 9216B
  unsigned short* Cl = (unsigned short*)(sm2 + 9216);   // [64][72] bf16-lo 9216B
  float* Dd  = (float*)(sm2 + 18432);                   // [64*65] dist tile 16640B
  float* sqc = (float*)(sm2 + 35072);                   // [64]
  float* sqq = (float*)(sm2 + 35328);                   // [64]
  u64* mrgA = (u64*)sm2;                                // overlay (post-scan)
  u64* mrgB = (u64*)(sm2 + 10752);
  int bb   = blockIdx.x >> 5;
  int qg   = (blockIdx.x >> 1) & 15;
  int half = blockIdx.x & 1;
  int tid = threadIdx.x;
  int q_l = tid & 63;
  int wv = tid >> 6;                 // wave index == selection slot
  int lane = tid & 63;
  int c16 = lane & 15, ag = lane >> 4, kb0 = ag*8;
  int qbase = bb*1024 + qg*64;
  // A-fragments: wave wv owns query rows wv*16..+16; lane row = c16
  bf16x8 qh0, qh1, ql0, ql1;
  {
    const float* qr = x1 + (size_t)(qbase + wv*16 + c16)*64;
    f32x4 v0 = *(const f32x4*)(qr + kb0);
    f32x4 v1 = *(const f32x4*)(qr + kb0 + 4);
    f32x4 v2 = *(const f32x4*)(qr + 32 + kb0);
    f32x4 v3 = *(const f32x4*)(qr + 36 + kb0);
    #pragma unroll
    for (int e = 0; e < 4; e++){
      unsigned short hh, ll;
      bfsplit(v0[e], hh, ll); qh0[e] = (short)hh; ql0[e] = (short)ll;
      bfsplit(v1[e], hh, ll); qh0[4+e] = (short)hh; ql0[4+e] = (short)ll;
      bfsplit(v2[e], hh, ll); qh1[e] = (short)hh; ql1[e] = (short)ll;
      bfsplit(v3[e], hh, ll); qh1[4+e] = (short)hh; ql1[4+e] = (short)ll;
    }
  }
  if (tid < 64){
    const float* xr = x1 + (size_t)(qbase + tid)*64;
    float s = 0.f;
    #pragma unroll
    for (int d4 = 0; d4 < 16; d4++){
      f32x4 v = *(const f32x4*)(xr + d4*4);
      s += v[0]*v[0] + v[1]*v[1] + v[2]*v[2] + v[3]*v[3];
    }
    sqq[tid] = s;
  }
  REP20(KDECLD)
  for (int ch = 0; ch < 8; ch++){
    int c0 = half*512 + ch*64;
    __syncthreads();                 // prev D consumed (and sqq ready on ch=0)
    // stage C chunk pre-split: 2048 float-pairs / 256 threads
    for (int pp = tid; pp < 2048; pp += 256){
      int row = pp >> 5, cp = pp & 31;
      const float* src = x1 + (size_t)(bb*1024 + c0 + row)*64 + cp*2;
      float v0 = src[0], v1 = src[1];
      unsigned short h0, l0, h1, l1;
      bfsplit(v0, h0, l0); bfsplit(v1, h1, l1);
      ((unsigned int*)Ch)[row*36 + cp] = (unsigned int)h0 | ((unsigned int)h1 << 16);
      ((unsigned int*)Cl)[row*36 + cp] = (unsigned int)l0 | ((unsigned int)l1 << 16);
    }
    __syncthreads();
    if (tid < 64){                   // sqc from exact split reconstruction
      float s = 0.f;
      for (int dw = 0; dw < 32; dw++){
        unsigned int hw = ((unsigned int*)Ch)[tid*36 + dw];
        unsigned int lw = ((unsigned int*)Cl)[tid*36 + dw];
        float a0 = __uint_as_float(hw << 16) + __uint_as_float(lw << 16);
        float a1 = __uint_as_float(hw & 0xFFFF0000u) + __uint_as_float(lw & 0xFFFF0000u);
        s += a0*a0 + a1*a1;
      }
      sqc[tid] = s;
    }
    __syncthreads();
    // MFMA phase: wave wv computes D rows [wv*16, wv*16+16) x 64 cands
    #pragma unroll
    for (int nt = 0; nt < 4; nt++){
      bf16x8 bh0 = *(const bf16x8*)(Ch + (nt*16 + c16)*72 + kb0);
      bf16x8 bh1 = *(const bf16x8*)(Ch + (nt*16 + c16)*72 + 32 + kb0);
      bf16x8 bl0 = *(const bf16x8*)(Cl + (nt*16 + c16)*72 + kb0);
      bf16x8 bl1 = *(const bf16x8*)(Cl + (nt*16 + c16)*72 + 32 + kb0);
      f32x4 p0 = {0.f,0.f,0.f,0.f}, p1 = {0.f,0.f,0.f,0.f}, p2 = {0.f,0.f,0.f,0.f};
      p0 = __builtin_amdgcn_mfma_f32_16x16x32_bf16(qh0, bh0, p0, 0, 0, 0);
      p0 = __builtin_amdgcn_mfma_f32_16x16x32_bf16(qh1, bh1, p0, 0, 0, 0);
      p1 = __builtin_amdgcn_mfma_f32_16x16x32_bf16(qh0, bl0, p1, 0, 0, 0);
      p1 = __builtin_amdgcn_mfma_f32_16x16x32_bf16(qh1, bl1, p1, 0, 0, 0);
      p2 = __builtin_amdgcn_mfma_f32_16x16x32_bf16(ql0, bh0, p2, 0, 0, 0);
      p2 = __builtin_amdgcn_mfma_f32_16x16x32_bf16(ql1, bh1, p2, 0, 0, 0);
      #pragma unroll
      for (int r = 0; r < 4; r++){
        int qrow = wv*16 + 4*ag + r;
        float d = sqq[qrow] + sqc[nt*16 + c16] - 2.0f*(p0[r] + p1[r] + p2[r]);
        Dd[qrow*65 + nt*16 + c16] = d;
      }
    }
    __syncthreads();
    // selection: lane = query q_l, wave = candidate slot (c = 4u+wv)
    for (int u = 0; u < 16; u += 2){
      int cA = 4*u + wv, cB = 4*(u+1) + wv;
      float dA = Dd[q_l*65 + cA];
      float dB = Dd[q_l*65 + cB];
      INS_MM(packkey(dA, c0 + cA));
      INS_MM(packkey(dB, c0 + cB));
    }
  }
  __syncthreads();                   // scan arrays dead from here (union!)
  if (wv == 1){ REP20(KPUB_A) }
  if (wv == 3){ REP20(KPUB_B) }
  __syncthreads();
  if ((wv & 1) == 0){
    const u64* src = (wv == 0) ? &mrgA[q_l*21] : &mrgB[q_l*21];
    for (int p = 0; p < KNN; p++){
      double kv = __longlong_as_double((long long)src[p]);
      if (kv > rk19) break;
      INS_MM(kv);
    }
  }
  __syncthreads();
  if (wv == 2){ REP20(KPUB_B) }
  __syncthreads();
  if (wv == 0){
    const u64* src = &mrgB[q_l*21];
    for (int p = 0; p < KNN; p++){
      double kv = __longlong_as_double((long long)src[p]);
      if (kv > rk19) break;
      INS_MM(kv);
    }
    int gi = qbase + q_l;
    u64* gpart = part + ((size_t)gi*2 + half)*KNN;
    REP20(KSTG)
  }
}

// ---------------- fast path: B2H = x1 @ Wbot[:, q-half] ----------------
__global__ __launch_bounds__(256) void k_B2h(const float* x1, const float* inb,
                                             int q, float* B2H){
  __shared__ __align__(16) float Wbh[4096];
  __shared__ __align__(16) float xsh[1024];
  int tid = threadIdx.x;
  const float* Wb = inb + IN_WBUF + WB_WBOT;
  for (int t = tid; t < 4096; t += 256){
    int r = t >> 6, cl = t & 63;
    Wbh[t] = Wb[r*128 + q*64 + cl];
  }
  int node0 = blockIdx.x * 16;
  for (int t = tid; t < 1024; t += 256) xsh[t] = x1[node0*64 + t];
  __syncthreads();
  int n_l = tid >> 4, cg = tid & 15;
  const float* xr = xsh + n_l*64;
  float4 acc = make_float4(0.f,0.f,0.f,0.f);
  #pragma unroll 8
  for (int d = 0; d < 64; d++){
    float v = xr[d];
    float4 w = *(const float4*)(Wbh + d*64 + cg*4);
    acc.x += v*w.x; acc.y += v*w.y; acc.z += v*w.z; acc.w += v*w.w;
  }
  *(float4*)(B2H + (node0 + n_l)*64 + cg*4) = acc;
}

// ---------------- fast path: x2 half = (x1_i@Wd + bc2) + max_j B2H[j] ----------------
__global__ __launch_bounds__(256) void k_x2h(const float* x1, const float* B2H,
                                             const float* inb, const int* idx2,
                                             int q, float* x2){
  __shared__ __align__(16) float Wdh[4096];
  __shared__ __align__(16) float xsh[256];
  int tid = threadIdx.x;
  const float* Wd = inb + IN_WBUF + WB_WD;
  for (int t = tid; t < 4096; t += 256){
    int r = t >> 6, cl = t & 63;
    Wdh[t] = Wd[r*128 + q*64 + cl];
  }
  int node0 = blockIdx.x * 4;
  xsh[tid] = x1[node0*64 + tid];
  __syncthreads();
  int n_l = tid >> 6, cl = tid & 63;
  int i = node0 + n_l;
  int b = i >> 10;
  const float* xr = xsh + n_l*64;
  float acc = inb[IN_BC2 + q*64 + cl];
  #pragma unroll 8
  for (int d = 0; d < 64; d++) acc += xr[d]*Wdh[d*64 + cl];
  float m = -FLT_MAX;
  for (int kk = 0; kk < KNN; kk++){
    int j = idx2[i*KNN + kk];
    m = fmaxf(m, B2H[((b<<10)+j)*64 + cl]);
  }
  x2[i*128 + q*64 + cl] = acc + m;
}

// ---------------- slow fallback: x2 direct, LDS-staged, no B2H buffer ----------------
__global__ __launch_bounds__(256) void k_x2d(const float* x1, const float* inb,
                                             const int* idx2, float* x2){
  __shared__ __align__(16) float Wdh[4096], Wbh[4096];
  __shared__ __align__(16) float xis[1024], xjs[1024];
  int tid = threadIdx.x;
  int q = blockIdx.x & 1;
  int node0 = (blockIdx.x >> 1) * 16;
  const float* Wd = inb + IN_WBUF + WB_WD;
  const float* Wb = inb + IN_WBUF + WB_WBOT;
  for (int t = tid; t < 4096; t += 256){
    int r = t >> 6, cl = t & 63;
    Wdh[t] = Wd[r*128 + q*64 + cl];
    Wbh[t] = Wb[r*128 + q*64 + cl];
  }
  for (int t = tid; t < 1024; t += 256) xis[t] = x1[node0*64 + t];
  __syncthreads();
  int n_l = tid >> 4, cg = tid & 15;
  int i = node0 + n_l, b = i >> 10;
  const float* xr = xis + n_l*64;
  float4 af = make_float4(inb[IN_BC2 + q*64 + cg*4],   inb[IN_BC2 + q*64 + cg*4+1],
                          inb[IN_BC2 + q*64 + cg*4+2], inb[IN_BC2 + q*64 + cg*4+3]);
  #pragma unroll 8
  for (int d = 0; d < 64; d++){
    float v = xr[d];
    float4 w = *(const float4*)(Wdh + d*64 + cg*4);
    af.x += v*w.x; af.y += v*w.y; af.z += v*w.z; af.w += v*w.w;
  }
  float4 mx = make_float4(-FLT_MAX,-FLT_MAX,-FLT_MAX,-FLT_MAX);
  for (int kk = 0; kk < KNN; kk++){
    __syncthreads();
    for (int t = tid; t < 1024; t += 256){
      int nn = t >> 6, r = t & 63;
      int jj = idx2[(node0+nn)*KNN + kk];
      xjs[t] = x1[((((node0+nn) >> 10) << 10) + jj)*64 + r];
    }
    __syncthreads();
    const float* xj = xjs + n_l*64;
    float4 acc = make_float4(0.f,0.f,0.f,0.f);
    #pragma unroll 8
    for (int d = 0; d < 64; d++){
      float v = xj[d];
      float4 w = *(const float4*)(Wbh + d*64 + cg*4);
      acc.x += v*w.x; acc.y += v*w.y; acc.z += v*w.z; acc.w += v*w.w;
    }
    mx.x = fmaxf(mx.x, acc.x); mx.y = fmaxf(mx.y, acc.y);
    mx.z = fmaxf(mx.z, acc.z); mx.w = fmaxf(mx.w, acc.w);
  }
  *(float4*)(x2 + i*128 + q*64 + cg*4) =
      make_float4(af.x+mx.x, af.y+mx.y, af.z+mx.z, af.w+mx.w);
}

// ---------------- lin (192->1024) via MFMA + max over node-quarter ----------------
__global__ __launch_bounds__(512, 2) void k_linpoolm(const float* x1, const float* x2,
    const float* inb, float* pool4){
  __shared__ __align__(16) float F[16*196];         // 12544B
  int tid = threadIdx.x;
  int b = blockIdx.x >> 4, cq = (blockIdx.x >> 2) & 3, nh = blockIdx.x & 3;
  int lane = tid & 63, wv = tid >> 6;
  int c16 = lane & 15, ag = lane >> 4;
  const float* Wl = inb + IN_WBUF + WB_WL;
  // B-fragments once per block
  bf16x8 w_h[2][6], w_l[2][6];
  #pragma unroll
  for (int nt = 0; nt < 2; nt++){
    int col = cq*256 + (wv*2+nt)*16 + c16;
    #pragma unroll
    for (int ks = 0; ks < 6; ks++){
      bf16x8 h8, l8;
      #pragma unroll
      for (int e = 0; e < 8; e++){
        unsigned short hh, ll;
        bfsplit(Wl[(ks*32 + ag*8 + e)*1024 + col], hh, ll);
        h8[e] = (short)hh; l8[e] = (short)ll;
      }
      w_h[nt][ks] = h8; w_l[nt][ks] = l8;
    }
  }
  float rmax[2] = {-FLT_MAX, -FLT_MAX};
  int n0 = b*1024 + nh*256;
  for (int chk = 0; chk < 16; chk++){
    int nb = n0 + chk*16;
    __syncthreads();
    {
      int row = tid >> 5;
      int d0 = (tid & 31)*6;
      #pragma unroll
      for (int u = 0; u < 6; u++){
        int d = d0 + u;
        F[row*196 + d] = (d < 64) ? x1[(size_t)(nb+row)*64 + d]
                                  : x2[(size_t)(nb+row)*128 + d - 64];
      }
    }
    __syncthreads();
    // A-fragments: row = c16 (node), k = ks*32 + ag*8 + e
    bf16x8 a_h[6], a_l[6];
    #pragma unroll
    for (int ks = 0; ks < 6; ks++){
      f32x4 v0 = *(const f32x4*)(F + c16*196 + ks*32 + ag*8);
      f32x4 v1 = *(const f32x4*)(F + c16*196 + ks*32 + ag*8 + 4);
      bf16x8 h8, l8;
      #pragma unroll
      for (int e = 0; e < 4; e++){
        unsigned short hh, ll;
        bfsplit(v0[e], hh, ll); h8[e] = (short)hh; l8[e] = (short)ll;
        bfsplit(v1[e], hh, ll); h8[4+e] = (short)hh; l8[4+e] = (short)ll;
      }
      a_h[ks] = h8; a_l[ks] = l8;
    }
    #pragma unroll
    for (int nt = 0; nt < 2; nt++){
      f32x4 p0 = {0.f,0.f,0.f,0.f}, p1 = {0.f,0.f,0.f,0.f}, p2 = {0.f,0.f,0.f,0.f};
      #pragma unroll
      for (int ks = 0; ks < 6; ks++){
        p0 = __builtin_amdgcn_mfma_f32_16x16x32_bf16(a_h[ks], w_h[nt][ks], p0, 0, 0, 0);
        p1 = __builtin_amdgcn_mfma_f32_16x16x32_bf16(a_h[ks], w_l[nt][ks], p1, 0, 0, 0);
        p2 = __builtin_amdgcn_mfma_f32_16x16x32_bf16(a_l[ks], w_h[nt][ks], p2, 0, 0, 0);
      }
      float m = -FLT_MAX;
      #pragma unroll
      for (int r = 0; r < 4; r++) m = fmaxf(m, p0[r] + p1[r] + p2[r]);
      m = fmaxf(m, __shfl_xor(m, 16));
      m = fmaxf(m, __shfl_xor(m, 32));
      rmax[nt] = fmaxf(rmax[nt], m);
    }
  }
  if (ag == 0){
    #pragma unroll
    for (int nt = 0; nt < 2; nt++)
      pool4[nh*32768 + b*1024 + cq*256 + (wv*2+nt)*16 + c16] = rmax[nt];
  }
}

// ================= head MLP, wave-per-column =================
__global__ __launch_bounds__(256) void k_h1(const float* pool4, const float* inb,
                                            float* s1g){
  __shared__ float pl[1024];
  int b = blockIdx.x >> 4, cg = blockIdx.x & 15;
  int tid = threadIdx.x;
  for (int t = tid; t < 1024; t += 256){
    float m = fmaxf(fmaxf(pool4[b*1024 + t],         pool4[32768 + b*1024 + t]),
                    fmaxf(pool4[65536 + b*1024 + t], pool4[98304 + b*1024 + t]));
    pl[t] = m + inb[IN_BL + t];
  }
  __syncthreads();
  int wv = tid >> 6, lane = tid & 63;
  f32x4 p0 = *(const f32x4*)(pl + lane*16);
  f32x4 p1 = *(const f32x4*)(pl + lane*16 + 4);
  f32x4 p2 = *(const f32x4*)(pl + lane*16 + 8);
  f32x4 p3 = *(const f32x4*)(pl + lane*16 + 12);
  const float* WT = inb + IN_WBUF + WB_WM1;    // [512][1024] transposed
  #pragma unroll
  for (int cc = 0; cc < 8; cc++){
    int c = cg*32 + wv*8 + cc;
    const float* wr = WT + (size_t)c*1024 + lane*16;
    f32x4 w0 = *(const f32x4*)(wr);
    f32x4 w1 = *(const f32x4*)(wr + 4);
    f32x4 w2 = *(const f32x4*)(wr + 8);
    f32x4 w3 = *(const f32x4*)(wr + 12);
    float acc = w0[0]*p0[0] + w0[1]*p0[1] + w0[2]*p0[2] + w0[3]*p0[3]
              + w1[0]*p1[0] + w1[1]*p1[1] + w1[2]*p1[2] + w1[3]*p1[3]
              + w2[0]*p2[0] + w2[1]*p2[1] + w2[2]*p2[2] + w2[3]*p2[3]
              + w3[0]*p3[0] + w3[1]*p3[1] + w3[2]*p3[2] + w3[3]*p3[3];
    acc += __shfl_xor(acc, 1);  acc += __shfl_xor(acc, 2);
    acc += __shfl_xor(acc, 4);  acc += __shfl_xor(acc, 8);
    acc += __shfl_xor(acc, 16); acc += __shfl_xor(acc, 32);
    if (lane == 0) s1g[b*512 + c] = fmaxf(acc + inb[IN_BM1 + c], 0.f);
  }
}

// k_h2: grid 256 = (b, cg of 32 cols of 256). K=512, lane slice 8.
__global__ __launch_bounds__(256) void k_h2(const float* s1g, const float* inb,
                                            float* s2g){
  __shared__ float s1[512];
  int b = blockIdx.x >> 3, cg = blockIdx.x & 7;
  int tid = threadIdx.x;
  for (int t = tid; t < 512; t += 256) s1[t] = s1g[b*512 + t];
  __syncthreads();
  int wv = tid >> 6, lane = tid & 63;
  f32x4 p0 = *(const f32x4*)(s1 + lane*8);
  f32x4 p1 = *(const f32x4*)(s1 + lane*8 + 4);
  const float* WT = inb + IN_WBUF + WB_WM2;    // [256][512] transposed
  #pragma unroll
  for (int cc = 0; cc < 8; cc++){
    int c = cg*32 + wv*8 + cc;
    const float* wr = WT + (size_t)c*512 + lane*8;
    f32x4 w0 = *(const f32x4*)(wr);
    f32x4 w1 = *(const f32x4*)(wr + 4);
    float acc = w0[0]*p0[0] + w0[1]*p0[1] + w0[2]*p0[2] + w0[3]*p0[3]
              + w1[0]*p1[0] + w1[1]*p1[1] + w1[2]*p1[2] + w1[3]*p1[3];
    acc += __shfl_xor(acc, 1);  acc += __shfl_xor(acc, 2);
    acc += __shfl_xor(acc, 4);  acc += __shfl_xor(acc, 8);
    acc += __shfl_xor(acc, 16); acc += __shfl_xor(acc, 32);
    if (lane == 0) s2g[b*256 + c] = fmaxf(acc + inb[IN_BM2 + c], 0.f);
  }
}

// k_h3: grid 32 (per batch). 40 cols, K=256, lane slice 4.
__global__ __launch_bounds__(256) void k_h3(const float* s2g, const float* inb,
                                            float* out){
  __shared__ float s2[256];
  int b = blockIdx.x;
  int tid = threadIdx.x;
  s2[tid] = s2g[b*256 + tid];
  __syncthreads();
  int wv = tid >> 6, lane = tid & 63;
  f32x4 p0 = *(const f32x4*)(s2 + lane*4);
  const float* WT = inb + IN_WBUF + WB_WM3;    // [40][256] transposed
  for (int cc = 0; cc < 10; cc++){
    int c = wv*10 + cc;
    const float* wr = WT + (size_t)c*256 + lane*4;
    f32x4 w0 = *(const f32x4*)(wr);
    float acc = w0[0]*p0[0] + w0[1]*p0[1] + w0[2]*p0[2] + w0[3]*p0[3];
    acc += __shfl_xor(acc, 1);  acc += __shfl_xor(acc, 2);
    acc += __shfl_xor(acc, 4);  acc += __shfl_xor(acc, 8);
    acc += __shfl_xor(acc, 16); acc += __shfl_xor(acc, 32);
    if (lane == 0) out[b*40 + c] = acc + inb[IN_BM3 + c];
  }
}

extern "C" void kernel_launch(void* const* d_in, const int* in_sizes, int n_in,
                              void* d_out, int out_size, void* d_ws, size_t ws_size,
                              hipStream_t stream){
  float* ws     = (float*)d_ws;
  double* stats = (double*)d_ws;
  int*   flag   = (int*)d_ws + OFF_FLAG;
  float* inb    = ws + OFF_INB;
  int*   idx    = (int*)d_ws + OFF_IDX;     // idx1 early, idx2 late
  float* x1p    = ws + OFF_X1;
  float* x2p    = ws + OFF_X2;
  float* a1     = ws + OFF_X2;              // a1/c1 alias x2 region (dead before x2 written)
  float* c1     = ws + OFF_C1;
  u64*   part   = (u64*)(ws + OFF_X2);      // kNN partials alias a1/c1 (see layout note)
  float* pool4  = ws + OFF_POOL;
  float* B2H    = ws + OFF_B2H;
  float* s1g    = ws + OFF_IDX;             // head acts alias idx (idx2 dead after x2)
  float* s2g    = ws + OFF_IDX + 16384;
  bool fast = ws_size >= (size_t)FAST_END * 4u;

  hipMemsetAsync(stats, 0, 256*sizeof(double), stream);
  k_sniff<<<1, 64, 0, stream>>>(d_in[0], flag);
  k_cvt<<<3859, 256, 0, stream>>>(
      d_in[0], d_in[1], d_in[2], d_in[3], d_in[4], d_in[5], d_in[6], d_in[7],
      d_in[8], d_in[9], d_in[10], d_in[11], d_in[12], d_in[13], d_in[14],
      d_in[15], d_in[16], d_in[17], d_in[18], d_in[19], d_in[20], flag, inb);
  k_knn1<<<1024, 256, 0, stream>>>(inb, part);      // partials in a1/c1 region
  k_mrg<<<128, 256, 0, stream>>>(part, idx);        // -> idx1
  k_prep1<<<8192, 256, 0, stream>>>(inb, a1, c1);   // overwrites dead partials
  k_stats1<<<640, 256, 0, stream>>>(a1, c1, idx, stats);
  k_stats2m<<<4096, 256, 0, stream>>>(a1, c1, idx, inb, stats);
  k_x1m<<<4096, 256, 0, stream>>>(a1, c1, idx, inb, stats, x1p);
  k_knn2<<<1024, 256, 0, stream>>>(x1p, part);      // a1/c1 dead after k_x1m
  k_mrg<<<128, 256, 0, stream>>>(part, idx);        // -> idx2
  if (fast){
    k_B2h<<<2048, 256, 0, stream>>>(x1p, inb, 0, B2H);
    k_x2h<<<8192, 256, 0, stream>>>(x1p, B2H, inb, idx, 0, x2p);
    k_B2h<<<2048, 256, 0, stream>>>(x1p, inb, 1, B2H);
    k_x2h<<<8192, 256, 0, stream>>>(x1p, B2H, inb, idx, 1, x2p);
  } else {
    k_x2d<<<4096, 256, 0, stream>>>(x1p, inb, idx, x2p);
  }
  k_linpoolm<<<512, 512, 0, stream>>>(x1p, x2p, inb, pool4);
  k_h1<<<512, 256, 0, stream>>>(pool4, inb, s1g);   // idx2 dead here
  k_h2<<<256, 256, 0, stream>>>(s1g, inb, s2g);
  k_h3<<<32, 256, 0, stream>>>(s2g, inb, (float*)d_out);
}

// Round 11
// 762.841 us; speedup vs baseline: 5.7942x; 1.0761x over previous
//
#include <hip/hip_runtime.h>
#include <hip/hip_bf16.h>
#include <float.h>
#include <math.h>

typedef __hip_bfloat16 bf16;
typedef unsigned long long u64;

#define BATCH 32
#define NPTS  1024
#define KNN   20
#define NB    (BATCH*NPTS)      // 32768 nodes
#define NEDGE (NB*KNN)          // 655360 edges

// ---- workspace layout (float units), ws_size-adaptive ----
#define OFF_FLAG 512u
#define OFF_INB  1024u
#define OFF_IDX  988928u          // 655360 ints (idx1 early, idx2 late; s1/s2 after x2)
#define OFF_X1   1644288u         // NB*64
#define OFF_X2   3741440u         // NB*128 ; a1 @ OFF_X2, c1 @ OFF_C1 (early)
#define OFF_C1   5838592u
#define OFF_POOL 7935744u         // pool4: 4 x 32*1024
#define SLOW_END 8066816u         // 32.3 MB
#define OFF_B2H  8066816u         // NB*64 (fast path only)
#define FAST_END 10163968u        // 40.7 MB
// kNN partial lists (u64) alias OFF_X2 (dead there at both kNN points).
// Head activations s1[32*512], s2[32*256] alias OFF_IDX (idx2 dead after x2).
// ---- layout inside inb (canonical fp32 inputs) ----
#define IN_POSF 0u
#define IN_B1   98304u
#define IN_G1   98368u
#define IN_BE1  98432u
#define IN_B2   98496u
#define IN_G2   98560u
#define IN_BE2  98624u
#define IN_B3   98688u
#define IN_BC2  98752u
#define IN_BL   98880u
#define IN_BM1  99904u
#define IN_BM2  100416u
#define IN_BM3  100672u
#define IN_W1   100736u
#define IN_WBUF 101120u
#define WB_W2   0u
#define WB_W3   4096u
#define WB_WD   8192u            // Wc2 top-bot diff [64x128]
#define WB_WBOT 16384u           // Wc2 bottom      [64x128]
#define WB_WL   24576u
#define WB_WM1  221184u          // stored TRANSPOSED [512][1024] (head wave-dots)
#define WB_WM2  745472u          // stored TRANSPOSED [256][512]
#define WB_WM3  876544u          // stored TRANSPOSED [40][256]
#define IN_TOTAL 987904u

__device__ __forceinline__ float bf2f(bf16 v){ return __bfloat162float(v); }

// monotone float->u32 map: preserves IEEE-754 total order for all finite values
__device__ __forceinline__ unsigned int mono32(float f){
  unsigned int b = __float_as_uint(f);
  return b ^ ((unsigned int)((int)b >> 31) | 0x80000000u);
}

// ======== MFMA machinery (bf16 hi/lo split, fp32-accurate) ========
typedef __attribute__((ext_vector_type(8))) short bf16x8;
typedef __attribute__((ext_vector_type(4))) float f32x4;

__device__ __forceinline__ unsigned short bfhi(float f){
  unsigned int u = __float_as_uint(f);
  u += 0x7FFFu + ((u >> 16) & 1u);      // RNE to bf16
  return (unsigned short)(u >> 16);
}
__device__ __forceinline__ void bfsplit(float f, unsigned short& h, unsigned short& l){
  h = bfhi(f);
  float fh = __uint_as_float(((unsigned int)h) << 16);
  l = bfhi(f - fh);
}

// ======== exact top-k via f64-packed keys + min/max sorted-insert ========
#define REP20(M) M(0) M(1) M(2) M(3) M(4) M(5) M(6) M(7) M(8) M(9) \
                 M(10) M(11) M(12) M(13) M(14) M(15) M(16) M(17) M(18) M(19)
#define SH19(M) M(19,18) M(18,17) M(17,16) M(16,15) M(15,14) M(14,13) M(13,12) \
                M(12,11) M(11,10) M(10,9) M(9,8) M(8,7) M(7,6) M(6,5) M(5,4) \
                M(4,3) M(3,2) M(2,1) M(1,0)

__device__ __forceinline__ double packkey(float d, int idx){
  unsigned int b = __float_as_uint(fmaxf(d, 0.0f));
  u64 k = 0x4000000000000000ULL | ((u64)b << 20) | (unsigned int)idx;
  return __longlong_as_double((long long)k);
}

#define KDECLD(p) double rk##p = DBL_MAX;
#define KMM(p,pm) rk##p = fmin(rk##p, fmax(rk##pm, _k));
#define INS_MM(kv) do{ double _k=(kv); SH19(KMM) rk0 = fmin(rk0, _k); }while(0)

#define KPUB_A(p) mrgA[q_l*21+p] = (u64)__double_as_longlong(rk##p);
#define KPUB_B(p) mrgB[q_l*21+p] = (u64)__double_as_longlong(rk##p);
#define KSTG(p)   gpart[p] = (u64)__double_as_longlong(rk##p);
#define KLDAD(p)  double rk##p = __longlong_as_double((long long)pa[p]);
#define KOUTU(p)  optr[p] = (int)((u64)__double_as_longlong(rk##p) & 1023ULL);

// ---------------- dtype sniff (fp32 vs bf16 inputs) ----------------
__global__ void k_sniff(const void* pos_raw, int* flag){
  if (blockIdx.x == 0 && threadIdx.x == 0){
    const unsigned short* h = (const unsigned short*)pos_raw;
    int wild = 0;
    for (int k = 0; k < 16; k++){
      unsigned int bits = ((unsigned int)h[2*k]) << 16;
      float v = __uint_as_float(bits);
      float a = fabsf(v);
      if (a != 0.0f && (v != v || a > 1e10f || a < 1e-10f)) wild++;
    }
    *flag = (wild >= 4) ? 1 : 0;
  }
}

__device__ __forceinline__ float rdv(const void* p, int i, int f){
  return f ? ((const float*)p)[i] : bf2f(((const bf16*)p)[i]);
}

// ---------------- normalize ALL inputs to canonical fp32 buffer ----------------
__global__ __launch_bounds__(256) void k_cvt(
    const void* pos, const void* W1, const void* b1, const void* g1, const void* be1,
    const void* W2, const void* b2, const void* g2, const void* be2,
    const void* W3, const void* b3, const void* Wc2, const void* bc2,
    const void* Wl, const void* bl, const void* Wm1, const void* bm1,
    const void* Wm2, const void* bm2, const void* Wm3, const void* bm3,
    const int* flag, float* inb){
  int id = blockIdx.x*256 + threadIdx.x;
  if (id >= (int)IN_TOTAL) return;
  int f = *flag;
  float v;
  if      (id < 98304)  v = rdv(pos, id, f);
  else if (id < 98368)  v = rdv(b1,  id-98304, f);
  else if (id < 98432)  v = rdv(g1,  id-98368, f);
  else if (id < 98496)  v = rdv(be1, id-98432, f);
  else if (id < 98560)  v = rdv(b2,  id-98496, f);
  else if (id < 98624)  v = rdv(g2,  id-98560, f);
  else if (id < 98688)  v = rdv(be2, id-98624, f);
  else if (id < 98752)  v = rdv(b3,  id-98688, f);
  else if (id < 98880)  v = rdv(bc2, id-98752, f);
  else if (id < 99904)  v = rdv(bl,  id-98880, f);
  else if (id < 100416) v = rdv(bm1, id-99904, f);
  else if (id < 100672) v = rdv(bm2, id-100416, f);
  else if (id < 100712) v = rdv(bm3, id-100672, f);
  else if (id < 100736) v = 0.0f;
  else if (id < 101120) v = rdv(W1,  id-100736, f);
  else {
    int t = id - 101120;
    if      (t < 4096)   v = rdv(W2, t, f);
    else if (t < 8192)   v = rdv(W3, t-4096, f);
    else if (t < 16384){ int u = t-8192;  v = rdv(Wc2, u, f) - rdv(Wc2, 8192+u, f); }
    else if (t < 24576){ int u = t-16384; v = rdv(Wc2, 8192+u, f); }
    else if (t < 221184) v = rdv(Wl,  t-24576, f);
    else if (t < 745472){ int u = t-221184; int c = u>>10, d = u&1023; v = rdv(Wm1, d*512+c, f); }
    else if (t < 876544){ int u = t-745472; int c = u>>9,  d = u&511;  v = rdv(Wm2, d*256+c, f); }
    else               { int u = t-876544; int c = u>>8,  d = u&255;  v = rdv(Wm3, d*40+c, f); }
  }
  inb[id] = v;
}

// ---------------- a1/c1: affine decomposition of EdgeConv1 layer1 ----------------
__global__ __launch_bounds__(256) void k_prep1(const float* inb, float* a1, float* c1){
  const float* posf = inb + IN_POSF;
  const float* W1f  = inb + IN_W1;
  const float* b1f  = inb + IN_B1;
  int id = blockIdx.x*256 + threadIdx.x;
  int bn = id >> 6, c = id & 63;
  float p0 = posf[bn*3], p1 = posf[bn*3+1], p2 = posf[bn*3+2];
  float wt0 = W1f[c],     wt1 = W1f[64+c],  wt2 = W1f[128+c];
  float wb0 = W1f[192+c], wb1 = W1f[256+c], wb2 = W1f[320+c];
  float cv = p0*wb0 + p1*wb1 + p2*wb2;
  float av = p0*(wt0-wb0) + p1*(wt1-wb1) + p2*(wt2-wb2) + b1f[c];
  a1[id] = av;  c1[id] = cv;
}

// ---------------- kNN in coordinate space (half-split, LDS-union, f64-key top-k) ----------------
__global__ __launch_bounds__(256, 2) void k_knn1(const float* inb, u64* part){
  const float* posf = inb + IN_POSF;
  __shared__ __align__(16) char sm1[21504];
  float* psx = (float*)sm1;
  float* psy = psx + 1024;
  float* psz = psy + 1024;
  float* sqs = psz + 1024;
  u64* mrgA = (u64*)sm1;              // overlay (post-scan only)
  u64* mrgB = (u64*)(sm1 + 10752);
  int bb   = blockIdx.x >> 5;
  int qg   = (blockIdx.x >> 1) & 15;
  int half = blockIdx.x & 1;
  int tid = threadIdx.x;
  int q_l = tid & 63;
  int slot = tid >> 6;
  for (int t = tid; t < 1024; t += 256){
    float x = posf[(bb*1024+t)*3], y = posf[(bb*1024+t)*3+1], z = posf[(bb*1024+t)*3+2];
    psx[t] = x; psy[t] = y; psz[t] = z; sqs[t] = x*x + y*y + z*z;
  }
  __syncthreads();
  int i_l = qg*64 + q_l;
  float xi0 = psx[i_l], xi1 = psy[i_l], xi2 = psz[i_l];
  float sqi = sqs[i_l];
  REP20(KDECLD)
  int cbase = half*512;
  for (int u = 0; u < 128; u++){
    int jj = cbase + 4*u + slot;
    float dot = xi0*psx[jj] + xi1*psy[jj] + xi2*psz[jj];
    float d = sqi + sqs[jj] - 2.0f*dot;
    INS_MM(packkey(d, jj));
  }
  __syncthreads();                    // scan arrays dead from here (union!)
  if (slot == 1){ REP20(KPUB_A) }
  if (slot == 3){ REP20(KPUB_B) }
  __syncthreads();
  if ((slot & 1) == 0){
    const u64* src = (slot == 0) ? &mrgA[q_l*21] : &mrgB[q_l*21];
    for (int p = 0; p < KNN; p++){
      double kv = __longlong_as_double((long long)src[p]);
      if (kv > rk19) break;          // sorted source: rest are worse
      INS_MM(kv);
    }
  }
  __syncthreads();
  if (slot == 2){ REP20(KPUB_B) }
  __syncthreads();
  if (slot == 0){
    const u64* src = &mrgB[q_l*21];
    for (int p = 0; p < KNN; p++){
      double kv = __longlong_as_double((long long)src[p]);
      if (kv > rk19) break;
      INS_MM(kv);
    }
    int gi = bb*1024 + i_l;
    u64* gpart = part + ((size_t)gi*2 + half)*KNN;
    REP20(KSTG)
  }
}

// ---------------- merge two sorted 20-entry half-lists per query ----------------
__global__ __launch_bounds__(256) void k_mrg(const u64* part, int* out){
  int gi = blockIdx.x*256 + threadIdx.x;    // grid 128 -> 32768 queries
  const u64* pa = part + (size_t)gi*2*KNN;
  REP20(KLDAD)                               // init from half-0 list (sorted)
  for (int p = 0; p < KNN; p++){
    double kv = __longlong_as_double((long long)pa[KNN + p]);
    if (kv > rk19) break;                    // sorted source: rest are worse
    INS_MM(kv);
  }
  int* optr = out + gi*KNN;
  REP20(KOUTU)
}

// ---------------- BN1 stats ----------------
__global__ __launch_bounds__(256) void k_stats1(const float* a1, const float* c1,
                                                const int* idx1, double* stats){
  __shared__ float rs[256], rs2[256];
  int tid = threadIdx.x, c = tid & 63, slot = tid >> 6;
  int base = blockIdx.x * 1024;
  float s = 0.f, s2 = 0.f;
  for (int t = 0; t < 256; t++){
    unsigned e = (unsigned)(base + t*4 + slot);
    int i = (int)(e / 20u);
    int b = i >> 10;
    int j = idx1[e];
    float h = a1[i*64+c] + c1[((b<<10)+j)*64 + c];
    s += h; s2 += h*h;
  }
  rs[tid] = s; rs2[tid] = s2;
  __syncthreads();
  if (slot == 0){
    double ts  = (double)rs[c]  + (double)rs[64+c]  + (double)rs[128+c]  + (double)rs[192+c];
    double ts2 = (double)rs2[c] + (double)rs2[64+c] + (double)rs2[128+c] + (double)rs2[192+c];
    atomicAdd(&stats[c], ts);
    atomicAdd(&stats[64+c], ts2);
  }
}

// ================= MFMA edge-MLP (round-11: packed edges, zero padding) =================
// Block = 8 nodes = 160 edges = EXACTLY 10 M-tiles of 16 (was 16 tiles with
// 20->32 row padding: 37.5% wasted A-builds/MFMAs). Tile T covers block-local
// edges 16T..16T+15; idx1 reads are fully coalesced (idx1[blk*160+row]);
// node = row/20 via magic-mul. A tile spans <=2 nodes with a wave-uniform
// boundary -> max-epilogue splits per-lane maxes into A/B sides, shfl-combines,
// and LDS-atomicMax (mono32) into per-node slots. Waves process tiles
// T = round*4 + wv (3 rounds; T>=10 skipped -> slight tail imbalance).
// fp32 accuracy via hi/lo bf16 split (3-term). b2 cancels in BN2; b3 after max.

// ---------------- BN2 stats over P = H1 @ W2 (raw, no b2) ----------------
__global__ __launch_bounds__(256) void k_stats2m(const float* a1, const float* c1,
    const int* idx1, const float* inb, double* stats){
  __shared__ __align__(16) unsigned short W2hF[4096], W2lF[4096];
  __shared__ float sc1s[64], sh1s[64];
  __shared__ float rs[4][64], rs2[4][64];
  int tid = threadIdx.x;
  const float* wbuf = inb + IN_WBUF;
  for (int t = tid; t < 4096; t += 256){
    int nt = t >> 10, ks = (t >> 9) & 1, ln = (t >> 3) & 63, e = t & 7;
    int row = ks*32 + (ln >> 4)*8 + e;
    int col = nt*16 + (ln & 15);
    unsigned short hh, ll;
    bfsplit(wbuf[WB_W2 + row*64 + col], hh, ll);
    W2hF[t] = hh; W2lF[t] = ll;
  }
  if (tid < 64){
    int c = tid;
    const double M = (double)NEDGE;
    double m1 = stats[c]/M;
    double v1 = stats[64+c]/M - m1*m1;
    double r1 = 1.0/sqrt(v1 + 1e-5);
    double g1 = (double)inb[IN_G1 + c];
    sc1s[c] = (float)(g1*r1);
    sh1s[c] = (float)((double)inb[IN_BE1 + c] - m1*g1*r1);
  }
  __syncthreads();
  int lane = tid & 63, wv = tid >> 6;
  int c16 = lane & 15, ag = lane >> 4, kb0 = ag*8;
  float sa[4] = {0,0,0,0}, qa[4] = {0,0,0,0};
  for (int rd = 0; rd < 3; rd++){
    int T = rd*4 + wv;
    if (T < 10){
      int krow = 16*T + c16;                       // block-local edge 0..159
      int node = (krow*52429) >> 20;               // krow/20
      int nodeg = blockIdx.x*8 + node;
      int j = idx1[blockIdx.x*160 + krow];         // coalesced
      int gj = ((nodeg >> 10) << 10) + j;
      const float* ar = a1 + (size_t)nodeg*64;
      const float* cr = c1 + (size_t)gj*64;
      f32x4 av0 = *(const f32x4*)(ar + kb0);
      f32x4 av1 = *(const f32x4*)(ar + kb0 + 4);
      f32x4 av2 = *(const f32x4*)(ar + 32 + kb0);
      f32x4 av3 = *(const f32x4*)(ar + 36 + kb0);
      f32x4 cv0 = *(const f32x4*)(cr + kb0);
      f32x4 cv1 = *(const f32x4*)(cr + kb0 + 4);
      f32x4 cv2 = *(const f32x4*)(cr + 32 + kb0);
      f32x4 cv3 = *(const f32x4*)(cr + 36 + kb0);
      bf16x8 a0h, a0l, a1h_, a1l_;
      #pragma unroll
      for (int e = 0; e < 4; e++){
        unsigned short hh, ll;
        float h;
        h = fmaxf((av0[e]+cv0[e])*sc1s[kb0+e] + sh1s[kb0+e], 0.f);
        bfsplit(h, hh, ll); a0h[e] = (short)hh; a0l[e] = (short)ll;
        h = fmaxf((av1[e]+cv1[e])*sc1s[kb0+4+e] + sh1s[kb0+4+e], 0.f);
        bfsplit(h, hh, ll); a0h[4+e] = (short)hh; a0l[4+e] = (short)ll;
        h = fmaxf((av2[e]+cv2[e])*sc1s[32+kb0+e] + sh1s[32+kb0+e], 0.f);
        bfsplit(h, hh, ll); a1h_[e] = (short)hh; a1l_[e] = (short)ll;
        h = fmaxf((av3[e]+cv3[e])*sc1s[36+kb0+e] + sh1s[36+kb0+e], 0.f);
        bfsplit(h, hh, ll); a1h_[4+e] = (short)hh; a1l_[4+e] = (short)ll;
      }
      #pragma unroll
      for (int nt = 0; nt < 4; nt++){
        bf16x8 wh0 = *(const bf16x8*)(W2hF + (nt*2+0)*512 + lane*8);
        bf16x8 wh1 = *(const bf16x8*)(W2hF + (nt*2+1)*512 + lane*8);
        bf16x8 wl0 = *(const bf16x8*)(W2lF + (nt*2+0)*512 + lane*8);
        bf16x8 wl1 = *(const bf16x8*)(W2lF + (nt*2+1)*512 + lane*8);
        f32x4 acc = {0.f, 0.f, 0.f, 0.f};
        acc = __builtin_amdgcn_mfma_f32_16x16x32_bf16(a0h,  wh0, acc, 0, 0, 0);
        acc = __builtin_amdgcn_mfma_f32_16x16x32_bf16(a1h_, wh1, acc, 0, 0, 0);
        acc = __builtin_amdgcn_mfma_f32_16x16x32_bf16(a0h,  wl0, acc, 0, 0, 0);
        acc = __builtin_amdgcn_mfma_f32_16x16x32_bf16(a1h_, wl1, acc, 0, 0, 0);
        acc = __builtin_amdgcn_mfma_f32_16x16x32_bf16(a0l,  wh0, acc, 0, 0, 0);
        acc = __builtin_amdgcn_mfma_f32_16x16x32_bf16(a1l_, wh1, acc, 0, 0, 0);
        #pragma unroll
        for (int r = 0; r < 4; r++){
          float v = acc[r];                        // all rows real (no padding)
          sa[nt] += v; qa[nt] += v*v;
        }
      }
    }
  }
  #pragma unroll
  for (int nt = 0; nt < 4; nt++){
    sa[nt] += __shfl_xor(sa[nt], 16); sa[nt] += __shfl_xor(sa[nt], 32);
    qa[nt] += __shfl_xor(qa[nt], 16); qa[nt] += __shfl_xor(qa[nt], 32);
  }
  if (ag == 0){
    #pragma unroll
    for (int nt = 0; nt < 4; nt++){
      rs[wv][nt*16+c16] = sa[nt];
      rs2[wv][nt*16+c16] = qa[nt];
    }
  }
  __syncthreads();
  if (tid < 64){
    double ts = (double)rs[0][tid] + (double)rs[1][tid]
              + (double)rs[2][tid] + (double)rs[3][tid];
    double tq = (double)rs2[0][tid] + (double)rs2[1][tid]
              + (double)rs2[2][tid] + (double)rs2[3][tid];
    atomicAdd(&stats[128+tid], ts);
    atomicAdd(&stats[192+tid], tq);
  }
}

// ---------------- full MLP1 via MFMA + max over k -> x1 (packed edges) ----------------
__global__ __launch_bounds__(256, 2) void k_x1m(const float* a1, const float* c1,
    const int* idx1, const float* inb, const double* stats, float* x1){
  __shared__ __align__(16) unsigned short W2hF[4096], W2lF[4096];   // 8KB each
  __shared__ __align__(16) unsigned short W3hF[4096], W3lF[4096];
  __shared__ __align__(16) float scr[4][16*68];     // per-wave H2 relayout scratch
  __shared__ unsigned int mxp2[8][64];              // per-node channel maxes (mono32)
  __shared__ float sc1s[64], sh1s[64], sc2s[64], sh2s[64];
  int tid = threadIdx.x;
  const float* wbuf = inb + IN_WBUF;
  for (int t = tid; t < 4096; t += 256){
    int nt = t >> 10, ks = (t >> 9) & 1, ln = (t >> 3) & 63, e = t & 7;
    int row = ks*32 + (ln >> 4)*8 + e;
    int col = nt*16 + (ln & 15);
    unsigned short hh, ll;
    bfsplit(wbuf[WB_W2 + row*64 + col], hh, ll);
    W2hF[t] = hh; W2lF[t] = ll;
    bfsplit(wbuf[WB_W3 + row*64 + col], hh, ll);
    W3hF[t] = hh; W3lF[t] = ll;
  }
  for (int t = tid; t < 512; t += 256) ((unsigned int*)mxp2)[t] = 0u;
  if (tid < 64){
    int c = tid;
    const double M = (double)NEDGE;
    double m1 = stats[c]/M;
    double v1 = stats[64+c]/M - m1*m1;
    double r1 = 1.0/sqrt(v1 + 1e-5);
    double g1 = (double)inb[IN_G1 + c];
    sc1s[c] = (float)(g1*r1);
    sh1s[c] = (float)((double)inb[IN_BE1 + c] - m1*g1*r1);
    double mp = stats[128+c]/M;                  // mean of raw P (b2 cancels in BN)
    double v2 = stats[192+c]/M - mp*mp;
    double r2 = 1.0/sqrt(v2 + 1e-5);
    double g2 = (double)inb[IN_G2 + c];
    sc2s[c] = (float)(g2*r2);
    sh2s[c] = (float)((double)inb[IN_BE2 + c] - mp*g2*r2);
  }
  __syncthreads();
  int lane = tid & 63, wv = tid >> 6;
  int c16 = lane & 15, ag = lane >> 4, kb0 = ag*8;
  float scn[4], shn[4];
  #pragma unroll
  for (int nt = 0; nt < 4; nt++){
    scn[nt] = sc2s[nt*16 + c16];
    shn[nt] = sh2s[nt*16 + c16];
  }
  float* sw = &scr[wv][0];
  for (int rd = 0; rd < 3; rd++){
    int T = rd*4 + wv;
    if (T < 10){
      int krow = 16*T + c16;                       // block-local edge 0..159
      int node = (krow*52429) >> 20;               // krow/20
      int nodeg = blockIdx.x*8 + node;
      int j = idx1[blockIdx.x*160 + krow];         // coalesced
      int gj = ((nodeg >> 10) << 10) + j;
      const float* ar = a1 + (size_t)nodeg*64;
      const float* cr = c1 + (size_t)gj*64;
      f32x4 av0 = *(const f32x4*)(ar + kb0);
      f32x4 av1 = *(const f32x4*)(ar + kb0 + 4);
      f32x4 av2 = *(const f32x4*)(ar + 32 + kb0);
      f32x4 av3 = *(const f32x4*)(ar + 36 + kb0);
      f32x4 cv0 = *(const f32x4*)(cr + kb0);
      f32x4 cv1 = *(const f32x4*)(cr + kb0 + 4);
      f32x4 cv2 = *(const f32x4*)(cr + 32 + kb0);
      f32x4 cv3 = *(const f32x4*)(cr + 36 + kb0);
      bf16x8 a0h, a0l, a1h_, a1l_;
      #pragma unroll
      for (int e = 0; e < 4; e++){
        unsigned short hh, ll;
        float h;
        h = fmaxf((av0[e]+cv0[e])*sc1s[kb0+e] + sh1s[kb0+e], 0.f);
        bfsplit(h, hh, ll); a0h[e] = (short)hh; a0l[e] = (short)ll;
        h = fmaxf((av1[e]+cv1[e])*sc1s[kb0+4+e] + sh1s[kb0+4+e], 0.f);
        bfsplit(h, hh, ll); a0h[4+e] = (short)hh; a0l[4+e] = (short)ll;
        h = fmaxf((av2[e]+cv2[e])*sc1s[32+kb0+e] + sh1s[32+kb0+e], 0.f);
        bfsplit(h, hh, ll); a1h_[e] = (short)hh; a1l_[e] = (short)ll;
        h = fmaxf((av3[e]+cv3[e])*sc1s[36+kb0+e] + sh1s[36+kb0+e], 0.f);
        bfsplit(h, hh, ll); a1h_[4+e] = (short)hh; a1l_[4+e] = (short)ll;
      }
      // ---- GEMM1: P = H1 @ W2 (B-fragments streamed from LDS) ----
      f32x4 pacc[4];
      #pragma unroll
      for (int nt = 0; nt < 4; nt++){
        bf16x8 wh0 = *(const bf16x8*)(W2hF + (nt*2+0)*512 + lane*8);
        bf16x8 wh1 = *(const bf16x8*)(W2hF + (nt*2+1)*512 + lane*8);
        bf16x8 wl0 = *(const bf16x8*)(W2lF + (nt*2+0)*512 + lane*8);
        bf16x8 wl1 = *(const bf16x8*)(W2lF + (nt*2+1)*512 + lane*8);
        f32x4 acc = {0.f, 0.f, 0.f, 0.f};
        acc = __builtin_amdgcn_mfma_f32_16x16x32_bf16(a0h,  wh0, acc, 0, 0, 0);
        acc = __builtin_amdgcn_mfma_f32_16x16x32_bf16(a1h_, wh1, acc, 0, 0, 0);
        acc = __builtin_amdgcn_mfma_f32_16x16x32_bf16(a0h,  wl0, acc, 0, 0, 0);
        acc = __builtin_amdgcn_mfma_f32_16x16x32_bf16(a1h_, wl1, acc, 0, 0, 0);
        acc = __builtin_amdgcn_mfma_f32_16x16x32_bf16(a0l,  wh0, acc, 0, 0, 0);
        acc = __builtin_amdgcn_mfma_f32_16x16x32_bf16(a1l_, wh1, acc, 0, 0, 0);
        pacc[nt] = acc;
      }
      // ---- BN2 + relu, relayout D->A via per-wave LDS scratch ----
      #pragma unroll
      for (int nt = 0; nt < 4; nt++){
        #pragma unroll
        for (int r = 0; r < 4; r++){
          float v = fmaxf(pacc[nt][r]*scn[nt] + shn[nt], 0.f);
          sw[(4*ag + r)*68 + nt*16 + c16] = v;
        }
      }
      f32x4 h20 = *(const f32x4*)(sw + c16*68 + kb0);
      f32x4 h21 = *(const f32x4*)(sw + c16*68 + kb0 + 4);
      f32x4 h22 = *(const f32x4*)(sw + c16*68 + 32 + kb0);
      f32x4 h23 = *(const f32x4*)(sw + c16*68 + 36 + kb0);
      bf16x8 b0h, b0l, b1h, b1l;
      #pragma unroll
      for (int e = 0; e < 4; e++){
        unsigned short hh, ll;
        bfsplit(h20[e], hh, ll); b0h[e] = (short)hh; b0l[e] = (short)ll;
        bfsplit(h21[e], hh, ll); b0h[4+e] = (short)hh; b0l[4+e] = (short)ll;
        bfsplit(h22[e], hh, ll); b1h[e] = (short)hh; b1l[e] = (short)ll;
        bfsplit(h23[e], hh, ll); b1h[4+e] = (short)hh; b1l[4+e] = (short)ll;
      }
      // ---- GEMM2 + boundary-split masked max into per-node LDS slots ----
      int rowA = 16*T;
      int nA = (rowA*52429) >> 20;                 // first node of tile (local)
      int bnd = nA*20 + 20 - rowA;                 // rows < bnd -> node nA
      int hasB = (bnd < 16);
      #pragma unroll
      for (int nt = 0; nt < 4; nt++){
        bf16x8 wh0 = *(const bf16x8*)(W3hF + (nt*2+0)*512 + lane*8);
        bf16x8 wh1 = *(const bf16x8*)(W3hF + (nt*2+1)*512 + lane*8);
        bf16x8 wl0 = *(const bf16x8*)(W3lF + (nt*2+0)*512 + lane*8);
        bf16x8 wl1 = *(const bf16x8*)(W3lF + (nt*2+1)*512 + lane*8);
        f32x4 acc = {0.f, 0.f, 0.f, 0.f};
        acc = __builtin_amdgcn_mfma_f32_16x16x32_bf16(b0h, wh0, acc, 0, 0, 0);
        acc = __builtin_amdgcn_mfma_f32_16x16x32_bf16(b1h, wh1, acc, 0, 0, 0);
        acc = __builtin_amdgcn_mfma_f32_16x16x32_bf16(b0h, wl0, acc, 0, 0, 0);
        acc = __builtin_amdgcn_mfma_f32_16x16x32_bf16(b1h, wl1, acc, 0, 0, 0);
        acc = __builtin_amdgcn_mfma_f32_16x16x32_bf16(b0l, wh0, acc, 0, 0, 0);
        acc = __builtin_amdgcn_mfma_f32_16x16x32_bf16(b1l, wh1, acc, 0, 0, 0);
        float mA = -FLT_MAX, mB = -FLT_MAX;
        #pragma unroll
        for (int r = 0; r < 4; r++){
          int rw = 4*ag + r;
          float v = acc[r];
          bool inA = (rw < bnd);
          mA = inA ? fmaxf(mA, v) : mA;
          mB = inA ? mB : fmaxf(mB, v);
        }
        mA = fmaxf(mA, __shfl_xor(mA, 16));
        mA = fmaxf(mA, __shfl_xor(mA, 32));
        mB = fmaxf(mB, __shfl_xor(mB, 16));
        mB = fmaxf(mB, __shfl_xor(mB, 32));
        if (ag == 0){
          atomicMax(&mxp2[nA][nt*16 + c16], mono32(mA));
          if (hasB) atomicMax(&mxp2[nA+1][nt*16 + c16], mono32(mB));
        }
      }
    }
  }
  __syncthreads();
  for (int s = tid; s < 512; s += 256){
    int nl = s >> 6, c = s & 63;
    unsigned int u = mxp2[nl][c];
    unsigned int bts = (u & 0x80000000u) ? (u ^ 0x80000000u) : ~u;
    x1[(size_t)(blockIdx.x*8 + nl)*64 + c] = __uint_as_float(bts) + inb[IN_B3 + c];
  }
}

// ---------------- kNN in 64-d feature space: MFMA distance tiles + f64-key top-k ----------------
__global__ __launch_bounds__(256, 4) void k_knn2(const float* x1, u64* part){
  __shared__ __align__(16) char sm2[35584];
  unsigned short* Ch = (unsigned short*)sm2;            // [64][72] bf16-hi 9216B
  unsigned short* Cl = (unsigned short*)(sm2 + 9216);   // [64][72] bf16-lo 9216B
  float* Dd  = (float*)(sm2 + 18432);                   // [64*65] dist tile 16640B
  float* sqc = (float*)(sm2 + 35072);                   // [64]
  float* sqq = (float*)(sm2 + 35328);                   // [64]
  u64* mrgA = (u64*)sm2;                                // overlay (post-scan)
  u64* mrgB = (u64*)(sm2 + 10752);
  int bb   = blockIdx.x >> 5;
  int qg   = (blockIdx.x >> 1) & 15;
  int half = blockIdx.x & 1;
  int tid = threadIdx.x;
  int q_l = tid & 63;
  int wv = tid >> 6;                 // wave index == selection slot
  int lane = tid & 63;
  int c16 = lane & 15, ag = lane >> 4, kb0 = ag*8;
  int qbase = bb*1024 + qg*64;
  // A-fragments: wave wv owns query rows wv*16..+16; lane row = c16
  bf16x8 qh0, qh1, ql0, ql1;
  {
    const float* qr = x1 + (size_t)(qbase + wv*16 + c16)*64;
    f32x4 v0 = *(const f32x4*)(qr + kb0);
    f32x4 v1 = *(const f32x4*)(qr + kb0 + 4);
    f32x4 v2 = *(const f32x4*)(qr + 32 + kb0);
    f32x4 v3 = *(const f32x4*)(qr + 36 + kb0);
    #pragma unroll
    for (int e = 0; e < 4; e++){
      unsigned short hh, ll;
      bfsplit(v0[e], hh, ll); qh0[e] = (short)hh; ql0[e] = (short)ll;
      bfsplit(v1[e], hh, ll); qh0[4+e] = (short)hh; ql0[4+e] = (short)ll;
      bfsplit(v2[e], hh, ll); qh1[e] = (short)hh; ql1[e] = (short)ll;
      bfsplit(v3[e], hh, ll); qh1[4+e] = (short)hh; ql1[4+e] = (short)ll;
    }
  }
  if (tid < 64){
    const float* xr = x1 + (size_t)(qbase + tid)*64;
    float s = 0.f;
    #pragma unroll
    for (int d4 = 0; d4 < 16; d4++){
      f32x4 v = *(const f32x4*)(xr + d4*4);
      s += v[0]*v[0] + v[1]*v[1] + v[2]*v[2] + v[3]*v[3];
    }
    sqq[tid] = s;
  }
  REP20(KDECLD)
  for (int ch = 0; ch < 8; ch++){
    int c0 = half*512 + ch*64;
    __syncthreads();                 // prev D consumed (and sqq ready on ch=0)
    // stage C chunk pre-split: 2048 float-pairs / 256 threads
    for (int pp = tid; pp < 2048; pp += 256){
      int row = pp >> 5, cp = pp & 31;
      const float* src = x1 + (size_t)(bb*1024 + c0 + row)*64 + cp*2;
      float v0 = src[0], v1 = src[1];
      unsigned short h0, l0, h1, l1;
      bfsplit(v0, h0, l0); bfsplit(v1, h1, l1);
      ((unsigned int*)Ch)[row*36 + cp] = (unsigned int)h0 | ((unsigned int)h1 << 16);
      ((unsigned int*)Cl)[row*36 + cp] = (unsigned int)l0 | ((unsigned int)l1 << 16);
    }
    __syncthreads();
    if (tid < 64){                   // sqc from exact split reconstruction
      float s = 0.f;
      for (int dw = 0; dw < 32; dw++){
        unsigned int hw = ((unsigned int*)Ch)[tid*36 + dw];
        unsigned int lw = ((unsigned int*)Cl)[tid*36 + dw];
        float a0 = __uint_as_float(hw << 16) + __uint_as_float(lw << 16);
        float a1 = __uint_as_float(hw & 0xFFFF0000u) + __uint_as_float(lw & 0xFFFF0000u);
        s += a0*a0 + a1*a1;
      }
      sqc[tid] = s;
    }
    __syncthreads();
    // MFMA phase: wave wv computes D rows [wv*16, wv*16+16) x 64 cands
    #pragma unroll
    for (int nt = 0; nt < 4; nt++){
      bf16x8 bh0 = *(const bf16x8*)(Ch + (nt*16 + c16)*72 + kb0);
      bf16x8 bh1 = *(const bf16x8*)(Ch + (nt*16 + c16)*72 + 32 + kb0);
      bf16x8 bl0 = *(const bf16x8*)(Cl + (nt*16 + c16)*72 + kb0);
      bf16x8 bl1 = *(const bf16x8*)(Cl + (nt*16 + c16)*72 + 32 + kb0);
      f32x4 p0 = {0.f,0.f,0.f,0.f}, p1 = {0.f,0.f,0.f,0.f}, p2 = {0.f,0.f,0.f,0.f};
      p0 = __builtin_amdgcn_mfma_f32_16x16x32_bf16(qh0, bh0, p0, 0, 0, 0);
      p0 = __builtin_amdgcn_mfma_f32_16x16x32_bf16(qh1, bh1, p0, 0, 0, 0);
      p1 = __builtin_amdgcn_mfma_f32_16x16x32_bf16(qh0, bl0, p1, 0, 0, 0);
      p1 = __builtin_amdgcn_mfma_f32_16x16x32_bf16(qh1, bl1, p1, 0, 0, 0);
      p2 = __builtin_amdgcn_mfma_f32_16x16x32_bf16(ql0, bh0, p2, 0, 0, 0);
      p2 = __builtin_amdgcn_mfma_f32_16x16x32_bf16(ql1, bh1, p2, 0, 0, 0);
      #pragma unroll
      for (int r = 0; r < 4; r++){
        int qrow = wv*16 + 4*ag + r;
        float d = sqq[qrow] + sqc[nt*16 + c16] - 2.0f*(p0[r] + p1[r] + p2[r]);
        Dd[qrow*65 + nt*16 + c16] = d;
      }
    }
    __syncthreads();
    // selection: lane = query q_l, wave = candidate slot (c = 4u+wv)
    for (int u = 0; u < 16; u += 2){
      int cA = 4*u + wv, cB = 4*(u+1) + wv;
      float dA = Dd[q_l*65 + cA];
      float dB = Dd[q_l*65 + cB];
      INS_MM(packkey(dA, c0 + cA));
      INS_MM(packkey(dB, c0 + cB));
    }
  }
  __syncthreads();                   // scan arrays dead from here (union!)
  if (wv == 1){ REP20(KPUB_A) }
  if (wv == 3){ REP20(KPUB_B) }
  __syncthreads();
  if ((wv & 1) == 0){
    const u64* src = (wv == 0) ? &mrgA[q_l*21] : &mrgB[q_l*21];
    for (int p = 0; p < KNN; p++){
      double kv = __longlong_as_double((long long)src[p]);
      if (kv > rk19) break;
      INS_MM(kv);
    }
  }
  __syncthreads();
  if (wv == 2){ REP20(KPUB_B) }
  __syncthreads();
  if (wv == 0){
    const u64* src = &mrgB[q_l*21];
    for (int p = 0; p < KNN; p++){
      double kv = __longlong_as_double((long long)src[p]);
      if (kv > rk19) break;
      INS_MM(kv);
    }
    int gi = qbase + q_l;
    u64* gpart = part + ((size_t)gi*2 + half)*KNN;
    REP20(KSTG)
  }
}

// ---------------- fast path: B2H = x1 @ Wbot[:, q-half] ----------------
__global__ __launch_bounds__(256) void k_B2h(const float* x1, const float* inb,
                                             int q, float* B2H){
  __shared__ __align__(16) float Wbh[4096];
  __shared__ __align__(16) float xsh[1024];
  int tid = threadIdx.x;
  const float* Wb = inb + IN_WBUF + WB_WBOT;
  for (int t = tid; t < 4096; t += 256){
    int r = t >> 6, cl = t & 63;
    Wbh[t] = Wb[r*128 + q*64 + cl];
  }
  int node0 = blockIdx.x * 16;
  for (int t = tid; t < 1024; t += 256) xsh[t] = x1[node0*64 + t];
  __syncthreads();
  int n_l = tid >> 4, cg = tid & 15;
  const float* xr = xsh + n_l*64;
  float4 acc = make_float4(0.f,0.f,0.f,0.f);
  #pragma unroll 8
  for (int d = 0; d < 64; d++){
    float v = xr[d];
    float4 w = *(const float4*)(Wbh + d*64 + cg*4);
    acc.x += v*w.x; acc.y += v*w.y; acc.z += v*w.z; acc.w += v*w.w;
  }
  *(float4*)(B2H + (node0 + n_l)*64 + cg*4) = acc;
}

// ---------------- fast path: x2 half = (x1_i@Wd + bc2) + max_j B2H[j] ----------------
__global__ __launch_bounds__(256) void k_x2h(const float* x1, const float* B2H,
                                             const float* inb, const int* idx2,
                                             int q, float* x2){
  __shared__ __align__(16) float Wdh[4096];
  __shared__ __align__(16) float xsh[256];
  int tid = threadIdx.x;
  const float* Wd = inb + IN_WBUF + WB_WD;
  for (int t = tid; t < 4096; t += 256){
    int r = t >> 6, cl = t & 63;
    Wdh[t] = Wd[r*128 + q*64 + cl];
  }
  int node0 = blockIdx.x * 4;
  xsh[tid] = x1[node0*64 + tid];
  __syncthreads();
  int n_l = tid >> 6, cl = tid & 63;
  int i = node0 + n_l;
  int b = i >> 10;
  const float* xr = xsh + n_l*64;
  float acc = inb[IN_BC2 + q*64 + cl];
  #pragma unroll 8
  for (int d = 0; d < 64; d++) acc += xr[d]*Wdh[d*64 + cl];
  float m = -FLT_MAX;
  for (int kk = 0; kk < KNN; kk++){
    int j = idx2[i*KNN + kk];
    m = fmaxf(m, B2H[((b<<10)+j)*64 + cl]);
  }
  x2[i*128 + q*64 + cl] = acc + m;
}

// ---------------- slow fallback: x2 direct, LDS-staged, no B2H buffer ----------------
__global__ __launch_bounds__(256) void k_x2d(const float* x1, const float* inb,
                                             const int* idx2, float* x2){
  __shared__ __align__(16) float Wdh[4096], Wbh[4096];
  __shared__ __align__(16) float xis[1024], xjs[1024];
  int tid = threadIdx.x;
  int q = blockIdx.x & 1;
  int node0 = (blockIdx.x >> 1) * 16;
  const float* Wd = inb + IN_WBUF + WB_WD;
  const float* Wb = inb + IN_WBUF + WB_WBOT;
  for (int t = tid; t < 4096; t += 256){
    int r = t >> 6, cl = t & 63;
    Wdh[t] = Wd[r*128 + q*64 + cl];
    Wbh[t] = Wb[r*128 + q*64 + cl];
  }
  for (int t = tid; t < 1024; t += 256) xis[t] = x1[node0*64 + t];
  __syncthreads();
  int n_l = tid >> 4, cg = tid & 15;
  int i = node0 + n_l, b = i >> 10;
  const float* xr = xis + n_l*64;
  float4 af = make_float4(inb[IN_BC2 + q*64 + cg*4],   inb[IN_BC2 + q*64 + cg*4+1],
                          inb[IN_BC2 + q*64 + cg*4+2], inb[IN_BC2 + q*64 + cg*4+3]);
  #pragma unroll 8
  for (int d = 0; d < 64; d++){
    float v = xr[d];
    float4 w = *(const float4*)(Wdh + d*64 + cg*4);
    af.x += v*w.x; af.y += v*w.y; af.z += v*w.z; af.w += v*w.w;
  }
  float4 mx = make_float4(-FLT_MAX,-FLT_MAX,-FLT_MAX,-FLT_MAX);
  for (int kk = 0; kk < KNN; kk++){
    __syncthreads();
    for (int t = tid; t < 1024; t += 256){
      int nn = t >> 6, r = t & 63;
      int jj = idx2[(node0+nn)*KNN + kk];
      xjs[t] = x1[((((node0+nn) >> 10) << 10) + jj)*64 + r];
    }
    __syncthreads();
    const float* xj = xjs + n_l*64;
    float4 acc = make_float4(0.f,0.f,0.f,0.f);
    #pragma unroll 8
    for (int d = 0; d < 64; d++){
      float v = xj[d];
      float4 w = *(const float4*)(Wbh + d*64 + cg*4);
      acc.x += v*w.x; acc.y += v*w.y; acc.z += v*w.z; acc.w += v*w.w;
    }
    mx.x = fmaxf(mx.x, acc.x); mx.y = fmaxf(mx.y, acc.y);
    mx.z = fmaxf(mx.z, acc.z); mx.w = fmaxf(mx.w, acc.w);
  }
  *(float4*)(x2 + i*128 + q*64 + cg*4) =
      make_float4(af.x+mx.x, af.y+mx.y, af.z+mx.z, af.w+mx.w);
}

// ---------------- lin (192->1024) via MFMA + max over node-quarter ----------------
__global__ __launch_bounds__(512, 2) void k_linpoolm(const float* x1, const float* x2,
    const float* inb, float* pool4){
  __shared__ __align__(16) float F[16*196];         // 12544B
  int tid = threadIdx.x;
  int b = blockIdx.x >> 4, cq = (blockIdx.x >> 2) & 3, nh = blockIdx.x & 3;
  int lane = tid & 63, wv = tid >> 6;
  int c16 = lane & 15, ag = lane >> 4;
  const float* Wl = inb + IN_WBUF + WB_WL;
  // B-fragments once per block
  bf16x8 w_h[2][6], w_l[2][6];
  #pragma unroll
  for (int nt = 0; nt < 2; nt++){
    int col = cq*256 + (wv*2+nt)*16 + c16;
    #pragma unroll
    for (int ks = 0; ks < 6; ks++){
      bf16x8 h8, l8;
      #pragma unroll
      for (int e = 0; e < 8; e++){
        unsigned short hh, ll;
        bfsplit(Wl[(ks*32 + ag*8 + e)*1024 + col], hh, ll);
        h8[e] = (short)hh; l8[e] = (short)ll;
      }
      w_h[nt][ks] = h8; w_l[nt][ks] = l8;
    }
  }
  float rmax[2] = {-FLT_MAX, -FLT_MAX};
  int n0 = b*1024 + nh*256;
  for (int chk = 0; chk < 16; chk++){
    int nb = n0 + chk*16;
    __syncthreads();
    {
      int row = tid >> 5;
      int d0 = (tid & 31)*6;
      #pragma unroll
      for (int u = 0; u < 6; u++){
        int d = d0 + u;
        F[row*196 + d] = (d < 64) ? x1[(size_t)(nb+row)*64 + d]
                                  : x2[(size_t)(nb+row)*128 + d - 64];
      }
    }
    __syncthreads();
    // A-fragments: row = c16 (node), k = ks*32 + ag*8 + e
    bf16x8 a_h[6], a_l[6];
    #pragma unroll
    for (int ks = 0; ks < 6; ks++){
      f32x4 v0 = *(const f32x4*)(F + c16*196 + ks*32 + ag*8);
      f32x4 v1 = *(const f32x4*)(F + c16*196 + ks*32 + ag*8 + 4);
      bf16x8 h8, l8;
      #pragma unroll
      for (int e = 0; e < 4; e++){
        unsigned short hh, ll;
        bfsplit(v0[e], hh, ll); h8[e] = (short)hh; l8[e] = (short)ll;
        bfsplit(v1[e], hh, ll); h8[4+e] = (short)hh; l8[4+e] = (short)ll;
      }
      a_h[ks] = h8; a_l[ks] = l8;
    }
    #pragma unroll
    for (int nt = 0; nt < 2; nt++){
      f32x4 p0 = {0.f,0.f,0.f,0.f}, p1 = {0.f,0.f,0.f,0.f}, p2 = {0.f,0.f,0.f,0.f};
      #pragma unroll
      for (int ks = 0; ks < 6; ks++){
        p0 = __builtin_amdgcn_mfma_f32_16x16x32_bf16(a_h[ks], w_h[nt][ks], p0, 0, 0, 0);
        p1 = __builtin_amdgcn_mfma_f32_16x16x32_bf16(a_h[ks], w_l[nt][ks], p1, 0, 0, 0);
        p2 = __builtin_amdgcn_mfma_f32_16x16x32_bf16(a_l[ks], w_h[nt][ks], p2, 0, 0, 0);
      }
      float m = -FLT_MAX;
      #pragma unroll
      for (int r = 0; r < 4; r++) m = fmaxf(m, p0[r] + p1[r] + p2[r]);
      m = fmaxf(m, __shfl_xor(m, 16));
      m = fmaxf(m, __shfl_xor(m, 32));
      rmax[nt] = fmaxf(rmax[nt], m);
    }
  }
  if (ag == 0){
    #pragma unroll
    for (int nt = 0; nt < 2; nt++)
      pool4[nh*32768 + b*1024 + cq*256 + (wv*2+nt)*16 + c16] = rmax[nt];
  }
}

// ================= head MLP, wave-per-column =================
__global__ __launch_bounds__(256) void k_h1(const float* pool4, const float* inb,
                                            float* s1g){
  __shared__ float pl[1024];
  int b = blockIdx.x >> 4, cg = blockIdx.x & 15;
  int tid = threadIdx.x;
  for (int t = tid; t < 1024; t += 256){
    float m = fmaxf(fmaxf(pool4[b*1024 + t],         pool4[32768 + b*1024 + t]),
                    fmaxf(pool4[65536 + b*1024 + t], pool4[98304 + b*1024 + t]));
    pl[t] = m + inb[IN_BL + t];
  }
  __syncthreads();
  int wv = tid >> 6, lane = tid & 63;
  f32x4 p0 = *(const f32x4*)(pl + lane*16);
  f32x4 p1 = *(const f32x4*)(pl + lane*16 + 4);
  f32x4 p2 = *(const f32x4*)(pl + lane*16 + 8);
  f32x4 p3 = *(const f32x4*)(pl + lane*16 + 12);
  const float* WT = inb + IN_WBUF + WB_WM1;    // [512][1024] transposed
  #pragma unroll
  for (int cc = 0; cc < 8; cc++){
    int c = cg*32 + wv*8 + cc;
    const float* wr = WT + (size_t)c*1024 + lane*16;
    f32x4 w0 = *(const f32x4*)(wr);
    f32x4 w1 = *(const f32x4*)(wr + 4);
    f32x4 w2 = *(const f32x4*)(wr + 8);
    f32x4 w3 = *(const f32x4*)(wr + 12);
    float acc = w0[0]*p0[0] + w0[1]*p0[1] + w0[2]*p0[2] + w0[3]*p0[3]
              + w1[0]*p1[0] + w1[1]*p1[1] + w1[2]*p1[2] + w1[3]*p1[3]
              + w2[0]*p2[0] + w2[1]*p2[1] + w2[2]*p2[2] + w2[3]*p2[3]
              + w3[0]*p3[0] + w3[1]*p3[1] + w3[2]*p3[2] + w3[3]*p3[3];
    acc += __shfl_xor(acc, 1);  acc += __shfl_xor(acc, 2);
    acc += __shfl_xor(acc, 4);  acc += __shfl_xor(acc, 8);
    acc += __shfl_xor(acc, 16); acc += __shfl_xor(acc, 32);
    if (lane == 0) s1g[b*512 + c] = fmaxf(acc + inb[IN_BM1 + c], 0.f);
  }
}

// k_h2: grid 256 = (b, cg of 32 cols of 256). K=512, lane slice 8.
__global__ __launch_bounds__(256) void k_h2(const float* s1g, const float* inb,
                                            float* s2g){
  __shared__ float s1[512];
  int b = blockIdx.x >> 3, cg = blockIdx.x & 7;
  int tid = threadIdx.x;
  for (int t = tid; t < 512; t += 256) s1[t] = s1g[b*512 + t];
  __syncthreads();
  int wv = tid >> 6, lane = tid & 63;
  f32x4 p0 = *(const f32x4*)(s1 + lane*8);
  f32x4 p1 = *(const f32x4*)(s1 + lane*8 + 4);
  const float* WT = inb + IN_WBUF + WB_WM2;    // [256][512] transposed
  #pragma unroll
  for (int cc = 0; cc < 8; cc++){
    int c = cg*32 + wv*8 + cc;
    const float* wr = WT + (size_t)c*512 + lane*8;
    f32x4 w0 = *(const f32x4*)(wr);
    f32x4 w1 = *(const f32x4*)(wr + 4);
    float acc = w0[0]*p0[0] + w0[1]*p0[1] + w0[2]*p0[2] + w0[3]*p0[3]
              + w1[0]*p1[0] + w1[1]*p1[1] + w1[2]*p1[2] + w1[3]*p1[3];
    acc += __shfl_xor(acc, 1);  acc += __shfl_xor(acc, 2);
    acc += __shfl_xor(acc, 4);  acc += __shfl_xor(acc, 8);
    acc += __shfl_xor(acc, 16); acc += __shfl_xor(acc, 32);
    if (lane == 0) s2g[b*256 + c] = fmaxf(acc + inb[IN_BM2 + c], 0.f);
  }
}

// k_h3: grid 32 (per batch). 40 cols, K=256, lane slice 4.
__global__ __launch_bounds__(256) void k_h3(const float* s2g, const float* inb,
                                            float* out){
  __shared__ float s2[256];
  int b = blockIdx.x;
  int tid = threadIdx.x;
  s2[tid] = s2g[b*256 + tid];
  __syncthreads();
  int wv = tid >> 6, lane = tid & 63;
  f32x4 p0 = *(const f32x4*)(s2 + lane*4);
  const float* WT = inb + IN_WBUF + WB_WM3;    // [40][256] transposed
  for (int cc = 0; cc < 10; cc++){
    int c = wv*10 + cc;
    const float* wr = WT + (size_t)c*256 + lane*4;
    f32x4 w0 = *(const f32x4*)(wr);
    float acc = w0[0]*p0[0] + w0[1]*p0[1] + w0[2]*p0[2] + w0[3]*p0[3];
    acc += __shfl_xor(acc, 1);  acc += __shfl_xor(acc, 2);
    acc += __shfl_xor(acc, 4);  acc += __shfl_xor(acc, 8);
    acc += __shfl_xor(acc, 16); acc += __shfl_xor(acc, 32);
    if (lane == 0) out[b*40 + c] = acc + inb[IN_BM3 + c];
  }
}

extern "C" void kernel_launch(void* const* d_in, const int* in_sizes, int n_in,
                              void* d_out, int out_size, void* d_ws, size_t ws_size,
                              hipStream_t stream){
  float* ws     = (float*)d_ws;
  double* stats = (double*)d_ws;
  int*   flag   = (int*)d_ws + OFF_FLAG;
  float* inb    = ws + OFF_INB;
  int*   idx    = (int*)d_ws + OFF_IDX;     // idx1 early, idx2 late
  float* x1p    = ws + OFF_X1;
  float* x2p    = ws + OFF_X2;
  float* a1     = ws + OFF_X2;              // a1/c1 alias x2 region (dead before x2 written)
  float* c1     = ws + OFF_C1;
  u64*   part   = (u64*)(ws + OFF_X2);      // kNN partials alias a1/c1 (see layout note)
  float* pool4  = ws + OFF_POOL;
  float* B2H    = ws + OFF_B2H;
  float* s1g    = ws + OFF_IDX;             // head acts alias idx (idx2 dead after x2)
  float* s2g    = ws + OFF_IDX + 16384;
  bool fast = ws_size >= (size_t)FAST_END * 4u;

  hipMemsetAsync(stats, 0, 256*sizeof(double), stream);
  k_sniff<<<1, 64, 0, stream>>>(d_in[0], flag);
  k_cvt<<<3859, 256, 0, stream>>>(
      d_in[0], d_in[1], d_in[2], d_in[3], d_in[4], d_in[5], d_in[6], d_in[7],
      d_in[8], d_in[9], d_in[10], d_in[11], d_in[12], d_in[13], d_in[14],
      d_in[15], d_in[16], d_in[17], d_in[18], d_in[19], d_in[20], flag, inb);
  k_knn1<<<1024, 256, 0, stream>>>(inb, part);      // partials in a1/c1 region
  k_mrg<<<128, 256, 0, stream>>>(part, idx);        // -> idx1
  k_prep1<<<8192, 256, 0, stream>>>(inb, a1, c1);   // overwrites dead partials
  k_stats1<<<640, 256, 0, stream>>>(a1, c1, idx, stats);
  k_stats2m<<<4096, 256, 0, stream>>>(a1, c1, idx, inb, stats);
  k_x1m<<<4096, 256, 0, stream>>>(a1, c1, idx, inb, stats, x1p);
  k_knn2<<<1024, 256, 0, stream>>>(x1p, part);      // a1/c1 dead after k_x1m
  k_mrg<<<128, 256, 0, stream>>>(part, idx);        // -> idx2
  if (fast){
    k_B2h<<<2048, 256, 0, stream>>>(x1p, inb, 0, B2H);
    k_x2h<<<8192, 256, 0, stream>>>(x1p, B2H, inb, idx, 0, x2p);
    k_B2h<<<2048, 256, 0, stream>>>(x1p, inb, 1, B2H);
    k_x2h<<<8192, 256, 0, stream>>>(x1p, B2H, inb, idx, 1, x2p);
  } else {
    k_x2d<<<4096, 256, 0, stream>>>(x1p, inb, idx, x2p);
  }
  k_linpoolm<<<512, 512, 0, stream>>>(x1p, x2p, inb, pool4);
  k_h1<<<512, 256, 0, stream>>>(pool4, inb, s1g);   // idx2 dead here
  k_h2<<<256, 256, 0, stream>>>(s1g, inb, s2g);
  k_h3<<<32, 256, 0, stream>>>(s2g, inb, (float*)d_out);
}